// Round 1
// baseline (2342.251 us; speedup 1.0000x reference)
//
#include <hip/hip_runtime.h>

#define NN 50000
#define EE 640000
#define GG 16
#define N64 (NN*64)

static inline int cdiv(int a,int b){return (a+b-1)/b;}

__device__ __forceinline__ float lrelu(float x){ return x>0.f? x : 0.2f*x; }
// monotonic float->uint encoding for atomicMax on floats
__device__ __forceinline__ unsigned fenc(float f){
  unsigned u=__float_as_uint(f);
  return (u&0x80000000u)? ~u : (u|0x80000000u);
}

__global__ void zero_kernel(unsigned* p, int n){
  int i=blockIdx.x*blockDim.x+threadIdx.x;
  if(i<n) p[i]=0u;
}

__global__ void hist_kernel(const int* __restrict__ dst, int* __restrict__ cnt){
  int e=blockIdx.x*blockDim.x+threadIdx.x;
  if(e<EE) atomicAdd(&cnt[dst[e]],1);
}

__global__ __launch_bounds__(1024) void scan_kernel(const int* __restrict__ cnt, int* __restrict__ rowptr){
  __shared__ int buf[2][1024];
  __shared__ int carry_s;
  int tid=threadIdx.x;
  if(tid==0) carry_s=0;
  __syncthreads();
  for(int base=0;base<NN;base+=1024){
    int i=base+tid;
    int v=(i<NN)?cnt[i]:0;
    int pin=0;
    buf[0][tid]=v;
    __syncthreads();
    for(int off=1;off<1024;off<<=1){
      int t=buf[pin][tid];
      if(tid>=off) t+=buf[pin][tid-off];
      buf[1-pin][tid]=t;
      pin^=1;
      __syncthreads();
    }
    int inc=buf[pin][tid];
    int carry=carry_s;
    if(i<NN) rowptr[i]=carry+inc-v;   // exclusive scan
    __syncthreads();
    if(tid==1023) carry_s=carry+buf[pin][1023];
    __syncthreads();
  }
  if(tid==0) rowptr[NN]=carry_s;
}

__global__ void fill_kernel(const int* __restrict__ src, const int* __restrict__ dst,
                            const int* __restrict__ rowptr, int* __restrict__ fillp,
                            int* __restrict__ srcS, int* __restrict__ dstS){
  int e=blockIdx.x*blockDim.x+threadIdx.x;
  if(e>=EE) return;
  int d=dst[e];
  int p=rowptr[d]+atomicAdd(&fillp[d],1);
  srcS[p]=src[e]; dstS[p]=d;
}

__global__ void invdeg_kernel(const int* __restrict__ cnt, float* __restrict__ invdeg){
  int i=blockIdx.x*blockDim.x+threadIdx.x;
  if(i<NN) invdeg[i]=1.f/fmaxf((float)cnt[i],1.f);
}

// C[NN, ldc(+nc0 slice)] = act(A[NN,K] @ W[K, ldw](cols wc..) + bias + addend)
template<int K>
__global__ __launch_bounds__(256) void gemm_kernel(
    const float* __restrict__ A, const float* __restrict__ W, int ldw, int wcol0,
    const float* __restrict__ bias, const float* __restrict__ addend,
    float* __restrict__ C, int ldc, int relu_flag){
  __shared__ float As[64][68];
  __shared__ float Ws[64][64];
  const int m0=blockIdx.x*64;
  const int nc0=blockIdx.y*64;
  const int wc=wcol0+nc0;
  const int tid=threadIdx.x, tx=tid&15, ty=tid>>4;
  float acc[4][4];
  #pragma unroll
  for(int i=0;i<4;i++){
    #pragma unroll
    for(int j=0;j<4;j++) acc[i][j]=bias? bias[wc+tx*4+j]:0.f;
  }
  for(int k0=0;k0<K;k0+=64){
    __syncthreads();
    #pragma unroll
    for(int it=0;it<4;it++){
      int linear=it*1024+tid*4;
      int m=linear>>6, k=linear&63;
      float4 v=make_float4(0.f,0.f,0.f,0.f);
      if(m0+m<NN) v=*(const float4*)(A+(size_t)(m0+m)*K+k0+k);
      *(float4*)&As[m][k]=v;
    }
    #pragma unroll
    for(int it=0;it<4;it++){
      int linear=it*1024+tid*4;
      int k=linear>>6, n=linear&63;
      *(float4*)&Ws[k][n]=*(const float4*)(W+(size_t)(k0+k)*ldw+wc+n);
    }
    __syncthreads();
    #pragma unroll 16
    for(int k=0;k<64;k++){
      float a0=As[ty*4+0][k],a1=As[ty*4+1][k],a2=As[ty*4+2][k],a3=As[ty*4+3][k];
      float4 w=*(float4*)&Ws[k][tx*4];
      acc[0][0]+=a0*w.x; acc[0][1]+=a0*w.y; acc[0][2]+=a0*w.z; acc[0][3]+=a0*w.w;
      acc[1][0]+=a1*w.x; acc[1][1]+=a1*w.y; acc[1][2]+=a1*w.z; acc[1][3]+=a1*w.w;
      acc[2][0]+=a2*w.x; acc[2][1]+=a2*w.y; acc[2][2]+=a2*w.z; acc[2][3]+=a2*w.w;
      acc[3][0]+=a3*w.x; acc[3][1]+=a3*w.y; acc[3][2]+=a3*w.z; acc[3][3]+=a3*w.w;
    }
  }
  #pragma unroll
  for(int i=0;i<4;i++){
    int m=m0+ty*4+i;
    if(m>=NN) continue;
    float r0=acc[i][0],r1=acc[i][1],r2=acc[i][2],r3=acc[i][3];
    if(addend){
      const float4 ad=*(const float4*)(addend+(size_t)m*ldc+nc0+tx*4);
      r0+=ad.x; r1+=ad.y; r2+=ad.z; r3+=ad.w;
    }
    if(relu_flag){ r0=fmaxf(r0,0.f); r1=fmaxf(r1,0.f); r2=fmaxf(r2,0.f); r3=fmaxf(r3,0.f); }
    *(float4*)(C+(size_t)m*ldc+nc0+tx*4)=make_float4(r0,r1,r2,r3);
  }
}

// ls[n,h] = <h[n,h,:], a_s[h,:]>, ld likewise. One wave per node.
__global__ __launch_bounds__(256) void attn_dots_kernel(const float* __restrict__ h,
    const float* __restrict__ a_s, const float* __restrict__ a_d,
    float* __restrict__ ls, float* __restrict__ ld){
  int w=blockIdx.x*4+(threadIdx.x>>6);
  int lane=threadIdx.x&63;
  if(w>=NN) return;
  const float* hr=h+(size_t)w*256;
  float s[4],d[4];
  #pragma unroll
  for(int k=0;k<4;k++){
    float v=hr[k*64+lane];
    s[k]=v*a_s[k*64+lane];
    d[k]=v*a_d[k*64+lane];
  }
  #pragma unroll
  for(int o=32;o>0;o>>=1){
    #pragma unroll
    for(int k=0;k<4;k++){
      s[k]+=__shfl_xor(s[k],o,64);
      d[k]+=__shfl_xor(d[k],o,64);
    }
  }
  if(lane==0){
    ls[w*4+0]=s[0]; ls[w*4+1]=s[1]; ls[w*4+2]=s[2]; ls[w*4+3]=s[3];
    ld[w*4+0]=d[0]; ld[w*4+1]=d[1]; ld[w*4+2]=d[2]; ld[w*4+3]=d[3];
  }
}

__global__ void gat_edge_logit_kernel(const int* __restrict__ srcS, const int* __restrict__ dstS,
    const float* __restrict__ ls, const float* __restrict__ ld, float* __restrict__ lg){
  int j=blockIdx.x*blockDim.x+threadIdx.x;
  if(j>=EE) return;
  int s=srcS[j], d=dstS[j];
  const float4 a=*(const float4*)(ls+4*s);
  const float4 b=*(const float4*)(ld+4*d);
  *(float4*)(lg+4*j)=make_float4(lrelu(a.x+b.x),lrelu(a.y+b.y),lrelu(a.z+b.z),lrelu(a.w+b.w));
}

// per-dst softmax incl. self-loop; stores exp() in lg, 1/z in zinv, self alpha in asel
__global__ void gat_softmax_kernel(const int* __restrict__ rowptr,
    const float* __restrict__ ls, const float* __restrict__ ld,
    float* __restrict__ lg, float* __restrict__ zinv, float* __restrict__ asel){
  int n=blockIdx.x*blockDim.x+threadIdx.x;
  if(n>=NN) return;
  int r0=rowptr[n], r1=rowptr[n+1];
  const float4 a=*(const float4*)(ls+4*n);
  const float4 b=*(const float4*)(ld+4*n);
  float sl[4]={lrelu(a.x+b.x),lrelu(a.y+b.y),lrelu(a.z+b.z),lrelu(a.w+b.w)};
  float m[4]={sl[0],sl[1],sl[2],sl[3]};
  for(int j=r0;j<r1;j++){
    float4 f=*(const float4*)(lg+4*j);
    m[0]=fmaxf(m[0],f.x); m[1]=fmaxf(m[1],f.y); m[2]=fmaxf(m[2],f.z); m[3]=fmaxf(m[3],f.w);
  }
  float es[4], z[4];
  #pragma unroll
  for(int hh=0;hh<4;hh++){ es[hh]=__expf(sl[hh]-m[hh]); z[hh]=es[hh]; }
  for(int j=r0;j<r1;j++){
    float4 f=*(float4*)(lg+4*j);
    float4 e=make_float4(__expf(f.x-m[0]),__expf(f.y-m[1]),__expf(f.z-m[2]),__expf(f.w-m[3]));
    z[0]+=e.x; z[1]+=e.y; z[2]+=e.z; z[3]+=e.w;
    *(float4*)(lg+4*j)=e;
  }
  float zi[4];
  #pragma unroll
  for(int hh=0;hh<4;hh++) zi[hh]=1.f/(z[hh]+1e-16f);
  *(float4*)(zinv+4*n)=make_float4(zi[0],zi[1],zi[2],zi[3]);
  *(float4*)(asel+4*n)=make_float4(es[0]*zi[0],es[1]*zi[1],es[2]*zi[2],es[3]*zi[3]);
}

// out[n,d] = relu( 0.25*sum_h( alpha_self*h[n,h,d] + sum_e alpha_e*h[src,h,d] ) + b[d] )
__global__ __launch_bounds__(256) void gat_agg_kernel(const float* __restrict__ h,
    const int* __restrict__ rowptr, const int* __restrict__ srcS,
    const float* __restrict__ lg, const float* __restrict__ zinv, const float* __restrict__ asel,
    const float* __restrict__ bias, float* __restrict__ out){
  int n=blockIdx.x*4+(threadIdx.x>>6);
  int lane=threadIdx.x&63;
  if(n>=NN) return;
  int r0=rowptr[n], r1=rowptr[n+1];
  const float4 zi=*(const float4*)(zinv+4*n);
  const float4 asf=*(const float4*)(asel+4*n);
  const float* hn=h+(size_t)n*256;
  float a0=asf.x*hn[lane], a1=asf.y*hn[64+lane], a2=asf.z*hn[128+lane], a3=asf.w*hn[192+lane];
  for(int j=r0;j<r1;j++){
    int s=srcS[j];
    float4 e=*(const float4*)(lg+4*j);
    const float* hs=h+(size_t)s*256;
    a0+=e.x*zi.x*hs[lane];
    a1+=e.y*zi.y*hs[64+lane];
    a2+=e.z*zi.z*hs[128+lane];
    a3+=e.w*zi.w*hs[192+lane];
  }
  out[(size_t)n*64+lane]=fmaxf(0.25f*(a0+a1+a2+a3)+bias[lane],0.f);
}

// mode 0: self + sum (GIN), mode 1: mean (SAGE)
__global__ __launch_bounds__(256) void agg_kernel(const float* __restrict__ xin,
    const int* __restrict__ rowptr, const int* __restrict__ srcS,
    const float* __restrict__ invdeg, float* __restrict__ out, int mode){
  int n=blockIdx.x*4+(threadIdx.x>>6);
  int lane=threadIdx.x&63;
  if(n>=NN) return;
  int r0=rowptr[n], r1=rowptr[n+1];
  float acc=(mode==0)? xin[(size_t)n*64+lane] : 0.f;
  for(int j=r0;j<r1;j++) acc+=xin[(size_t)srcS[j]*64+lane];
  if(mode==1) acc*=invdeg[n];
  out[(size_t)n*64+lane]=acc;
}

__global__ __launch_bounds__(256) void tr_logit_kernel(const int* __restrict__ srcS, const int* __restrict__ dstS,
    const float* __restrict__ q, const float* __restrict__ k, float* __restrict__ lg){
  int j=blockIdx.x*4+(threadIdx.x>>6);
  int lane=threadIdx.x&63;
  if(j>=EE) return;
  int s=srcS[j], d=dstS[j];
  float v=q[(size_t)d*64+lane]*k[(size_t)s*64+lane];
  #pragma unroll
  for(int o=32;o>0;o>>=1) v+=__shfl_xor(v,o,64);
  if(lane==0) lg[j]=v*0.125f;
}

__global__ void tr_softmax_kernel(const int* __restrict__ rowptr, float* __restrict__ lg, float* __restrict__ zinv){
  int n=blockIdx.x*blockDim.x+threadIdx.x;
  if(n>=NN) return;
  int r0=rowptr[n], r1=rowptr[n+1];
  if(r0==r1){ zinv[n]=0.f; return; }
  float m=-1e30f;
  for(int j=r0;j<r1;j++) m=fmaxf(m,lg[j]);
  float z=0.f;
  for(int j=r0;j<r1;j++){ float e=__expf(lg[j]-m); lg[j]=e; z+=e; }
  zinv[n]=1.f/(z+1e-16f);
}

__global__ __launch_bounds__(256) void tr_agg_kernel(const int* __restrict__ rowptr, const int* __restrict__ srcS,
    const float* __restrict__ lg, const float* __restrict__ zinv,
    const float* __restrict__ v, float* __restrict__ tout){
  int n=blockIdx.x*4+(threadIdx.x>>6);
  int lane=threadIdx.x&63;
  if(n>=NN) return;
  int r0=rowptr[n], r1=rowptr[n+1];
  float acc=0.f;
  for(int j=r0;j<r1;j++) acc+=lg[j]*v[(size_t)srcS[j]*64+lane];
  tout[(size_t)n*64+lane]+=acc*zinv[n];
}

__global__ void x5_kernel(const float* __restrict__ tout, const float* __restrict__ u, float* __restrict__ x5){
  int i=blockIdx.x*blockDim.x+threadIdx.x;
  if(i<N64) x5[i]=fmaxf(0.25f*tout[i]+u[i],0.f);
}

// fused EdgeConv: feat gather -> GEMM1(+b1,relu) -> GEMM2(+b2) -> run-merged atomicMax to emax
__global__ __launch_bounds__(256) void edgeconv_kernel(const float* __restrict__ x5,
    const int* __restrict__ srcS, const int* __restrict__ dstS,
    const float* __restrict__ W1, const float* __restrict__ b1,
    const float* __restrict__ W2, const float* __restrict__ b2,
    unsigned* __restrict__ emax){
  __shared__ float As[64][68];   // feat tile, then reused as hidden tile
  __shared__ float Ws[64][64];
  const int e0=blockIdx.x*64;
  const int tid=threadIdx.x, tx=tid&15, ty=tid>>4;
  float acc[4][4];
  #pragma unroll
  for(int i=0;i<4;i++)
    #pragma unroll
    for(int j=0;j<4;j++) acc[i][j]=b1[tx*4+j];
  for(int c=0;c<2;c++){
    __syncthreads();
    #pragma unroll
    for(int it=0;it<4;it++){
      int linear=it*1024+tid*4;
      int m=linear>>6, k=linear&63;
      int e=e0+m;
      float4 v=make_float4(0.f,0.f,0.f,0.f);
      if(e<EE){
        int dn=dstS[e];
        float4 xi=*(const float4*)(x5+(size_t)dn*64+k);
        if(c==0) v=xi;
        else{
          int sn=srcS[e];
          float4 xj=*(const float4*)(x5+(size_t)sn*64+k);
          v=make_float4(xj.x-xi.x,xj.y-xi.y,xj.z-xi.z,xj.w-xi.w);
        }
      }
      *(float4*)&As[m][k]=v;
    }
    #pragma unroll
    for(int it=0;it<4;it++){
      int linear=it*1024+tid*4;
      int k=linear>>6, n=linear&63;
      *(float4*)&Ws[k][n]=*(const float4*)(W1+(size_t)(c*64+k)*64+n);
    }
    __syncthreads();
    #pragma unroll 16
    for(int k=0;k<64;k++){
      float a0=As[ty*4+0][k],a1=As[ty*4+1][k],a2=As[ty*4+2][k],a3=As[ty*4+3][k];
      float4 w=*(float4*)&Ws[k][tx*4];
      acc[0][0]+=a0*w.x; acc[0][1]+=a0*w.y; acc[0][2]+=a0*w.z; acc[0][3]+=a0*w.w;
      acc[1][0]+=a1*w.x; acc[1][1]+=a1*w.y; acc[1][2]+=a1*w.z; acc[1][3]+=a1*w.w;
      acc[2][0]+=a2*w.x; acc[2][1]+=a2*w.y; acc[2][2]+=a2*w.z; acc[2][3]+=a2*w.w;
      acc[3][0]+=a3*w.x; acc[3][1]+=a3*w.y; acc[3][2]+=a3*w.z; acc[3][3]+=a3*w.w;
    }
  }
  __syncthreads();
  #pragma unroll
  for(int i=0;i<4;i++)
    #pragma unroll
    for(int j=0;j<4;j++)
      As[ty*4+i][tx*4+j]=fmaxf(acc[i][j],0.f);   // hidden (relu) into As
  #pragma unroll
  for(int it=0;it<4;it++){
    int linear=it*1024+tid*4;
    int k=linear>>6, n=linear&63;
    *(float4*)&Ws[k][n]=*(const float4*)(W2+(size_t)k*64+n);
  }
  __syncthreads();
  float acc2[4][4];
  #pragma unroll
  for(int i=0;i<4;i++)
    #pragma unroll
    for(int j=0;j<4;j++) acc2[i][j]=b2[tx*4+j];
  #pragma unroll 16
  for(int k=0;k<64;k++){
    float a0=As[ty*4+0][k],a1=As[ty*4+1][k],a2=As[ty*4+2][k],a3=As[ty*4+3][k];
    float4 w=*(float4*)&Ws[k][tx*4];
    acc2[0][0]+=a0*w.x; acc2[0][1]+=a0*w.y; acc2[0][2]+=a0*w.z; acc2[0][3]+=a0*w.w;
    acc2[1][0]+=a1*w.x; acc2[1][1]+=a1*w.y; acc2[1][2]+=a1*w.z; acc2[1][3]+=a1*w.w;
    acc2[2][0]+=a2*w.x; acc2[2][1]+=a2*w.y; acc2[2][2]+=a2*w.z; acc2[2][3]+=a2*w.w;
    acc2[3][0]+=a3*w.x; acc2[3][1]+=a3*w.y; acc2[3][2]+=a3*w.z; acc2[3][3]+=a3*w.w;
  }
  // run-merge consecutive rows with same dst, then atomicMax
  int dprev=-1;
  float mx0=0,mx1=0,mx2=0,mx3=0;
  #pragma unroll
  for(int i=0;i<4;i++){
    int e=e0+ty*4+i;
    if(e>=EE) continue;
    int dn=dstS[e];
    if(dn!=dprev){
      if(dprev>=0){
        atomicMax(&emax[(size_t)dprev*64+tx*4+0],fenc(mx0));
        atomicMax(&emax[(size_t)dprev*64+tx*4+1],fenc(mx1));
        atomicMax(&emax[(size_t)dprev*64+tx*4+2],fenc(mx2));
        atomicMax(&emax[(size_t)dprev*64+tx*4+3],fenc(mx3));
      }
      dprev=dn; mx0=acc2[i][0]; mx1=acc2[i][1]; mx2=acc2[i][2]; mx3=acc2[i][3];
    }else{
      mx0=fmaxf(mx0,acc2[i][0]); mx1=fmaxf(mx1,acc2[i][1]);
      mx2=fmaxf(mx2,acc2[i][2]); mx3=fmaxf(mx3,acc2[i][3]);
    }
  }
  if(dprev>=0){
    atomicMax(&emax[(size_t)dprev*64+tx*4+0],fenc(mx0));
    atomicMax(&emax[(size_t)dprev*64+tx*4+1],fenc(mx1));
    atomicMax(&emax[(size_t)dprev*64+tx*4+2],fenc(mx2));
    atomicMax(&emax[(size_t)dprev*64+tx*4+3],fenc(mx3));
  }
}

__global__ void x6_kernel(const unsigned* __restrict__ emax, float* __restrict__ x6){
  int i=blockIdx.x*blockDim.x+threadIdx.x;
  if(i>=N64) return;
  unsigned u=emax[i];
  // encoded values >= 0x80000000 correspond to original >= +0; relu clamps the rest to 0
  x6[i]=(u>=0x80000000u)? __uint_as_float(u&0x7fffffffu) : 0.f;
}

__global__ __launch_bounds__(256) void pool_kernel(const float* __restrict__ x6, const int* __restrict__ batch,
                                                   float* __restrict__ pooled){
  const int NB=2000;
  int base=blockIdx.x*NB;
  int lane=threadIdx.x&63;
  int wsub=threadIdx.x>>6;
  float acc=0.f; int curg=-1;
  for(int idx=wsub; idx<NB; idx+=4){
    int n=base+idx;
    if(n>=NN) break;
    int g=batch[n];
    if(g!=curg){
      if(curg>=0) atomicAdd(&pooled[curg*64+lane],acc);
      acc=0.f; curg=g;
    }
    acc+=x6[(size_t)n*64+lane];
  }
  if(curg>=0) atomicAdd(&pooled[curg*64+lane],acc);
}

__global__ __launch_bounds__(256) void final_kernel(const float* __restrict__ pooled, const int* __restrict__ batch,
    const float* __restrict__ fc1W, const float* __restrict__ fc1b,
    const float* __restrict__ fc2W, const float* __restrict__ fc2b,
    float* __restrict__ out){
  __shared__ float gm[16][64];
  __shared__ float t1[16][64];
  __shared__ int cgs[17];
  int t=threadIdx.x;
  if(t<17){
    int lo=0, hi=NN;
    while(lo<hi){ int mid=(lo+hi)>>1; if(batch[mid]<t) lo=mid+1; else hi=mid; }
    cgs[t]=lo;
  }
  __syncthreads();
  for(int r=0;r<4;r++){
    int idx=r*256+t; int g=idx>>6, d=idx&63;
    float c=(float)(cgs[g+1]-cgs[g]);
    gm[g][d]=pooled[idx]/fmaxf(c,1.f);
  }
  __syncthreads();
  for(int r=0;r<4;r++){
    int idx=r*256+t; int g=idx>>6, d=idx&63;
    float a=fc1b[d];
    for(int k2=0;k2<64;k2++) a+=gm[g][k2]*fc1W[k2*64+d];
    t1[g][d]=fmaxf(a,0.f);
  }
  __syncthreads();
  for(int r=0;r<4;r++){
    int idx=r*256+t; int g=idx>>6, d=idx&63;
    float a=fc2b[d];
    for(int k2=0;k2<64;k2++) a+=t1[g][k2]*fc2W[k2*64+d];
    out[idx]=a;
  }
}

extern "C" void kernel_launch(void* const* d_in, const int* in_sizes, int n_in,
                              void* d_out, int out_size, void* d_ws, size_t ws_size,
                              hipStream_t stream){
  const float* x       =(const float*)d_in[0];
  const int*   ei      =(const int*)  d_in[1];
  const int*   src     =ei;
  const int*   dst     =ei+EE;
  const int*   batch   =(const int*)  d_in[2];
  const float* gat1_W  =(const float*)d_in[3];
  const float* gat1_as =(const float*)d_in[4];
  const float* gat1_ad =(const float*)d_in[5];
  const float* gat1_b  =(const float*)d_in[6];
  const float* gat2_W  =(const float*)d_in[7];
  const float* gat2_as =(const float*)d_in[8];
  const float* gat2_ad =(const float*)d_in[9];
  const float* gat2_b  =(const float*)d_in[10];
  const float* gin_W1  =(const float*)d_in[11];
  const float* gin_b1  =(const float*)d_in[12];
  const float* gin_W2  =(const float*)d_in[13];
  const float* gin_b2  =(const float*)d_in[14];
  const float* sage1_Wl=(const float*)d_in[15];
  const float* sage1_bl=(const float*)d_in[16];
  const float* sage1_Wr=(const float*)d_in[17];
  const float* sage2_Wl=(const float*)d_in[18];
  const float* sage2_bl=(const float*)d_in[19];
  const float* sage2_Wr=(const float*)d_in[20];
  const float* tr_Wq   =(const float*)d_in[21];
  const float* tr_bq   =(const float*)d_in[22];
  const float* tr_Wk   =(const float*)d_in[23];
  const float* tr_bk   =(const float*)d_in[24];
  const float* tr_Wv   =(const float*)d_in[25];
  const float* tr_bv   =(const float*)d_in[26];
  const float* tr_Ws   =(const float*)d_in[27];
  const float* tr_bs   =(const float*)d_in[28];
  const float* ec_W1   =(const float*)d_in[29];
  const float* ec_b1   =(const float*)d_in[30];
  const float* ec_W2   =(const float*)d_in[31];
  const float* ec_b2   =(const float*)d_in[32];
  const float* fc1_W   =(const float*)d_in[33];
  const float* fc1_b   =(const float*)d_in[34];
  const float* fc2_W   =(const float*)d_in[35];
  const float* fc2_b   =(const float*)d_in[36];

  // ---- workspace layout (floats first, then ints) ----
  float* base=(float*)d_ws;
  size_t off=0;
  auto alloc=[&](size_t n){ float* p=base+off; off+=n; return p; };
  float* h_big =alloc((size_t)NN*256);     // GAT h / TR q,k,v
  float* nb0   =alloc(N64);
  float* nb1   =alloc(N64);
  float* nb2   =alloc(N64);
  float* nb3   =alloc(N64);
  float* nb4   =alloc(N64);                // tout (zeroed)
  float* nb5   =alloc(N64);                // emax (as unsigned, zeroed)
  float* logitE=alloc((size_t)EE*4);
  float* ls    =alloc(NN*4);
  float* ldb   =alloc(NN*4);
  float* zinv  =alloc(NN*4);
  float* asel  =alloc(NN*4);
  float* invdeg=alloc(NN);
  float* pooled=alloc(GG*64);
  int* ibase=(int*)(base+off);
  int* srcS  =ibase;
  int* dstS  =ibase+EE;
  int* cnt   =ibase+2*EE;
  int* fillp =ibase+2*EE+NN;
  int* rowptr=ibase+2*EE+2*NN;             // NN+1 ints

  const int BT=256;
  // ---- zero init ----
  zero_kernel<<<cdiv(NN,BT),BT,0,stream>>>((unsigned*)cnt,NN);
  zero_kernel<<<cdiv(NN,BT),BT,0,stream>>>((unsigned*)fillp,NN);
  zero_kernel<<<cdiv(GG*64,BT),BT,0,stream>>>((unsigned*)pooled,GG*64);
  zero_kernel<<<cdiv(N64,BT),BT,0,stream>>>((unsigned*)nb4,N64);
  zero_kernel<<<cdiv(N64,BT),BT,0,stream>>>((unsigned*)nb5,N64);
  // ---- CSR ----
  hist_kernel<<<cdiv(EE,BT),BT,0,stream>>>(dst,cnt);
  scan_kernel<<<1,1024,0,stream>>>(cnt,rowptr);
  fill_kernel<<<cdiv(EE,BT),BT,0,stream>>>(src,dst,rowptr,fillp,srcS,dstS);
  invdeg_kernel<<<cdiv(NN,BT),BT,0,stream>>>(cnt,invdeg);

  const int GB=cdiv(NN,64);        // 782 row tiles
  const int GW=cdiv(NN,4);         // wave-per-node blocks (12500)

  // ---- GAT1 ----
  gemm_kernel<128><<<dim3(GB,4),BT,0,stream>>>(x,gat1_W,256,0,nullptr,nullptr,h_big,256,0);
  attn_dots_kernel<<<GW,BT,0,stream>>>(h_big,gat1_as,gat1_ad,ls,ldb);
  gat_edge_logit_kernel<<<cdiv(EE,BT),BT,0,stream>>>(srcS,dstS,ls,ldb,logitE);
  gat_softmax_kernel<<<cdiv(NN,BT),BT,0,stream>>>(rowptr,ls,ldb,logitE,zinv,asel);
  gat_agg_kernel<<<GW,BT,0,stream>>>(h_big,rowptr,srcS,logitE,zinv,asel,gat1_b,nb0);   // x1
  // ---- GAT2 ----
  gemm_kernel<64><<<dim3(GB,4),BT,0,stream>>>(nb0,gat2_W,256,0,nullptr,nullptr,h_big,256,0);
  attn_dots_kernel<<<GW,BT,0,stream>>>(h_big,gat2_as,gat2_ad,ls,ldb);
  gat_edge_logit_kernel<<<cdiv(EE,BT),BT,0,stream>>>(srcS,dstS,ls,ldb,logitE);
  gat_softmax_kernel<<<cdiv(NN,BT),BT,0,stream>>>(rowptr,ls,ldb,logitE,zinv,asel);
  gat_agg_kernel<<<GW,BT,0,stream>>>(h_big,rowptr,srcS,logitE,zinv,asel,gat2_b,nb1);   // x2
  // ---- GIN ----
  agg_kernel<<<GW,BT,0,stream>>>(nb1,rowptr,srcS,invdeg,nb2,0);                        // t = x2+agg
  gemm_kernel<64><<<dim3(GB,1),BT,0,stream>>>(nb2,gin_W1,64,0,gin_b1,nullptr,nb3,64,1);
  gemm_kernel<64><<<dim3(GB,1),BT,0,stream>>>(nb3,gin_W2,64,0,gin_b2,nullptr,nb0,64,1); // x3
  // ---- SAGE1 ----
  agg_kernel<<<GW,BT,0,stream>>>(nb0,rowptr,srcS,invdeg,nb2,1);                        // mean(x3)
  gemm_kernel<64><<<dim3(GB,1),BT,0,stream>>>(nb0,sage1_Wr,64,0,nullptr,nullptr,nb3,64,0);
  gemm_kernel<64><<<dim3(GB,1),BT,0,stream>>>(nb2,sage1_Wl,64,0,sage1_bl,nb3,nb1,64,1); // xs
  // ---- SAGE2 ----
  agg_kernel<<<GW,BT,0,stream>>>(nb1,rowptr,srcS,invdeg,nb2,1);
  gemm_kernel<64><<<dim3(GB,1),BT,0,stream>>>(nb1,sage2_Wr,64,0,nullptr,nullptr,nb3,64,0);
  gemm_kernel<64><<<dim3(GB,1),BT,0,stream>>>(nb2,sage2_Wl,64,0,sage2_bl,nb3,nb0,64,1); // x4
  // ---- TransformerConv (per head; tout=nb4 pre-zeroed) ----
  float* qh=h_big;
  float* kh=h_big+(size_t)N64;
  float* vh=h_big+(size_t)2*N64;
  for(int hh=0;hh<4;hh++){
    gemm_kernel<64><<<dim3(GB,1),BT,0,stream>>>(nb0,tr_Wq,256,hh*64,tr_bq,nullptr,qh,64,0);
    gemm_kernel<64><<<dim3(GB,1),BT,0,stream>>>(nb0,tr_Wk,256,hh*64,tr_bk,nullptr,kh,64,0);
    gemm_kernel<64><<<dim3(GB,1),BT,0,stream>>>(nb0,tr_Wv,256,hh*64,tr_bv,nullptr,vh,64,0);
    tr_logit_kernel<<<cdiv(EE,4),BT,0,stream>>>(srcS,dstS,qh,kh,logitE);
    tr_softmax_kernel<<<cdiv(NN,BT),BT,0,stream>>>(rowptr,logitE,zinv);
    tr_agg_kernel<<<GW,BT,0,stream>>>(rowptr,srcS,logitE,zinv,vh,nb4);
  }
  gemm_kernel<64><<<dim3(GB,1),BT,0,stream>>>(nb0,tr_Ws,64,0,tr_bs,nullptr,nb1,64,0);  // skip path
  x5_kernel<<<cdiv(N64,BT),BT,0,stream>>>(nb4,nb1,nb2);                                // x5
  // ---- EdgeConv ----
  edgeconv_kernel<<<EE/64,BT,0,stream>>>(nb2,srcS,dstS,ec_W1,ec_b1,ec_W2,ec_b2,(unsigned*)nb5);
  x6_kernel<<<cdiv(N64,BT),BT,0,stream>>>((unsigned*)nb5,nb0);                          // x6
  // ---- pool + MLP ----
  pool_kernel<<<25,BT,0,stream>>>(nb0,batch,pooled);
  final_kernel<<<1,BT,0,stream>>>(pooled,batch,fc1_W,fc1_b,fc2_W,fc2_b,(float*)d_out);
}

// Round 2
// 1769.572 us; speedup vs baseline: 1.3236x; 1.3236x over previous
//
#include <hip/hip_runtime.h>

#define NN 50000
#define EE 640000
#define GG 16
#define N64 (NN*64)

static inline int cdiv(int a,int b){return (a+b-1)/b;}

__device__ __forceinline__ float lrelu(float x){ return x>0.f? x : 0.2f*x; }
// monotonic float->uint encoding for atomicMax on floats
__device__ __forceinline__ unsigned fenc(float f){
  unsigned u=__float_as_uint(f);
  return (u&0x80000000u)? ~u : (u|0x80000000u);
}

// acc[0..3] += av . {w0..w3} columns
__device__ __forceinline__ void mac4(float* acc, const float4 av,
    const float4 w0, const float4 w1, const float4 w2, const float4 w3){
  acc[0]+=av.x*w0.x+av.y*w1.x+av.z*w2.x+av.w*w3.x;
  acc[1]+=av.x*w0.y+av.y*w1.y+av.z*w2.y+av.w*w3.y;
  acc[2]+=av.x*w0.z+av.y*w1.z+av.z*w2.z+av.w*w3.z;
  acc[3]+=av.x*w0.w+av.y*w1.w+av.z*w2.w+av.w*w3.w;
}

__global__ void zero_kernel(unsigned* p, int n){
  int i=blockIdx.x*blockDim.x+threadIdx.x;
  if(i<n) p[i]=0u;
}

__global__ void hist_kernel(const int* __restrict__ dst, int* __restrict__ cnt){
  int e=blockIdx.x*blockDim.x+threadIdx.x;
  if(e<EE) atomicAdd(&cnt[dst[e]],1);
}

__global__ __launch_bounds__(1024) void scan_kernel(const int* __restrict__ cnt, int* __restrict__ rowptr){
  __shared__ int buf[2][1024];
  __shared__ int carry_s;
  int tid=threadIdx.x;
  if(tid==0) carry_s=0;
  __syncthreads();
  for(int base=0;base<NN;base+=1024){
    int i=base+tid;
    int v=(i<NN)?cnt[i]:0;
    int pin=0;
    buf[0][tid]=v;
    __syncthreads();
    for(int off=1;off<1024;off<<=1){
      int t=buf[pin][tid];
      if(tid>=off) t+=buf[pin][tid-off];
      buf[1-pin][tid]=t;
      pin^=1;
      __syncthreads();
    }
    int inc=buf[pin][tid];
    int carry=carry_s;
    if(i<NN) rowptr[i]=carry+inc-v;   // exclusive scan
    __syncthreads();
    if(tid==1023) carry_s=carry+buf[pin][1023];
    __syncthreads();
  }
  if(tid==0) rowptr[NN]=carry_s;
}

__global__ void fill_kernel(const int* __restrict__ src, const int* __restrict__ dst,
                            const int* __restrict__ rowptr, int* __restrict__ fillp,
                            int* __restrict__ srcS, int* __restrict__ dstS){
  int e=blockIdx.x*blockDim.x+threadIdx.x;
  if(e>=EE) return;
  int d=dst[e];
  int p=rowptr[d]+atomicAdd(&fillp[d],1);
  srcS[p]=src[e]; dstS[p]=d;
}

__global__ void invdeg_kernel(const int* __restrict__ cnt, float* __restrict__ invdeg){
  int i=blockIdx.x*blockDim.x+threadIdx.x;
  if(i<NN) invdeg[i]=1.f/fmaxf((float)cnt[i],1.f);
}

// C[NN, ldc(+nc0 slice)] = act(A[NN,K] @ W[K, ldw](cols wc..) + bias + addend)
// If Wb != nullptr, rows >=64 of the combined weight come from Wb (rows 0..63 there).
template<int K>
__global__ __launch_bounds__(256) void gemm_kernel(
    const float* __restrict__ A, const float* __restrict__ W, const float* __restrict__ Wb,
    int ldw, int wcol0,
    const float* __restrict__ bias, const float* __restrict__ addend,
    float* __restrict__ C, int ldc, int relu_flag){
  __shared__ float As[64][68];
  __shared__ float Ws[64][64];
  const int m0=blockIdx.x*64;
  const int nc0=blockIdx.y*64;
  const int wc=wcol0+nc0;
  const int tid=threadIdx.x, tx=tid&15, ty=tid>>4;
  float acc[4][4];
  #pragma unroll
  for(int i=0;i<4;i++){
    #pragma unroll
    for(int j=0;j<4;j++) acc[i][j]=bias? bias[wc+tx*4+j]:0.f;
  }
  for(int k0=0;k0<K;k0+=64){
    const float* Wp=(Wb && k0>=64)? Wb : W;
    const int kb =(Wb && k0>=64)? k0-64 : k0;
    __syncthreads();
    #pragma unroll
    for(int it=0;it<4;it++){
      int linear=it*1024+tid*4;
      int m=linear>>6, k=linear&63;
      float4 v=make_float4(0.f,0.f,0.f,0.f);
      if(m0+m<NN) v=*(const float4*)(A+(size_t)(m0+m)*K+k0+k);
      *(float4*)&As[m][k]=v;
    }
    #pragma unroll
    for(int it=0;it<4;it++){
      int linear=it*1024+tid*4;
      int k=linear>>6, n=linear&63;
      *(float4*)&Ws[k][n]=*(const float4*)(Wp+(size_t)(kb+k)*ldw+wc+n);
    }
    __syncthreads();
    #pragma unroll 8
    for(int k=0;k<64;k+=4){
      float4 a0=*(float4*)&As[ty*4+0][k];
      float4 a1=*(float4*)&As[ty*4+1][k];
      float4 a2=*(float4*)&As[ty*4+2][k];
      float4 a3=*(float4*)&As[ty*4+3][k];
      float4 w0=*(float4*)&Ws[k+0][tx*4];
      float4 w1=*(float4*)&Ws[k+1][tx*4];
      float4 w2=*(float4*)&Ws[k+2][tx*4];
      float4 w3=*(float4*)&Ws[k+3][tx*4];
      mac4(acc[0],a0,w0,w1,w2,w3);
      mac4(acc[1],a1,w0,w1,w2,w3);
      mac4(acc[2],a2,w0,w1,w2,w3);
      mac4(acc[3],a3,w0,w1,w2,w3);
    }
  }
  #pragma unroll
  for(int i=0;i<4;i++){
    int m=m0+ty*4+i;
    if(m>=NN) continue;
    float r0=acc[i][0],r1=acc[i][1],r2=acc[i][2],r3=acc[i][3];
    if(addend){
      const float4 ad=*(const float4*)(addend+(size_t)m*ldc+nc0+tx*4);
      r0+=ad.x; r1+=ad.y; r2+=ad.z; r3+=ad.w;
    }
    if(relu_flag){ r0=fmaxf(r0,0.f); r1=fmaxf(r1,0.f); r2=fmaxf(r2,0.f); r3=fmaxf(r3,0.f); }
    *(float4*)(C+(size_t)m*ldc+nc0+tx*4)=make_float4(r0,r1,r2,r3);
  }
}

// ls[n,h] = <h[n,h,:], a_s[h,:]>, ld likewise. One wave per node.
__global__ __launch_bounds__(256) void attn_dots_kernel(const float* __restrict__ h,
    const float* __restrict__ a_s, const float* __restrict__ a_d,
    float* __restrict__ ls, float* __restrict__ ld){
  int w=blockIdx.x*4+(threadIdx.x>>6);
  int lane=threadIdx.x&63;
  if(w>=NN) return;
  const float* hr=h+(size_t)w*256;
  float s[4],d[4];
  #pragma unroll
  for(int k=0;k<4;k++){
    float v=hr[k*64+lane];
    s[k]=v*a_s[k*64+lane];
    d[k]=v*a_d[k*64+lane];
  }
  #pragma unroll
  for(int o=32;o>0;o>>=1){
    #pragma unroll
    for(int k=0;k<4;k++){
      s[k]+=__shfl_xor(s[k],o,64);
      d[k]+=__shfl_xor(d[k],o,64);
    }
  }
  if(lane==0){
    ls[w*4+0]=s[0]; ls[w*4+1]=s[1]; ls[w*4+2]=s[2]; ls[w*4+3]=s[3];
    ld[w*4+0]=d[0]; ld[w*4+1]=d[1]; ld[w*4+2]=d[2]; ld[w*4+3]=d[3];
  }
}

__global__ void gat_edge_logit_kernel(const int* __restrict__ srcS, const int* __restrict__ dstS,
    const float* __restrict__ ls, const float* __restrict__ ld, float* __restrict__ lg){
  int j=blockIdx.x*blockDim.x+threadIdx.x;
  if(j>=EE) return;
  int s=srcS[j], d=dstS[j];
  const float4 a=*(const float4*)(ls+4*s);
  const float4 b=*(const float4*)(ld+4*d);
  *(float4*)(lg+4*j)=make_float4(lrelu(a.x+b.x),lrelu(a.y+b.y),lrelu(a.z+b.z),lrelu(a.w+b.w));
}

// per-dst softmax incl. self-loop; stores exp() in lg, 1/z in zinv, self alpha in asel
__global__ void gat_softmax_kernel(const int* __restrict__ rowptr,
    const float* __restrict__ ls, const float* __restrict__ ld,
    float* __restrict__ lg, float* __restrict__ zinv, float* __restrict__ asel){
  int n=blockIdx.x*blockDim.x+threadIdx.x;
  if(n>=NN) return;
  int r0=rowptr[n], r1=rowptr[n+1];
  const float4 a=*(const float4*)(ls+4*n);
  const float4 b=*(const float4*)(ld+4*n);
  float sl[4]={lrelu(a.x+b.x),lrelu(a.y+b.y),lrelu(a.z+b.z),lrelu(a.w+b.w)};
  float m[4]={sl[0],sl[1],sl[2],sl[3]};
  for(int j=r0;j<r1;j++){
    float4 f=*(const float4*)(lg+4*j);
    m[0]=fmaxf(m[0],f.x); m[1]=fmaxf(m[1],f.y); m[2]=fmaxf(m[2],f.z); m[3]=fmaxf(m[3],f.w);
  }
  float es[4], z[4];
  #pragma unroll
  for(int hh=0;hh<4;hh++){ es[hh]=__expf(sl[hh]-m[hh]); z[hh]=es[hh]; }
  for(int j=r0;j<r1;j++){
    float4 f=*(float4*)(lg+4*j);
    float4 e=make_float4(__expf(f.x-m[0]),__expf(f.y-m[1]),__expf(f.z-m[2]),__expf(f.w-m[3]));
    z[0]+=e.x; z[1]+=e.y; z[2]+=e.z; z[3]+=e.w;
    *(float4*)(lg+4*j)=e;
  }
  float zi[4];
  #pragma unroll
  for(int hh=0;hh<4;hh++) zi[hh]=1.f/(z[hh]+1e-16f);
  *(float4*)(zinv+4*n)=make_float4(zi[0],zi[1],zi[2],zi[3]);
  *(float4*)(asel+4*n)=make_float4(es[0]*zi[0],es[1]*zi[1],es[2]*zi[2],es[3]*zi[3]);
}

// out[n,d] = relu( 0.25*sum_h( alpha_self*h[n,h,d] + sum_e alpha_e*h[src,h,d] ) + b[d] )
__global__ __launch_bounds__(256) void gat_agg_kernel(const float* __restrict__ h,
    const int* __restrict__ rowptr, const int* __restrict__ srcS,
    const float* __restrict__ lg, const float* __restrict__ zinv, const float* __restrict__ asel,
    const float* __restrict__ bias, float* __restrict__ out){
  int n=blockIdx.x*4+(threadIdx.x>>6);
  int lane=threadIdx.x&63;
  if(n>=NN) return;
  int r0=rowptr[n], r1=rowptr[n+1];
  const float4 zi=*(const float4*)(zinv+4*n);
  const float4 asf=*(const float4*)(asel+4*n);
  const float* hn=h+(size_t)n*256;
  float a0=asf.x*hn[lane], a1=asf.y*hn[64+lane], a2=asf.z*hn[128+lane], a3=asf.w*hn[192+lane];
  for(int j=r0;j<r1;j++){
    int s=srcS[j];
    float4 e=*(const float4*)(lg+4*j);
    const float* hs=h+(size_t)s*256;
    a0+=e.x*zi.x*hs[lane];
    a1+=e.y*zi.y*hs[64+lane];
    a2+=e.z*zi.z*hs[128+lane];
    a3+=e.w*zi.w*hs[192+lane];
  }
  out[(size_t)n*64+lane]=fmaxf(0.25f*(a0+a1+a2+a3)+bias[lane],0.f);
}

// mode 0: self + sum (GIN) -> out[N,64]
__global__ __launch_bounds__(256) void agg_kernel(const float* __restrict__ xin,
    const int* __restrict__ rowptr, const int* __restrict__ srcS,
    float* __restrict__ out){
  int n=blockIdx.x*4+(threadIdx.x>>6);
  int lane=threadIdx.x&63;
  if(n>=NN) return;
  int r0=rowptr[n], r1=rowptr[n+1];
  float acc=xin[(size_t)n*64+lane];
  for(int j=r0;j<r1;j++) acc+=xin[(size_t)srcS[j]*64+lane];
  out[(size_t)n*64+lane]=acc;
}

// SAGE staging: out128[n] = [ mean_neigh(xin), xin[n] ]
__global__ __launch_bounds__(256) void agg2_kernel(const float* __restrict__ xin,
    const int* __restrict__ rowptr, const int* __restrict__ srcS,
    const float* __restrict__ invdeg, float* __restrict__ out128){
  int n=blockIdx.x*4+(threadIdx.x>>6);
  int lane=threadIdx.x&63;
  if(n>=NN) return;
  int r0=rowptr[n], r1=rowptr[n+1];
  float acc=0.f;
  for(int j=r0;j<r1;j++) acc+=xin[(size_t)srcS[j]*64+lane];
  out128[(size_t)n*128+lane]=acc*invdeg[n];
  out128[(size_t)n*128+64+lane]=xin[(size_t)n*64+lane];
}

// all-head q.k dots: one wave per edge, q/k are [N,256]
__global__ __launch_bounds__(256) void tr_logit4_kernel(const int* __restrict__ srcS, const int* __restrict__ dstS,
    const float* __restrict__ q, const float* __restrict__ k, float* __restrict__ lg){
  int j=blockIdx.x*4+(threadIdx.x>>6);
  int lane=threadIdx.x&63;
  if(j>=EE) return;
  int s=srcS[j], d=dstS[j];
  const float* qd=q+(size_t)d*256;
  const float* ks=k+(size_t)s*256;
  float v[4];
  #pragma unroll
  for(int hh=0;hh<4;hh++) v[hh]=qd[hh*64+lane]*ks[hh*64+lane];
  #pragma unroll
  for(int o=32;o>0;o>>=1){
    #pragma unroll
    for(int hh=0;hh<4;hh++) v[hh]+=__shfl_xor(v[hh],o,64);
  }
  if(lane==0)
    *(float4*)(lg+4*j)=make_float4(v[0]*0.125f,v[1]*0.125f,v[2]*0.125f,v[3]*0.125f);
}

__global__ void tr_softmax4_kernel(const int* __restrict__ rowptr, float* __restrict__ lg, float* __restrict__ zinvH){
  int n=blockIdx.x*blockDim.x+threadIdx.x;
  if(n>=NN) return;
  int r0=rowptr[n], r1=rowptr[n+1];
  if(r0==r1){ *(float4*)(zinvH+4*n)=make_float4(0.f,0.f,0.f,0.f); return; }
  float m[4]={-1e30f,-1e30f,-1e30f,-1e30f};
  for(int j=r0;j<r1;j++){
    float4 f=*(const float4*)(lg+4*j);
    m[0]=fmaxf(m[0],f.x); m[1]=fmaxf(m[1],f.y); m[2]=fmaxf(m[2],f.z); m[3]=fmaxf(m[3],f.w);
  }
  float z[4]={0.f,0.f,0.f,0.f};
  for(int j=r0;j<r1;j++){
    float4 f=*(float4*)(lg+4*j);
    float4 e=make_float4(__expf(f.x-m[0]),__expf(f.y-m[1]),__expf(f.z-m[2]),__expf(f.w-m[3]));
    z[0]+=e.x; z[1]+=e.y; z[2]+=e.z; z[3]+=e.w;
    *(float4*)(lg+4*j)=e;
  }
  *(float4*)(zinvH+4*n)=make_float4(1.f/(z[0]+1e-16f),1.f/(z[1]+1e-16f),1.f/(z[2]+1e-16f),1.f/(z[3]+1e-16f));
}

// x5[n,d] = relu( 0.25 * sum_h zinv_h * sum_e e_h * v[src,h,d]  + skip[n,d] )
__global__ __launch_bounds__(256) void tr_aggx5_kernel(const int* __restrict__ rowptr, const int* __restrict__ srcS,
    const float* __restrict__ lg, const float* __restrict__ zinvH,
    const float* __restrict__ v, const float* __restrict__ skip, float* __restrict__ x5){
  int n=blockIdx.x*4+(threadIdx.x>>6);
  int lane=threadIdx.x&63;
  if(n>=NN) return;
  int r0=rowptr[n], r1=rowptr[n+1];
  float a0=0.f,a1=0.f,a2=0.f,a3=0.f;
  for(int j=r0;j<r1;j++){
    int s=srcS[j];
    float4 e=*(const float4*)(lg+4*j);
    const float* vs=v+(size_t)s*256;
    a0+=e.x*vs[lane];
    a1+=e.y*vs[64+lane];
    a2+=e.z*vs[128+lane];
    a3+=e.w*vs[192+lane];
  }
  const float4 zi=*(const float4*)(zinvH+4*n);
  float t=0.25f*(a0*zi.x+a1*zi.y+a2*zi.z+a3*zi.w)+skip[(size_t)n*64+lane];
  x5[(size_t)n*64+lane]=fmaxf(t,0.f);
}

// fused EdgeConv: feat gather -> GEMM1(+b1,relu) -> GEMM2(+b2) -> run-merged atomicMax to emax
__global__ __launch_bounds__(256) void edgeconv_kernel(const float* __restrict__ x5,
    const int* __restrict__ srcS, const int* __restrict__ dstS,
    const float* __restrict__ W1, const float* __restrict__ b1,
    const float* __restrict__ W2, const float* __restrict__ b2,
    unsigned* __restrict__ emax){
  __shared__ float As[64][68];   // feat tile, then reused as hidden tile
  __shared__ float Ws[64][64];
  const int e0=blockIdx.x*64;
  const int tid=threadIdx.x, tx=tid&15, ty=tid>>4;
  float acc[4][4];
  #pragma unroll
  for(int i=0;i<4;i++)
    #pragma unroll
    for(int j=0;j<4;j++) acc[i][j]=b1[tx*4+j];
  for(int c=0;c<2;c++){
    __syncthreads();
    #pragma unroll
    for(int it=0;it<4;it++){
      int linear=it*1024+tid*4;
      int m=linear>>6, k=linear&63;
      int e=e0+m;
      float4 v=make_float4(0.f,0.f,0.f,0.f);
      if(e<EE){
        int dn=dstS[e];
        float4 xi=*(const float4*)(x5+(size_t)dn*64+k);
        if(c==0) v=xi;
        else{
          int sn=srcS[e];
          float4 xj=*(const float4*)(x5+(size_t)sn*64+k);
          v=make_float4(xj.x-xi.x,xj.y-xi.y,xj.z-xi.z,xj.w-xi.w);
        }
      }
      *(float4*)&As[m][k]=v;
    }
    #pragma unroll
    for(int it=0;it<4;it++){
      int linear=it*1024+tid*4;
      int k=linear>>6, n=linear&63;
      *(float4*)&Ws[k][n]=*(const float4*)(W1+(size_t)(c*64+k)*64+n);
    }
    __syncthreads();
    #pragma unroll 8
    for(int k=0;k<64;k+=4){
      float4 a0=*(float4*)&As[ty*4+0][k];
      float4 a1=*(float4*)&As[ty*4+1][k];
      float4 a2=*(float4*)&As[ty*4+2][k];
      float4 a3=*(float4*)&As[ty*4+3][k];
      float4 w0=*(float4*)&Ws[k+0][tx*4];
      float4 w1=*(float4*)&Ws[k+1][tx*4];
      float4 w2=*(float4*)&Ws[k+2][tx*4];
      float4 w3=*(float4*)&Ws[k+3][tx*4];
      mac4(acc[0],a0,w0,w1,w2,w3);
      mac4(acc[1],a1,w0,w1,w2,w3);
      mac4(acc[2],a2,w0,w1,w2,w3);
      mac4(acc[3],a3,w0,w1,w2,w3);
    }
  }
  __syncthreads();
  #pragma unroll
  for(int i=0;i<4;i++)
    #pragma unroll
    for(int j=0;j<4;j++)
      As[ty*4+i][tx*4+j]=fmaxf(acc[i][j],0.f);   // hidden (relu) into As
  #pragma unroll
  for(int it=0;it<4;it++){
    int linear=it*1024+tid*4;
    int k=linear>>6, n=linear&63;
    *(float4*)&Ws[k][n]=*(const float4*)(W2+(size_t)k*64+n);
  }
  __syncthreads();
  float acc2[4][4];
  #pragma unroll
  for(int i=0;i<4;i++)
    #pragma unroll
    for(int j=0;j<4;j++) acc2[i][j]=b2[tx*4+j];
  #pragma unroll 8
  for(int k=0;k<64;k+=4){
    float4 a0=*(float4*)&As[ty*4+0][k];
    float4 a1=*(float4*)&As[ty*4+1][k];
    float4 a2=*(float4*)&As[ty*4+2][k];
    float4 a3=*(float4*)&As[ty*4+3][k];
    float4 w0=*(float4*)&Ws[k+0][tx*4];
    float4 w1=*(float4*)&Ws[k+1][tx*4];
    float4 w2=*(float4*)&Ws[k+2][tx*4];
    float4 w3=*(float4*)&Ws[k+3][tx*4];
    mac4(acc2[0],a0,w0,w1,w2,w3);
    mac4(acc2[1],a1,w0,w1,w2,w3);
    mac4(acc2[2],a2,w0,w1,w2,w3);
    mac4(acc2[3],a3,w0,w1,w2,w3);
  }
  // run-merge consecutive rows with same dst, then atomicMax
  int dprev=-1;
  float mx0=0,mx1=0,mx2=0,mx3=0;
  #pragma unroll
  for(int i=0;i<4;i++){
    int e=e0+ty*4+i;
    if(e>=EE) continue;
    int dn=dstS[e];
    if(dn!=dprev){
      if(dprev>=0){
        atomicMax(&emax[(size_t)dprev*64+tx*4+0],fenc(mx0));
        atomicMax(&emax[(size_t)dprev*64+tx*4+1],fenc(mx1));
        atomicMax(&emax[(size_t)dprev*64+tx*4+2],fenc(mx2));
        atomicMax(&emax[(size_t)dprev*64+tx*4+3],fenc(mx3));
      }
      dprev=dn; mx0=acc2[i][0]; mx1=acc2[i][1]; mx2=acc2[i][2]; mx3=acc2[i][3];
    }else{
      mx0=fmaxf(mx0,acc2[i][0]); mx1=fmaxf(mx1,acc2[i][1]);
      mx2=fmaxf(mx2,acc2[i][2]); mx3=fmaxf(mx3,acc2[i][3]);
    }
  }
  if(dprev>=0){
    atomicMax(&emax[(size_t)dprev*64+tx*4+0],fenc(mx0));
    atomicMax(&emax[(size_t)dprev*64+tx*4+1],fenc(mx1));
    atomicMax(&emax[(size_t)dprev*64+tx*4+2],fenc(mx2));
    atomicMax(&emax[(size_t)dprev*64+tx*4+3],fenc(mx3));
  }
}

// pool with emax decode fused: x6 = relu(decode(emax)); pooled[g] += x6
__global__ __launch_bounds__(256) void pool_kernel(const unsigned* __restrict__ emax, const int* __restrict__ batch,
                                                   float* __restrict__ pooled){
  const int NB=2000;
  int base=blockIdx.x*NB;
  int lane=threadIdx.x&63;
  int wsub=threadIdx.x>>6;
  float acc=0.f; int curg=-1;
  for(int idx=wsub; idx<NB; idx+=4){
    int n=base+idx;
    if(n>=NN) break;
    int g=batch[n];
    if(g!=curg){
      if(curg>=0) atomicAdd(&pooled[curg*64+lane],acc);
      acc=0.f; curg=g;
    }
    unsigned u=emax[(size_t)n*64+lane];
    acc+=(u>=0x80000000u)? __uint_as_float(u&0x7fffffffu) : 0.f;
  }
  if(curg>=0) atomicAdd(&pooled[curg*64+lane],acc);
}

__global__ __launch_bounds__(256) void final_kernel(const float* __restrict__ pooled, const int* __restrict__ batch,
    const float* __restrict__ fc1W, const float* __restrict__ fc1b,
    const float* __restrict__ fc2W, const float* __restrict__ fc2b,
    float* __restrict__ out){
  __shared__ float gm[16][64];
  __shared__ float t1[16][64];
  __shared__ int cgs[17];
  int t=threadIdx.x;
  if(t<17){
    int lo=0, hi=NN;
    while(lo<hi){ int mid=(lo+hi)>>1; if(batch[mid]<t) lo=mid+1; else hi=mid; }
    cgs[t]=lo;
  }
  __syncthreads();
  for(int r=0;r<4;r++){
    int idx=r*256+t; int g=idx>>6, d=idx&63;
    float c=(float)(cgs[g+1]-cgs[g]);
    gm[g][d]=pooled[idx]/fmaxf(c,1.f);
  }
  __syncthreads();
  for(int r=0;r<4;r++){
    int idx=r*256+t; int g=idx>>6, d=idx&63;
    float a=fc1b[d];
    for(int k2=0;k2<64;k2++) a+=gm[g][k2]*fc1W[k2*64+d];
    t1[g][d]=fmaxf(a,0.f);
  }
  __syncthreads();
  for(int r=0;r<4;r++){
    int idx=r*256+t; int g=idx>>6, d=idx&63;
    float a=fc2b[d];
    for(int k2=0;k2<64;k2++) a+=t1[g][k2]*fc2W[k2*64+d];
    out[idx]=a;
  }
}

extern "C" void kernel_launch(void* const* d_in, const int* in_sizes, int n_in,
                              void* d_out, int out_size, void* d_ws, size_t ws_size,
                              hipStream_t stream){
  const float* x       =(const float*)d_in[0];
  const int*   ei      =(const int*)  d_in[1];
  const int*   src     =ei;
  const int*   dst     =ei+EE;
  const int*   batch   =(const int*)  d_in[2];
  const float* gat1_W  =(const float*)d_in[3];
  const float* gat1_as =(const float*)d_in[4];
  const float* gat1_ad =(const float*)d_in[5];
  const float* gat1_b  =(const float*)d_in[6];
  const float* gat2_W  =(const float*)d_in[7];
  const float* gat2_as =(const float*)d_in[8];
  const float* gat2_ad =(const float*)d_in[9];
  const float* gat2_b  =(const float*)d_in[10];
  const float* gin_W1  =(const float*)d_in[11];
  const float* gin_b1  =(const float*)d_in[12];
  const float* gin_W2  =(const float*)d_in[13];
  const float* gin_b2  =(const float*)d_in[14];
  const float* sage1_Wl=(const float*)d_in[15];
  const float* sage1_bl=(const float*)d_in[16];
  const float* sage1_Wr=(const float*)d_in[17];
  const float* sage2_Wl=(const float*)d_in[18];
  const float* sage2_bl=(const float*)d_in[19];
  const float* sage2_Wr=(const float*)d_in[20];
  const float* tr_Wq   =(const float*)d_in[21];
  const float* tr_bq   =(const float*)d_in[22];
  const float* tr_Wk   =(const float*)d_in[23];
  const float* tr_bk   =(const float*)d_in[24];
  const float* tr_Wv   =(const float*)d_in[25];
  const float* tr_bv   =(const float*)d_in[26];
  const float* tr_Ws   =(const float*)d_in[27];
  const float* tr_bs   =(const float*)d_in[28];
  const float* ec_W1   =(const float*)d_in[29];
  const float* ec_b1   =(const float*)d_in[30];
  const float* ec_W2   =(const float*)d_in[31];
  const float* ec_b2   =(const float*)d_in[32];
  const float* fc1_W   =(const float*)d_in[33];
  const float* fc1_b   =(const float*)d_in[34];
  const float* fc2_W   =(const float*)d_in[35];
  const float* fc2_b   =(const float*)d_in[36];

  // ---- workspace layout (floats first, then ints) ----
  float* base=(float*)d_ws;
  size_t off=0;
  auto alloc=[&](size_t n){ float* p=base+off; off+=n; return p; };
  float* A_big =alloc((size_t)NN*256);     // GAT h / TR q / TR v / SAGE xcat
  float* nb0   =alloc(N64);
  float* nb1   =alloc(N64);                // nb1..nb4 contiguous: also TR k [N,256]
  float* nb2   =alloc(N64);
  float* nb3   =alloc(N64);
  float* nb4   =alloc(N64);
  float* nb5   =alloc(N64);                // emax (as unsigned, zeroed)
  float* logitE=alloc((size_t)EE*4);
  float* ls    =alloc(NN*4);
  float* ldb   =alloc(NN*4);
  float* zinv  =alloc(NN*4);
  float* asel  =alloc(NN*4);
  float* invdeg=alloc(NN);
  float* pooled=alloc(GG*64);
  int* ibase=(int*)(base+off);
  int* srcS  =ibase;
  int* dstS  =ibase+EE;
  int* cnt   =ibase+2*EE;
  int* fillp =ibase+2*EE+NN;               // cnt,fillp contiguous (zeroed together)
  int* rowptr=ibase+2*EE+2*NN;             // NN+1 ints

  const int BT=256;
  // ---- zero init (cnt+fillp contiguous) ----
  zero_kernel<<<cdiv(2*NN,BT),BT,0,stream>>>((unsigned*)cnt,2*NN);
  zero_kernel<<<cdiv(GG*64,BT),BT,0,stream>>>((unsigned*)pooled,GG*64);
  zero_kernel<<<cdiv(N64,BT),BT,0,stream>>>((unsigned*)nb5,N64);
  // ---- CSR ----
  hist_kernel<<<cdiv(EE,BT),BT,0,stream>>>(dst,cnt);
  scan_kernel<<<1,1024,0,stream>>>(cnt,rowptr);
  fill_kernel<<<cdiv(EE,BT),BT,0,stream>>>(src,dst,rowptr,fillp,srcS,dstS);
  invdeg_kernel<<<cdiv(NN,BT),BT,0,stream>>>(cnt,invdeg);

  const int GB=cdiv(NN,64);        // 782 row tiles
  const int GW=cdiv(NN,4);         // wave-per-node blocks (12500)

  // ---- GAT1 ----
  gemm_kernel<128><<<dim3(GB,4),BT,0,stream>>>(x,gat1_W,nullptr,256,0,nullptr,nullptr,A_big,256,0);
  attn_dots_kernel<<<GW,BT,0,stream>>>(A_big,gat1_as,gat1_ad,ls,ldb);
  gat_edge_logit_kernel<<<cdiv(EE,BT),BT,0,stream>>>(srcS,dstS,ls,ldb,logitE);
  gat_softmax_kernel<<<cdiv(NN,BT),BT,0,stream>>>(rowptr,ls,ldb,logitE,zinv,asel);
  gat_agg_kernel<<<GW,BT,0,stream>>>(A_big,rowptr,srcS,logitE,zinv,asel,gat1_b,nb0);   // x1
  // ---- GAT2 ----
  gemm_kernel<64><<<dim3(GB,4),BT,0,stream>>>(nb0,gat2_W,nullptr,256,0,nullptr,nullptr,A_big,256,0);
  attn_dots_kernel<<<GW,BT,0,stream>>>(A_big,gat2_as,gat2_ad,ls,ldb);
  gat_edge_logit_kernel<<<cdiv(EE,BT),BT,0,stream>>>(srcS,dstS,ls,ldb,logitE);
  gat_softmax_kernel<<<cdiv(NN,BT),BT,0,stream>>>(rowptr,ls,ldb,logitE,zinv,asel);
  gat_agg_kernel<<<GW,BT,0,stream>>>(A_big,rowptr,srcS,logitE,zinv,asel,gat2_b,nb1);   // x2
  // ---- GIN ----
  agg_kernel<<<GW,BT,0,stream>>>(nb1,rowptr,srcS,nb2);                                 // t = x2+agg
  gemm_kernel<64><<<dim3(GB,1),BT,0,stream>>>(nb2,gin_W1,nullptr,64,0,gin_b1,nullptr,nb3,64,1);
  gemm_kernel<64><<<dim3(GB,1),BT,0,stream>>>(nb3,gin_W2,nullptr,64,0,gin_b2,nullptr,nb0,64,1); // x3
  // ---- SAGE1: xcat=[mean(x3), x3] @ [Wl;Wr] + bl ----
  agg2_kernel<<<GW,BT,0,stream>>>(nb0,rowptr,srcS,invdeg,A_big);
  gemm_kernel<128><<<dim3(GB,1),BT,0,stream>>>(A_big,sage1_Wl,sage1_Wr,64,0,sage1_bl,nullptr,nb1,64,1); // xs
  // ---- SAGE2 ----
  agg2_kernel<<<GW,BT,0,stream>>>(nb1,rowptr,srcS,invdeg,A_big);
  gemm_kernel<128><<<dim3(GB,1),BT,0,stream>>>(A_big,sage2_Wl,sage2_Wr,64,0,sage2_bl,nullptr,nb0,64,1); // x4
  // ---- TransformerConv, all heads fused ----
  float* qv=A_big;                 // q, later overwritten by v
  float* kh=nb1;                   // k occupies nb1..nb4 [N,256]
  gemm_kernel<64><<<dim3(GB,4),BT,0,stream>>>(nb0,tr_Wq,nullptr,256,0,tr_bq,nullptr,qv,256,0);
  gemm_kernel<64><<<dim3(GB,4),BT,0,stream>>>(nb0,tr_Wk,nullptr,256,0,tr_bk,nullptr,kh,256,0);
  tr_logit4_kernel<<<cdiv(EE,4),BT,0,stream>>>(srcS,dstS,qv,kh,logitE);
  tr_softmax4_kernel<<<cdiv(NN,BT),BT,0,stream>>>(rowptr,logitE,zinv);
  gemm_kernel<64><<<dim3(GB,4),BT,0,stream>>>(nb0,tr_Wv,nullptr,256,0,tr_bv,nullptr,qv,256,0); // v over q
  gemm_kernel<64><<<dim3(GB,1),BT,0,stream>>>(nb0,tr_Ws,nullptr,64,0,tr_bs,nullptr,nb1,64,0);  // skip (k dead)
  tr_aggx5_kernel<<<GW,BT,0,stream>>>(rowptr,srcS,logitE,zinv,qv,nb1,nb2);             // x5
  // ---- EdgeConv ----
  edgeconv_kernel<<<EE/64,BT,0,stream>>>(nb2,srcS,dstS,ec_W1,ec_b1,ec_W2,ec_b2,(unsigned*)nb5);
  // ---- pool (emax decode fused) + MLP ----
  pool_kernel<<<25,BT,0,stream>>>((unsigned*)nb5,batch,pooled);
  final_kernel<<<1,BT,0,stream>>>(pooled,batch,fc1_W,fc1_b,fc2_W,fc2_b,(float*)d_out);
}

// Round 3
// 1409.560 us; speedup vs baseline: 1.6617x; 1.2554x over previous
//
#include <hip/hip_runtime.h>

#define NN 50000
#define EE 640000
#define GG 16
#define N64 (NN*64)

static inline int cdiv(int a,int b){return (a+b-1)/b;}

__device__ __forceinline__ float lrelu(float x){ return x>0.f? x : 0.2f*x; }
// monotonic float->uint encoding for atomicMax on floats
__device__ __forceinline__ unsigned fenc(float f){
  unsigned u=__float_as_uint(f);
  return (u&0x80000000u)? ~u : (u|0x80000000u);
}

// acc[0..3] += av . {w0..w3} columns
__device__ __forceinline__ void mac4(float* acc, const float4 av,
    const float4 w0, const float4 w1, const float4 w2, const float4 w3){
  acc[0]+=av.x*w0.x+av.y*w1.x+av.z*w2.x+av.w*w3.x;
  acc[1]+=av.x*w0.y+av.y*w1.y+av.z*w2.y+av.w*w3.y;
  acc[2]+=av.x*w0.z+av.y*w1.z+av.z*w2.z+av.w*w3.z;
  acc[3]+=av.x*w0.w+av.y*w1.w+av.z*w2.w+av.w*w3.w;
}

__global__ void zero_kernel(unsigned* p, int n){
  int i=blockIdx.x*blockDim.x+threadIdx.x;
  if(i<n) p[i]=0u;
}

__global__ void hist_kernel(const int* __restrict__ dst, int* __restrict__ cnt){
  int e=blockIdx.x*blockDim.x+threadIdx.x;
  if(e<EE) atomicAdd(&cnt[dst[e]],1);
}

// 3-stage scan: scan1 (per-1024-block shfl scan), scan2 (block sums), scan3 (add offsets)
__global__ __launch_bounds__(1024) void scan1_kernel(const int* __restrict__ cnt,
    int* __restrict__ rowptr, int* __restrict__ bsum){
  __shared__ int wsum[16];
  int t=threadIdx.x, b=blockIdx.x;
  int i=b*1024+t;
  int v=(i<NN)?cnt[i]:0;
  int lane=t&63, w=t>>6;
  int inc=v;
  #pragma unroll
  for(int o=1;o<64;o<<=1){ int u=__shfl_up(inc,o,64); if(lane>=o) inc+=u; }
  if(lane==63) wsum[w]=inc;
  __syncthreads();
  if(t<16){
    int s=wsum[t];
    #pragma unroll
    for(int o=1;o<16;o<<=1){ int u=__shfl_up(s,o,16); if(t>=o) s+=u; }
    wsum[t]=s;
  }
  __syncthreads();
  int woff=(w>0)?wsum[w-1]:0;
  if(i<NN) rowptr[i]=woff+inc-v;   // block-local exclusive
  if(t==1023) bsum[b]=wsum[15];
}

__global__ void scan2_kernel(const int* __restrict__ bsum, int* __restrict__ boff, int* __restrict__ rowptr, int nb){
  int t=threadIdx.x;  // 64 threads
  int v=(t<nb)?bsum[t]:0;
  int inc=v;
  #pragma unroll
  for(int o=1;o<64;o<<=1){ int u=__shfl_up(inc,o,64); if(t>=o) inc+=u; }
  if(t<nb) boff[t]=inc-v;
  if(t==63) rowptr[NN]=inc;
}

__global__ void scan3_kernel(int* __restrict__ rowptr, const int* __restrict__ boff){
  int i=blockIdx.x*blockDim.x+threadIdx.x;
  if(i<NN) rowptr[i]+=boff[i>>10];
}

__global__ void fill_kernel(const int* __restrict__ src, const int* __restrict__ dst,
                            const int* __restrict__ rowptr, int* __restrict__ fillp,
                            int* __restrict__ srcS, int* __restrict__ dstS){
  int e=blockIdx.x*blockDim.x+threadIdx.x;
  if(e>=EE) return;
  int d=dst[e];
  int p=rowptr[d]+atomicAdd(&fillp[d],1);
  srcS[p]=src[e]; dstS[p]=d;
}

__global__ void invdeg_kernel(const int* __restrict__ cnt, float* __restrict__ invdeg){
  int i=blockIdx.x*blockDim.x+threadIdx.x;
  if(i<NN) invdeg[i]=1.f/fmaxf((float)cnt[i],1.f);
}

// C[NN, ldc(+nc0 slice)] = act(A[NN,K] @ W[K, ldw](cols wc..) + bias + addend)
// If Wb != nullptr, rows >=64 of the combined weight come from Wb (rows 0..63 there).
// If lsO != nullptr: epilogue computes per-row dots with a_s/a_d for head=blockIdx.y.
template<int K>
__global__ __launch_bounds__(256) void gemm_kernel(
    const float* __restrict__ A, const float* __restrict__ W, const float* __restrict__ Wb,
    int ldw, int wcol0,
    const float* __restrict__ bias, const float* __restrict__ addend,
    float* __restrict__ C, int ldc, int relu_flag,
    const float* __restrict__ a_s, const float* __restrict__ a_d,
    float* __restrict__ lsO, float* __restrict__ ldO){
  __shared__ float As[64][68];
  __shared__ float Ws[64][64];
  const int m0=blockIdx.x*64;
  const int nc0=blockIdx.y*64;
  const int wc=wcol0+nc0;
  const int tid=threadIdx.x, tx=tid&15, ty=tid>>4;
  float acc[4][4];
  #pragma unroll
  for(int i=0;i<4;i++){
    #pragma unroll
    for(int j=0;j<4;j++) acc[i][j]=bias? bias[wc+tx*4+j]:0.f;
  }
  for(int k0=0;k0<K;k0+=64){
    const float* Wp=(Wb && k0>=64)? Wb : W;
    const int kb =(Wb && k0>=64)? k0-64 : k0;
    __syncthreads();
    #pragma unroll
    for(int it=0;it<4;it++){
      int linear=it*1024+tid*4;
      int m=linear>>6, k=linear&63;
      float4 v=make_float4(0.f,0.f,0.f,0.f);
      if(m0+m<NN) v=*(const float4*)(A+(size_t)(m0+m)*K+k0+k);
      *(float4*)&As[m][k]=v;
    }
    #pragma unroll
    for(int it=0;it<4;it++){
      int linear=it*1024+tid*4;
      int k=linear>>6, n=linear&63;
      *(float4*)&Ws[k][n]=*(const float4*)(Wp+(size_t)(kb+k)*ldw+wc+n);
    }
    __syncthreads();
    #pragma unroll 8
    for(int k=0;k<64;k+=4){
      float4 a0=*(float4*)&As[ty*4+0][k];
      float4 a1=*(float4*)&As[ty*4+1][k];
      float4 a2=*(float4*)&As[ty*4+2][k];
      float4 a3=*(float4*)&As[ty*4+3][k];
      float4 w0=*(float4*)&Ws[k+0][tx*4];
      float4 w1=*(float4*)&Ws[k+1][tx*4];
      float4 w2=*(float4*)&Ws[k+2][tx*4];
      float4 w3=*(float4*)&Ws[k+3][tx*4];
      mac4(acc[0],a0,w0,w1,w2,w3);
      mac4(acc[1],a1,w0,w1,w2,w3);
      mac4(acc[2],a2,w0,w1,w2,w3);
      mac4(acc[3],a3,w0,w1,w2,w3);
    }
  }
  float4 asv,adv;
  if(lsO){
    asv=*(const float4*)(a_s+(size_t)blockIdx.y*64+tx*4);
    adv=*(const float4*)(a_d+(size_t)blockIdx.y*64+tx*4);
  }
  #pragma unroll
  for(int i=0;i<4;i++){
    int m=m0+ty*4+i;
    bool valid=(m<NN);
    float r0=acc[i][0],r1=acc[i][1],r2=acc[i][2],r3=acc[i][3];
    if(valid){
      if(addend){
        const float4 ad=*(const float4*)(addend+(size_t)m*ldc+nc0+tx*4);
        r0+=ad.x; r1+=ad.y; r2+=ad.z; r3+=ad.w;
      }
      if(relu_flag){ r0=fmaxf(r0,0.f); r1=fmaxf(r1,0.f); r2=fmaxf(r2,0.f); r3=fmaxf(r3,0.f); }
      *(float4*)(C+(size_t)m*ldc+nc0+tx*4)=make_float4(r0,r1,r2,r3);
    }
    if(lsO){
      float ps=r0*asv.x+r1*asv.y+r2*asv.z+r3*asv.w;
      float pd=r0*adv.x+r1*adv.y+r2*adv.z+r3*adv.w;
      #pragma unroll
      for(int o=1;o<16;o<<=1){ ps+=__shfl_xor(ps,o,16); pd+=__shfl_xor(pd,o,16); }
      if(valid && tx==0){
        lsO[(size_t)m*4+blockIdx.y]=ps;
        ldO[(size_t)m*4+blockIdx.y]=pd;
      }
    }
  }
}

// fused GAT: per-node 2-pass (max; exp+gather-accumulate), self-loop included.
__global__ __launch_bounds__(256) void gat_fused_kernel(const float* __restrict__ h,
    const int* __restrict__ rowptr, const int* __restrict__ srcS,
    const float* __restrict__ ls4, const float* __restrict__ ld4,
    const float* __restrict__ bias, float* __restrict__ out){
  int n=blockIdx.x*4+(threadIdx.x>>6);
  int lane=threadIdx.x&63;
  if(n>=NN) return;
  int r0=rowptr[n], r1=rowptr[n+1];
  const float4 ldv=*(const float4*)(ld4+(size_t)4*n);
  const float4 lsv=*(const float4*)(ls4+(size_t)4*n);
  float sl0=lrelu(lsv.x+ldv.x), sl1=lrelu(lsv.y+ldv.y);
  float sl2=lrelu(lsv.z+ldv.z), sl3=lrelu(lsv.w+ldv.w);
  float m0=sl0,m1=sl1,m2=sl2,m3=sl3;
  for(int j=r0;j<r1;j++){
    const float4 a=*(const float4*)(ls4+(size_t)4*srcS[j]);
    m0=fmaxf(m0,lrelu(a.x+ldv.x)); m1=fmaxf(m1,lrelu(a.y+ldv.y));
    m2=fmaxf(m2,lrelu(a.z+ldv.z)); m3=fmaxf(m3,lrelu(a.w+ldv.w));
  }
  float z0=__expf(sl0-m0), z1=__expf(sl1-m1), z2=__expf(sl2-m2), z3=__expf(sl3-m3);
  const float* hn=h+(size_t)n*256;
  float a0=z0*hn[lane], a1=z1*hn[64+lane], a2=z2*hn[128+lane], a3=z3*hn[192+lane];
  int j=r0;
  for(; j+1<r1; j+=2){
    int s0=srcS[j], s1=srcS[j+1];
    const float4 A0=*(const float4*)(ls4+(size_t)4*s0);
    const float4 A1=*(const float4*)(ls4+(size_t)4*s1);
    const float* h0=h+(size_t)s0*256;
    const float* h1=h+(size_t)s1*256;
    float e00=__expf(lrelu(A0.x+ldv.x)-m0), e01=__expf(lrelu(A0.y+ldv.y)-m1);
    float e02=__expf(lrelu(A0.z+ldv.z)-m2), e03=__expf(lrelu(A0.w+ldv.w)-m3);
    float e10=__expf(lrelu(A1.x+ldv.x)-m0), e11=__expf(lrelu(A1.y+ldv.y)-m1);
    float e12=__expf(lrelu(A1.z+ldv.z)-m2), e13=__expf(lrelu(A1.w+ldv.w)-m3);
    z0+=e00+e10; z1+=e01+e11; z2+=e02+e12; z3+=e03+e13;
    float v00=h0[lane], v01=h0[64+lane], v02=h0[128+lane], v03=h0[192+lane];
    float v10=h1[lane], v11=h1[64+lane], v12=h1[128+lane], v13=h1[192+lane];
    a0+=e00*v00+e10*v10; a1+=e01*v01+e11*v11;
    a2+=e02*v02+e12*v12; a3+=e03*v03+e13*v13;
  }
  if(j<r1){
    int s0=srcS[j];
    const float4 A0=*(const float4*)(ls4+(size_t)4*s0);
    const float* h0=h+(size_t)s0*256;
    float e00=__expf(lrelu(A0.x+ldv.x)-m0), e01=__expf(lrelu(A0.y+ldv.y)-m1);
    float e02=__expf(lrelu(A0.z+ldv.z)-m2), e03=__expf(lrelu(A0.w+ldv.w)-m3);
    z0+=e00; z1+=e01; z2+=e02; z3+=e03;
    a0+=e00*h0[lane]; a1+=e01*h0[64+lane]; a2+=e02*h0[128+lane]; a3+=e03*h0[192+lane];
  }
  float zi0=1.f/(z0+1e-16f), zi1=1.f/(z1+1e-16f), zi2=1.f/(z2+1e-16f), zi3=1.f/(z3+1e-16f);
  out[(size_t)n*64+lane]=fmaxf(0.25f*(a0*zi0+a1*zi1+a2*zi2+a3*zi3)+bias[lane],0.f);
}

// GIN: self + sum -> out[N,64] (unrolled gather)
__global__ __launch_bounds__(256) void agg_kernel(const float* __restrict__ xin,
    const int* __restrict__ rowptr, const int* __restrict__ srcS,
    float* __restrict__ out){
  int n=blockIdx.x*4+(threadIdx.x>>6);
  int lane=threadIdx.x&63;
  if(n>=NN) return;
  int r0=rowptr[n], r1=rowptr[n+1];
  float acc=xin[(size_t)n*64+lane];
  int j=r0;
  for(; j+1<r1; j+=2){
    int s0=srcS[j], s1=srcS[j+1];
    acc+=xin[(size_t)s0*64+lane]+xin[(size_t)s1*64+lane];
  }
  if(j<r1) acc+=xin[(size_t)srcS[j]*64+lane];
  out[(size_t)n*64+lane]=acc;
}

// SAGE staging: out128[n] = [ mean_neigh(xin), xin[n] ]
__global__ __launch_bounds__(256) void agg2_kernel(const float* __restrict__ xin,
    const int* __restrict__ rowptr, const int* __restrict__ srcS,
    const float* __restrict__ invdeg, float* __restrict__ out128){
  int n=blockIdx.x*4+(threadIdx.x>>6);
  int lane=threadIdx.x&63;
  if(n>=NN) return;
  int r0=rowptr[n], r1=rowptr[n+1];
  float acc=0.f;
  int j=r0;
  for(; j+1<r1; j+=2){
    int s0=srcS[j], s1=srcS[j+1];
    acc+=xin[(size_t)s0*64+lane]+xin[(size_t)s1*64+lane];
  }
  if(j<r1) acc+=xin[(size_t)srcS[j]*64+lane];
  out128[(size_t)n*128+lane]=acc*invdeg[n];
  out128[(size_t)n*128+64+lane]=xin[(size_t)n*64+lane];
}

// all-head q.k dots: one wave per edge, q/k are [N,256]
__global__ __launch_bounds__(256) void tr_logit4_kernel(const int* __restrict__ srcS, const int* __restrict__ dstS,
    const float* __restrict__ q, const float* __restrict__ k, float* __restrict__ lg){
  int j=blockIdx.x*4+(threadIdx.x>>6);
  int lane=threadIdx.x&63;
  if(j>=EE) return;
  int s=srcS[j], d=dstS[j];
  const float* qd=q+(size_t)d*256;
  const float* ks=k+(size_t)s*256;
  float v[4];
  #pragma unroll
  for(int hh=0;hh<4;hh++) v[hh]=qd[hh*64+lane]*ks[hh*64+lane];
  #pragma unroll
  for(int o=32;o>0;o>>=1){
    #pragma unroll
    for(int hh=0;hh<4;hh++) v[hh]+=__shfl_xor(v[hh],o,64);
  }
  if(lane==0)
    *(float4*)(lg+4*j)=make_float4(v[0]*0.125f,v[1]*0.125f,v[2]*0.125f,v[3]*0.125f);
}

// fused TR: per-node 2-pass softmax + v-gather + skip + relu -> x5
__global__ __launch_bounds__(256) void tr_fused_kernel(const int* __restrict__ rowptr, const int* __restrict__ srcS,
    const float* __restrict__ lg, const float* __restrict__ v,
    const float* __restrict__ skip, float* __restrict__ x5){
  int n=blockIdx.x*4+(threadIdx.x>>6);
  int lane=threadIdx.x&63;
  if(n>=NN) return;
  int r0=rowptr[n], r1=rowptr[n+1];
  float m0=-1e30f,m1=-1e30f,m2=-1e30f,m3=-1e30f;
  for(int j=r0;j<r1;j++){
    const float4 f=*(const float4*)(lg+(size_t)4*j);
    m0=fmaxf(m0,f.x); m1=fmaxf(m1,f.y); m2=fmaxf(m2,f.z); m3=fmaxf(m3,f.w);
  }
  float z0=0.f,z1=0.f,z2=0.f,z3=0.f;
  float a0=0.f,a1=0.f,a2=0.f,a3=0.f;
  int j=r0;
  for(; j+1<r1; j+=2){
    int s0=srcS[j], s1=srcS[j+1];
    const float4 f0=*(const float4*)(lg+(size_t)4*j);
    const float4 f1=*(const float4*)(lg+(size_t)4*(j+1));
    const float* v0=v+(size_t)s0*256;
    const float* v1=v+(size_t)s1*256;
    float e00=__expf(f0.x-m0), e01=__expf(f0.y-m1), e02=__expf(f0.z-m2), e03=__expf(f0.w-m3);
    float e10=__expf(f1.x-m0), e11=__expf(f1.y-m1), e12=__expf(f1.z-m2), e13=__expf(f1.w-m3);
    z0+=e00+e10; z1+=e01+e11; z2+=e02+e12; z3+=e03+e13;
    a0+=e00*v0[lane]+e10*v1[lane];
    a1+=e01*v0[64+lane]+e11*v1[64+lane];
    a2+=e02*v0[128+lane]+e12*v1[128+lane];
    a3+=e03*v0[192+lane]+e13*v1[192+lane];
  }
  if(j<r1){
    int s0=srcS[j];
    const float4 f0=*(const float4*)(lg+(size_t)4*j);
    const float* v0=v+(size_t)s0*256;
    float e00=__expf(f0.x-m0), e01=__expf(f0.y-m1), e02=__expf(f0.z-m2), e03=__expf(f0.w-m3);
    z0+=e00; z1+=e01; z2+=e02; z3+=e03;
    a0+=e00*v0[lane]; a1+=e01*v0[64+lane]; a2+=e02*v0[128+lane]; a3+=e03*v0[192+lane];
  }
  float zi0=1.f/(z0+1e-16f), zi1=1.f/(z1+1e-16f), zi2=1.f/(z2+1e-16f), zi3=1.f/(z3+1e-16f);
  float t=0.25f*(a0*zi0+a1*zi1+a2*zi2+a3*zi3)+skip[(size_t)n*64+lane];
  x5[(size_t)n*64+lane]=fmaxf(t,0.f);
}

// fused EdgeConv: feat gather -> GEMM1(+b1,relu) -> GEMM2(+b2) -> run-merged atomicMax to emax
__global__ __launch_bounds__(256) void edgeconv_kernel(const float* __restrict__ x5,
    const int* __restrict__ srcS, const int* __restrict__ dstS,
    const float* __restrict__ W1, const float* __restrict__ b1,
    const float* __restrict__ W2, const float* __restrict__ b2,
    unsigned* __restrict__ emax){
  __shared__ float As[64][68];   // feat tile, then reused as hidden tile
  __shared__ float Ws[64][64];
  const int e0=blockIdx.x*64;
  const int tid=threadIdx.x, tx=tid&15, ty=tid>>4;
  float acc[4][4];
  #pragma unroll
  for(int i=0;i<4;i++)
    #pragma unroll
    for(int j=0;j<4;j++) acc[i][j]=b1[tx*4+j];
  for(int c=0;c<2;c++){
    __syncthreads();
    #pragma unroll
    for(int it=0;it<4;it++){
      int linear=it*1024+tid*4;
      int m=linear>>6, k=linear&63;
      int e=e0+m;
      float4 v=make_float4(0.f,0.f,0.f,0.f);
      if(e<EE){
        int dn=dstS[e];
        float4 xi=*(const float4*)(x5+(size_t)dn*64+k);
        if(c==0) v=xi;
        else{
          int sn=srcS[e];
          float4 xj=*(const float4*)(x5+(size_t)sn*64+k);
          v=make_float4(xj.x-xi.x,xj.y-xi.y,xj.z-xi.z,xj.w-xi.w);
        }
      }
      *(float4*)&As[m][k]=v;
    }
    #pragma unroll
    for(int it=0;it<4;it++){
      int linear=it*1024+tid*4;
      int k=linear>>6, n=linear&63;
      *(float4*)&Ws[k][n]=*(const float4*)(W1+(size_t)(c*64+k)*64+n);
    }
    __syncthreads();
    #pragma unroll 8
    for(int k=0;k<64;k+=4){
      float4 a0=*(float4*)&As[ty*4+0][k];
      float4 a1=*(float4*)&As[ty*4+1][k];
      float4 a2=*(float4*)&As[ty*4+2][k];
      float4 a3=*(float4*)&As[ty*4+3][k];
      float4 w0=*(float4*)&Ws[k+0][tx*4];
      float4 w1=*(float4*)&Ws[k+1][tx*4];
      float4 w2=*(float4*)&Ws[k+2][tx*4];
      float4 w3=*(float4*)&Ws[k+3][tx*4];
      mac4(acc[0],a0,w0,w1,w2,w3);
      mac4(acc[1],a1,w0,w1,w2,w3);
      mac4(acc[2],a2,w0,w1,w2,w3);
      mac4(acc[3],a3,w0,w1,w2,w3);
    }
  }
  __syncthreads();
  #pragma unroll
  for(int i=0;i<4;i++)
    #pragma unroll
    for(int j=0;j<4;j++)
      As[ty*4+i][tx*4+j]=fmaxf(acc[i][j],0.f);   // hidden (relu) into As
  #pragma unroll
  for(int it=0;it<4;it++){
    int linear=it*1024+tid*4;
    int k=linear>>6, n=linear&63;
    *(float4*)&Ws[k][n]=*(const float4*)(W2+(size_t)k*64+n);
  }
  __syncthreads();
  float acc2[4][4];
  #pragma unroll
  for(int i=0;i<4;i++)
    #pragma unroll
    for(int j=0;j<4;j++) acc2[i][j]=b2[tx*4+j];
  #pragma unroll 8
  for(int k=0;k<64;k+=4){
    float4 a0=*(float4*)&As[ty*4+0][k];
    float4 a1=*(float4*)&As[ty*4+1][k];
    float4 a2=*(float4*)&As[ty*4+2][k];
    float4 a3=*(float4*)&As[ty*4+3][k];
    float4 w0=*(float4*)&Ws[k+0][tx*4];
    float4 w1=*(float4*)&Ws[k+1][tx*4];
    float4 w2=*(float4*)&Ws[k+2][tx*4];
    float4 w3=*(float4*)&Ws[k+3][tx*4];
    mac4(acc2[0],a0,w0,w1,w2,w3);
    mac4(acc2[1],a1,w0,w1,w2,w3);
    mac4(acc2[2],a2,w0,w1,w2,w3);
    mac4(acc2[3],a3,w0,w1,w2,w3);
  }
  // run-merge consecutive rows with same dst, then atomicMax
  int dprev=-1;
  float mx0=0,mx1=0,mx2=0,mx3=0;
  #pragma unroll
  for(int i=0;i<4;i++){
    int e=e0+ty*4+i;
    if(e>=EE) continue;
    int dn=dstS[e];
    if(dn!=dprev){
      if(dprev>=0){
        atomicMax(&emax[(size_t)dprev*64+tx*4+0],fenc(mx0));
        atomicMax(&emax[(size_t)dprev*64+tx*4+1],fenc(mx1));
        atomicMax(&emax[(size_t)dprev*64+tx*4+2],fenc(mx2));
        atomicMax(&emax[(size_t)dprev*64+tx*4+3],fenc(mx3));
      }
      dprev=dn; mx0=acc2[i][0]; mx1=acc2[i][1]; mx2=acc2[i][2]; mx3=acc2[i][3];
    }else{
      mx0=fmaxf(mx0,acc2[i][0]); mx1=fmaxf(mx1,acc2[i][1]);
      mx2=fmaxf(mx2,acc2[i][2]); mx3=fmaxf(mx3,acc2[i][3]);
    }
  }
  if(dprev>=0){
    atomicMax(&emax[(size_t)dprev*64+tx*4+0],fenc(mx0));
    atomicMax(&emax[(size_t)dprev*64+tx*4+1],fenc(mx1));
    atomicMax(&emax[(size_t)dprev*64+tx*4+2],fenc(mx2));
    atomicMax(&emax[(size_t)dprev*64+tx*4+3],fenc(mx3));
  }
}

// pool with emax decode fused: x6 = relu(decode(emax)); pooled[g] += x6
__global__ __launch_bounds__(256) void pool_kernel(const unsigned* __restrict__ emax, const int* __restrict__ batch,
                                                   float* __restrict__ pooled){
  const int NB=200;
  int base=blockIdx.x*NB;
  int lane=threadIdx.x&63;
  int wsub=threadIdx.x>>6;
  float acc=0.f; int curg=-1;
  for(int idx=wsub; idx<NB; idx+=4){
    int n=base+idx;
    if(n>=NN) break;
    int g=batch[n];
    if(g!=curg){
      if(curg>=0) atomicAdd(&pooled[curg*64+lane],acc);
      acc=0.f; curg=g;
    }
    unsigned u=emax[(size_t)n*64+lane];
    acc+=(u>=0x80000000u)? __uint_as_float(u&0x7fffffffu) : 0.f;
  }
  if(curg>=0) atomicAdd(&pooled[curg*64+lane],acc);
}

__global__ __launch_bounds__(256) void final_kernel(const float* __restrict__ pooled, const int* __restrict__ batch,
    const float* __restrict__ fc1W, const float* __restrict__ fc1b,
    const float* __restrict__ fc2W, const float* __restrict__ fc2b,
    float* __restrict__ out){
  __shared__ float gm[16][64];
  __shared__ float t1[16][64];
  __shared__ int cgs[17];
  int t=threadIdx.x;
  if(t<17){
    int lo=0, hi=NN;
    while(lo<hi){ int mid=(lo+hi)>>1; if(batch[mid]<t) lo=mid+1; else hi=mid; }
    cgs[t]=lo;
  }
  __syncthreads();
  for(int r=0;r<4;r++){
    int idx=r*256+t; int g=idx>>6, d=idx&63;
    float c=(float)(cgs[g+1]-cgs[g]);
    gm[g][d]=pooled[idx]/fmaxf(c,1.f);
  }
  __syncthreads();
  for(int r=0;r<4;r++){
    int idx=r*256+t; int g=idx>>6, d=idx&63;
    float a=fc1b[d];
    for(int k2=0;k2<64;k2++) a+=gm[g][k2]*fc1W[k2*64+d];
    t1[g][d]=fmaxf(a,0.f);
  }
  __syncthreads();
  for(int r=0;r<4;r++){
    int idx=r*256+t; int g=idx>>6, d=idx&63;
    float a=fc2b[d];
    for(int k2=0;k2<64;k2++) a+=t1[g][k2]*fc2W[k2*64+d];
    out[idx]=a;
  }
}

extern "C" void kernel_launch(void* const* d_in, const int* in_sizes, int n_in,
                              void* d_out, int out_size, void* d_ws, size_t ws_size,
                              hipStream_t stream){
  const float* x       =(const float*)d_in[0];
  const int*   ei      =(const int*)  d_in[1];
  const int*   src     =ei;
  const int*   dst     =ei+EE;
  const int*   batch   =(const int*)  d_in[2];
  const float* gat1_W  =(const float*)d_in[3];
  const float* gat1_as =(const float*)d_in[4];
  const float* gat1_ad =(const float*)d_in[5];
  const float* gat1_b  =(const float*)d_in[6];
  const float* gat2_W  =(const float*)d_in[7];
  const float* gat2_as =(const float*)d_in[8];
  const float* gat2_ad =(const float*)d_in[9];
  const float* gat2_b  =(const float*)d_in[10];
  const float* gin_W1  =(const float*)d_in[11];
  const float* gin_b1  =(const float*)d_in[12];
  const float* gin_W2  =(const float*)d_in[13];
  const float* gin_b2  =(const float*)d_in[14];
  const float* sage1_Wl=(const float*)d_in[15];
  const float* sage1_bl=(const float*)d_in[16];
  const float* sage1_Wr=(const float*)d_in[17];
  const float* sage2_Wl=(const float*)d_in[18];
  const float* sage2_bl=(const float*)d_in[19];
  const float* sage2_Wr=(const float*)d_in[20];
  const float* tr_Wq   =(const float*)d_in[21];
  const float* tr_bq   =(const float*)d_in[22];
  const float* tr_Wk   =(const float*)d_in[23];
  const float* tr_bk   =(const float*)d_in[24];
  const float* tr_Wv   =(const float*)d_in[25];
  const float* tr_bv   =(const float*)d_in[26];
  const float* tr_Ws   =(const float*)d_in[27];
  const float* tr_bs   =(const float*)d_in[28];
  const float* ec_W1   =(const float*)d_in[29];
  const float* ec_b1   =(const float*)d_in[30];
  const float* ec_W2   =(const float*)d_in[31];
  const float* ec_b2   =(const float*)d_in[32];
  const float* fc1_W   =(const float*)d_in[33];
  const float* fc1_b   =(const float*)d_in[34];
  const float* fc2_W   =(const float*)d_in[35];
  const float* fc2_b   =(const float*)d_in[36];

  // ---- workspace layout (floats first, then ints) ----
  float* base=(float*)d_ws;
  size_t off=0;
  auto alloc=[&](size_t n){ float* p=base+off; off+=n; return p; };
  float* A_big =alloc((size_t)NN*256);     // GAT h / TR q / TR v / SAGE xcat
  float* nb0   =alloc(N64);
  float* nb1   =alloc(N64);                // nb1..nb4 contiguous: also TR k [N,256]
  float* nb2   =alloc(N64);
  float* nb3   =alloc(N64);
  float* nb4   =alloc(N64);
  float* nb5   =alloc(N64);                // emax (as unsigned, zeroed)
  float* logitE=alloc((size_t)EE*4);
  float* ls    =alloc(NN*4);
  float* ldb   =alloc(NN*4);
  float* invdeg=alloc(NN);
  float* pooled=alloc(GG*64);
  int* ibase=(int*)(base+off);
  int* srcS  =ibase;
  int* dstS  =ibase+EE;
  int* cnt   =ibase+2*EE;
  int* fillp =ibase+2*EE+NN;               // cnt,fillp contiguous (zeroed together)
  int* rowptr=ibase+2*EE+2*NN;             // NN+1 ints
  int* bsum  =ibase+2*EE+3*NN+8;           // 49 ints
  int* boff  =bsum+64;                     // 49 ints

  const int BT=256;
  const int NSB=cdiv(NN,1024);             // 49 scan blocks
  // ---- zero init (cnt+fillp contiguous) ----
  zero_kernel<<<cdiv(2*NN,BT),BT,0,stream>>>((unsigned*)cnt,2*NN);
  zero_kernel<<<cdiv(GG*64,BT),BT,0,stream>>>((unsigned*)pooled,GG*64);
  zero_kernel<<<cdiv(N64,BT),BT,0,stream>>>((unsigned*)nb5,N64);
  // ---- CSR ----
  hist_kernel<<<cdiv(EE,BT),BT,0,stream>>>(dst,cnt);
  scan1_kernel<<<NSB,1024,0,stream>>>(cnt,rowptr,bsum);
  scan2_kernel<<<1,64,0,stream>>>(bsum,boff,rowptr,NSB);
  scan3_kernel<<<cdiv(NN,BT),BT,0,stream>>>(rowptr,boff);
  fill_kernel<<<cdiv(EE,BT),BT,0,stream>>>(src,dst,rowptr,fillp,srcS,dstS);
  invdeg_kernel<<<cdiv(NN,BT),BT,0,stream>>>(cnt,invdeg);

  const int GB=cdiv(NN,64);        // 782 row tiles
  const int GW=cdiv(NN,4);         // wave-per-node blocks (12500)

  // ---- GAT1 (attn dots fused in GEMM epilogue) ----
  gemm_kernel<128><<<dim3(GB,4),BT,0,stream>>>(x,gat1_W,nullptr,256,0,nullptr,nullptr,A_big,256,0,
                                               gat1_as,gat1_ad,ls,ldb);
  gat_fused_kernel<<<GW,BT,0,stream>>>(A_big,rowptr,srcS,ls,ldb,gat1_b,nb0);           // x1
  // ---- GAT2 ----
  gemm_kernel<64><<<dim3(GB,4),BT,0,stream>>>(nb0,gat2_W,nullptr,256,0,nullptr,nullptr,A_big,256,0,
                                              gat2_as,gat2_ad,ls,ldb);
  gat_fused_kernel<<<GW,BT,0,stream>>>(A_big,rowptr,srcS,ls,ldb,gat2_b,nb1);           // x2
  // ---- GIN ----
  agg_kernel<<<GW,BT,0,stream>>>(nb1,rowptr,srcS,nb2);                                 // t = x2+agg
  gemm_kernel<64><<<dim3(GB,1),BT,0,stream>>>(nb2,gin_W1,nullptr,64,0,gin_b1,nullptr,nb3,64,1,
                                              nullptr,nullptr,nullptr,nullptr);
  gemm_kernel<64><<<dim3(GB,1),BT,0,stream>>>(nb3,gin_W2,nullptr,64,0,gin_b2,nullptr,nb0,64,1,
                                              nullptr,nullptr,nullptr,nullptr);        // x3
  // ---- SAGE1: xcat=[mean(x3), x3] @ [Wl;Wr] + bl ----
  agg2_kernel<<<GW,BT,0,stream>>>(nb0,rowptr,srcS,invdeg,A_big);
  gemm_kernel<128><<<dim3(GB,1),BT,0,stream>>>(A_big,sage1_Wl,sage1_Wr,64,0,sage1_bl,nullptr,nb1,64,1,
                                               nullptr,nullptr,nullptr,nullptr);       // xs
  // ---- SAGE2 ----
  agg2_kernel<<<GW,BT,0,stream>>>(nb1,rowptr,srcS,invdeg,A_big);
  gemm_kernel<128><<<dim3(GB,1),BT,0,stream>>>(A_big,sage2_Wl,sage2_Wr,64,0,sage2_bl,nullptr,nb0,64,1,
                                               nullptr,nullptr,nullptr,nullptr);       // x4
  // ---- TransformerConv, all heads fused ----
  float* qv=A_big;                 // q, later overwritten by v
  float* kh=nb1;                   // k occupies nb1..nb4 [N,256]
  gemm_kernel<64><<<dim3(GB,4),BT,0,stream>>>(nb0,tr_Wq,nullptr,256,0,tr_bq,nullptr,qv,256,0,
                                              nullptr,nullptr,nullptr,nullptr);
  gemm_kernel<64><<<dim3(GB,4),BT,0,stream>>>(nb0,tr_Wk,nullptr,256,0,tr_bk,nullptr,kh,256,0,
                                              nullptr,nullptr,nullptr,nullptr);
  tr_logit4_kernel<<<cdiv(EE,4),BT,0,stream>>>(srcS,dstS,qv,kh,logitE);
  gemm_kernel<64><<<dim3(GB,4),BT,0,stream>>>(nb0,tr_Wv,nullptr,256,0,tr_bv,nullptr,qv,256,0,
                                              nullptr,nullptr,nullptr,nullptr);        // v over q
  gemm_kernel<64><<<dim3(GB,1),BT,0,stream>>>(nb0,tr_Ws,nullptr,64,0,tr_bs,nullptr,nb1,64,0,
                                              nullptr,nullptr,nullptr,nullptr);        // skip (k dead)
  tr_fused_kernel<<<GW,BT,0,stream>>>(rowptr,srcS,logitE,qv,nb1,nb2);                  // x5
  // ---- EdgeConv ----
  edgeconv_kernel<<<EE/64,BT,0,stream>>>(nb2,srcS,dstS,ec_W1,ec_b1,ec_W2,ec_b2,(unsigned*)nb5);
  // ---- pool (emax decode fused) + MLP ----
  pool_kernel<<<cdiv(NN,200),BT,0,stream>>>((unsigned*)nb5,batch,pooled);
  final_kernel<<<1,BT,0,stream>>>(pooled,batch,fc1_W,fc1_b,fc2_W,fc2_b,(float*)d_out);
}

// Round 4
// 1369.097 us; speedup vs baseline: 1.7108x; 1.0296x over previous
//
#include <hip/hip_runtime.h>

#define NN 50000
#define EE 640000
#define GG 16
#define N64 (NN*64)

static inline int cdiv(int a,int b){return (a+b-1)/b;}

__device__ __forceinline__ float lrelu(float x){ return x>0.f? x : 0.2f*x; }
// monotonic float->uint encoding for atomicMax on floats
__device__ __forceinline__ unsigned fenc(float f){
  unsigned u=__float_as_uint(f);
  return (u&0x80000000u)? ~u : (u|0x80000000u);
}

// acc[0..3] += av . {w0..w3} columns
__device__ __forceinline__ void mac4(float* acc, const float4 av,
    const float4 w0, const float4 w1, const float4 w2, const float4 w3){
  acc[0]+=av.x*w0.x+av.y*w1.x+av.z*w2.x+av.w*w3.x;
  acc[1]+=av.x*w0.y+av.y*w1.y+av.z*w2.y+av.w*w3.y;
  acc[2]+=av.x*w0.z+av.y*w1.z+av.z*w2.z+av.w*w3.z;
  acc[3]+=av.x*w0.w+av.y*w1.w+av.z*w2.w+av.w*w3.w;
}

__global__ void zero_kernel(unsigned* p, int n){
  int i=blockIdx.x*blockDim.x+threadIdx.x;
  if(i<n) p[i]=0u;
}

__global__ void hist_kernel(const int* __restrict__ dst, int* __restrict__ cnt){
  int e=blockIdx.x*blockDim.x+threadIdx.x;
  if(e<EE) atomicAdd(&cnt[dst[e]],1);
}

// 3-stage scan
__global__ __launch_bounds__(1024) void scan1_kernel(const int* __restrict__ cnt,
    int* __restrict__ rowptr, int* __restrict__ bsum){
  __shared__ int wsum[16];
  int t=threadIdx.x, b=blockIdx.x;
  int i=b*1024+t;
  int v=(i<NN)?cnt[i]:0;
  int lane=t&63, w=t>>6;
  int inc=v;
  #pragma unroll
  for(int o=1;o<64;o<<=1){ int u=__shfl_up(inc,o,64); if(lane>=o) inc+=u; }
  if(lane==63) wsum[w]=inc;
  __syncthreads();
  if(t<16){
    int s=wsum[t];
    #pragma unroll
    for(int o=1;o<16;o<<=1){ int u=__shfl_up(s,o,16); if(t>=o) s+=u; }
    wsum[t]=s;
  }
  __syncthreads();
  int woff=(w>0)?wsum[w-1]:0;
  if(i<NN) rowptr[i]=woff+inc-v;   // block-local exclusive
  if(t==1023) bsum[b]=wsum[15];
}

__global__ void scan2_kernel(const int* __restrict__ bsum, int* __restrict__ boff, int* __restrict__ rowptr, int nb){
  int t=threadIdx.x;  // 64 threads
  int v=(t<nb)?bsum[t]:0;
  int inc=v;
  #pragma unroll
  for(int o=1;o<64;o<<=1){ int u=__shfl_up(inc,o,64); if(t>=o) inc+=u; }
  if(t<nb) boff[t]=inc-v;
  if(t==63) rowptr[NN]=inc;
}

__global__ void scan3_kernel(int* __restrict__ rowptr, const int* __restrict__ boff){
  int i=blockIdx.x*blockDim.x+threadIdx.x;
  if(i<NN) rowptr[i]+=boff[i>>10];
}

__global__ void fill_kernel(const int* __restrict__ src, const int* __restrict__ dst,
                            const int* __restrict__ rowptr, int* __restrict__ fillp,
                            int* __restrict__ srcS, int* __restrict__ dstS){
  int e=blockIdx.x*blockDim.x+threadIdx.x;
  if(e>=EE) return;
  int d=dst[e];
  int p=rowptr[d]+atomicAdd(&fillp[d],1);
  srcS[p]=src[e]; dstS[p]=d;
}

__global__ void invdeg_kernel(const int* __restrict__ cnt, float* __restrict__ invdeg){
  int i=blockIdx.x*blockDim.x+threadIdx.x;
  if(i<NN) invdeg[i]=1.f/fmaxf((float)cnt[i],1.f);
}

// Wd[k][n] = W1[k][n] - W1[64+k][n]   (64x64)
__global__ void wd_kernel(const float* __restrict__ W1, float* __restrict__ Wd){
  int i=blockIdx.x*blockDim.x+threadIdx.x;
  if(i<4096) Wd[i]=W1[i]-W1[4096+i];
}

// C[NN, ldc(+nc0 slice)] = act(A[NN,K] @ W[K, ldw](cols wc..) + bias + addend)
// Wb: rows >=64 of combined weight. lsO: fused GAT attn-dot epilogue (head=blockIdx.y).
template<int K>
__global__ __launch_bounds__(256) void gemm_kernel(
    const float* __restrict__ A, const float* __restrict__ W, const float* __restrict__ Wb,
    int ldw, int wcol0,
    const float* __restrict__ bias, const float* __restrict__ addend,
    float* __restrict__ C, int ldc, int relu_flag,
    const float* __restrict__ a_s, const float* __restrict__ a_d,
    float* __restrict__ lsO, float* __restrict__ ldO){
  __shared__ float As[64][68];
  __shared__ float Ws[64][64];
  const int m0=blockIdx.x*64;
  const int nc0=blockIdx.y*64;
  const int wc=wcol0+nc0;
  const int tid=threadIdx.x, tx=tid&15, ty=tid>>4;
  float acc[4][4];
  #pragma unroll
  for(int i=0;i<4;i++){
    #pragma unroll
    for(int j=0;j<4;j++) acc[i][j]=bias? bias[wc+tx*4+j]:0.f;
  }
  for(int k0=0;k0<K;k0+=64){
    const float* Wp=(Wb && k0>=64)? Wb : W;
    const int kb =(Wb && k0>=64)? k0-64 : k0;
    __syncthreads();
    #pragma unroll
    for(int it=0;it<4;it++){
      int linear=it*1024+tid*4;
      int m=linear>>6, k=linear&63;
      float4 v=make_float4(0.f,0.f,0.f,0.f);
      if(m0+m<NN) v=*(const float4*)(A+(size_t)(m0+m)*K+k0+k);
      *(float4*)&As[m][k]=v;
    }
    #pragma unroll
    for(int it=0;it<4;it++){
      int linear=it*1024+tid*4;
      int k=linear>>6, n=linear&63;
      *(float4*)&Ws[k][n]=*(const float4*)(Wp+(size_t)(kb+k)*ldw+wc+n);
    }
    __syncthreads();
    #pragma unroll 8
    for(int k=0;k<64;k+=4){
      float4 a0=*(float4*)&As[ty*4+0][k];
      float4 a1=*(float4*)&As[ty*4+1][k];
      float4 a2=*(float4*)&As[ty*4+2][k];
      float4 a3=*(float4*)&As[ty*4+3][k];
      float4 w0=*(float4*)&Ws[k+0][tx*4];
      float4 w1=*(float4*)&Ws[k+1][tx*4];
      float4 w2=*(float4*)&Ws[k+2][tx*4];
      float4 w3=*(float4*)&Ws[k+3][tx*4];
      mac4(acc[0],a0,w0,w1,w2,w3);
      mac4(acc[1],a1,w0,w1,w2,w3);
      mac4(acc[2],a2,w0,w1,w2,w3);
      mac4(acc[3],a3,w0,w1,w2,w3);
    }
  }
  float4 asv,adv;
  if(lsO){
    asv=*(const float4*)(a_s+(size_t)blockIdx.y*64+tx*4);
    adv=*(const float4*)(a_d+(size_t)blockIdx.y*64+tx*4);
  }
  #pragma unroll
  for(int i=0;i<4;i++){
    int m=m0+ty*4+i;
    bool valid=(m<NN);
    float r0=acc[i][0],r1=acc[i][1],r2=acc[i][2],r3=acc[i][3];
    if(valid){
      if(addend){
        const float4 ad=*(const float4*)(addend+(size_t)m*ldc+nc0+tx*4);
        r0+=ad.x; r1+=ad.y; r2+=ad.z; r3+=ad.w;
      }
      if(relu_flag){ r0=fmaxf(r0,0.f); r1=fmaxf(r1,0.f); r2=fmaxf(r2,0.f); r3=fmaxf(r3,0.f); }
      *(float4*)(C+(size_t)m*ldc+nc0+tx*4)=make_float4(r0,r1,r2,r3);
    }
    if(lsO){
      float ps=r0*asv.x+r1*asv.y+r2*asv.z+r3*asv.w;
      float pd=r0*adv.x+r1*adv.y+r2*adv.z+r3*adv.w;
      #pragma unroll
      for(int o=1;o<16;o<<=1){ ps+=__shfl_xor(ps,o,16); pd+=__shfl_xor(pd,o,16); }
      if(valid && tx==0){
        lsO[(size_t)m*4+blockIdx.y]=ps;
        ldO[(size_t)m*4+blockIdx.y]=pd;
      }
    }
  }
}

// fused GAT: per-node 2-pass (max; exp+gather-accumulate), self-loop included.
__global__ __launch_bounds__(256) void gat_fused_kernel(const float* __restrict__ h,
    const int* __restrict__ rowptr, const int* __restrict__ srcS,
    const float* __restrict__ ls4, const float* __restrict__ ld4,
    const float* __restrict__ bias, float* __restrict__ out){
  int n=blockIdx.x*4+(threadIdx.x>>6);
  int lane=threadIdx.x&63;
  if(n>=NN) return;
  int r0=rowptr[n], r1=rowptr[n+1];
  const float4 ldv=*(const float4*)(ld4+(size_t)4*n);
  const float4 lsv=*(const float4*)(ls4+(size_t)4*n);
  float sl0=lrelu(lsv.x+ldv.x), sl1=lrelu(lsv.y+ldv.y);
  float sl2=lrelu(lsv.z+ldv.z), sl3=lrelu(lsv.w+ldv.w);
  float m0=sl0,m1=sl1,m2=sl2,m3=sl3;
  for(int j=r0;j<r1;j++){
    const float4 a=*(const float4*)(ls4+(size_t)4*srcS[j]);
    m0=fmaxf(m0,lrelu(a.x+ldv.x)); m1=fmaxf(m1,lrelu(a.y+ldv.y));
    m2=fmaxf(m2,lrelu(a.z+ldv.z)); m3=fmaxf(m3,lrelu(a.w+ldv.w));
  }
  float z0=__expf(sl0-m0), z1=__expf(sl1-m1), z2=__expf(sl2-m2), z3=__expf(sl3-m3);
  const float* hn=h+(size_t)n*256;
  float a0=z0*hn[lane], a1=z1*hn[64+lane], a2=z2*hn[128+lane], a3=z3*hn[192+lane];
  int j=r0;
  for(; j+1<r1; j+=2){
    int s0=srcS[j], s1=srcS[j+1];
    const float4 A0=*(const float4*)(ls4+(size_t)4*s0);
    const float4 A1=*(const float4*)(ls4+(size_t)4*s1);
    const float* h0=h+(size_t)s0*256;
    const float* h1=h+(size_t)s1*256;
    float e00=__expf(lrelu(A0.x+ldv.x)-m0), e01=__expf(lrelu(A0.y+ldv.y)-m1);
    float e02=__expf(lrelu(A0.z+ldv.z)-m2), e03=__expf(lrelu(A0.w+ldv.w)-m3);
    float e10=__expf(lrelu(A1.x+ldv.x)-m0), e11=__expf(lrelu(A1.y+ldv.y)-m1);
    float e12=__expf(lrelu(A1.z+ldv.z)-m2), e13=__expf(lrelu(A1.w+ldv.w)-m3);
    z0+=e00+e10; z1+=e01+e11; z2+=e02+e12; z3+=e03+e13;
    float v00=h0[lane], v01=h0[64+lane], v02=h0[128+lane], v03=h0[192+lane];
    float v10=h1[lane], v11=h1[64+lane], v12=h1[128+lane], v13=h1[192+lane];
    a0+=e00*v00+e10*v10; a1+=e01*v01+e11*v11;
    a2+=e02*v02+e12*v12; a3+=e03*v03+e13*v13;
  }
  if(j<r1){
    int s0=srcS[j];
    const float4 A0=*(const float4*)(ls4+(size_t)4*s0);
    const float* h0=h+(size_t)s0*256;
    float e00=__expf(lrelu(A0.x+ldv.x)-m0), e01=__expf(lrelu(A0.y+ldv.y)-m1);
    float e02=__expf(lrelu(A0.z+ldv.z)-m2), e03=__expf(lrelu(A0.w+ldv.w)-m3);
    z0+=e00; z1+=e01; z2+=e02; z3+=e03;
    a0+=e00*h0[lane]; a1+=e01*h0[64+lane]; a2+=e02*h0[128+lane]; a3+=e03*h0[192+lane];
  }
  float zi0=1.f/(z0+1e-16f), zi1=1.f/(z1+1e-16f), zi2=1.f/(z2+1e-16f), zi3=1.f/(z3+1e-16f);
  out[(size_t)n*64+lane]=fmaxf(0.25f*(a0*zi0+a1*zi1+a2*zi2+a3*zi3)+bias[lane],0.f);
}

// GIN: self + sum -> out[N,64]
__global__ __launch_bounds__(256) void agg_kernel(const float* __restrict__ xin,
    const int* __restrict__ rowptr, const int* __restrict__ srcS,
    float* __restrict__ out){
  int n=blockIdx.x*4+(threadIdx.x>>6);
  int lane=threadIdx.x&63;
  if(n>=NN) return;
  int r0=rowptr[n], r1=rowptr[n+1];
  float acc=xin[(size_t)n*64+lane];
  int j=r0;
  for(; j+1<r1; j+=2){
    int s0=srcS[j], s1=srcS[j+1];
    acc+=xin[(size_t)s0*64+lane]+xin[(size_t)s1*64+lane];
  }
  if(j<r1) acc+=xin[(size_t)srcS[j]*64+lane];
  out[(size_t)n*64+lane]=acc;
}

// SAGE staging: out128[n] = [ mean_neigh(xin), xin[n] ]
__global__ __launch_bounds__(256) void agg2_kernel(const float* __restrict__ xin,
    const int* __restrict__ rowptr, const int* __restrict__ srcS,
    const float* __restrict__ invdeg, float* __restrict__ out128){
  int n=blockIdx.x*4+(threadIdx.x>>6);
  int lane=threadIdx.x&63;
  if(n>=NN) return;
  int r0=rowptr[n], r1=rowptr[n+1];
  float acc=0.f;
  int j=r0;
  for(; j+1<r1; j+=2){
    int s0=srcS[j], s1=srcS[j+1];
    acc+=xin[(size_t)s0*64+lane]+xin[(size_t)s1*64+lane];
  }
  if(j<r1) acc+=xin[(size_t)srcS[j]*64+lane];
  out128[(size_t)n*128+lane]=acc*invdeg[n];
  out128[(size_t)n*128+64+lane]=xin[(size_t)n*64+lane];
}

// TR pass1: per-node. q row loaded once; k gathered per edge; logits + running max.
__global__ __launch_bounds__(256) void tr_pass1_kernel(const int* __restrict__ rowptr, const int* __restrict__ srcS,
    const float* __restrict__ q, const float* __restrict__ k,
    float* __restrict__ lg, float* __restrict__ mx4){
  int n=blockIdx.x*4+(threadIdx.x>>6);
  int lane=threadIdx.x&63;
  if(n>=NN) return;
  int r0=rowptr[n], r1=rowptr[n+1];
  const float* qn=q+(size_t)n*256;
  float q0=qn[lane], q1=qn[64+lane], q2=qn[128+lane], q3=qn[192+lane];
  float m0=-1e30f,m1=-1e30f,m2=-1e30f,m3=-1e30f;
  for(int j=r0;j<r1;j++){
    const float* ks=k+(size_t)srcS[j]*256;
    float v0=q0*ks[lane], v1=q1*ks[64+lane], v2=q2*ks[128+lane], v3=q3*ks[192+lane];
    #pragma unroll
    for(int o=32;o>0;o>>=1){
      v0+=__shfl_xor(v0,o,64); v1+=__shfl_xor(v1,o,64);
      v2+=__shfl_xor(v2,o,64); v3+=__shfl_xor(v3,o,64);
    }
    v0*=0.125f; v1*=0.125f; v2*=0.125f; v3*=0.125f;
    m0=fmaxf(m0,v0); m1=fmaxf(m1,v1); m2=fmaxf(m2,v2); m3=fmaxf(m3,v3);
    if(lane==0) *(float4*)(lg+(size_t)4*j)=make_float4(v0,v1,v2,v3);
  }
  if(lane==0) *(float4*)(mx4+(size_t)4*n)=make_float4(m0,m1,m2,m3);
}

// TR pass2: exp + v-gather + skip + relu -> x5
__global__ __launch_bounds__(256) void tr_pass2_kernel(const int* __restrict__ rowptr, const int* __restrict__ srcS,
    const float* __restrict__ lg, const float* __restrict__ mx4,
    const float* __restrict__ v, const float* __restrict__ skip, float* __restrict__ x5){
  int n=blockIdx.x*4+(threadIdx.x>>6);
  int lane=threadIdx.x&63;
  if(n>=NN) return;
  int r0=rowptr[n], r1=rowptr[n+1];
  const float4 mv=*(const float4*)(mx4+(size_t)4*n);
  float m0=mv.x,m1=mv.y,m2=mv.z,m3=mv.w;
  float z0=0.f,z1=0.f,z2=0.f,z3=0.f;
  float a0=0.f,a1=0.f,a2=0.f,a3=0.f;
  int j=r0;
  for(; j+1<r1; j+=2){
    int s0=srcS[j], s1=srcS[j+1];
    const float4 f0=*(const float4*)(lg+(size_t)4*j);
    const float4 f1=*(const float4*)(lg+(size_t)4*(j+1));
    const float* v0=v+(size_t)s0*256;
    const float* v1=v+(size_t)s1*256;
    float e00=__expf(f0.x-m0), e01=__expf(f0.y-m1), e02=__expf(f0.z-m2), e03=__expf(f0.w-m3);
    float e10=__expf(f1.x-m0), e11=__expf(f1.y-m1), e12=__expf(f1.z-m2), e13=__expf(f1.w-m3);
    z0+=e00+e10; z1+=e01+e11; z2+=e02+e12; z3+=e03+e13;
    a0+=e00*v0[lane]+e10*v1[lane];
    a1+=e01*v0[64+lane]+e11*v1[64+lane];
    a2+=e02*v0[128+lane]+e12*v1[128+lane];
    a3+=e03*v0[192+lane]+e13*v1[192+lane];
  }
  if(j<r1){
    int s0=srcS[j];
    const float4 f0=*(const float4*)(lg+(size_t)4*j);
    const float* v0=v+(size_t)s0*256;
    float e00=__expf(f0.x-m0), e01=__expf(f0.y-m1), e02=__expf(f0.z-m2), e03=__expf(f0.w-m3);
    z0+=e00; z1+=e01; z2+=e02; z3+=e03;
    a0+=e00*v0[lane]; a1+=e01*v0[64+lane]; a2+=e02*v0[128+lane]; a3+=e03*v0[192+lane];
  }
  float zi0=1.f/(z0+1e-16f), zi1=1.f/(z1+1e-16f), zi2=1.f/(z2+1e-16f), zi3=1.f/(z3+1e-16f);
  float t=0.25f*(a0*zi0+a1*zi1+a2*zi2+a3*zi3)+skip[(size_t)n*64+lane];
  x5[(size_t)n*64+lane]=fmaxf(t,0.f);
}

// EdgeConv v2: hidden = relu(P[dst]+Q[src]) -> GEMM2(+b2) -> run-merged atomicMax
__global__ __launch_bounds__(256) void edgeconv2_kernel(
    const float* __restrict__ P, const float* __restrict__ Q,
    const int* __restrict__ srcS, const int* __restrict__ dstS,
    const float* __restrict__ W2, const float* __restrict__ b2,
    unsigned* __restrict__ emax){
  __shared__ float As[64][68];   // hidden tile
  __shared__ float Ws[64][64];
  const int e0=blockIdx.x*64;
  const int tid=threadIdx.x, tx=tid&15, ty=tid>>4;
  #pragma unroll
  for(int it=0;it<4;it++){
    int linear=it*1024+tid*4;
    int m=linear>>6, k=linear&63;
    int e=e0+m;
    float4 v=make_float4(0.f,0.f,0.f,0.f);
    if(e<EE){
      int dn=dstS[e], sn=srcS[e];
      const float4 p=*(const float4*)(P+(size_t)dn*64+k);
      const float4 q=*(const float4*)(Q+(size_t)sn*64+k);
      v=make_float4(fmaxf(p.x+q.x,0.f),fmaxf(p.y+q.y,0.f),fmaxf(p.z+q.z,0.f),fmaxf(p.w+q.w,0.f));
    }
    *(float4*)&As[m][k]=v;
  }
  #pragma unroll
  for(int it=0;it<4;it++){
    int linear=it*1024+tid*4;
    int k=linear>>6, n=linear&63;
    *(float4*)&Ws[k][n]=*(const float4*)(W2+(size_t)k*64+n);
  }
  __syncthreads();
  float acc2[4][4];
  #pragma unroll
  for(int i=0;i<4;i++)
    #pragma unroll
    for(int j=0;j<4;j++) acc2[i][j]=b2[tx*4+j];
  #pragma unroll 8
  for(int k=0;k<64;k+=4){
    float4 a0=*(float4*)&As[ty*4+0][k];
    float4 a1=*(float4*)&As[ty*4+1][k];
    float4 a2=*(float4*)&As[ty*4+2][k];
    float4 a3=*(float4*)&As[ty*4+3][k];
    float4 w0=*(float4*)&Ws[k+0][tx*4];
    float4 w1=*(float4*)&Ws[k+1][tx*4];
    float4 w2=*(float4*)&Ws[k+2][tx*4];
    float4 w3=*(float4*)&Ws[k+3][tx*4];
    mac4(acc2[0],a0,w0,w1,w2,w3);
    mac4(acc2[1],a1,w0,w1,w2,w3);
    mac4(acc2[2],a2,w0,w1,w2,w3);
    mac4(acc2[3],a3,w0,w1,w2,w3);
  }
  // run-merge consecutive rows with same dst, then atomicMax
  int dprev=-1;
  float mx0=0,mx1=0,mx2=0,mx3=0;
  #pragma unroll
  for(int i=0;i<4;i++){
    int e=e0+ty*4+i;
    if(e>=EE) continue;
    int dn=dstS[e];
    if(dn!=dprev){
      if(dprev>=0){
        atomicMax(&emax[(size_t)dprev*64+tx*4+0],fenc(mx0));
        atomicMax(&emax[(size_t)dprev*64+tx*4+1],fenc(mx1));
        atomicMax(&emax[(size_t)dprev*64+tx*4+2],fenc(mx2));
        atomicMax(&emax[(size_t)dprev*64+tx*4+3],fenc(mx3));
      }
      dprev=dn; mx0=acc2[i][0]; mx1=acc2[i][1]; mx2=acc2[i][2]; mx3=acc2[i][3];
    }else{
      mx0=fmaxf(mx0,acc2[i][0]); mx1=fmaxf(mx1,acc2[i][1]);
      mx2=fmaxf(mx2,acc2[i][2]); mx3=fmaxf(mx3,acc2[i][3]);
    }
  }
  if(dprev>=0){
    atomicMax(&emax[(size_t)dprev*64+tx*4+0],fenc(mx0));
    atomicMax(&emax[(size_t)dprev*64+tx*4+1],fenc(mx1));
    atomicMax(&emax[(size_t)dprev*64+tx*4+2],fenc(mx2));
    atomicMax(&emax[(size_t)dprev*64+tx*4+3],fenc(mx3));
  }
}

// pool with emax decode fused
__global__ __launch_bounds__(256) void pool_kernel(const unsigned* __restrict__ emax, const int* __restrict__ batch,
                                                   float* __restrict__ pooled){
  const int NB=200;
  int base=blockIdx.x*NB;
  int lane=threadIdx.x&63;
  int wsub=threadIdx.x>>6;
  float acc=0.f; int curg=-1;
  for(int idx=wsub; idx<NB; idx+=4){
    int n=base+idx;
    if(n>=NN) break;
    int g=batch[n];
    if(g!=curg){
      if(curg>=0) atomicAdd(&pooled[curg*64+lane],acc);
      acc=0.f; curg=g;
    }
    unsigned u=emax[(size_t)n*64+lane];
    acc+=(u>=0x80000000u)? __uint_as_float(u&0x7fffffffu) : 0.f;
  }
  if(curg>=0) atomicAdd(&pooled[curg*64+lane],acc);
}

__global__ __launch_bounds__(256) void final_kernel(const float* __restrict__ pooled, const int* __restrict__ batch,
    const float* __restrict__ fc1W, const float* __restrict__ fc1b,
    const float* __restrict__ fc2W, const float* __restrict__ fc2b,
    float* __restrict__ out){
  __shared__ float gm[16][64];
  __shared__ float t1[16][64];
  __shared__ int cgs[17];
  int t=threadIdx.x;
  if(t<17){
    int lo=0, hi=NN;
    while(lo<hi){ int mid=(lo+hi)>>1; if(batch[mid]<t) lo=mid+1; else hi=mid; }
    cgs[t]=lo;
  }
  __syncthreads();
  for(int r=0;r<4;r++){
    int idx=r*256+t; int g=idx>>6, d=idx&63;
    float c=(float)(cgs[g+1]-cgs[g]);
    gm[g][d]=pooled[idx]/fmaxf(c,1.f);
  }
  __syncthreads();
  for(int r=0;r<4;r++){
    int idx=r*256+t; int g=idx>>6, d=idx&63;
    float a=fc1b[d];
    for(int k2=0;k2<64;k2++) a+=gm[g][k2]*fc1W[k2*64+d];
    t1[g][d]=fmaxf(a,0.f);
  }
  __syncthreads();
  for(int r=0;r<4;r++){
    int idx=r*256+t; int g=idx>>6, d=idx&63;
    float a=fc2b[d];
    for(int k2=0;k2<64;k2++) a+=t1[g][k2]*fc2W[k2*64+d];
    out[idx]=a;
  }
}

extern "C" void kernel_launch(void* const* d_in, const int* in_sizes, int n_in,
                              void* d_out, int out_size, void* d_ws, size_t ws_size,
                              hipStream_t stream){
  const float* x       =(const float*)d_in[0];
  const int*   ei      =(const int*)  d_in[1];
  const int*   src     =ei;
  const int*   dst     =ei+EE;
  const int*   batch   =(const int*)  d_in[2];
  const float* gat1_W  =(const float*)d_in[3];
  const float* gat1_as =(const float*)d_in[4];
  const float* gat1_ad =(const float*)d_in[5];
  const float* gat1_b  =(const float*)d_in[6];
  const float* gat2_W  =(const float*)d_in[7];
  const float* gat2_as =(const float*)d_in[8];
  const float* gat2_ad =(const float*)d_in[9];
  const float* gat2_b  =(const float*)d_in[10];
  const float* gin_W1  =(const float*)d_in[11];
  const float* gin_b1  =(const float*)d_in[12];
  const float* gin_W2  =(const float*)d_in[13];
  const float* gin_b2  =(const float*)d_in[14];
  const float* sage1_Wl=(const float*)d_in[15];
  const float* sage1_bl=(const float*)d_in[16];
  const float* sage1_Wr=(const float*)d_in[17];
  const float* sage2_Wl=(const float*)d_in[18];
  const float* sage2_bl=(const float*)d_in[19];
  const float* sage2_Wr=(const float*)d_in[20];
  const float* tr_Wq   =(const float*)d_in[21];
  const float* tr_bq   =(const float*)d_in[22];
  const float* tr_Wk   =(const float*)d_in[23];
  const float* tr_bk   =(const float*)d_in[24];
  const float* tr_Wv   =(const float*)d_in[25];
  const float* tr_bv   =(const float*)d_in[26];
  const float* tr_Ws   =(const float*)d_in[27];
  const float* tr_bs   =(const float*)d_in[28];
  const float* ec_W1   =(const float*)d_in[29];
  const float* ec_b1   =(const float*)d_in[30];
  const float* ec_W2   =(const float*)d_in[31];
  const float* ec_b2   =(const float*)d_in[32];
  const float* fc1_W   =(const float*)d_in[33];
  const float* fc1_b   =(const float*)d_in[34];
  const float* fc2_W   =(const float*)d_in[35];
  const float* fc2_b   =(const float*)d_in[36];

  // ---- workspace layout (floats first, then ints) ----
  float* base=(float*)d_ws;
  size_t off=0;
  auto alloc=[&](size_t n){ float* p=base+off; off+=n; return p; };
  float* A_big =alloc((size_t)NN*256);     // GAT h / SAGE xcat / TR q then v
  float* nb0   =alloc(N64);
  float* nb1   =alloc(N64);                // nb1..nb4 contiguous: TR k [N,256]
  float* nb2   =alloc(N64);
  float* nb3   =alloc(N64);
  float* nb4   =alloc(N64);
  float* nb5   =alloc(N64);                // emax (as unsigned, zeroed)
  float* logitE=alloc((size_t)EE*4);
  float* ls    =alloc(NN*4);               // GAT ls / TR max
  float* ldb   =alloc(NN*4);               // GAT ld / EdgeConv Wd (4096)
  float* invdeg=alloc(NN);
  float* pooled=alloc(GG*64);
  int* ibase=(int*)(base+off);
  int* srcS  =ibase;
  int* dstS  =ibase+EE;
  int* cnt   =ibase+2*EE;
  int* fillp =ibase+2*EE+NN;               // cnt,fillp contiguous (zeroed together)
  int* rowptr=ibase+2*EE+2*NN;             // NN+1 ints
  int* bsum  =ibase+2*EE+3*NN+8;           // 49 ints
  int* boff  =bsum+64;                     // 49 ints

  const int BT=256;
  const int NSB=cdiv(NN,1024);             // 49 scan blocks
  // ---- zero init ----
  zero_kernel<<<cdiv(2*NN,BT),BT,0,stream>>>((unsigned*)cnt,2*NN);
  zero_kernel<<<cdiv(GG*64,BT),BT,0,stream>>>((unsigned*)pooled,GG*64);
  zero_kernel<<<cdiv(N64,BT),BT,0,stream>>>((unsigned*)nb5,N64);
  // ---- CSR ----
  hist_kernel<<<cdiv(EE,BT),BT,0,stream>>>(dst,cnt);
  scan1_kernel<<<NSB,1024,0,stream>>>(cnt,rowptr,bsum);
  scan2_kernel<<<1,64,0,stream>>>(bsum,boff,rowptr,NSB);
  scan3_kernel<<<cdiv(NN,BT),BT,0,stream>>>(rowptr,boff);
  fill_kernel<<<cdiv(EE,BT),BT,0,stream>>>(src,dst,rowptr,fillp,srcS,dstS);
  invdeg_kernel<<<cdiv(NN,BT),BT,0,stream>>>(cnt,invdeg);

  const int GB=cdiv(NN,64);        // 782 row tiles
  const int GW=cdiv(NN,4);         // wave-per-node blocks (12500)

  // ---- GAT1 (attn dots fused in GEMM epilogue) ----
  gemm_kernel<128><<<dim3(GB,4),BT,0,stream>>>(x,gat1_W,nullptr,256,0,nullptr,nullptr,A_big,256,0,
                                               gat1_as,gat1_ad,ls,ldb);
  gat_fused_kernel<<<GW,BT,0,stream>>>(A_big,rowptr,srcS,ls,ldb,gat1_b,nb0);           // x1
  // ---- GAT2 ----
  gemm_kernel<64><<<dim3(GB,4),BT,0,stream>>>(nb0,gat2_W,nullptr,256,0,nullptr,nullptr,A_big,256,0,
                                              gat2_as,gat2_ad,ls,ldb);
  gat_fused_kernel<<<GW,BT,0,stream>>>(A_big,rowptr,srcS,ls,ldb,gat2_b,nb1);           // x2
  // ---- GIN ----
  agg_kernel<<<GW,BT,0,stream>>>(nb1,rowptr,srcS,nb2);                                 // t = x2+agg
  gemm_kernel<64><<<dim3(GB,1),BT,0,stream>>>(nb2,gin_W1,nullptr,64,0,gin_b1,nullptr,nb3,64,1,
                                              nullptr,nullptr,nullptr,nullptr);
  gemm_kernel<64><<<dim3(GB,1),BT,0,stream>>>(nb3,gin_W2,nullptr,64,0,gin_b2,nullptr,nb0,64,1,
                                              nullptr,nullptr,nullptr,nullptr);        // x3
  // ---- SAGE1: xcat=[mean(x3), x3] @ [Wl;Wr] + bl ----
  agg2_kernel<<<GW,BT,0,stream>>>(nb0,rowptr,srcS,invdeg,A_big);
  gemm_kernel<128><<<dim3(GB,1),BT,0,stream>>>(A_big,sage1_Wl,sage1_Wr,64,0,sage1_bl,nullptr,nb1,64,1,
                                               nullptr,nullptr,nullptr,nullptr);       // xs
  // ---- SAGE2 ----
  agg2_kernel<<<GW,BT,0,stream>>>(nb1,rowptr,srcS,invdeg,A_big);
  gemm_kernel<128><<<dim3(GB,1),BT,0,stream>>>(A_big,sage2_Wl,sage2_Wr,64,0,sage2_bl,nullptr,nb0,64,1,
                                               nullptr,nullptr,nullptr,nullptr);       // x4
  // ---- TransformerConv ----
  float* qv=A_big;                 // q, later overwritten by v
  float* kh=nb1;                   // k occupies nb1..nb4 [N,256]
  gemm_kernel<64><<<dim3(GB,4),BT,0,stream>>>(nb0,tr_Wq,nullptr,256,0,tr_bq,nullptr,qv,256,0,
                                              nullptr,nullptr,nullptr,nullptr);
  gemm_kernel<64><<<dim3(GB,4),BT,0,stream>>>(nb0,tr_Wk,nullptr,256,0,tr_bk,nullptr,kh,256,0,
                                              nullptr,nullptr,nullptr,nullptr);
  tr_pass1_kernel<<<GW,BT,0,stream>>>(rowptr,srcS,qv,kh,logitE,ls);                    // logits+max
  gemm_kernel<64><<<dim3(GB,4),BT,0,stream>>>(nb0,tr_Wv,nullptr,256,0,tr_bv,nullptr,qv,256,0,
                                              nullptr,nullptr,nullptr,nullptr);        // v over q
  gemm_kernel<64><<<dim3(GB,1),BT,0,stream>>>(nb0,tr_Ws,nullptr,64,0,tr_bs,nullptr,nb1,64,0,
                                              nullptr,nullptr,nullptr,nullptr);        // skip (k dead)
  tr_pass2_kernel<<<GW,BT,0,stream>>>(rowptr,srcS,logitE,ls,qv,nb1,nb2);               // x5
  // ---- EdgeConv (factored): P=x5@(W1a-W1b)+b1, Q=x5@W1b ----
  wd_kernel<<<16,BT,0,stream>>>(ec_W1,ldb);
  gemm_kernel<64><<<dim3(GB,1),BT,0,stream>>>(nb2,ldb,nullptr,64,0,ec_b1,nullptr,nb3,64,0,
                                              nullptr,nullptr,nullptr,nullptr);        // P
  gemm_kernel<64><<<dim3(GB,1),BT,0,stream>>>(nb2,ec_W1+4096,nullptr,64,0,nullptr,nullptr,nb4,64,0,
                                              nullptr,nullptr,nullptr,nullptr);        // Q
  edgeconv2_kernel<<<EE/64,BT,0,stream>>>(nb3,nb4,srcS,dstS,ec_W2,ec_b2,(unsigned*)nb5);
  // ---- pool (emax decode fused) + MLP ----
  pool_kernel<<<cdiv(NN,200),BT,0,stream>>>((unsigned*)nb5,batch,pooled);
  final_kernel<<<1,BT,0,stream>>>(pooled,batch,fc1_W,fc1_b,fc2_W,fc2_b,(float*)d_out);
}

// Round 5
// 1272.297 us; speedup vs baseline: 1.8410x; 1.0761x over previous
//
#include <hip/hip_runtime.h>

#define NN 50000
#define EE 640000
#define GG 16
#define N64 (NN*64)

static inline int cdiv(int a,int b){return (a+b-1)/b;}

__device__ __forceinline__ float lrelu(float x){ return x>0.f? x : 0.2f*x; }
// monotonic float->uint encoding for atomicMax on floats
__device__ __forceinline__ unsigned fenc(float f){
  unsigned u=__float_as_uint(f);
  return (u&0x80000000u)? ~u : (u|0x80000000u);
}

// acc[0..3] += av . {w0..w3} columns
__device__ __forceinline__ void mac4(float* acc, const float4 av,
    const float4 w0, const float4 w1, const float4 w2, const float4 w3){
  acc[0]+=av.x*w0.x+av.y*w1.x+av.z*w2.x+av.w*w3.x;
  acc[1]+=av.x*w0.y+av.y*w1.y+av.z*w2.y+av.w*w3.y;
  acc[2]+=av.x*w0.z+av.y*w1.z+av.z*w2.z+av.w*w3.z;
  acc[3]+=av.x*w0.w+av.y*w1.w+av.z*w2.w+av.w*w3.w;
}

__global__ void zero_kernel(unsigned* p, int n){
  int i=blockIdx.x*blockDim.x+threadIdx.x;
  if(i<n) p[i]=0u;
}

__global__ void hist_kernel(const int* __restrict__ dst, int* __restrict__ cnt){
  int e=blockIdx.x*blockDim.x+threadIdx.x;
  if(e<EE) atomicAdd(&cnt[dst[e]],1);
}

// 3-stage scan
__global__ __launch_bounds__(1024) void scan1_kernel(const int* __restrict__ cnt,
    int* __restrict__ rowptr, int* __restrict__ bsum){
  __shared__ int wsum[16];
  int t=threadIdx.x, b=blockIdx.x;
  int i=b*1024+t;
  int v=(i<NN)?cnt[i]:0;
  int lane=t&63, w=t>>6;
  int inc=v;
  #pragma unroll
  for(int o=1;o<64;o<<=1){ int u=__shfl_up(inc,o,64); if(lane>=o) inc+=u; }
  if(lane==63) wsum[w]=inc;
  __syncthreads();
  if(t<16){
    int s=wsum[t];
    #pragma unroll
    for(int o=1;o<16;o<<=1){ int u=__shfl_up(s,o,16); if(t>=o) s+=u; }
    wsum[t]=s;
  }
  __syncthreads();
  int woff=(w>0)?wsum[w-1]:0;
  if(i<NN) rowptr[i]=woff+inc-v;   // block-local exclusive
  if(t==1023) bsum[b]=wsum[15];
}

__global__ void scan2_kernel(const int* __restrict__ bsum, int* __restrict__ boff, int* __restrict__ rowptr, int nb){
  int t=threadIdx.x;  // 64 threads
  int v=(t<nb)?bsum[t]:0;
  int inc=v;
  #pragma unroll
  for(int o=1;o<64;o<<=1){ int u=__shfl_up(inc,o,64); if(t>=o) inc+=u; }
  if(t<nb) boff[t]=inc-v;
  if(t==63) rowptr[NN]=inc;
}

__global__ void scan3_kernel(int* __restrict__ rowptr, const int* __restrict__ boff){
  int i=blockIdx.x*blockDim.x+threadIdx.x;
  if(i<NN) rowptr[i]+=boff[i>>10];
}

__global__ void fill_kernel(const int* __restrict__ src, const int* __restrict__ dst,
                            const int* __restrict__ rowptr, int* __restrict__ fillp,
                            int* __restrict__ srcS, int* __restrict__ dstS){
  int e=blockIdx.x*blockDim.x+threadIdx.x;
  if(e>=EE) return;
  int d=dst[e];
  int p=rowptr[d]+atomicAdd(&fillp[d],1);
  srcS[p]=src[e]; dstS[p]=d;
}

__global__ void invdeg_kernel(const int* __restrict__ cnt, float* __restrict__ invdeg){
  int i=blockIdx.x*blockDim.x+threadIdx.x;
  if(i<NN) invdeg[i]=1.f/fmaxf((float)cnt[i],1.f);
}

// Wd[k][n] = W1[k][n] - W1[64+k][n]   (64x64)
__global__ void wd_kernel(const float* __restrict__ W1, float* __restrict__ Wd){
  int i=blockIdx.x*blockDim.x+threadIdx.x;
  if(i<4096) Wd[i]=W1[i]-W1[4096+i];
}

// C[NN, ldc(+nc0 slice)] = act(A[NN,K] @ W[K, ldw](cols wc..) + bias + addend)
// Wb: rows >=64 of combined weight. lsO: fused GAT attn-dot epilogue (head=blockIdx.y).
template<int K>
__global__ __launch_bounds__(256) void gemm_kernel(
    const float* __restrict__ A, const float* __restrict__ W, const float* __restrict__ Wb,
    int ldw, int wcol0,
    const float* __restrict__ bias, const float* __restrict__ addend,
    float* __restrict__ C, int ldc, int relu_flag,
    const float* __restrict__ a_s, const float* __restrict__ a_d,
    float* __restrict__ lsO, float* __restrict__ ldO){
  __shared__ float As[64][68];
  __shared__ float Ws[64][64];
  const int m0=blockIdx.x*64;
  const int nc0=blockIdx.y*64;
  const int wc=wcol0+nc0;
  const int tid=threadIdx.x, tx=tid&15, ty=tid>>4;
  float acc[4][4];
  #pragma unroll
  for(int i=0;i<4;i++){
    #pragma unroll
    for(int j=0;j<4;j++) acc[i][j]=bias? bias[wc+tx*4+j]:0.f;
  }
  for(int k0=0;k0<K;k0+=64){
    const float* Wp=(Wb && k0>=64)? Wb : W;
    const int kb =(Wb && k0>=64)? k0-64 : k0;
    __syncthreads();
    #pragma unroll
    for(int it=0;it<4;it++){
      int linear=it*1024+tid*4;
      int m=linear>>6, k=linear&63;
      float4 v=make_float4(0.f,0.f,0.f,0.f);
      if(m0+m<NN) v=*(const float4*)(A+(size_t)(m0+m)*K+k0+k);
      *(float4*)&As[m][k]=v;
    }
    #pragma unroll
    for(int it=0;it<4;it++){
      int linear=it*1024+tid*4;
      int k=linear>>6, n=linear&63;
      *(float4*)&Ws[k][n]=*(const float4*)(Wp+(size_t)(kb+k)*ldw+wc+n);
    }
    __syncthreads();
    #pragma unroll 8
    for(int k=0;k<64;k+=4){
      float4 a0=*(float4*)&As[ty*4+0][k];
      float4 a1=*(float4*)&As[ty*4+1][k];
      float4 a2=*(float4*)&As[ty*4+2][k];
      float4 a3=*(float4*)&As[ty*4+3][k];
      float4 w0=*(float4*)&Ws[k+0][tx*4];
      float4 w1=*(float4*)&Ws[k+1][tx*4];
      float4 w2=*(float4*)&Ws[k+2][tx*4];
      float4 w3=*(float4*)&Ws[k+3][tx*4];
      mac4(acc[0],a0,w0,w1,w2,w3);
      mac4(acc[1],a1,w0,w1,w2,w3);
      mac4(acc[2],a2,w0,w1,w2,w3);
      mac4(acc[3],a3,w0,w1,w2,w3);
    }
  }
  float4 asv,adv;
  if(lsO){
    asv=*(const float4*)(a_s+(size_t)blockIdx.y*64+tx*4);
    adv=*(const float4*)(a_d+(size_t)blockIdx.y*64+tx*4);
  }
  #pragma unroll
  for(int i=0;i<4;i++){
    int m=m0+ty*4+i;
    bool valid=(m<NN);
    float r0=acc[i][0],r1=acc[i][1],r2=acc[i][2],r3=acc[i][3];
    if(valid){
      if(addend){
        const float4 ad=*(const float4*)(addend+(size_t)m*ldc+nc0+tx*4);
        r0+=ad.x; r1+=ad.y; r2+=ad.z; r3+=ad.w;
      }
      if(relu_flag){ r0=fmaxf(r0,0.f); r1=fmaxf(r1,0.f); r2=fmaxf(r2,0.f); r3=fmaxf(r3,0.f); }
      *(float4*)(C+(size_t)m*ldc+nc0+tx*4)=make_float4(r0,r1,r2,r3);
    }
    if(lsO){
      float ps=r0*asv.x+r1*asv.y+r2*asv.z+r3*asv.w;
      float pd=r0*adv.x+r1*adv.y+r2*adv.z+r3*adv.w;
      #pragma unroll
      for(int o=1;o<16;o<<=1){ ps+=__shfl_xor(ps,o,16); pd+=__shfl_xor(pd,o,16); }
      if(valid && tx==0){
        lsO[(size_t)m*4+blockIdx.y]=ps;
        ldO[(size_t)m*4+blockIdx.y]=pd;
      }
    }
  }
}

// single-pass GAT (no max subtraction; logits are O(1) so exp is safe):
// out[n,d]=relu(0.25*sum_h (e_self*h[n]+sum_e e*h[src])/z_h + b)
__global__ __launch_bounds__(256) void gat1p_kernel(const float* __restrict__ h,
    const int* __restrict__ rowptr, const int* __restrict__ srcS,
    const float* __restrict__ ls4, const float* __restrict__ ld4,
    const float* __restrict__ bias, float* __restrict__ out){
  int n=blockIdx.x*4+(threadIdx.x>>6);
  int lane=threadIdx.x&63;
  if(n>=NN) return;
  int r0=rowptr[n], r1=rowptr[n+1];
  const float4 ldv=*(const float4*)(ld4+(size_t)4*n);
  const float4 lsv=*(const float4*)(ls4+(size_t)4*n);
  float z0=__expf(lrelu(lsv.x+ldv.x)), z1=__expf(lrelu(lsv.y+ldv.y));
  float z2=__expf(lrelu(lsv.z+ldv.z)), z3=__expf(lrelu(lsv.w+ldv.w));
  const float* hn=h+(size_t)n*256;
  float a0=z0*hn[lane], a1=z1*hn[64+lane], a2=z2*hn[128+lane], a3=z3*hn[192+lane];
  int j=r0;
  for(; j+1<r1; j+=2){
    int s0=srcS[j], s1=srcS[j+1];
    const float4 A0=*(const float4*)(ls4+(size_t)4*s0);
    const float4 A1=*(const float4*)(ls4+(size_t)4*s1);
    const float* h0=h+(size_t)s0*256;
    const float* h1=h+(size_t)s1*256;
    float e00=__expf(lrelu(A0.x+ldv.x)), e01=__expf(lrelu(A0.y+ldv.y));
    float e02=__expf(lrelu(A0.z+ldv.z)), e03=__expf(lrelu(A0.w+ldv.w));
    float e10=__expf(lrelu(A1.x+ldv.x)), e11=__expf(lrelu(A1.y+ldv.y));
    float e12=__expf(lrelu(A1.z+ldv.z)), e13=__expf(lrelu(A1.w+ldv.w));
    z0+=e00+e10; z1+=e01+e11; z2+=e02+e12; z3+=e03+e13;
    a0+=e00*h0[lane]+e10*h1[lane];
    a1+=e01*h0[64+lane]+e11*h1[64+lane];
    a2+=e02*h0[128+lane]+e12*h1[128+lane];
    a3+=e03*h0[192+lane]+e13*h1[192+lane];
  }
  if(j<r1){
    int s0=srcS[j];
    const float4 A0=*(const float4*)(ls4+(size_t)4*s0);
    const float* h0=h+(size_t)s0*256;
    float e00=__expf(lrelu(A0.x+ldv.x)), e01=__expf(lrelu(A0.y+ldv.y));
    float e02=__expf(lrelu(A0.z+ldv.z)), e03=__expf(lrelu(A0.w+ldv.w));
    z0+=e00; z1+=e01; z2+=e02; z3+=e03;
    a0+=e00*h0[lane]; a1+=e01*h0[64+lane]; a2+=e02*h0[128+lane]; a3+=e03*h0[192+lane];
  }
  float zi0=1.f/(z0+1e-16f), zi1=1.f/(z1+1e-16f), zi2=1.f/(z2+1e-16f), zi3=1.f/(z3+1e-16f);
  out[(size_t)n*64+lane]=fmaxf(0.25f*(a0*zi0+a1*zi1+a2*zi2+a3*zi3)+bias[lane],0.f);
}

// GIN: self + sum -> out[N,64] (unroll 4)
__global__ __launch_bounds__(256) void agg_kernel(const float* __restrict__ xin,
    const int* __restrict__ rowptr, const int* __restrict__ srcS,
    float* __restrict__ out){
  int n=blockIdx.x*4+(threadIdx.x>>6);
  int lane=threadIdx.x&63;
  if(n>=NN) return;
  int r0=rowptr[n], r1=rowptr[n+1];
  float acc=xin[(size_t)n*64+lane];
  int j=r0;
  for(; j+3<r1; j+=4){
    int s0=srcS[j], s1=srcS[j+1], s2=srcS[j+2], s3=srcS[j+3];
    acc+=(xin[(size_t)s0*64+lane]+xin[(size_t)s1*64+lane])
        +(xin[(size_t)s2*64+lane]+xin[(size_t)s3*64+lane]);
  }
  for(; j<r1; j++) acc+=xin[(size_t)srcS[j]*64+lane];
  out[(size_t)n*64+lane]=acc;
}

// SAGE staging: out128[n] = [ mean_neigh(xin), xin[n] ]  (unroll 4)
__global__ __launch_bounds__(256) void agg2_kernel(const float* __restrict__ xin,
    const int* __restrict__ rowptr, const int* __restrict__ srcS,
    const float* __restrict__ invdeg, float* __restrict__ out128){
  int n=blockIdx.x*4+(threadIdx.x>>6);
  int lane=threadIdx.x&63;
  if(n>=NN) return;
  int r0=rowptr[n], r1=rowptr[n+1];
  float acc=0.f;
  int j=r0;
  for(; j+3<r1; j+=4){
    int s0=srcS[j], s1=srcS[j+1], s2=srcS[j+2], s3=srcS[j+3];
    acc+=(xin[(size_t)s0*64+lane]+xin[(size_t)s1*64+lane])
        +(xin[(size_t)s2*64+lane]+xin[(size_t)s3*64+lane]);
  }
  for(; j<r1; j++) acc+=xin[(size_t)srcS[j]*64+lane];
  out128[(size_t)n*128+lane]=acc*invdeg[n];
  out128[(size_t)n*128+64+lane]=xin[(size_t)n*64+lane];
}

// TR pass1: per-node logits (no max needed), unroll 2 with dual shfl chains.
__global__ __launch_bounds__(256) void tr_pass1_kernel(const int* __restrict__ rowptr, const int* __restrict__ srcS,
    const float* __restrict__ q, const float* __restrict__ k,
    float* __restrict__ lg){
  int n=blockIdx.x*4+(threadIdx.x>>6);
  int lane=threadIdx.x&63;
  if(n>=NN) return;
  int r0=rowptr[n], r1=rowptr[n+1];
  const float* qn=q+(size_t)n*256;
  float q0=qn[lane], q1=qn[64+lane], q2=qn[128+lane], q3=qn[192+lane];
  int j=r0;
  for(; j+1<r1; j+=2){
    const float* k0=k+(size_t)srcS[j]*256;
    const float* k1=k+(size_t)srcS[j+1]*256;
    float d00=q0*k0[lane], d01=q1*k0[64+lane], d02=q2*k0[128+lane], d03=q3*k0[192+lane];
    float d10=q0*k1[lane], d11=q1*k1[64+lane], d12=q2*k1[128+lane], d13=q3*k1[192+lane];
    #pragma unroll
    for(int o=32;o>0;o>>=1){
      d00+=__shfl_xor(d00,o,64); d01+=__shfl_xor(d01,o,64);
      d02+=__shfl_xor(d02,o,64); d03+=__shfl_xor(d03,o,64);
      d10+=__shfl_xor(d10,o,64); d11+=__shfl_xor(d11,o,64);
      d12+=__shfl_xor(d12,o,64); d13+=__shfl_xor(d13,o,64);
    }
    if(lane==0){
      *(float4*)(lg+(size_t)4*j)  =make_float4(d00*0.125f,d01*0.125f,d02*0.125f,d03*0.125f);
      *(float4*)(lg+(size_t)4*(j+1))=make_float4(d10*0.125f,d11*0.125f,d12*0.125f,d13*0.125f);
    }
  }
  if(j<r1){
    const float* k0=k+(size_t)srcS[j]*256;
    float d00=q0*k0[lane], d01=q1*k0[64+lane], d02=q2*k0[128+lane], d03=q3*k0[192+lane];
    #pragma unroll
    for(int o=32;o>0;o>>=1){
      d00+=__shfl_xor(d00,o,64); d01+=__shfl_xor(d01,o,64);
      d02+=__shfl_xor(d02,o,64); d03+=__shfl_xor(d03,o,64);
    }
    if(lane==0) *(float4*)(lg+(size_t)4*j)=make_float4(d00*0.125f,d01*0.125f,d02*0.125f,d03*0.125f);
  }
}

// TR pass2: exp (no max) + v-gather + skip + relu -> x5
__global__ __launch_bounds__(256) void tr_pass2_kernel(const int* __restrict__ rowptr, const int* __restrict__ srcS,
    const float* __restrict__ lg,
    const float* __restrict__ v, const float* __restrict__ skip, float* __restrict__ x5){
  int n=blockIdx.x*4+(threadIdx.x>>6);
  int lane=threadIdx.x&63;
  if(n>=NN) return;
  int r0=rowptr[n], r1=rowptr[n+1];
  float z0=0.f,z1=0.f,z2=0.f,z3=0.f;
  float a0=0.f,a1=0.f,a2=0.f,a3=0.f;
  int j=r0;
  for(; j+1<r1; j+=2){
    int s0=srcS[j], s1=srcS[j+1];
    const float4 f0=*(const float4*)(lg+(size_t)4*j);
    const float4 f1=*(const float4*)(lg+(size_t)4*(j+1));
    const float* v0=v+(size_t)s0*256;
    const float* v1=v+(size_t)s1*256;
    float e00=__expf(f0.x), e01=__expf(f0.y), e02=__expf(f0.z), e03=__expf(f0.w);
    float e10=__expf(f1.x), e11=__expf(f1.y), e12=__expf(f1.z), e13=__expf(f1.w);
    z0+=e00+e10; z1+=e01+e11; z2+=e02+e12; z3+=e03+e13;
    a0+=e00*v0[lane]+e10*v1[lane];
    a1+=e01*v0[64+lane]+e11*v1[64+lane];
    a2+=e02*v0[128+lane]+e12*v1[128+lane];
    a3+=e03*v0[192+lane]+e13*v1[192+lane];
  }
  if(j<r1){
    int s0=srcS[j];
    const float4 f0=*(const float4*)(lg+(size_t)4*j);
    const float* v0=v+(size_t)s0*256;
    float e00=__expf(f0.x), e01=__expf(f0.y), e02=__expf(f0.z), e03=__expf(f0.w);
    z0+=e00; z1+=e01; z2+=e02; z3+=e03;
    a0+=e00*v0[lane]; a1+=e01*v0[64+lane]; a2+=e02*v0[128+lane]; a3+=e03*v0[192+lane];
  }
  float zi0=1.f/(z0+1e-16f), zi1=1.f/(z1+1e-16f), zi2=1.f/(z2+1e-16f), zi3=1.f/(z3+1e-16f);
  float t=0.25f*(a0*zi0+a1*zi1+a2*zi2+a3*zi3)+skip[(size_t)n*64+lane];
  x5[(size_t)n*64+lane]=fmaxf(t,0.f);
}

// EdgeConv v2: hidden = relu(P[dst]+Q[src]) -> GEMM2(+b2) -> run-merged atomicMax
__global__ __launch_bounds__(256) void edgeconv2_kernel(
    const float* __restrict__ P, const float* __restrict__ Q,
    const int* __restrict__ srcS, const int* __restrict__ dstS,
    const float* __restrict__ W2, const float* __restrict__ b2,
    unsigned* __restrict__ emax){
  __shared__ float As[64][68];   // hidden tile
  __shared__ float Ws[64][64];
  const int e0=blockIdx.x*64;
  const int tid=threadIdx.x, tx=tid&15, ty=tid>>4;
  #pragma unroll
  for(int it=0;it<4;it++){
    int linear=it*1024+tid*4;
    int m=linear>>6, k=linear&63;
    int e=e0+m;
    float4 v=make_float4(0.f,0.f,0.f,0.f);
    if(e<EE){
      int dn=dstS[e], sn=srcS[e];
      const float4 p=*(const float4*)(P+(size_t)dn*64+k);
      const float4 q=*(const float4*)(Q+(size_t)sn*64+k);
      v=make_float4(fmaxf(p.x+q.x,0.f),fmaxf(p.y+q.y,0.f),fmaxf(p.z+q.z,0.f),fmaxf(p.w+q.w,0.f));
    }
    *(float4*)&As[m][k]=v;
  }
  #pragma unroll
  for(int it=0;it<4;it++){
    int linear=it*1024+tid*4;
    int k=linear>>6, n=linear&63;
    *(float4*)&Ws[k][n]=*(const float4*)(W2+(size_t)k*64+n);
  }
  __syncthreads();
  float acc2[4][4];
  #pragma unroll
  for(int i=0;i<4;i++)
    #pragma unroll
    for(int j=0;j<4;j++) acc2[i][j]=b2[tx*4+j];
  #pragma unroll 8
  for(int k=0;k<64;k+=4){
    float4 a0=*(float4*)&As[ty*4+0][k];
    float4 a1=*(float4*)&As[ty*4+1][k];
    float4 a2=*(float4*)&As[ty*4+2][k];
    float4 a3=*(float4*)&As[ty*4+3][k];
    float4 w0=*(float4*)&Ws[k+0][tx*4];
    float4 w1=*(float4*)&Ws[k+1][tx*4];
    float4 w2=*(float4*)&Ws[k+2][tx*4];
    float4 w3=*(float4*)&Ws[k+3][tx*4];
    mac4(acc2[0],a0,w0,w1,w2,w3);
    mac4(acc2[1],a1,w0,w1,w2,w3);
    mac4(acc2[2],a2,w0,w1,w2,w3);
    mac4(acc2[3],a3,w0,w1,w2,w3);
  }
  // run-merge consecutive rows with same dst, then atomicMax
  int dprev=-1;
  float mx0=0,mx1=0,mx2=0,mx3=0;
  #pragma unroll
  for(int i=0;i<4;i++){
    int e=e0+ty*4+i;
    if(e>=EE) continue;
    int dn=dstS[e];
    if(dn!=dprev){
      if(dprev>=0){
        atomicMax(&emax[(size_t)dprev*64+tx*4+0],fenc(mx0));
        atomicMax(&emax[(size_t)dprev*64+tx*4+1],fenc(mx1));
        atomicMax(&emax[(size_t)dprev*64+tx*4+2],fenc(mx2));
        atomicMax(&emax[(size_t)dprev*64+tx*4+3],fenc(mx3));
      }
      dprev=dn; mx0=acc2[i][0]; mx1=acc2[i][1]; mx2=acc2[i][2]; mx3=acc2[i][3];
    }else{
      mx0=fmaxf(mx0,acc2[i][0]); mx1=fmaxf(mx1,acc2[i][1]);
      mx2=fmaxf(mx2,acc2[i][2]); mx3=fmaxf(mx3,acc2[i][3]);
    }
  }
  if(dprev>=0){
    atomicMax(&emax[(size_t)dprev*64+tx*4+0],fenc(mx0));
    atomicMax(&emax[(size_t)dprev*64+tx*4+1],fenc(mx1));
    atomicMax(&emax[(size_t)dprev*64+tx*4+2],fenc(mx2));
    atomicMax(&emax[(size_t)dprev*64+tx*4+3],fenc(mx3));
  }
}

// pool with emax decode fused
__global__ __launch_bounds__(256) void pool_kernel(const unsigned* __restrict__ emax, const int* __restrict__ batch,
                                                   float* __restrict__ pooled){
  const int NB=200;
  int base=blockIdx.x*NB;
  int lane=threadIdx.x&63;
  int wsub=threadIdx.x>>6;
  float acc=0.f; int curg=-1;
  for(int idx=wsub; idx<NB; idx+=4){
    int n=base+idx;
    if(n>=NN) break;
    int g=batch[n];
    if(g!=curg){
      if(curg>=0) atomicAdd(&pooled[curg*64+lane],acc);
      acc=0.f; curg=g;
    }
    unsigned u=emax[(size_t)n*64+lane];
    acc+=(u>=0x80000000u)? __uint_as_float(u&0x7fffffffu) : 0.f;
  }
  if(curg>=0) atomicAdd(&pooled[curg*64+lane],acc);
}

__global__ __launch_bounds__(256) void final_kernel(const float* __restrict__ pooled, const int* __restrict__ batch,
    const float* __restrict__ fc1W, const float* __restrict__ fc1b,
    const float* __restrict__ fc2W, const float* __restrict__ fc2b,
    float* __restrict__ out){
  __shared__ float gm[16][64];
  __shared__ float t1[16][64];
  __shared__ int cgs[17];
  int t=threadIdx.x;
  if(t<17){
    int lo=0, hi=NN;
    while(lo<hi){ int mid=(lo+hi)>>1; if(batch[mid]<t) lo=mid+1; else hi=mid; }
    cgs[t]=lo;
  }
  __syncthreads();
  for(int r=0;r<4;r++){
    int idx=r*256+t; int g=idx>>6, d=idx&63;
    float c=(float)(cgs[g+1]-cgs[g]);
    gm[g][d]=pooled[idx]/fmaxf(c,1.f);
  }
  __syncthreads();
  for(int r=0;r<4;r++){
    int idx=r*256+t; int g=idx>>6, d=idx&63;
    float a=fc1b[d];
    for(int k2=0;k2<64;k2++) a+=gm[g][k2]*fc1W[k2*64+d];
    t1[g][d]=fmaxf(a,0.f);
  }
  __syncthreads();
  for(int r=0;r<4;r++){
    int idx=r*256+t; int g=idx>>6, d=idx&63;
    float a=fc2b[d];
    for(int k2=0;k2<64;k2++) a+=t1[g][k2]*fc2W[k2*64+d];
    out[idx]=a;
  }
}

extern "C" void kernel_launch(void* const* d_in, const int* in_sizes, int n_in,
                              void* d_out, int out_size, void* d_ws, size_t ws_size,
                              hipStream_t stream){
  const float* x       =(const float*)d_in[0];
  const int*   ei      =(const int*)  d_in[1];
  const int*   src     =ei;
  const int*   dst     =ei+EE;
  const int*   batch   =(const int*)  d_in[2];
  const float* gat1_W  =(const float*)d_in[3];
  const float* gat1_as =(const float*)d_in[4];
  const float* gat1_ad =(const float*)d_in[5];
  const float* gat1_b  =(const float*)d_in[6];
  const float* gat2_W  =(const float*)d_in[7];
  const float* gat2_as =(const float*)d_in[8];
  const float* gat2_ad =(const float*)d_in[9];
  const float* gat2_b  =(const float*)d_in[10];
  const float* gin_W1  =(const float*)d_in[11];
  const float* gin_b1  =(const float*)d_in[12];
  const float* gin_W2  =(const float*)d_in[13];
  const float* gin_b2  =(const float*)d_in[14];
  const float* sage1_Wl=(const float*)d_in[15];
  const float* sage1_bl=(const float*)d_in[16];
  const float* sage1_Wr=(const float*)d_in[17];
  const float* sage2_Wl=(const float*)d_in[18];
  const float* sage2_bl=(const float*)d_in[19];
  const float* sage2_Wr=(const float*)d_in[20];
  const float* tr_Wq   =(const float*)d_in[21];
  const float* tr_bq   =(const float*)d_in[22];
  const float* tr_Wk   =(const float*)d_in[23];
  const float* tr_bk   =(const float*)d_in[24];
  const float* tr_Wv   =(const float*)d_in[25];
  const float* tr_bv   =(const float*)d_in[26];
  const float* tr_Ws   =(const float*)d_in[27];
  const float* tr_bs   =(const float*)d_in[28];
  const float* ec_W1   =(const float*)d_in[29];
  const float* ec_b1   =(const float*)d_in[30];
  const float* ec_W2   =(const float*)d_in[31];
  const float* ec_b2   =(const float*)d_in[32];
  const float* fc1_W   =(const float*)d_in[33];
  const float* fc1_b   =(const float*)d_in[34];
  const float* fc2_W   =(const float*)d_in[35];
  const float* fc2_b   =(const float*)d_in[36];

  // ---- workspace layout (floats first, then ints) ----
  float* base=(float*)d_ws;
  size_t off=0;
  auto alloc=[&](size_t n){ float* p=base+off; off+=n; return p; };
  float* A_big =alloc((size_t)NN*256);     // GAT h / SAGE xcat / TR q then v
  float* nb0   =alloc(N64);
  float* nb1   =alloc(N64);                // nb1..nb4 contiguous: TR k [N,256]
  float* nb2   =alloc(N64);
  float* nb3   =alloc(N64);
  float* nb4   =alloc(N64);
  float* nb5   =alloc(N64);                // emax (as unsigned, zeroed)
  float* logitE=alloc((size_t)EE*4);
  float* ls    =alloc(NN*4);               // GAT ls
  float* ldb   =alloc(NN*4);               // GAT ld / EdgeConv Wd (4096)
  float* invdeg=alloc(NN);
  float* pooled=alloc(GG*64);
  int* ibase=(int*)(base+off);
  int* srcS  =ibase;
  int* dstS  =ibase+EE;
  int* cnt   =ibase+2*EE;
  int* fillp =ibase+2*EE+NN;               // cnt,fillp contiguous (zeroed together)
  int* rowptr=ibase+2*EE+2*NN;             // NN+1 ints
  int* bsum  =ibase+2*EE+3*NN+8;           // 49 ints
  int* boff  =bsum+64;                     // 49 ints

  const int BT=256;
  const int NSB=cdiv(NN,1024);             // 49 scan blocks
  // ---- zero init ----
  zero_kernel<<<cdiv(2*NN,BT),BT,0,stream>>>((unsigned*)cnt,2*NN);
  zero_kernel<<<cdiv(GG*64,BT),BT,0,stream>>>((unsigned*)pooled,GG*64);
  zero_kernel<<<cdiv(N64,BT),BT,0,stream>>>((unsigned*)nb5,N64);
  // ---- CSR ----
  hist_kernel<<<cdiv(EE,BT),BT,0,stream>>>(dst,cnt);
  scan1_kernel<<<NSB,1024,0,stream>>>(cnt,rowptr,bsum);
  scan2_kernel<<<1,64,0,stream>>>(bsum,boff,rowptr,NSB);
  scan3_kernel<<<cdiv(NN,BT),BT,0,stream>>>(rowptr,boff);
  fill_kernel<<<cdiv(EE,BT),BT,0,stream>>>(src,dst,rowptr,fillp,srcS,dstS);
  invdeg_kernel<<<cdiv(NN,BT),BT,0,stream>>>(cnt,invdeg);

  const int GB=cdiv(NN,64);        // 782 row tiles
  const int GW=cdiv(NN,4);         // wave-per-node blocks (12500)

  // ---- GAT1 (attn dots fused in GEMM epilogue) ----
  gemm_kernel<128><<<dim3(GB,4),BT,0,stream>>>(x,gat1_W,nullptr,256,0,nullptr,nullptr,A_big,256,0,
                                               gat1_as,gat1_ad,ls,ldb);
  gat1p_kernel<<<GW,BT,0,stream>>>(A_big,rowptr,srcS,ls,ldb,gat1_b,nb0);               // x1
  // ---- GAT2 ----
  gemm_kernel<64><<<dim3(GB,4),BT,0,stream>>>(nb0,gat2_W,nullptr,256,0,nullptr,nullptr,A_big,256,0,
                                              gat2_as,gat2_ad,ls,ldb);
  gat1p_kernel<<<GW,BT,0,stream>>>(A_big,rowptr,srcS,ls,ldb,gat2_b,nb1);               // x2
  // ---- GIN ----
  agg_kernel<<<GW,BT,0,stream>>>(nb1,rowptr,srcS,nb2);                                 // t = x2+agg
  gemm_kernel<64><<<dim3(GB,1),BT,0,stream>>>(nb2,gin_W1,nullptr,64,0,gin_b1,nullptr,nb3,64,1,
                                              nullptr,nullptr,nullptr,nullptr);
  gemm_kernel<64><<<dim3(GB,1),BT,0,stream>>>(nb3,gin_W2,nullptr,64,0,gin_b2,nullptr,nb0,64,1,
                                              nullptr,nullptr,nullptr,nullptr);        // x3
  // ---- SAGE1: xcat=[mean(x3), x3] @ [Wl;Wr] + bl ----
  agg2_kernel<<<GW,BT,0,stream>>>(nb0,rowptr,srcS,invdeg,A_big);
  gemm_kernel<128><<<dim3(GB,1),BT,0,stream>>>(A_big,sage1_Wl,sage1_Wr,64,0,sage1_bl,nullptr,nb1,64,1,
                                               nullptr,nullptr,nullptr,nullptr);       // xs
  // ---- SAGE2 ----
  agg2_kernel<<<GW,BT,0,stream>>>(nb1,rowptr,srcS,invdeg,A_big);
  gemm_kernel<128><<<dim3(GB,1),BT,0,stream>>>(A_big,sage2_Wl,sage2_Wr,64,0,sage2_bl,nullptr,nb0,64,1,
                                               nullptr,nullptr,nullptr,nullptr);       // x4
  // ---- TransformerConv ----
  float* qv=A_big;                 // q, later overwritten by v
  float* kh=nb1;                   // k occupies nb1..nb4 [N,256]
  gemm_kernel<64><<<dim3(GB,4),BT,0,stream>>>(nb0,tr_Wq,nullptr,256,0,tr_bq,nullptr,qv,256,0,
                                              nullptr,nullptr,nullptr,nullptr);
  gemm_kernel<64><<<dim3(GB,4),BT,0,stream>>>(nb0,tr_Wk,nullptr,256,0,tr_bk,nullptr,kh,256,0,
                                              nullptr,nullptr,nullptr,nullptr);
  tr_pass1_kernel<<<GW,BT,0,stream>>>(rowptr,srcS,qv,kh,logitE);                       // logits
  gemm_kernel<64><<<dim3(GB,4),BT,0,stream>>>(nb0,tr_Wv,nullptr,256,0,tr_bv,nullptr,qv,256,0,
                                              nullptr,nullptr,nullptr,nullptr);        // v over q
  gemm_kernel<64><<<dim3(GB,1),BT,0,stream>>>(nb0,tr_Ws,nullptr,64,0,tr_bs,nullptr,nb1,64,0,
                                              nullptr,nullptr,nullptr,nullptr);        // skip (k dead)
  tr_pass2_kernel<<<GW,BT,0,stream>>>(rowptr,srcS,logitE,qv,nb1,nb2);                  // x5
  // ---- EdgeConv (factored): P=x5@(W1a-W1b)+b1, Q=x5@W1b ----
  wd_kernel<<<16,BT,0,stream>>>(ec_W1,ldb);
  gemm_kernel<64><<<dim3(GB,1),BT,0,stream>>>(nb2,ldb,nullptr,64,0,ec_b1,nullptr,nb3,64,0,
                                              nullptr,nullptr,nullptr,nullptr);        // P
  gemm_kernel<64><<<dim3(GB,1),BT,0,stream>>>(nb2,ec_W1+4096,nullptr,64,0,nullptr,nullptr,nb4,64,0,
                                              nullptr,nullptr,nullptr,nullptr);        // Q
  edgeconv2_kernel<<<EE/64,BT,0,stream>>>(nb3,nb4,srcS,dstS,ec_W2,ec_b2,(unsigned*)nb5);
  // ---- pool (emax decode fused) + MLP ----
  pool_kernel<<<cdiv(NN,200),BT,0,stream>>>((unsigned*)nb5,batch,pooled);
  final_kernel<<<1,BT,0,stream>>>(pooled,batch,fc1_W,fc1_b,fc2_W,fc2_b,(float*)d_out);
}

// Round 6
// 1200.612 us; speedup vs baseline: 1.9509x; 1.0597x over previous
//
#include <hip/hip_runtime.h>

#define NN 50000
#define EE 640000
#define GG 16
#define N64 (NN*64)

static inline int cdiv(int a,int b){return (a+b-1)/b;}

__device__ __forceinline__ float lrelu(float x){ return x>0.f? x : 0.2f*x; }
// monotonic float->uint encoding for atomicMax on floats
__device__ __forceinline__ unsigned fenc(float f){
  unsigned u=__float_as_uint(f);
  return (u&0x80000000u)? ~u : (u|0x80000000u);
}

// acc[0..3] += av . {w0..w3} columns
__device__ __forceinline__ void mac4(float* acc, const float4 av,
    const float4 w0, const float4 w1, const float4 w2, const float4 w3){
  acc[0]+=av.x*w0.x+av.y*w1.x+av.z*w2.x+av.w*w3.x;
  acc[1]+=av.x*w0.y+av.y*w1.y+av.z*w2.y+av.w*w3.y;
  acc[2]+=av.x*w0.z+av.y*w1.z+av.z*w2.z+av.w*w3.z;
  acc[3]+=av.x*w0.w+av.y*w1.w+av.z*w2.w+av.w*w3.w;
}

__global__ void zero_kernel(unsigned* p, int n){
  int i=blockIdx.x*blockDim.x+threadIdx.x;
  if(i<n) p[i]=0u;
}

__global__ void hist_kernel(const int* __restrict__ dst, int* __restrict__ cnt){
  int e=blockIdx.x*blockDim.x+threadIdx.x;
  if(e<EE) atomicAdd(&cnt[dst[e]],1);
}

// 3-stage scan
__global__ __launch_bounds__(1024) void scan1_kernel(const int* __restrict__ cnt,
    int* __restrict__ rowptr, int* __restrict__ bsum){
  __shared__ int wsum[16];
  int t=threadIdx.x, b=blockIdx.x;
  int i=b*1024+t;
  int v=(i<NN)?cnt[i]:0;
  int lane=t&63, w=t>>6;
  int inc=v;
  #pragma unroll
  for(int o=1;o<64;o<<=1){ int u=__shfl_up(inc,o,64); if(lane>=o) inc+=u; }
  if(lane==63) wsum[w]=inc;
  __syncthreads();
  if(t<16){
    int s=wsum[t];
    #pragma unroll
    for(int o=1;o<16;o<<=1){ int u=__shfl_up(s,o,16); if(t>=o) s+=u; }
    wsum[t]=s;
  }
  __syncthreads();
  int woff=(w>0)?wsum[w-1]:0;
  if(i<NN) rowptr[i]=woff+inc-v;   // block-local exclusive
  if(t==1023) bsum[b]=wsum[15];
}

__global__ void scan2_kernel(const int* __restrict__ bsum, int* __restrict__ boff, int* __restrict__ rowptr, int nb){
  int t=threadIdx.x;  // 64 threads
  int v=(t<nb)?bsum[t]:0;
  int inc=v;
  #pragma unroll
  for(int o=1;o<64;o<<=1){ int u=__shfl_up(inc,o,64); if(t>=o) inc+=u; }
  if(t<nb) boff[t]=inc-v;
  if(t==63) rowptr[NN]=inc;
}

__global__ void scan3_kernel(int* __restrict__ rowptr, const int* __restrict__ boff){
  int i=blockIdx.x*blockDim.x+threadIdx.x;
  if(i<NN) rowptr[i]+=boff[i>>10];
}

__global__ void fill_kernel(const int* __restrict__ src, const int* __restrict__ dst,
                            const int* __restrict__ rowptr, int* __restrict__ fillp,
                            int* __restrict__ srcS, int* __restrict__ dstS){
  int e=blockIdx.x*blockDim.x+threadIdx.x;
  if(e>=EE) return;
  int d=dst[e];
  int p=rowptr[d]+atomicAdd(&fillp[d],1);
  srcS[p]=src[e]; dstS[p]=d;
}

__global__ void invdeg_kernel(const int* __restrict__ cnt, float* __restrict__ invdeg){
  int i=blockIdx.x*blockDim.x+threadIdx.x;
  if(i<NN) invdeg[i]=1.f/fmaxf((float)cnt[i],1.f);
}

// Wd[k][n] = W1[k][n] - W1[64+k][n]   (64x64)
__global__ void wd_kernel(const float* __restrict__ W1, float* __restrict__ Wd){
  int i=blockIdx.x*blockDim.x+threadIdx.x;
  if(i<4096) Wd[i]=W1[i]-W1[4096+i];
}

// C[NN, ldc(+nc0 slice)] = act(A[NN,K] @ W[K, ldw](cols wc..) + bias + addend)
// Wb: rows >=64 of combined weight. lsO: fused GAT attn-dot epilogue (head=blockIdx.y).
template<int K>
__global__ __launch_bounds__(256) void gemm_kernel(
    const float* __restrict__ A, const float* __restrict__ W, const float* __restrict__ Wb,
    int ldw, int wcol0,
    const float* __restrict__ bias, const float* __restrict__ addend,
    float* __restrict__ C, int ldc, int relu_flag,
    const float* __restrict__ a_s, const float* __restrict__ a_d,
    float* __restrict__ lsO, float* __restrict__ ldO){
  __shared__ float As[64][68];
  __shared__ float Ws[64][64];
  const int m0=blockIdx.x*64;
  const int nc0=blockIdx.y*64;
  const int wc=wcol0+nc0;
  const int tid=threadIdx.x, tx=tid&15, ty=tid>>4;
  float acc[4][4];
  #pragma unroll
  for(int i=0;i<4;i++){
    #pragma unroll
    for(int j=0;j<4;j++) acc[i][j]=bias? bias[wc+tx*4+j]:0.f;
  }
  for(int k0=0;k0<K;k0+=64){
    const float* Wp=(Wb && k0>=64)? Wb : W;
    const int kb =(Wb && k0>=64)? k0-64 : k0;
    __syncthreads();
    #pragma unroll
    for(int it=0;it<4;it++){
      int linear=it*1024+tid*4;
      int m=linear>>6, k=linear&63;
      float4 v=make_float4(0.f,0.f,0.f,0.f);
      if(m0+m<NN) v=*(const float4*)(A+(size_t)(m0+m)*K+k0+k);
      *(float4*)&As[m][k]=v;
    }
    #pragma unroll
    for(int it=0;it<4;it++){
      int linear=it*1024+tid*4;
      int k=linear>>6, n=linear&63;
      *(float4*)&Ws[k][n]=*(const float4*)(Wp+(size_t)(kb+k)*ldw+wc+n);
    }
    __syncthreads();
    #pragma unroll 8
    for(int k=0;k<64;k+=4){
      float4 a0=*(float4*)&As[ty*4+0][k];
      float4 a1=*(float4*)&As[ty*4+1][k];
      float4 a2=*(float4*)&As[ty*4+2][k];
      float4 a3=*(float4*)&As[ty*4+3][k];
      float4 w0=*(float4*)&Ws[k+0][tx*4];
      float4 w1=*(float4*)&Ws[k+1][tx*4];
      float4 w2=*(float4*)&Ws[k+2][tx*4];
      float4 w3=*(float4*)&Ws[k+3][tx*4];
      mac4(acc[0],a0,w0,w1,w2,w3);
      mac4(acc[1],a1,w0,w1,w2,w3);
      mac4(acc[2],a2,w0,w1,w2,w3);
      mac4(acc[3],a3,w0,w1,w2,w3);
    }
  }
  float4 asv,adv;
  if(lsO){
    asv=*(const float4*)(a_s+(size_t)blockIdx.y*64+tx*4);
    adv=*(const float4*)(a_d+(size_t)blockIdx.y*64+tx*4);
  }
  #pragma unroll
  for(int i=0;i<4;i++){
    int m=m0+ty*4+i;
    bool valid=(m<NN);
    float r0=acc[i][0],r1=acc[i][1],r2=acc[i][2],r3=acc[i][3];
    if(valid){
      if(addend){
        const float4 ad=*(const float4*)(addend+(size_t)m*ldc+nc0+tx*4);
        r0+=ad.x; r1+=ad.y; r2+=ad.z; r3+=ad.w;
      }
      if(relu_flag){ r0=fmaxf(r0,0.f); r1=fmaxf(r1,0.f); r2=fmaxf(r2,0.f); r3=fmaxf(r3,0.f); }
      *(float4*)(C+(size_t)m*ldc+nc0+tx*4)=make_float4(r0,r1,r2,r3);
    }
    if(lsO){
      float ps=r0*asv.x+r1*asv.y+r2*asv.z+r3*asv.w;
      float pd=r0*adv.x+r1*adv.y+r2*adv.z+r3*adv.w;
      #pragma unroll
      for(int o=1;o<16;o<<=1){ ps+=__shfl_xor(ps,o,16); pd+=__shfl_xor(pd,o,16); }
      if(valid && tx==0){
        lsO[(size_t)m*4+blockIdx.y]=ps;
        ldO[(size_t)m*4+blockIdx.y]=pd;
      }
    }
  }
}

// single-pass GAT (no max subtraction; logits are O(1) so exp is safe), unroll 4.
__global__ __launch_bounds__(256) void gat1p_kernel(const float* __restrict__ h,
    const int* __restrict__ rowptr, const int* __restrict__ srcS,
    const float* __restrict__ ls4, const float* __restrict__ ld4,
    const float* __restrict__ bias, float* __restrict__ out){
  int n=blockIdx.x*4+(threadIdx.x>>6);
  int lane=threadIdx.x&63;
  if(n>=NN) return;
  int r0=rowptr[n], r1=rowptr[n+1];
  const float4 ldv=*(const float4*)(ld4+(size_t)4*n);
  const float4 lsv=*(const float4*)(ls4+(size_t)4*n);
  float z0=__expf(lrelu(lsv.x+ldv.x)), z1=__expf(lrelu(lsv.y+ldv.y));
  float z2=__expf(lrelu(lsv.z+ldv.z)), z3=__expf(lrelu(lsv.w+ldv.w));
  const float* hn=h+(size_t)n*256;
  float a0=z0*hn[lane], a1=z1*hn[64+lane], a2=z2*hn[128+lane], a3=z3*hn[192+lane];
  int j=r0;
  for(; j+3<r1; j+=4){
    int s0=srcS[j], s1=srcS[j+1], s2=srcS[j+2], s3=srcS[j+3];
    const float4 A0=*(const float4*)(ls4+(size_t)4*s0);
    const float4 A1=*(const float4*)(ls4+(size_t)4*s1);
    const float4 A2=*(const float4*)(ls4+(size_t)4*s2);
    const float4 A3=*(const float4*)(ls4+(size_t)4*s3);
    const float* h0=h+(size_t)s0*256;
    const float* h1=h+(size_t)s1*256;
    const float* h2=h+(size_t)s2*256;
    const float* h3=h+(size_t)s3*256;
    float e00=__expf(lrelu(A0.x+ldv.x)), e01=__expf(lrelu(A0.y+ldv.y));
    float e02=__expf(lrelu(A0.z+ldv.z)), e03=__expf(lrelu(A0.w+ldv.w));
    float e10=__expf(lrelu(A1.x+ldv.x)), e11=__expf(lrelu(A1.y+ldv.y));
    float e12=__expf(lrelu(A1.z+ldv.z)), e13=__expf(lrelu(A1.w+ldv.w));
    float e20=__expf(lrelu(A2.x+ldv.x)), e21=__expf(lrelu(A2.y+ldv.y));
    float e22=__expf(lrelu(A2.z+ldv.z)), e23=__expf(lrelu(A2.w+ldv.w));
    float e30=__expf(lrelu(A3.x+ldv.x)), e31=__expf(lrelu(A3.y+ldv.y));
    float e32=__expf(lrelu(A3.z+ldv.z)), e33=__expf(lrelu(A3.w+ldv.w));
    z0+=(e00+e10)+(e20+e30); z1+=(e01+e11)+(e21+e31);
    z2+=(e02+e12)+(e22+e32); z3+=(e03+e13)+(e23+e33);
    a0+=(e00*h0[lane]+e10*h1[lane])+(e20*h2[lane]+e30*h3[lane]);
    a1+=(e01*h0[64+lane]+e11*h1[64+lane])+(e21*h2[64+lane]+e31*h3[64+lane]);
    a2+=(e02*h0[128+lane]+e12*h1[128+lane])+(e22*h2[128+lane]+e32*h3[128+lane]);
    a3+=(e03*h0[192+lane]+e13*h1[192+lane])+(e23*h2[192+lane]+e33*h3[192+lane]);
  }
  for(; j<r1; j++){
    int s0=srcS[j];
    const float4 A0=*(const float4*)(ls4+(size_t)4*s0);
    const float* h0=h+(size_t)s0*256;
    float e00=__expf(lrelu(A0.x+ldv.x)), e01=__expf(lrelu(A0.y+ldv.y));
    float e02=__expf(lrelu(A0.z+ldv.z)), e03=__expf(lrelu(A0.w+ldv.w));
    z0+=e00; z1+=e01; z2+=e02; z3+=e03;
    a0+=e00*h0[lane]; a1+=e01*h0[64+lane]; a2+=e02*h0[128+lane]; a3+=e03*h0[192+lane];
  }
  float zi0=1.f/(z0+1e-16f), zi1=1.f/(z1+1e-16f), zi2=1.f/(z2+1e-16f), zi3=1.f/(z3+1e-16f);
  out[(size_t)n*64+lane]=fmaxf(0.25f*(a0*zi0+a1*zi1+a2*zi2+a3*zi3)+bias[lane],0.f);
}

// GIN: self + sum -> out[N,64] (unroll 4)
__global__ __launch_bounds__(256) void agg_kernel(const float* __restrict__ xin,
    const int* __restrict__ rowptr, const int* __restrict__ srcS,
    float* __restrict__ out){
  int n=blockIdx.x*4+(threadIdx.x>>6);
  int lane=threadIdx.x&63;
  if(n>=NN) return;
  int r0=rowptr[n], r1=rowptr[n+1];
  float acc=xin[(size_t)n*64+lane];
  int j=r0;
  for(; j+3<r1; j+=4){
    int s0=srcS[j], s1=srcS[j+1], s2=srcS[j+2], s3=srcS[j+3];
    acc+=(xin[(size_t)s0*64+lane]+xin[(size_t)s1*64+lane])
        +(xin[(size_t)s2*64+lane]+xin[(size_t)s3*64+lane]);
  }
  for(; j<r1; j++) acc+=xin[(size_t)srcS[j]*64+lane];
  out[(size_t)n*64+lane]=acc;
}

// SAGE staging: out128[n] = [ mean_neigh(xin), xin[n] ]  (unroll 4)
__global__ __launch_bounds__(256) void agg2_kernel(const float* __restrict__ xin,
    const int* __restrict__ rowptr, const int* __restrict__ srcS,
    const float* __restrict__ invdeg, float* __restrict__ out128){
  int n=blockIdx.x*4+(threadIdx.x>>6);
  int lane=threadIdx.x&63;
  if(n>=NN) return;
  int r0=rowptr[n], r1=rowptr[n+1];
  float acc=0.f;
  int j=r0;
  for(; j+3<r1; j+=4){
    int s0=srcS[j], s1=srcS[j+1], s2=srcS[j+2], s3=srcS[j+3];
    acc+=(xin[(size_t)s0*64+lane]+xin[(size_t)s1*64+lane])
        +(xin[(size_t)s2*64+lane]+xin[(size_t)s3*64+lane]);
  }
  for(; j<r1; j++) acc+=xin[(size_t)srcS[j]*64+lane];
  out128[(size_t)n*128+lane]=acc*invdeg[n];
  out128[(size_t)n*128+64+lane]=xin[(size_t)n*64+lane];
}

// TR pass1 (edge-parallel SDDMM): 16 lanes per edge, all 4 heads.
// lane t of edge-group holds q/k float4 slices; 8 independent float4 loads in flight.
__global__ __launch_bounds__(256) void tr_pass1_kernel(const int* __restrict__ srcS, const int* __restrict__ dstS,
    const float* __restrict__ q, const float* __restrict__ k,
    float* __restrict__ lg){
  int e=blockIdx.x*16+(threadIdx.x>>4);
  int t=threadIdx.x&15;
  if(e>=EE) return;
  int s=srcS[e], d=dstS[e];
  const float* ks=k+(size_t)s*256+t*4;
  const float* qd=q+(size_t)d*256+t*4;
  float4 k0=*(const float4*)(ks);
  float4 k1=*(const float4*)(ks+64);
  float4 k2=*(const float4*)(ks+128);
  float4 k3=*(const float4*)(ks+192);
  float4 q0=*(const float4*)(qd);
  float4 q1=*(const float4*)(qd+64);
  float4 q2=*(const float4*)(qd+128);
  float4 q3=*(const float4*)(qd+192);
  float v0=k0.x*q0.x+k0.y*q0.y+k0.z*q0.z+k0.w*q0.w;
  float v1=k1.x*q1.x+k1.y*q1.y+k1.z*q1.z+k1.w*q1.w;
  float v2=k2.x*q2.x+k2.y*q2.y+k2.z*q2.z+k2.w*q2.w;
  float v3=k3.x*q3.x+k3.y*q3.y+k3.z*q3.z+k3.w*q3.w;
  #pragma unroll
  for(int o=1;o<16;o<<=1){
    v0+=__shfl_xor(v0,o,16); v1+=__shfl_xor(v1,o,16);
    v2+=__shfl_xor(v2,o,16); v3+=__shfl_xor(v3,o,16);
  }
  if(t==0)
    *(float4*)(lg+(size_t)4*e)=make_float4(v0*0.125f,v1*0.125f,v2*0.125f,v3*0.125f);
}

// TR pass2: exp (no max) + v-gather + skip + relu -> x5 (unroll 4)
__global__ __launch_bounds__(256) void tr_pass2_kernel(const int* __restrict__ rowptr, const int* __restrict__ srcS,
    const float* __restrict__ lg,
    const float* __restrict__ v, const float* __restrict__ skip, float* __restrict__ x5){
  int n=blockIdx.x*4+(threadIdx.x>>6);
  int lane=threadIdx.x&63;
  if(n>=NN) return;
  int r0=rowptr[n], r1=rowptr[n+1];
  float z0=0.f,z1=0.f,z2=0.f,z3=0.f;
  float a0=0.f,a1=0.f,a2=0.f,a3=0.f;
  int j=r0;
  for(; j+3<r1; j+=4){
    int s0=srcS[j], s1=srcS[j+1], s2=srcS[j+2], s3=srcS[j+3];
    const float4 f0=*(const float4*)(lg+(size_t)4*j);
    const float4 f1=*(const float4*)(lg+(size_t)4*(j+1));
    const float4 f2=*(const float4*)(lg+(size_t)4*(j+2));
    const float4 f3=*(const float4*)(lg+(size_t)4*(j+3));
    const float* v0=v+(size_t)s0*256;
    const float* v1=v+(size_t)s1*256;
    const float* v2=v+(size_t)s2*256;
    const float* v3=v+(size_t)s3*256;
    float e00=__expf(f0.x), e01=__expf(f0.y), e02=__expf(f0.z), e03=__expf(f0.w);
    float e10=__expf(f1.x), e11=__expf(f1.y), e12=__expf(f1.z), e13=__expf(f1.w);
    float e20=__expf(f2.x), e21=__expf(f2.y), e22=__expf(f2.z), e23=__expf(f2.w);
    float e30=__expf(f3.x), e31=__expf(f3.y), e32=__expf(f3.z), e33=__expf(f3.w);
    z0+=(e00+e10)+(e20+e30); z1+=(e01+e11)+(e21+e31);
    z2+=(e02+e12)+(e22+e32); z3+=(e03+e13)+(e23+e33);
    a0+=(e00*v0[lane]+e10*v1[lane])+(e20*v2[lane]+e30*v3[lane]);
    a1+=(e01*v0[64+lane]+e11*v1[64+lane])+(e21*v2[64+lane]+e31*v3[64+lane]);
    a2+=(e02*v0[128+lane]+e12*v1[128+lane])+(e22*v2[128+lane]+e32*v3[128+lane]);
    a3+=(e03*v0[192+lane]+e13*v1[192+lane])+(e23*v2[192+lane]+e33*v3[192+lane]);
  }
  for(; j<r1; j++){
    int s0=srcS[j];
    const float4 f0=*(const float4*)(lg+(size_t)4*j);
    const float* v0=v+(size_t)s0*256;
    float e00=__expf(f0.x), e01=__expf(f0.y), e02=__expf(f0.z), e03=__expf(f0.w);
    z0+=e00; z1+=e01; z2+=e02; z3+=e03;
    a0+=e00*v0[lane]; a1+=e01*v0[64+lane]; a2+=e02*v0[128+lane]; a3+=e03*v0[192+lane];
  }
  float zi0=1.f/(z0+1e-16f), zi1=1.f/(z1+1e-16f), zi2=1.f/(z2+1e-16f), zi3=1.f/(z3+1e-16f);
  float t=0.25f*(a0*zi0+a1*zi1+a2*zi2+a3*zi3)+skip[(size_t)n*64+lane];
  x5[(size_t)n*64+lane]=fmaxf(t,0.f);
}

// EdgeConv v2: hidden = relu(P[dst]+Q[src]) -> GEMM2(+b2) -> run-merged atomicMax
__global__ __launch_bounds__(256) void edgeconv2_kernel(
    const float* __restrict__ P, const float* __restrict__ Q,
    const int* __restrict__ srcS, const int* __restrict__ dstS,
    const float* __restrict__ W2, const float* __restrict__ b2,
    unsigned* __restrict__ emax){
  __shared__ float As[64][68];   // hidden tile
  __shared__ float Ws[64][64];
  const int e0=blockIdx.x*64;
  const int tid=threadIdx.x, tx=tid&15, ty=tid>>4;
  #pragma unroll
  for(int it=0;it<4;it++){
    int linear=it*1024+tid*4;
    int m=linear>>6, k=linear&63;
    int e=e0+m;
    float4 v=make_float4(0.f,0.f,0.f,0.f);
    if(e<EE){
      int dn=dstS[e], sn=srcS[e];
      const float4 p=*(const float4*)(P+(size_t)dn*64+k);
      const float4 q=*(const float4*)(Q+(size_t)sn*64+k);
      v=make_float4(fmaxf(p.x+q.x,0.f),fmaxf(p.y+q.y,0.f),fmaxf(p.z+q.z,0.f),fmaxf(p.w+q.w,0.f));
    }
    *(float4*)&As[m][k]=v;
  }
  #pragma unroll
  for(int it=0;it<4;it++){
    int linear=it*1024+tid*4;
    int k=linear>>6, n=linear&63;
    *(float4*)&Ws[k][n]=*(const float4*)(W2+(size_t)k*64+n);
  }
  __syncthreads();
  float acc2[4][4];
  #pragma unroll
  for(int i=0;i<4;i++)
    #pragma unroll
    for(int j=0;j<4;j++) acc2[i][j]=b2[tx*4+j];
  #pragma unroll 8
  for(int k=0;k<64;k+=4){
    float4 a0=*(float4*)&As[ty*4+0][k];
    float4 a1=*(float4*)&As[ty*4+1][k];
    float4 a2=*(float4*)&As[ty*4+2][k];
    float4 a3=*(float4*)&As[ty*4+3][k];
    float4 w0=*(float4*)&Ws[k+0][tx*4];
    float4 w1=*(float4*)&Ws[k+1][tx*4];
    float4 w2=*(float4*)&Ws[k+2][tx*4];
    float4 w3=*(float4*)&Ws[k+3][tx*4];
    mac4(acc2[0],a0,w0,w1,w2,w3);
    mac4(acc2[1],a1,w0,w1,w2,w3);
    mac4(acc2[2],a2,w0,w1,w2,w3);
    mac4(acc2[3],a3,w0,w1,w2,w3);
  }
  // run-merge consecutive rows with same dst, then atomicMax
  int dprev=-1;
  float mx0=0,mx1=0,mx2=0,mx3=0;
  #pragma unroll
  for(int i=0;i<4;i++){
    int e=e0+ty*4+i;
    if(e>=EE) continue;
    int dn=dstS[e];
    if(dn!=dprev){
      if(dprev>=0){
        atomicMax(&emax[(size_t)dprev*64+tx*4+0],fenc(mx0));
        atomicMax(&emax[(size_t)dprev*64+tx*4+1],fenc(mx1));
        atomicMax(&emax[(size_t)dprev*64+tx*4+2],fenc(mx2));
        atomicMax(&emax[(size_t)dprev*64+tx*4+3],fenc(mx3));
      }
      dprev=dn; mx0=acc2[i][0]; mx1=acc2[i][1]; mx2=acc2[i][2]; mx3=acc2[i][3];
    }else{
      mx0=fmaxf(mx0,acc2[i][0]); mx1=fmaxf(mx1,acc2[i][1]);
      mx2=fmaxf(mx2,acc2[i][2]); mx3=fmaxf(mx3,acc2[i][3]);
    }
  }
  if(dprev>=0){
    atomicMax(&emax[(size_t)dprev*64+tx*4+0],fenc(mx0));
    atomicMax(&emax[(size_t)dprev*64+tx*4+1],fenc(mx1));
    atomicMax(&emax[(size_t)dprev*64+tx*4+2],fenc(mx2));
    atomicMax(&emax[(size_t)dprev*64+tx*4+3],fenc(mx3));
  }
}

// pool with emax decode fused
__global__ __launch_bounds__(256) void pool_kernel(const unsigned* __restrict__ emax, const int* __restrict__ batch,
                                                   float* __restrict__ pooled){
  const int NB=200;
  int base=blockIdx.x*NB;
  int lane=threadIdx.x&63;
  int wsub=threadIdx.x>>6;
  float acc=0.f; int curg=-1;
  for(int idx=wsub; idx<NB; idx+=4){
    int n=base+idx;
    if(n>=NN) break;
    int g=batch[n];
    if(g!=curg){
      if(curg>=0) atomicAdd(&pooled[curg*64+lane],acc);
      acc=0.f; curg=g;
    }
    unsigned u=emax[(size_t)n*64+lane];
    acc+=(u>=0x80000000u)? __uint_as_float(u&0x7fffffffu) : 0.f;
  }
  if(curg>=0) atomicAdd(&pooled[curg*64+lane],acc);
}

__global__ __launch_bounds__(256) void final_kernel(const float* __restrict__ pooled, const int* __restrict__ batch,
    const float* __restrict__ fc1W, const float* __restrict__ fc1b,
    const float* __restrict__ fc2W, const float* __restrict__ fc2b,
    float* __restrict__ out){
  __shared__ float gm[16][64];
  __shared__ float t1[16][64];
  __shared__ int cgs[17];
  int t=threadIdx.x;
  if(t<17){
    int lo=0, hi=NN;
    while(lo<hi){ int mid=(lo+hi)>>1; if(batch[mid]<t) lo=mid+1; else hi=mid; }
    cgs[t]=lo;
  }
  __syncthreads();
  for(int r=0;r<4;r++){
    int idx=r*256+t; int g=idx>>6, d=idx&63;
    float c=(float)(cgs[g+1]-cgs[g]);
    gm[g][d]=pooled[idx]/fmaxf(c,1.f);
  }
  __syncthreads();
  for(int r=0;r<4;r++){
    int idx=r*256+t; int g=idx>>6, d=idx&63;
    float a=fc1b[d];
    for(int k2=0;k2<64;k2++) a+=gm[g][k2]*fc1W[k2*64+d];
    t1[g][d]=fmaxf(a,0.f);
  }
  __syncthreads();
  for(int r=0;r<4;r++){
    int idx=r*256+t; int g=idx>>6, d=idx&63;
    float a=fc2b[d];
    for(int k2=0;k2<64;k2++) a+=t1[g][k2]*fc2W[k2*64+d];
    out[idx]=a;
  }
}

extern "C" void kernel_launch(void* const* d_in, const int* in_sizes, int n_in,
                              void* d_out, int out_size, void* d_ws, size_t ws_size,
                              hipStream_t stream){
  const float* x       =(const float*)d_in[0];
  const int*   ei      =(const int*)  d_in[1];
  const int*   src     =ei;
  const int*   dst     =ei+EE;
  const int*   batch   =(const int*)  d_in[2];
  const float* gat1_W  =(const float*)d_in[3];
  const float* gat1_as =(const float*)d_in[4];
  const float* gat1_ad =(const float*)d_in[5];
  const float* gat1_b  =(const float*)d_in[6];
  const float* gat2_W  =(const float*)d_in[7];
  const float* gat2_as =(const float*)d_in[8];
  const float* gat2_ad =(const float*)d_in[9];
  const float* gat2_b  =(const float*)d_in[10];
  const float* gin_W1  =(const float*)d_in[11];
  const float* gin_b1  =(const float*)d_in[12];
  const float* gin_W2  =(const float*)d_in[13];
  const float* gin_b2  =(const float*)d_in[14];
  const float* sage1_Wl=(const float*)d_in[15];
  const float* sage1_bl=(const float*)d_in[16];
  const float* sage1_Wr=(const float*)d_in[17];
  const float* sage2_Wl=(const float*)d_in[18];
  const float* sage2_bl=(const float*)d_in[19];
  const float* sage2_Wr=(const float*)d_in[20];
  const float* tr_Wq   =(const float*)d_in[21];
  const float* tr_bq   =(const float*)d_in[22];
  const float* tr_Wk   =(const float*)d_in[23];
  const float* tr_bk   =(const float*)d_in[24];
  const float* tr_Wv   =(const float*)d_in[25];
  const float* tr_bv   =(const float*)d_in[26];
  const float* tr_Ws   =(const float*)d_in[27];
  const float* tr_bs   =(const float*)d_in[28];
  const float* ec_W1   =(const float*)d_in[29];
  const float* ec_b1   =(const float*)d_in[30];
  const float* ec_W2   =(const float*)d_in[31];
  const float* ec_b2   =(const float*)d_in[32];
  const float* fc1_W   =(const float*)d_in[33];
  const float* fc1_b   =(const float*)d_in[34];
  const float* fc2_W   =(const float*)d_in[35];
  const float* fc2_b   =(const float*)d_in[36];

  // ---- workspace layout (floats first, then ints) ----
  float* base=(float*)d_ws;
  size_t off=0;
  auto alloc=[&](size_t n){ float* p=base+off; off+=n; return p; };
  float* A_big =alloc((size_t)NN*256);     // GAT h / SAGE xcat / TR q then v
  float* nb0   =alloc(N64);
  float* nb1   =alloc(N64);                // nb1..nb4 contiguous: TR k [N,256]
  float* nb2   =alloc(N64);
  float* nb3   =alloc(N64);
  float* nb4   =alloc(N64);
  float* nb5   =alloc(N64);                // emax (as unsigned, zeroed)
  float* logitE=alloc((size_t)EE*4);
  float* ls    =alloc(NN*4);               // GAT ls
  float* ldb   =alloc(NN*4);               // GAT ld / EdgeConv Wd (4096)
  float* invdeg=alloc(NN);
  float* pooled=alloc(GG*64);
  int* ibase=(int*)(base+off);
  int* srcS  =ibase;
  int* dstS  =ibase+EE;
  int* cnt   =ibase+2*EE;
  int* fillp =ibase+2*EE+NN;               // cnt,fillp contiguous (zeroed together)
  int* rowptr=ibase+2*EE+2*NN;             // NN+1 ints
  int* bsum  =ibase+2*EE+3*NN+8;           // 49 ints
  int* boff  =bsum+64;                     // 49 ints

  const int BT=256;
  const int NSB=cdiv(NN,1024);             // 49 scan blocks
  // ---- zero init ----
  zero_kernel<<<cdiv(2*NN,BT),BT,0,stream>>>((unsigned*)cnt,2*NN);
  zero_kernel<<<cdiv(GG*64,BT),BT,0,stream>>>((unsigned*)pooled,GG*64);
  zero_kernel<<<cdiv(N64,BT),BT,0,stream>>>((unsigned*)nb5,N64);
  // ---- CSR ----
  hist_kernel<<<cdiv(EE,BT),BT,0,stream>>>(dst,cnt);
  scan1_kernel<<<NSB,1024,0,stream>>>(cnt,rowptr,bsum);
  scan2_kernel<<<1,64,0,stream>>>(bsum,boff,rowptr,NSB);
  scan3_kernel<<<cdiv(NN,BT),BT,0,stream>>>(rowptr,boff);
  fill_kernel<<<cdiv(EE,BT),BT,0,stream>>>(src,dst,rowptr,fillp,srcS,dstS);
  invdeg_kernel<<<cdiv(NN,BT),BT,0,stream>>>(cnt,invdeg);

  const int GB=cdiv(NN,64);        // 782 row tiles
  const int GW=cdiv(NN,4);         // wave-per-node blocks (12500)

  // ---- GAT1 (attn dots fused in GEMM epilogue) ----
  gemm_kernel<128><<<dim3(GB,4),BT,0,stream>>>(x,gat1_W,nullptr,256,0,nullptr,nullptr,A_big,256,0,
                                               gat1_as,gat1_ad,ls,ldb);
  gat1p_kernel<<<GW,BT,0,stream>>>(A_big,rowptr,srcS,ls,ldb,gat1_b,nb0);               // x1
  // ---- GAT2 ----
  gemm_kernel<64><<<dim3(GB,4),BT,0,stream>>>(nb0,gat2_W,nullptr,256,0,nullptr,nullptr,A_big,256,0,
                                              gat2_as,gat2_ad,ls,ldb);
  gat1p_kernel<<<GW,BT,0,stream>>>(A_big,rowptr,srcS,ls,ldb,gat2_b,nb1);               // x2
  // ---- GIN ----
  agg_kernel<<<GW,BT,0,stream>>>(nb1,rowptr,srcS,nb2);                                 // t = x2+agg
  gemm_kernel<64><<<dim3(GB,1),BT,0,stream>>>(nb2,gin_W1,nullptr,64,0,gin_b1,nullptr,nb3,64,1,
                                              nullptr,nullptr,nullptr,nullptr);
  gemm_kernel<64><<<dim3(GB,1),BT,0,stream>>>(nb3,gin_W2,nullptr,64,0,gin_b2,nullptr,nb0,64,1,
                                              nullptr,nullptr,nullptr,nullptr);        // x3
  // ---- SAGE1: xcat=[mean(x3), x3] @ [Wl;Wr] + bl ----
  agg2_kernel<<<GW,BT,0,stream>>>(nb0,rowptr,srcS,invdeg,A_big);
  gemm_kernel<128><<<dim3(GB,1),BT,0,stream>>>(A_big,sage1_Wl,sage1_Wr,64,0,sage1_bl,nullptr,nb1,64,1,
                                               nullptr,nullptr,nullptr,nullptr);       // xs
  // ---- SAGE2 ----
  agg2_kernel<<<GW,BT,0,stream>>>(nb1,rowptr,srcS,invdeg,A_big);
  gemm_kernel<128><<<dim3(GB,1),BT,0,stream>>>(A_big,sage2_Wl,sage2_Wr,64,0,sage2_bl,nullptr,nb0,64,1,
                                               nullptr,nullptr,nullptr,nullptr);       // x4
  // ---- TransformerConv ----
  float* qv=A_big;                 // q, later overwritten by v
  float* kh=nb1;                   // k occupies nb1..nb4 [N,256]
  gemm_kernel<64><<<dim3(GB,4),BT,0,stream>>>(nb0,tr_Wq,nullptr,256,0,tr_bq,nullptr,qv,256,0,
                                              nullptr,nullptr,nullptr,nullptr);
  gemm_kernel<64><<<dim3(GB,4),BT,0,stream>>>(nb0,tr_Wk,nullptr,256,0,tr_bk,nullptr,kh,256,0,
                                              nullptr,nullptr,nullptr,nullptr);
  tr_pass1_kernel<<<cdiv(EE,16),BT,0,stream>>>(srcS,dstS,qv,kh,logitE);                // logits
  gemm_kernel<64><<<dim3(GB,4),BT,0,stream>>>(nb0,tr_Wv,nullptr,256,0,tr_bv,nullptr,qv,256,0,
                                              nullptr,nullptr,nullptr,nullptr);        // v over q
  gemm_kernel<64><<<dim3(GB,1),BT,0,stream>>>(nb0,tr_Ws,nullptr,64,0,tr_bs,nullptr,nb1,64,0,
                                              nullptr,nullptr,nullptr,nullptr);        // skip (k dead)
  tr_pass2_kernel<<<GW,BT,0,stream>>>(rowptr,srcS,logitE,qv,nb1,nb2);                  // x5
  // ---- EdgeConv (factored): P=x5@(W1a-W1b)+b1, Q=x5@W1b ----
  wd_kernel<<<16,BT,0,stream>>>(ec_W1,ldb);
  gemm_kernel<64><<<dim3(GB,1),BT,0,stream>>>(nb2,ldb,nullptr,64,0,ec_b1,nullptr,nb3,64,0,
                                              nullptr,nullptr,nullptr,nullptr);        // P
  gemm_kernel<64><<<dim3(GB,1),BT,0,stream>>>(nb2,ec_W1+4096,nullptr,64,0,nullptr,nullptr,nb4,64,0,
                                              nullptr,nullptr,nullptr,nullptr);        // Q
  edgeconv2_kernel<<<EE/64,BT,0,stream>>>(nb3,nb4,srcS,dstS,ec_W2,ec_b2,(unsigned*)nb5);
  // ---- pool (emax decode fused) + MLP ----
  pool_kernel<<<cdiv(NN,200),BT,0,stream>>>((unsigned*)nb5,batch,pooled);
  final_kernel<<<1,BT,0,stream>>>(pooled,batch,fc1_W,fc1_b,fc2_W,fc2_b,(float*)d_out);
}

// Round 7
// 1134.866 us; speedup vs baseline: 2.0639x; 1.0579x over previous
//
#include <hip/hip_runtime.h>

#define NN 50000
#define EE 640000
#define GG 16
#define N64 (NN*64)

static inline int cdiv(int a,int b){return (a+b-1)/b;}

__device__ __forceinline__ float lrelu(float x){ return x>0.f? x : 0.2f*x; }
// monotonic float->uint encoding for atomicMax on floats
__device__ __forceinline__ unsigned fenc(float f){
  unsigned u=__float_as_uint(f);
  return (u&0x80000000u)? ~u : (u|0x80000000u);
}

// acc[0..3] += av . {w0..w3} columns
__device__ __forceinline__ void mac4(float* acc, const float4 av,
    const float4 w0, const float4 w1, const float4 w2, const float4 w3){
  acc[0]+=av.x*w0.x+av.y*w1.x+av.z*w2.x+av.w*w3.x;
  acc[1]+=av.x*w0.y+av.y*w1.y+av.z*w2.y+av.w*w3.y;
  acc[2]+=av.x*w0.z+av.y*w1.z+av.z*w2.z+av.w*w3.z;
  acc[3]+=av.x*w0.w+av.y*w1.w+av.z*w2.w+av.w*w3.w;
}

__global__ void zero_kernel(unsigned* p, int n){
  int i=blockIdx.x*blockDim.x+threadIdx.x;
  if(i<n) p[i]=0u;
}

__global__ void hist_kernel(const int* __restrict__ dst, int* __restrict__ cnt){
  int e=blockIdx.x*blockDim.x+threadIdx.x;
  if(e<EE) atomicAdd(&cnt[dst[e]],1);
}

// 3-stage scan
__global__ __launch_bounds__(1024) void scan1_kernel(const int* __restrict__ cnt,
    int* __restrict__ rowptr, int* __restrict__ bsum){
  __shared__ int wsum[16];
  int t=threadIdx.x, b=blockIdx.x;
  int i=b*1024+t;
  int v=(i<NN)?cnt[i]:0;
  int lane=t&63, w=t>>6;
  int inc=v;
  #pragma unroll
  for(int o=1;o<64;o<<=1){ int u=__shfl_up(inc,o,64); if(lane>=o) inc+=u; }
  if(lane==63) wsum[w]=inc;
  __syncthreads();
  if(t<16){
    int s=wsum[t];
    #pragma unroll
    for(int o=1;o<16;o<<=1){ int u=__shfl_up(s,o,16); if(t>=o) s+=u; }
    wsum[t]=s;
  }
  __syncthreads();
  int woff=(w>0)?wsum[w-1]:0;
  if(i<NN) rowptr[i]=woff+inc-v;   // block-local exclusive
  if(t==1023) bsum[b]=wsum[15];
}

__global__ void scan2_kernel(const int* __restrict__ bsum, int* __restrict__ boff, int* __restrict__ rowptr, int nb){
  int t=threadIdx.x;  // 64 threads
  int v=(t<nb)?bsum[t]:0;
  int inc=v;
  #pragma unroll
  for(int o=1;o<64;o<<=1){ int u=__shfl_up(inc,o,64); if(t>=o) inc+=u; }
  if(t<nb) boff[t]=inc-v;
  if(t==63) rowptr[NN]=inc;
}

__global__ void scan3_kernel(int* __restrict__ rowptr, const int* __restrict__ boff){
  int i=blockIdx.x*blockDim.x+threadIdx.x;
  if(i<NN) rowptr[i]+=boff[i>>10];
}

__global__ void fill_kernel(const int* __restrict__ src, const int* __restrict__ dst,
                            const int* __restrict__ rowptr, int* __restrict__ fillp,
                            int* __restrict__ srcS, int* __restrict__ dstS){
  int e=blockIdx.x*blockDim.x+threadIdx.x;
  if(e>=EE) return;
  int d=dst[e];
  int p=rowptr[d]+atomicAdd(&fillp[d],1);
  srcS[p]=src[e]; dstS[p]=d;
}

__global__ void invdeg_kernel(const int* __restrict__ cnt, float* __restrict__ invdeg){
  int i=blockIdx.x*blockDim.x+threadIdx.x;
  if(i<NN) invdeg[i]=1.f/fmaxf((float)cnt[i],1.f);
}

// Wd[k][n] = W1[k][n] - W1[64+k][n]   (64x64)
__global__ void wd_kernel(const float* __restrict__ W1, float* __restrict__ Wd){
  int i=blockIdx.x*blockDim.x+threadIdx.x;
  if(i<4096) Wd[i]=W1[i]-W1[4096+i];
}

// C[NN, ldc(+nc0 slice)] = act(A[NN,K] @ W[K, ldw](cols wc..) + bias + addend)
// Wb: rows >=64 of combined weight. lsO: fused GAT attn-dot epilogue (head=blockIdx.y).
template<int K>
__global__ __launch_bounds__(256) void gemm_kernel(
    const float* __restrict__ A, const float* __restrict__ W, const float* __restrict__ Wb,
    int ldw, int wcol0,
    const float* __restrict__ bias, const float* __restrict__ addend,
    float* __restrict__ C, int ldc, int relu_flag,
    const float* __restrict__ a_s, const float* __restrict__ a_d,
    float* __restrict__ lsO, float* __restrict__ ldO){
  __shared__ float As[64][68];
  __shared__ float Ws[64][64];
  const int m0=blockIdx.x*64;
  const int nc0=blockIdx.y*64;
  const int wc=wcol0+nc0;
  const int tid=threadIdx.x, tx=tid&15, ty=tid>>4;
  float acc[4][4];
  #pragma unroll
  for(int i=0;i<4;i++){
    #pragma unroll
    for(int j=0;j<4;j++) acc[i][j]=bias? bias[wc+tx*4+j]:0.f;
  }
  for(int k0=0;k0<K;k0+=64){
    const float* Wp=(Wb && k0>=64)? Wb : W;
    const int kb =(Wb && k0>=64)? k0-64 : k0;
    __syncthreads();
    #pragma unroll
    for(int it=0;it<4;it++){
      int linear=it*1024+tid*4;
      int m=linear>>6, k=linear&63;
      float4 v=make_float4(0.f,0.f,0.f,0.f);
      if(m0+m<NN) v=*(const float4*)(A+(size_t)(m0+m)*K+k0+k);
      *(float4*)&As[m][k]=v;
    }
    #pragma unroll
    for(int it=0;it<4;it++){
      int linear=it*1024+tid*4;
      int k=linear>>6, n=linear&63;
      *(float4*)&Ws[k][n]=*(const float4*)(Wp+(size_t)(kb+k)*ldw+wc+n);
    }
    __syncthreads();
    #pragma unroll 8
    for(int k=0;k<64;k+=4){
      float4 a0=*(float4*)&As[ty*4+0][k];
      float4 a1=*(float4*)&As[ty*4+1][k];
      float4 a2=*(float4*)&As[ty*4+2][k];
      float4 a3=*(float4*)&As[ty*4+3][k];
      float4 w0=*(float4*)&Ws[k+0][tx*4];
      float4 w1=*(float4*)&Ws[k+1][tx*4];
      float4 w2=*(float4*)&Ws[k+2][tx*4];
      float4 w3=*(float4*)&Ws[k+3][tx*4];
      mac4(acc[0],a0,w0,w1,w2,w3);
      mac4(acc[1],a1,w0,w1,w2,w3);
      mac4(acc[2],a2,w0,w1,w2,w3);
      mac4(acc[3],a3,w0,w1,w2,w3);
    }
  }
  float4 asv,adv;
  if(lsO){
    asv=*(const float4*)(a_s+(size_t)blockIdx.y*64+tx*4);
    adv=*(const float4*)(a_d+(size_t)blockIdx.y*64+tx*4);
  }
  #pragma unroll
  for(int i=0;i<4;i++){
    int m=m0+ty*4+i;
    bool valid=(m<NN);
    float r0=acc[i][0],r1=acc[i][1],r2=acc[i][2],r3=acc[i][3];
    if(valid){
      if(addend){
        const float4 ad=*(const float4*)(addend+(size_t)m*ldc+nc0+tx*4);
        r0+=ad.x; r1+=ad.y; r2+=ad.z; r3+=ad.w;
      }
      if(relu_flag){ r0=fmaxf(r0,0.f); r1=fmaxf(r1,0.f); r2=fmaxf(r2,0.f); r3=fmaxf(r3,0.f); }
      *(float4*)(C+(size_t)m*ldc+nc0+tx*4)=make_float4(r0,r1,r2,r3);
    }
    if(lsO){
      float ps=r0*asv.x+r1*asv.y+r2*asv.z+r3*asv.w;
      float pd=r0*adv.x+r1*adv.y+r2*adv.z+r3*adv.w;
      #pragma unroll
      for(int o=1;o<16;o<<=1){ ps+=__shfl_xor(ps,o,16); pd+=__shfl_xor(pd,o,16); }
      if(valid && tx==0){
        lsO[(size_t)m*4+blockIdx.y]=ps;
        ldO[(size_t)m*4+blockIdx.y]=pd;
      }
    }
  }
}

// single-pass GAT (no max subtraction; logits are O(1) so exp is safe), unroll 4.
__global__ __launch_bounds__(256) void gat1p_kernel(const float* __restrict__ h,
    const int* __restrict__ rowptr, const int* __restrict__ srcS,
    const float* __restrict__ ls4, const float* __restrict__ ld4,
    const float* __restrict__ bias, float* __restrict__ out){
  int n=blockIdx.x*4+(threadIdx.x>>6);
  int lane=threadIdx.x&63;
  if(n>=NN) return;
  int r0=rowptr[n], r1=rowptr[n+1];
  const float4 ldv=*(const float4*)(ld4+(size_t)4*n);
  const float4 lsv=*(const float4*)(ls4+(size_t)4*n);
  float z0=__expf(lrelu(lsv.x+ldv.x)), z1=__expf(lrelu(lsv.y+ldv.y));
  float z2=__expf(lrelu(lsv.z+ldv.z)), z3=__expf(lrelu(lsv.w+ldv.w));
  const float* hn=h+(size_t)n*256;
  float a0=z0*hn[lane], a1=z1*hn[64+lane], a2=z2*hn[128+lane], a3=z3*hn[192+lane];
  int j=r0;
  for(; j+3<r1; j+=4){
    int s0=srcS[j], s1=srcS[j+1], s2=srcS[j+2], s3=srcS[j+3];
    const float4 A0=*(const float4*)(ls4+(size_t)4*s0);
    const float4 A1=*(const float4*)(ls4+(size_t)4*s1);
    const float4 A2=*(const float4*)(ls4+(size_t)4*s2);
    const float4 A3=*(const float4*)(ls4+(size_t)4*s3);
    const float* h0=h+(size_t)s0*256;
    const float* h1=h+(size_t)s1*256;
    const float* h2=h+(size_t)s2*256;
    const float* h3=h+(size_t)s3*256;
    float e00=__expf(lrelu(A0.x+ldv.x)), e01=__expf(lrelu(A0.y+ldv.y));
    float e02=__expf(lrelu(A0.z+ldv.z)), e03=__expf(lrelu(A0.w+ldv.w));
    float e10=__expf(lrelu(A1.x+ldv.x)), e11=__expf(lrelu(A1.y+ldv.y));
    float e12=__expf(lrelu(A1.z+ldv.z)), e13=__expf(lrelu(A1.w+ldv.w));
    float e20=__expf(lrelu(A2.x+ldv.x)), e21=__expf(lrelu(A2.y+ldv.y));
    float e22=__expf(lrelu(A2.z+ldv.z)), e23=__expf(lrelu(A2.w+ldv.w));
    float e30=__expf(lrelu(A3.x+ldv.x)), e31=__expf(lrelu(A3.y+ldv.y));
    float e32=__expf(lrelu(A3.z+ldv.z)), e33=__expf(lrelu(A3.w+ldv.w));
    z0+=(e00+e10)+(e20+e30); z1+=(e01+e11)+(e21+e31);
    z2+=(e02+e12)+(e22+e32); z3+=(e03+e13)+(e23+e33);
    a0+=(e00*h0[lane]+e10*h1[lane])+(e20*h2[lane]+e30*h3[lane]);
    a1+=(e01*h0[64+lane]+e11*h1[64+lane])+(e21*h2[64+lane]+e31*h3[64+lane]);
    a2+=(e02*h0[128+lane]+e12*h1[128+lane])+(e22*h2[128+lane]+e32*h3[128+lane]);
    a3+=(e03*h0[192+lane]+e13*h1[192+lane])+(e23*h2[192+lane]+e33*h3[192+lane]);
  }
  for(; j<r1; j++){
    int s0=srcS[j];
    const float4 A0=*(const float4*)(ls4+(size_t)4*s0);
    const float* h0=h+(size_t)s0*256;
    float e00=__expf(lrelu(A0.x+ldv.x)), e01=__expf(lrelu(A0.y+ldv.y));
    float e02=__expf(lrelu(A0.z+ldv.z)), e03=__expf(lrelu(A0.w+ldv.w));
    z0+=e00; z1+=e01; z2+=e02; z3+=e03;
    a0+=e00*h0[lane]; a1+=e01*h0[64+lane]; a2+=e02*h0[128+lane]; a3+=e03*h0[192+lane];
  }
  float zi0=1.f/(z0+1e-16f), zi1=1.f/(z1+1e-16f), zi2=1.f/(z2+1e-16f), zi3=1.f/(z3+1e-16f);
  out[(size_t)n*64+lane]=fmaxf(0.25f*(a0*zi0+a1*zi1+a2*zi2+a3*zi3)+bias[lane],0.f);
}

// GIN: self + sum -> out[N,64] (unroll 4)
__global__ __launch_bounds__(256) void agg_kernel(const float* __restrict__ xin,
    const int* __restrict__ rowptr, const int* __restrict__ srcS,
    float* __restrict__ out){
  int n=blockIdx.x*4+(threadIdx.x>>6);
  int lane=threadIdx.x&63;
  if(n>=NN) return;
  int r0=rowptr[n], r1=rowptr[n+1];
  float acc=xin[(size_t)n*64+lane];
  int j=r0;
  for(; j+3<r1; j+=4){
    int s0=srcS[j], s1=srcS[j+1], s2=srcS[j+2], s3=srcS[j+3];
    acc+=(xin[(size_t)s0*64+lane]+xin[(size_t)s1*64+lane])
        +(xin[(size_t)s2*64+lane]+xin[(size_t)s3*64+lane]);
  }
  for(; j<r1; j++) acc+=xin[(size_t)srcS[j]*64+lane];
  out[(size_t)n*64+lane]=acc;
}

// SAGE staging: out128[n] = [ mean_neigh(xin), xin[n] ]  (unroll 4)
__global__ __launch_bounds__(256) void agg2_kernel(const float* __restrict__ xin,
    const int* __restrict__ rowptr, const int* __restrict__ srcS,
    const float* __restrict__ invdeg, float* __restrict__ out128){
  int n=blockIdx.x*4+(threadIdx.x>>6);
  int lane=threadIdx.x&63;
  if(n>=NN) return;
  int r0=rowptr[n], r1=rowptr[n+1];
  float acc=0.f;
  int j=r0;
  for(; j+3<r1; j+=4){
    int s0=srcS[j], s1=srcS[j+1], s2=srcS[j+2], s3=srcS[j+3];
    acc+=(xin[(size_t)s0*64+lane]+xin[(size_t)s1*64+lane])
        +(xin[(size_t)s2*64+lane]+xin[(size_t)s3*64+lane]);
  }
  for(; j<r1; j++) acc+=xin[(size_t)srcS[j]*64+lane];
  out128[(size_t)n*128+lane]=acc*invdeg[n];
  out128[(size_t)n*128+64+lane]=xin[(size_t)n*64+lane];
}

// TR pass1 (edge-parallel SDDMM): 16 lanes per edge, all 4 heads.
__global__ __launch_bounds__(256) void tr_pass1_kernel(const int* __restrict__ srcS, const int* __restrict__ dstS,
    const float* __restrict__ q, const float* __restrict__ k,
    float* __restrict__ lg){
  int e=blockIdx.x*16+(threadIdx.x>>4);
  int t=threadIdx.x&15;
  if(e>=EE) return;
  int s=srcS[e], d=dstS[e];
  const float* ks=k+(size_t)s*256+t*4;
  const float* qd=q+(size_t)d*256+t*4;
  float4 k0=*(const float4*)(ks);
  float4 k1=*(const float4*)(ks+64);
  float4 k2=*(const float4*)(ks+128);
  float4 k3=*(const float4*)(ks+192);
  float4 q0=*(const float4*)(qd);
  float4 q1=*(const float4*)(qd+64);
  float4 q2=*(const float4*)(qd+128);
  float4 q3=*(const float4*)(qd+192);
  float v0=k0.x*q0.x+k0.y*q0.y+k0.z*q0.z+k0.w*q0.w;
  float v1=k1.x*q1.x+k1.y*q1.y+k1.z*q1.z+k1.w*q1.w;
  float v2=k2.x*q2.x+k2.y*q2.y+k2.z*q2.z+k2.w*q2.w;
  float v3=k3.x*q3.x+k3.y*q3.y+k3.z*q3.z+k3.w*q3.w;
  #pragma unroll
  for(int o=1;o<16;o<<=1){
    v0+=__shfl_xor(v0,o,16); v1+=__shfl_xor(v1,o,16);
    v2+=__shfl_xor(v2,o,16); v3+=__shfl_xor(v3,o,16);
  }
  if(t==0)
    *(float4*)(lg+(size_t)4*e)=make_float4(v0*0.125f,v1*0.125f,v2*0.125f,v3*0.125f);
}

// TR pass2: exp (no max) + v-gather + skip + relu -> x5 (unroll 4)
__global__ __launch_bounds__(256) void tr_pass2_kernel(const int* __restrict__ rowptr, const int* __restrict__ srcS,
    const float* __restrict__ lg,
    const float* __restrict__ v, const float* __restrict__ skip, float* __restrict__ x5){
  int n=blockIdx.x*4+(threadIdx.x>>6);
  int lane=threadIdx.x&63;
  if(n>=NN) return;
  int r0=rowptr[n], r1=rowptr[n+1];
  float z0=0.f,z1=0.f,z2=0.f,z3=0.f;
  float a0=0.f,a1=0.f,a2=0.f,a3=0.f;
  int j=r0;
  for(; j+3<r1; j+=4){
    int s0=srcS[j], s1=srcS[j+1], s2=srcS[j+2], s3=srcS[j+3];
    const float4 f0=*(const float4*)(lg+(size_t)4*j);
    const float4 f1=*(const float4*)(lg+(size_t)4*(j+1));
    const float4 f2=*(const float4*)(lg+(size_t)4*(j+2));
    const float4 f3=*(const float4*)(lg+(size_t)4*(j+3));
    const float* v0=v+(size_t)s0*256;
    const float* v1=v+(size_t)s1*256;
    const float* v2=v+(size_t)s2*256;
    const float* v3=v+(size_t)s3*256;
    float e00=__expf(f0.x), e01=__expf(f0.y), e02=__expf(f0.z), e03=__expf(f0.w);
    float e10=__expf(f1.x), e11=__expf(f1.y), e12=__expf(f1.z), e13=__expf(f1.w);
    float e20=__expf(f2.x), e21=__expf(f2.y), e22=__expf(f2.z), e23=__expf(f2.w);
    float e30=__expf(f3.x), e31=__expf(f3.y), e32=__expf(f3.z), e33=__expf(f3.w);
    z0+=(e00+e10)+(e20+e30); z1+=(e01+e11)+(e21+e31);
    z2+=(e02+e12)+(e22+e32); z3+=(e03+e13)+(e23+e33);
    a0+=(e00*v0[lane]+e10*v1[lane])+(e20*v2[lane]+e30*v3[lane]);
    a1+=(e01*v0[64+lane]+e11*v1[64+lane])+(e21*v2[64+lane]+e31*v3[64+lane]);
    a2+=(e02*v0[128+lane]+e12*v1[128+lane])+(e22*v2[128+lane]+e32*v3[128+lane]);
    a3+=(e03*v0[192+lane]+e13*v1[192+lane])+(e23*v2[192+lane]+e33*v3[192+lane]);
  }
  for(; j<r1; j++){
    int s0=srcS[j];
    const float4 f0=*(const float4*)(lg+(size_t)4*j);
    const float* v0=v+(size_t)s0*256;
    float e00=__expf(f0.x), e01=__expf(f0.y), e02=__expf(f0.z), e03=__expf(f0.w);
    z0+=e00; z1+=e01; z2+=e02; z3+=e03;
    a0+=e00*v0[lane]; a1+=e01*v0[64+lane]; a2+=e02*v0[128+lane]; a3+=e03*v0[192+lane];
  }
  float zi0=1.f/(z0+1e-16f), zi1=1.f/(z1+1e-16f), zi2=1.f/(z2+1e-16f), zi3=1.f/(z3+1e-16f);
  float t=0.25f*(a0*zi0+a1*zi1+a2*zi2+a3*zi3)+skip[(size_t)n*64+lane];
  x5[(size_t)n*64+lane]=fmaxf(t,0.f);
}

// EdgeConv v3: hidden = relu(P[dst]+Q[src]) -> GEMM2(+b2) -> LDS segmented max ->
// plain store for interior dst (all its edges inside this tile), atomicMax only for
// the tile's first/last dst. Edges are dst-sorted, so interior dst are block-private.
__global__ __launch_bounds__(256) void edgeconv2_kernel(
    const float* __restrict__ P, const float* __restrict__ Q,
    const int* __restrict__ srcS, const int* __restrict__ dstS,
    const float* __restrict__ W2, const float* __restrict__ b2,
    unsigned* __restrict__ emax){
  __shared__ float As[64][68];   // hidden tile, then reused for output tile
  __shared__ float Ws[64][64];
  __shared__ int dstL[64];
  const int e0=blockIdx.x*64;    // EE is a multiple of 64
  const int tid=threadIdx.x, tx=tid&15, ty=tid>>4;
  if(tid<64) dstL[tid]=dstS[e0+tid];
  #pragma unroll
  for(int it=0;it<4;it++){
    int linear=it*1024+tid*4;
    int m=linear>>6, k=linear&63;
    int e=e0+m;
    int dn=dstS[e], sn=srcS[e];
    const float4 p=*(const float4*)(P+(size_t)dn*64+k);
    const float4 q=*(const float4*)(Q+(size_t)sn*64+k);
    float4 v=make_float4(fmaxf(p.x+q.x,0.f),fmaxf(p.y+q.y,0.f),fmaxf(p.z+q.z,0.f),fmaxf(p.w+q.w,0.f));
    *(float4*)&As[m][k]=v;
  }
  #pragma unroll
  for(int it=0;it<4;it++){
    int linear=it*1024+tid*4;
    int k=linear>>6, n=linear&63;
    *(float4*)&Ws[k][n]=*(const float4*)(W2+(size_t)k*64+n);
  }
  __syncthreads();
  float acc2[4][4];
  #pragma unroll
  for(int i=0;i<4;i++)
    #pragma unroll
    for(int j=0;j<4;j++) acc2[i][j]=b2[tx*4+j];
  #pragma unroll 8
  for(int k=0;k<64;k+=4){
    float4 a0=*(float4*)&As[ty*4+0][k];
    float4 a1=*(float4*)&As[ty*4+1][k];
    float4 a2=*(float4*)&As[ty*4+2][k];
    float4 a3=*(float4*)&As[ty*4+3][k];
    float4 w0=*(float4*)&Ws[k+0][tx*4];
    float4 w1=*(float4*)&Ws[k+1][tx*4];
    float4 w2=*(float4*)&Ws[k+2][tx*4];
    float4 w3=*(float4*)&Ws[k+3][tx*4];
    mac4(acc2[0],a0,w0,w1,w2,w3);
    mac4(acc2[1],a1,w0,w1,w2,w3);
    mac4(acc2[2],a2,w0,w1,w2,w3);
    mac4(acc2[3],a3,w0,w1,w2,w3);
  }
  __syncthreads();   // done reading As
  #pragma unroll
  for(int i=0;i<4;i++)
    #pragma unroll
    for(int j=0;j<4;j++)
      As[ty*4+i][tx*4+j]=acc2[i][j];   // output tile [edge][col]
  __syncthreads();
  if(tid<64){
    const int c=tid;
    const int dFirst=dstL[0], dLast=dstL[63];
    int dprev=dFirst;
    float mx=As[0][c];
    #pragma unroll 8
    for(int m=1;m<64;m++){
      int dn=dstL[m];
      float v=As[m][c];
      if(dn!=dprev){
        unsigned* addr=&emax[(size_t)dprev*64+c];
        unsigned enc=fenc(mx);
        if(dprev!=dFirst && dprev!=dLast) *addr=enc;
        else atomicMax(addr,enc);
        dprev=dn; mx=v;
      }else mx=fmaxf(mx,v);
    }
    unsigned* addr=&emax[(size_t)dprev*64+c];
    unsigned enc=fenc(mx);
    if(dprev!=dFirst && dprev!=dLast) *addr=enc;
    else atomicMax(addr,enc);
  }
}

// pool with emax decode fused
__global__ __launch_bounds__(256) void pool_kernel(const unsigned* __restrict__ emax, const int* __restrict__ batch,
                                                   float* __restrict__ pooled){
  const int NB=200;
  int base=blockIdx.x*NB;
  int lane=threadIdx.x&63;
  int wsub=threadIdx.x>>6;
  float acc=0.f; int curg=-1;
  for(int idx=wsub; idx<NB; idx+=4){
    int n=base+idx;
    if(n>=NN) break;
    int g=batch[n];
    if(g!=curg){
      if(curg>=0) atomicAdd(&pooled[curg*64+lane],acc);
      acc=0.f; curg=g;
    }
    unsigned u=emax[(size_t)n*64+lane];
    acc+=(u>=0x80000000u)? __uint_as_float(u&0x7fffffffu) : 0.f;
  }
  if(curg>=0) atomicAdd(&pooled[curg*64+lane],acc);
}

__global__ __launch_bounds__(256) void final_kernel(const float* __restrict__ pooled, const int* __restrict__ batch,
    const float* __restrict__ fc1W, const float* __restrict__ fc1b,
    const float* __restrict__ fc2W, const float* __restrict__ fc2b,
    float* __restrict__ out){
  __shared__ float gm[16][64];
  __shared__ float t1[16][64];
  __shared__ int cgs[17];
  int t=threadIdx.x;
  if(t<17){
    int lo=0, hi=NN;
    while(lo<hi){ int mid=(lo+hi)>>1; if(batch[mid]<t) lo=mid+1; else hi=mid; }
    cgs[t]=lo;
  }
  __syncthreads();
  for(int r=0;r<4;r++){
    int idx=r*256+t; int g=idx>>6, d=idx&63;
    float c=(float)(cgs[g+1]-cgs[g]);
    gm[g][d]=pooled[idx]/fmaxf(c,1.f);
  }
  __syncthreads();
  for(int r=0;r<4;r++){
    int idx=r*256+t; int g=idx>>6, d=idx&63;
    float a=fc1b[d];
    for(int k2=0;k2<64;k2++) a+=gm[g][k2]*fc1W[k2*64+d];
    t1[g][d]=fmaxf(a,0.f);
  }
  __syncthreads();
  for(int r=0;r<4;r++){
    int idx=r*256+t; int g=idx>>6, d=idx&63;
    float a=fc2b[d];
    for(int k2=0;k2<64;k2++) a+=t1[g][k2]*fc2W[k2*64+d];
    out[idx]=a;
  }
}

extern "C" void kernel_launch(void* const* d_in, const int* in_sizes, int n_in,
                              void* d_out, int out_size, void* d_ws, size_t ws_size,
                              hipStream_t stream){
  const float* x       =(const float*)d_in[0];
  const int*   ei      =(const int*)  d_in[1];
  const int*   src     =ei;
  const int*   dst     =ei+EE;
  const int*   batch   =(const int*)  d_in[2];
  const float* gat1_W  =(const float*)d_in[3];
  const float* gat1_as =(const float*)d_in[4];
  const float* gat1_ad =(const float*)d_in[5];
  const float* gat1_b  =(const float*)d_in[6];
  const float* gat2_W  =(const float*)d_in[7];
  const float* gat2_as =(const float*)d_in[8];
  const float* gat2_ad =(const float*)d_in[9];
  const float* gat2_b  =(const float*)d_in[10];
  const float* gin_W1  =(const float*)d_in[11];
  const float* gin_b1  =(const float*)d_in[12];
  const float* gin_W2  =(const float*)d_in[13];
  const float* gin_b2  =(const float*)d_in[14];
  const float* sage1_Wl=(const float*)d_in[15];
  const float* sage1_bl=(const float*)d_in[16];
  const float* sage1_Wr=(const float*)d_in[17];
  const float* sage2_Wl=(const float*)d_in[18];
  const float* sage2_bl=(const float*)d_in[19];
  const float* sage2_Wr=(const float*)d_in[20];
  const float* tr_Wq   =(const float*)d_in[21];
  const float* tr_bq   =(const float*)d_in[22];
  const float* tr_Wk   =(const float*)d_in[23];
  const float* tr_bk   =(const float*)d_in[24];
  const float* tr_Wv   =(const float*)d_in[25];
  const float* tr_bv   =(const float*)d_in[26];
  const float* tr_Ws   =(const float*)d_in[27];
  const float* tr_bs   =(const float*)d_in[28];
  const float* ec_W1   =(const float*)d_in[29];
  const float* ec_b1   =(const float*)d_in[30];
  const float* ec_W2   =(const float*)d_in[31];
  const float* ec_b2   =(const float*)d_in[32];
  const float* fc1_W   =(const float*)d_in[33];
  const float* fc1_b   =(const float*)d_in[34];
  const float* fc2_W   =(const float*)d_in[35];
  const float* fc2_b   =(const float*)d_in[36];

  // ---- workspace layout (floats first, then ints) ----
  float* base=(float*)d_ws;
  size_t off=0;
  auto alloc=[&](size_t n){ float* p=base+off; off+=n; return p; };
  float* A_big =alloc((size_t)NN*256);     // GAT h / SAGE xcat / TR q then v
  float* nb0   =alloc(N64);
  float* nb1   =alloc(N64);                // nb1..nb4 contiguous: TR k [N,256]
  float* nb2   =alloc(N64);
  float* nb3   =alloc(N64);
  float* nb4   =alloc(N64);
  float* nb5   =alloc(N64);                // emax (as unsigned, zeroed)
  float* logitE=alloc((size_t)EE*4);
  float* ls    =alloc(NN*4);               // GAT ls
  float* ldb   =alloc(NN*4);               // GAT ld / EdgeConv Wd (4096)
  float* invdeg=alloc(NN);
  float* pooled=alloc(GG*64);
  int* ibase=(int*)(base+off);
  int* srcS  =ibase;
  int* dstS  =ibase+EE;
  int* cnt   =ibase+2*EE;
  int* fillp =ibase+2*EE+NN;               // cnt,fillp contiguous (zeroed together)
  int* rowptr=ibase+2*EE+2*NN;             // NN+1 ints
  int* bsum  =ibase+2*EE+3*NN+8;           // 49 ints
  int* boff  =bsum+64;                     // 49 ints

  const int BT=256;
  const int NSB=cdiv(NN,1024);             // 49 scan blocks
  // ---- zero init ----
  zero_kernel<<<cdiv(2*NN,BT),BT,0,stream>>>((unsigned*)cnt,2*NN);
  zero_kernel<<<cdiv(GG*64,BT),BT,0,stream>>>((unsigned*)pooled,GG*64);
  zero_kernel<<<cdiv(N64,BT),BT,0,stream>>>((unsigned*)nb5,N64);
  // ---- CSR ----
  hist_kernel<<<cdiv(EE,BT),BT,0,stream>>>(dst,cnt);
  scan1_kernel<<<NSB,1024,0,stream>>>(cnt,rowptr,bsum);
  scan2_kernel<<<1,64,0,stream>>>(bsum,boff,rowptr,NSB);
  scan3_kernel<<<cdiv(NN,BT),BT,0,stream>>>(rowptr,boff);
  fill_kernel<<<cdiv(EE,BT),BT,0,stream>>>(src,dst,rowptr,fillp,srcS,dstS);
  invdeg_kernel<<<cdiv(NN,BT),BT,0,stream>>>(cnt,invdeg);

  const int GB=cdiv(NN,64);        // 782 row tiles
  const int GW=cdiv(NN,4);         // wave-per-node blocks (12500)

  // ---- GAT1 (attn dots fused in GEMM epilogue) ----
  gemm_kernel<128><<<dim3(GB,4),BT,0,stream>>>(x,gat1_W,nullptr,256,0,nullptr,nullptr,A_big,256,0,
                                               gat1_as,gat1_ad,ls,ldb);
  gat1p_kernel<<<GW,BT,0,stream>>>(A_big,rowptr,srcS,ls,ldb,gat1_b,nb0);               // x1
  // ---- GAT2 ----
  gemm_kernel<64><<<dim3(GB,4),BT,0,stream>>>(nb0,gat2_W,nullptr,256,0,nullptr,nullptr,A_big,256,0,
                                              gat2_as,gat2_ad,ls,ldb);
  gat1p_kernel<<<GW,BT,0,stream>>>(A_big,rowptr,srcS,ls,ldb,gat2_b,nb1);               // x2
  // ---- GIN ----
  agg_kernel<<<GW,BT,0,stream>>>(nb1,rowptr,srcS,nb2);                                 // t = x2+agg
  gemm_kernel<64><<<dim3(GB,1),BT,0,stream>>>(nb2,gin_W1,nullptr,64,0,gin_b1,nullptr,nb3,64,1,
                                              nullptr,nullptr,nullptr,nullptr);
  gemm_kernel<64><<<dim3(GB,1),BT,0,stream>>>(nb3,gin_W2,nullptr,64,0,gin_b2,nullptr,nb0,64,1,
                                              nullptr,nullptr,nullptr,nullptr);        // x3
  // ---- SAGE1: xcat=[mean(x3), x3] @ [Wl;Wr] + bl ----
  agg2_kernel<<<GW,BT,0,stream>>>(nb0,rowptr,srcS,invdeg,A_big);
  gemm_kernel<128><<<dim3(GB,1),BT,0,stream>>>(A_big,sage1_Wl,sage1_Wr,64,0,sage1_bl,nullptr,nb1,64,1,
                                               nullptr,nullptr,nullptr,nullptr);       // xs
  // ---- SAGE2 ----
  agg2_kernel<<<GW,BT,0,stream>>>(nb1,rowptr,srcS,invdeg,A_big);
  gemm_kernel<128><<<dim3(GB,1),BT,0,stream>>>(A_big,sage2_Wl,sage2_Wr,64,0,sage2_bl,nullptr,nb0,64,1,
                                               nullptr,nullptr,nullptr,nullptr);       // x4
  // ---- TransformerConv ----
  float* qv=A_big;                 // q, later overwritten by v
  float* kh=nb1;                   // k occupies nb1..nb4 [N,256]
  gemm_kernel<64><<<dim3(GB,4),BT,0,stream>>>(nb0,tr_Wq,nullptr,256,0,tr_bq,nullptr,qv,256,0,
                                              nullptr,nullptr,nullptr,nullptr);
  gemm_kernel<64><<<dim3(GB,4),BT,0,stream>>>(nb0,tr_Wk,nullptr,256,0,tr_bk,nullptr,kh,256,0,
                                              nullptr,nullptr,nullptr,nullptr);
  tr_pass1_kernel<<<cdiv(EE,16),BT,0,stream>>>(srcS,dstS,qv,kh,logitE);                // logits
  gemm_kernel<64><<<dim3(GB,4),BT,0,stream>>>(nb0,tr_Wv,nullptr,256,0,tr_bv,nullptr,qv,256,0,
                                              nullptr,nullptr,nullptr,nullptr);        // v over q
  gemm_kernel<64><<<dim3(GB,1),BT,0,stream>>>(nb0,tr_Ws,nullptr,64,0,tr_bs,nullptr,nb1,64,0,
                                              nullptr,nullptr,nullptr,nullptr);        // skip (k dead)
  tr_pass2_kernel<<<GW,BT,0,stream>>>(rowptr,srcS,logitE,qv,nb1,nb2);                  // x5
  // ---- EdgeConv (factored): P=x5@(W1a-W1b)+b1, Q=x5@W1b ----
  wd_kernel<<<16,BT,0,stream>>>(ec_W1,ldb);
  gemm_kernel<64><<<dim3(GB,1),BT,0,stream>>>(nb2,ldb,nullptr,64,0,ec_b1,nullptr,nb3,64,0,
                                              nullptr,nullptr,nullptr,nullptr);        // P
  gemm_kernel<64><<<dim3(GB,1),BT,0,stream>>>(nb2,ec_W1+4096,nullptr,64,0,nullptr,nullptr,nb4,64,0,
                                              nullptr,nullptr,nullptr,nullptr);        // Q
  edgeconv2_kernel<<<EE/64,BT,0,stream>>>(nb3,nb4,srcS,dstS,ec_W2,ec_b2,(unsigned*)nb5);
  // ---- pool (emax decode fused) + MLP ----
  pool_kernel<<<cdiv(NN,200),BT,0,stream>>>((unsigned*)nb5,batch,pooled);
  final_kernel<<<1,BT,0,stream>>>(pooled,batch,fc1_W,fc1_b,fc2_W,fc2_b,(float*)d_out);
}

// Round 8
// 975.503 us; speedup vs baseline: 2.4011x; 1.1634x over previous
//
#include <hip/hip_runtime.h>

#define NN 50000
#define EE 640000
#define GG 16
#define N64 (NN*64)

static inline int cdiv(int a,int b){return (a+b-1)/b;}

__device__ __forceinline__ float lrelu(float x){ return x>0.f? x : 0.2f*x; }
// monotonic float->uint encoding for atomicMax on floats
__device__ __forceinline__ unsigned fenc(float f){
  unsigned u=__float_as_uint(f);
  return (u&0x80000000u)? ~u : (u|0x80000000u);
}
// bf16 helpers (RNE encode, shift decode)
__device__ __forceinline__ float bf2f(unsigned short u){ return __uint_as_float(((unsigned)u)<<16); }
__device__ __forceinline__ unsigned short f2bf(float f){
  unsigned u=__float_as_uint(f);
  u += 0x7FFFu + ((u>>16)&1u);
  return (unsigned short)(u>>16);
}

// acc[0..3] += av . {w0..w3} columns
__device__ __forceinline__ void mac4(float* acc, const float4 av,
    const float4 w0, const float4 w1, const float4 w2, const float4 w3){
  acc[0]+=av.x*w0.x+av.y*w1.x+av.z*w2.x+av.w*w3.x;
  acc[1]+=av.x*w0.y+av.y*w1.y+av.z*w2.y+av.w*w3.y;
  acc[2]+=av.x*w0.z+av.y*w1.z+av.z*w2.z+av.w*w3.z;
  acc[3]+=av.x*w0.w+av.y*w1.w+av.z*w2.w+av.w*w3.w;
}

__global__ void zero_kernel(unsigned* p, int n){
  int i=blockIdx.x*blockDim.x+threadIdx.x;
  if(i<n) p[i]=0u;
}

__global__ void hist_kernel(const int* __restrict__ dst, int* __restrict__ cnt){
  int e=blockIdx.x*blockDim.x+threadIdx.x;
  if(e<EE) atomicAdd(&cnt[dst[e]],1);
}

// 3-stage scan
__global__ __launch_bounds__(1024) void scan1_kernel(const int* __restrict__ cnt,
    int* __restrict__ rowptr, int* __restrict__ bsum){
  __shared__ int wsum[16];
  int t=threadIdx.x, b=blockIdx.x;
  int i=b*1024+t;
  int v=(i<NN)?cnt[i]:0;
  int lane=t&63, w=t>>6;
  int inc=v;
  #pragma unroll
  for(int o=1;o<64;o<<=1){ int u=__shfl_up(inc,o,64); if(lane>=o) inc+=u; }
  if(lane==63) wsum[w]=inc;
  __syncthreads();
  if(t<16){
    int s=wsum[t];
    #pragma unroll
    for(int o=1;o<16;o<<=1){ int u=__shfl_up(s,o,16); if(t>=o) s+=u; }
    wsum[t]=s;
  }
  __syncthreads();
  int woff=(w>0)?wsum[w-1]:0;
  if(i<NN) rowptr[i]=woff+inc-v;   // block-local exclusive
  if(t==1023) bsum[b]=wsum[15];
}

__global__ void scan2_kernel(const int* __restrict__ bsum, int* __restrict__ boff, int* __restrict__ rowptr, int nb){
  int t=threadIdx.x;  // 64 threads
  int v=(t<nb)?bsum[t]:0;
  int inc=v;
  #pragma unroll
  for(int o=1;o<64;o<<=1){ int u=__shfl_up(inc,o,64); if(t>=o) inc+=u; }
  if(t<nb) boff[t]=inc-v;
  if(t==63) rowptr[NN]=inc;
}

__global__ void scan3_kernel(int* __restrict__ rowptr, const int* __restrict__ boff){
  int i=blockIdx.x*blockDim.x+threadIdx.x;
  if(i<NN) rowptr[i]+=boff[i>>10];
}

__global__ void fill_kernel(const int* __restrict__ src, const int* __restrict__ dst,
                            const int* __restrict__ rowptr, int* __restrict__ fillp,
                            int* __restrict__ srcS, int* __restrict__ dstS){
  int e=blockIdx.x*blockDim.x+threadIdx.x;
  if(e>=EE) return;
  int d=dst[e];
  int p=rowptr[d]+atomicAdd(&fillp[d],1);
  srcS[p]=src[e]; dstS[p]=d;
}

__global__ void invdeg_kernel(const int* __restrict__ cnt, float* __restrict__ invdeg){
  int i=blockIdx.x*blockDim.x+threadIdx.x;
  if(i<NN) invdeg[i]=1.f/fmaxf((float)cnt[i],1.f);
}

// Wd[k][n] = W1[k][n] - W1[64+k][n]   (64x64)
__global__ void wd_kernel(const float* __restrict__ W1, float* __restrict__ Wd){
  int i=blockIdx.x*blockDim.x+threadIdx.x;
  if(i<4096) Wd[i]=W1[i]-W1[4096+i];
}

// C = act(A[NN,K] @ W + bias + addend). Cbf!=null -> write bf16 instead of fp32.
// Wb: rows >=64 of combined weight. lsO: fused GAT attn-dot epilogue (head=blockIdx.y).
template<int K>
__global__ __launch_bounds__(256) void gemm_kernel(
    const float* __restrict__ A, const float* __restrict__ W, const float* __restrict__ Wb,
    int ldw, int wcol0,
    const float* __restrict__ bias, const float* __restrict__ addend,
    float* __restrict__ C, unsigned short* __restrict__ Cbf, int ldc, int relu_flag,
    const float* __restrict__ a_s, const float* __restrict__ a_d,
    float* __restrict__ lsO, float* __restrict__ ldO){
  __shared__ float As[64][68];
  __shared__ float Ws[64][64];
  const int m0=blockIdx.x*64;
  const int nc0=blockIdx.y*64;
  const int wc=wcol0+nc0;
  const int tid=threadIdx.x, tx=tid&15, ty=tid>>4;
  float acc[4][4];
  #pragma unroll
  for(int i=0;i<4;i++){
    #pragma unroll
    for(int j=0;j<4;j++) acc[i][j]=bias? bias[wc+tx*4+j]:0.f;
  }
  for(int k0=0;k0<K;k0+=64){
    const float* Wp=(Wb && k0>=64)? Wb : W;
    const int kb =(Wb && k0>=64)? k0-64 : k0;
    __syncthreads();
    #pragma unroll
    for(int it=0;it<4;it++){
      int linear=it*1024+tid*4;
      int m=linear>>6, k=linear&63;
      float4 v=make_float4(0.f,0.f,0.f,0.f);
      if(m0+m<NN) v=*(const float4*)(A+(size_t)(m0+m)*K+k0+k);
      *(float4*)&As[m][k]=v;
    }
    #pragma unroll
    for(int it=0;it<4;it++){
      int linear=it*1024+tid*4;
      int k=linear>>6, n=linear&63;
      *(float4*)&Ws[k][n]=*(const float4*)(Wp+(size_t)(kb+k)*ldw+wc+n);
    }
    __syncthreads();
    #pragma unroll 8
    for(int k=0;k<64;k+=4){
      float4 a0=*(float4*)&As[ty*4+0][k];
      float4 a1=*(float4*)&As[ty*4+1][k];
      float4 a2=*(float4*)&As[ty*4+2][k];
      float4 a3=*(float4*)&As[ty*4+3][k];
      float4 w0=*(float4*)&Ws[k+0][tx*4];
      float4 w1=*(float4*)&Ws[k+1][tx*4];
      float4 w2=*(float4*)&Ws[k+2][tx*4];
      float4 w3=*(float4*)&Ws[k+3][tx*4];
      mac4(acc[0],a0,w0,w1,w2,w3);
      mac4(acc[1],a1,w0,w1,w2,w3);
      mac4(acc[2],a2,w0,w1,w2,w3);
      mac4(acc[3],a3,w0,w1,w2,w3);
    }
  }
  float4 asv,adv;
  if(lsO){
    asv=*(const float4*)(a_s+(size_t)blockIdx.y*64+tx*4);
    adv=*(const float4*)(a_d+(size_t)blockIdx.y*64+tx*4);
  }
  #pragma unroll
  for(int i=0;i<4;i++){
    int m=m0+ty*4+i;
    bool valid=(m<NN);
    float r0=acc[i][0],r1=acc[i][1],r2=acc[i][2],r3=acc[i][3];
    if(valid){
      if(addend){
        const float4 ad=*(const float4*)(addend+(size_t)m*ldc+nc0+tx*4);
        r0+=ad.x; r1+=ad.y; r2+=ad.z; r3+=ad.w;
      }
      if(relu_flag){ r0=fmaxf(r0,0.f); r1=fmaxf(r1,0.f); r2=fmaxf(r2,0.f); r3=fmaxf(r3,0.f); }
      if(Cbf){
        ushort4 o; o.x=f2bf(r0); o.y=f2bf(r1); o.z=f2bf(r2); o.w=f2bf(r3);
        *(ushort4*)(Cbf+(size_t)m*ldc+nc0+tx*4)=o;
      }else{
        *(float4*)(C+(size_t)m*ldc+nc0+tx*4)=make_float4(r0,r1,r2,r3);
      }
    }
    if(lsO){
      float ps=r0*asv.x+r1*asv.y+r2*asv.z+r3*asv.w;
      float pd=r0*adv.x+r1*adv.y+r2*adv.z+r3*adv.w;
      #pragma unroll
      for(int o=1;o<16;o<<=1){ ps+=__shfl_xor(ps,o,16); pd+=__shfl_xor(pd,o,16); }
      if(valid && tx==0){
        lsO[(size_t)m*4+blockIdx.y]=ps;
        ldO[(size_t)m*4+blockIdx.y]=pd;
      }
    }
  }
}

// single-pass GAT (no max subtraction), bf16 h gather, unroll 4.
// outf!=null -> fp32 out; else bf16 out to outb.
__global__ __launch_bounds__(256) void gat1p_kernel(const unsigned short* __restrict__ h,
    const int* __restrict__ rowptr, const int* __restrict__ srcS,
    const float* __restrict__ ls4, const float* __restrict__ ld4,
    const float* __restrict__ bias, float* __restrict__ outf, unsigned short* __restrict__ outb){
  int n=blockIdx.x*4+(threadIdx.x>>6);
  int lane=threadIdx.x&63;
  if(n>=NN) return;
  int r0=rowptr[n], r1=rowptr[n+1];
  const float4 ldv=*(const float4*)(ld4+(size_t)4*n);
  const float4 lsv=*(const float4*)(ls4+(size_t)4*n);
  float z0=__expf(lrelu(lsv.x+ldv.x)), z1=__expf(lrelu(lsv.y+ldv.y));
  float z2=__expf(lrelu(lsv.z+ldv.z)), z3=__expf(lrelu(lsv.w+ldv.w));
  const unsigned short* hn=h+(size_t)n*256;
  float a0=z0*bf2f(hn[lane]), a1=z1*bf2f(hn[64+lane]), a2=z2*bf2f(hn[128+lane]), a3=z3*bf2f(hn[192+lane]);
  int j=r0;
  for(; j+3<r1; j+=4){
    int s0=srcS[j], s1=srcS[j+1], s2=srcS[j+2], s3=srcS[j+3];
    const float4 A0=*(const float4*)(ls4+(size_t)4*s0);
    const float4 A1=*(const float4*)(ls4+(size_t)4*s1);
    const float4 A2=*(const float4*)(ls4+(size_t)4*s2);
    const float4 A3=*(const float4*)(ls4+(size_t)4*s3);
    const unsigned short* h0=h+(size_t)s0*256;
    const unsigned short* h1=h+(size_t)s1*256;
    const unsigned short* h2=h+(size_t)s2*256;
    const unsigned short* h3=h+(size_t)s3*256;
    float e00=__expf(lrelu(A0.x+ldv.x)), e01=__expf(lrelu(A0.y+ldv.y));
    float e02=__expf(lrelu(A0.z+ldv.z)), e03=__expf(lrelu(A0.w+ldv.w));
    float e10=__expf(lrelu(A1.x+ldv.x)), e11=__expf(lrelu(A1.y+ldv.y));
    float e12=__expf(lrelu(A1.z+ldv.z)), e13=__expf(lrelu(A1.w+ldv.w));
    float e20=__expf(lrelu(A2.x+ldv.x)), e21=__expf(lrelu(A2.y+ldv.y));
    float e22=__expf(lrelu(A2.z+ldv.z)), e23=__expf(lrelu(A2.w+ldv.w));
    float e30=__expf(lrelu(A3.x+ldv.x)), e31=__expf(lrelu(A3.y+ldv.y));
    float e32=__expf(lrelu(A3.z+ldv.z)), e33=__expf(lrelu(A3.w+ldv.w));
    z0+=(e00+e10)+(e20+e30); z1+=(e01+e11)+(e21+e31);
    z2+=(e02+e12)+(e22+e32); z3+=(e03+e13)+(e23+e33);
    a0+=(e00*bf2f(h0[lane])+e10*bf2f(h1[lane]))+(e20*bf2f(h2[lane])+e30*bf2f(h3[lane]));
    a1+=(e01*bf2f(h0[64+lane])+e11*bf2f(h1[64+lane]))+(e21*bf2f(h2[64+lane])+e31*bf2f(h3[64+lane]));
    a2+=(e02*bf2f(h0[128+lane])+e12*bf2f(h1[128+lane]))+(e22*bf2f(h2[128+lane])+e32*bf2f(h3[128+lane]));
    a3+=(e03*bf2f(h0[192+lane])+e13*bf2f(h1[192+lane]))+(e23*bf2f(h2[192+lane])+e33*bf2f(h3[192+lane]));
  }
  for(; j<r1; j++){
    int s0=srcS[j];
    const float4 A0=*(const float4*)(ls4+(size_t)4*s0);
    const unsigned short* h0=h+(size_t)s0*256;
    float e00=__expf(lrelu(A0.x+ldv.x)), e01=__expf(lrelu(A0.y+ldv.y));
    float e02=__expf(lrelu(A0.z+ldv.z)), e03=__expf(lrelu(A0.w+ldv.w));
    z0+=e00; z1+=e01; z2+=e02; z3+=e03;
    a0+=e00*bf2f(h0[lane]); a1+=e01*bf2f(h0[64+lane]); a2+=e02*bf2f(h0[128+lane]); a3+=e03*bf2f(h0[192+lane]);
  }
  float zi0=1.f/(z0+1e-16f), zi1=1.f/(z1+1e-16f), zi2=1.f/(z2+1e-16f), zi3=1.f/(z3+1e-16f);
  float r=fmaxf(0.25f*(a0*zi0+a1*zi1+a2*zi2+a3*zi3)+bias[lane],0.f);
  if(outf) outf[(size_t)n*64+lane]=r;
  else     outb[(size_t)n*64+lane]=f2bf(r);
}

// GIN: self + sum (bf16 in, fp32 out), unroll 4
__global__ __launch_bounds__(256) void agg_kernel(const unsigned short* __restrict__ xin,
    const int* __restrict__ rowptr, const int* __restrict__ srcS,
    float* __restrict__ out){
  int n=blockIdx.x*4+(threadIdx.x>>6);
  int lane=threadIdx.x&63;
  if(n>=NN) return;
  int r0=rowptr[n], r1=rowptr[n+1];
  float acc=bf2f(xin[(size_t)n*64+lane]);
  int j=r0;
  for(; j+3<r1; j+=4){
    int s0=srcS[j], s1=srcS[j+1], s2=srcS[j+2], s3=srcS[j+3];
    acc+=(bf2f(xin[(size_t)s0*64+lane])+bf2f(xin[(size_t)s1*64+lane]))
        +(bf2f(xin[(size_t)s2*64+lane])+bf2f(xin[(size_t)s3*64+lane]));
  }
  for(; j<r1; j++) acc+=bf2f(xin[(size_t)srcS[j]*64+lane]);
  out[(size_t)n*64+lane]=acc;
}

// SAGE staging: out128[n]=[mean_neigh, self] (bf16 in, fp32 out), unroll 4
__global__ __launch_bounds__(256) void agg2_kernel(const unsigned short* __restrict__ xin,
    const int* __restrict__ rowptr, const int* __restrict__ srcS,
    const float* __restrict__ invdeg, float* __restrict__ out128){
  int n=blockIdx.x*4+(threadIdx.x>>6);
  int lane=threadIdx.x&63;
  if(n>=NN) return;
  int r0=rowptr[n], r1=rowptr[n+1];
  float acc=0.f;
  int j=r0;
  for(; j+3<r1; j+=4){
    int s0=srcS[j], s1=srcS[j+1], s2=srcS[j+2], s3=srcS[j+3];
    acc+=(bf2f(xin[(size_t)s0*64+lane])+bf2f(xin[(size_t)s1*64+lane]))
        +(bf2f(xin[(size_t)s2*64+lane])+bf2f(xin[(size_t)s3*64+lane]));
  }
  for(; j<r1; j++) acc+=bf2f(xin[(size_t)srcS[j]*64+lane]);
  out128[(size_t)n*128+lane]=acc*invdeg[n];
  out128[(size_t)n*128+64+lane]=bf2f(xin[(size_t)n*64+lane]);
}

// TR pass1 (edge-parallel SDDMM): 16 lanes/edge, bf16 q/k, fp32 dot.
__global__ __launch_bounds__(256) void tr_pass1_kernel(const int* __restrict__ srcS, const int* __restrict__ dstS,
    const unsigned short* __restrict__ q, const unsigned short* __restrict__ k,
    float* __restrict__ lg){
  int e=blockIdx.x*16+(threadIdx.x>>4);
  int t=threadIdx.x&15;
  if(e>=EE) return;
  int s=srcS[e], d=dstS[e];
  const unsigned short* ks=k+(size_t)s*256+t*4;
  const unsigned short* qd=q+(size_t)d*256+t*4;
  ushort4 ku0=*(const ushort4*)(ks);
  ushort4 ku1=*(const ushort4*)(ks+64);
  ushort4 ku2=*(const ushort4*)(ks+128);
  ushort4 ku3=*(const ushort4*)(ks+192);
  ushort4 qu0=*(const ushort4*)(qd);
  ushort4 qu1=*(const ushort4*)(qd+64);
  ushort4 qu2=*(const ushort4*)(qd+128);
  ushort4 qu3=*(const ushort4*)(qd+192);
  float v0=bf2f(ku0.x)*bf2f(qu0.x)+bf2f(ku0.y)*bf2f(qu0.y)+bf2f(ku0.z)*bf2f(qu0.z)+bf2f(ku0.w)*bf2f(qu0.w);
  float v1=bf2f(ku1.x)*bf2f(qu1.x)+bf2f(ku1.y)*bf2f(qu1.y)+bf2f(ku1.z)*bf2f(qu1.z)+bf2f(ku1.w)*bf2f(qu1.w);
  float v2=bf2f(ku2.x)*bf2f(qu2.x)+bf2f(ku2.y)*bf2f(qu2.y)+bf2f(ku2.z)*bf2f(qu2.z)+bf2f(ku2.w)*bf2f(qu2.w);
  float v3=bf2f(ku3.x)*bf2f(qu3.x)+bf2f(ku3.y)*bf2f(qu3.y)+bf2f(ku3.z)*bf2f(qu3.z)+bf2f(ku3.w)*bf2f(qu3.w);
  #pragma unroll
  for(int o=1;o<16;o<<=1){
    v0+=__shfl_xor(v0,o,16); v1+=__shfl_xor(v1,o,16);
    v2+=__shfl_xor(v2,o,16); v3+=__shfl_xor(v3,o,16);
  }
  if(t==0)
    *(float4*)(lg+(size_t)4*e)=make_float4(v0*0.125f,v1*0.125f,v2*0.125f,v3*0.125f);
}

// TR pass2: exp + bf16 v-gather + skip + relu -> x5 (unroll 4)
__global__ __launch_bounds__(256) void tr_pass2_kernel(const int* __restrict__ rowptr, const int* __restrict__ srcS,
    const float* __restrict__ lg,
    const unsigned short* __restrict__ v, const float* __restrict__ skip, float* __restrict__ x5){
  int n=blockIdx.x*4+(threadIdx.x>>6);
  int lane=threadIdx.x&63;
  if(n>=NN) return;
  int r0=rowptr[n], r1=rowptr[n+1];
  float z0=0.f,z1=0.f,z2=0.f,z3=0.f;
  float a0=0.f,a1=0.f,a2=0.f,a3=0.f;
  int j=r0;
  for(; j+3<r1; j+=4){
    int s0=srcS[j], s1=srcS[j+1], s2=srcS[j+2], s3=srcS[j+3];
    const float4 f0=*(const float4*)(lg+(size_t)4*j);
    const float4 f1=*(const float4*)(lg+(size_t)4*(j+1));
    const float4 f2=*(const float4*)(lg+(size_t)4*(j+2));
    const float4 f3=*(const float4*)(lg+(size_t)4*(j+3));
    const unsigned short* v0=v+(size_t)s0*256;
    const unsigned short* v1=v+(size_t)s1*256;
    const unsigned short* v2=v+(size_t)s2*256;
    const unsigned short* v3=v+(size_t)s3*256;
    float e00=__expf(f0.x), e01=__expf(f0.y), e02=__expf(f0.z), e03=__expf(f0.w);
    float e10=__expf(f1.x), e11=__expf(f1.y), e12=__expf(f1.z), e13=__expf(f1.w);
    float e20=__expf(f2.x), e21=__expf(f2.y), e22=__expf(f2.z), e23=__expf(f2.w);
    float e30=__expf(f3.x), e31=__expf(f3.y), e32=__expf(f3.z), e33=__expf(f3.w);
    z0+=(e00+e10)+(e20+e30); z1+=(e01+e11)+(e21+e31);
    z2+=(e02+e12)+(e22+e32); z3+=(e03+e13)+(e23+e33);
    a0+=(e00*bf2f(v0[lane])+e10*bf2f(v1[lane]))+(e20*bf2f(v2[lane])+e30*bf2f(v3[lane]));
    a1+=(e01*bf2f(v0[64+lane])+e11*bf2f(v1[64+lane]))+(e21*bf2f(v2[64+lane])+e31*bf2f(v3[64+lane]));
    a2+=(e02*bf2f(v0[128+lane])+e12*bf2f(v1[128+lane]))+(e22*bf2f(v2[128+lane])+e32*bf2f(v3[128+lane]));
    a3+=(e03*bf2f(v0[192+lane])+e13*bf2f(v1[192+lane]))+(e23*bf2f(v2[192+lane])+e33*bf2f(v3[192+lane]));
  }
  for(; j<r1; j++){
    int s0=srcS[j];
    const float4 f0=*(const float4*)(lg+(size_t)4*j);
    const unsigned short* v0=v+(size_t)s0*256;
    float e00=__expf(f0.x), e01=__expf(f0.y), e02=__expf(f0.z), e03=__expf(f0.w);
    z0+=e00; z1+=e01; z2+=e02; z3+=e03;
    a0+=e00*bf2f(v0[lane]); a1+=e01*bf2f(v0[64+lane]); a2+=e02*bf2f(v0[128+lane]); a3+=e03*bf2f(v0[192+lane]);
  }
  float zi0=1.f/(z0+1e-16f), zi1=1.f/(z1+1e-16f), zi2=1.f/(z2+1e-16f), zi3=1.f/(z3+1e-16f);
  float t=0.25f*(a0*zi0+a1*zi1+a2*zi2+a3*zi3)+skip[(size_t)n*64+lane];
  x5[(size_t)n*64+lane]=fmaxf(t,0.f);
}

// EdgeConv v3: hidden = relu(P[dst]+Q[src]) -> GEMM2(+b2) -> LDS segmented max ->
// plain store for interior dst, atomicMax only for tile-boundary dst.
__global__ __launch_bounds__(256) void edgeconv2_kernel(
    const float* __restrict__ P, const float* __restrict__ Q,
    const int* __restrict__ srcS, const int* __restrict__ dstS,
    const float* __restrict__ W2, const float* __restrict__ b2,
    unsigned* __restrict__ emax){
  __shared__ float As[64][68];   // hidden tile, then reused for output tile
  __shared__ float Ws[64][64];
  __shared__ int dstL[64];
  const int e0=blockIdx.x*64;    // EE is a multiple of 64
  const int tid=threadIdx.x, tx=tid&15, ty=tid>>4;
  if(tid<64) dstL[tid]=dstS[e0+tid];
  #pragma unroll
  for(int it=0;it<4;it++){
    int linear=it*1024+tid*4;
    int m=linear>>6, k=linear&63;
    int e=e0+m;
    int dn=dstS[e], sn=srcS[e];
    const float4 p=*(const float4*)(P+(size_t)dn*64+k);
    const float4 q=*(const float4*)(Q+(size_t)sn*64+k);
    float4 v=make_float4(fmaxf(p.x+q.x,0.f),fmaxf(p.y+q.y,0.f),fmaxf(p.z+q.z,0.f),fmaxf(p.w+q.w,0.f));
    *(float4*)&As[m][k]=v;
  }
  #pragma unroll
  for(int it=0;it<4;it++){
    int linear=it*1024+tid*4;
    int k=linear>>6, n=linear&63;
    *(float4*)&Ws[k][n]=*(const float4*)(W2+(size_t)k*64+n);
  }
  __syncthreads();
  float acc2[4][4];
  #pragma unroll
  for(int i=0;i<4;i++)
    #pragma unroll
    for(int j=0;j<4;j++) acc2[i][j]=b2[tx*4+j];
  #pragma unroll 8
  for(int k=0;k<64;k+=4){
    float4 a0=*(float4*)&As[ty*4+0][k];
    float4 a1=*(float4*)&As[ty*4+1][k];
    float4 a2=*(float4*)&As[ty*4+2][k];
    float4 a3=*(float4*)&As[ty*4+3][k];
    float4 w0=*(float4*)&Ws[k+0][tx*4];
    float4 w1=*(float4*)&Ws[k+1][tx*4];
    float4 w2=*(float4*)&Ws[k+2][tx*4];
    float4 w3=*(float4*)&Ws[k+3][tx*4];
    mac4(acc2[0],a0,w0,w1,w2,w3);
    mac4(acc2[1],a1,w0,w1,w2,w3);
    mac4(acc2[2],a2,w0,w1,w2,w3);
    mac4(acc2[3],a3,w0,w1,w2,w3);
  }
  __syncthreads();   // done reading As
  #pragma unroll
  for(int i=0;i<4;i++)
    #pragma unroll
    for(int j=0;j<4;j++)
      As[ty*4+i][tx*4+j]=acc2[i][j];   // output tile [edge][col]
  __syncthreads();
  if(tid<64){
    const int c=tid;
    const int dFirst=dstL[0], dLast=dstL[63];
    int dprev=dFirst;
    float mx=As[0][c];
    #pragma unroll 8
    for(int m=1;m<64;m++){
      int dn=dstL[m];
      float v=As[m][c];
      if(dn!=dprev){
        unsigned* addr=&emax[(size_t)dprev*64+c];
        unsigned enc=fenc(mx);
        if(dprev!=dFirst && dprev!=dLast) *addr=enc;
        else atomicMax(addr,enc);
        dprev=dn; mx=v;
      }else mx=fmaxf(mx,v);
    }
    unsigned* addr=&emax[(size_t)dprev*64+c];
    unsigned enc=fenc(mx);
    if(dprev!=dFirst && dprev!=dLast) *addr=enc;
    else atomicMax(addr,enc);
  }
}

// pool with emax decode fused
__global__ __launch_bounds__(256) void pool_kernel(const unsigned* __restrict__ emax, const int* __restrict__ batch,
                                                   float* __restrict__ pooled){
  const int NB=200;
  int base=blockIdx.x*NB;
  int lane=threadIdx.x&63;
  int wsub=threadIdx.x>>6;
  float acc=0.f; int curg=-1;
  for(int idx=wsub; idx<NB; idx+=4){
    int n=base+idx;
    if(n>=NN) break;
    int g=batch[n];
    if(g!=curg){
      if(curg>=0) atomicAdd(&pooled[curg*64+lane],acc);
      acc=0.f; curg=g;
    }
    unsigned u=emax[(size_t)n*64+lane];
    acc+=(u>=0x80000000u)? __uint_as_float(u&0x7fffffffu) : 0.f;
  }
  if(curg>=0) atomicAdd(&pooled[curg*64+lane],acc);
}

__global__ __launch_bounds__(256) void final_kernel(const float* __restrict__ pooled, const int* __restrict__ batch,
    const float* __restrict__ fc1W, const float* __restrict__ fc1b,
    const float* __restrict__ fc2W, const float* __restrict__ fc2b,
    float* __restrict__ out){
  __shared__ float gm[16][64];
  __shared__ float t1[16][64];
  __shared__ int cgs[17];
  int t=threadIdx.x;
  if(t<17){
    int lo=0, hi=NN;
    while(lo<hi){ int mid=(lo+hi)>>1; if(batch[mid]<t) lo=mid+1; else hi=mid; }
    cgs[t]=lo;
  }
  __syncthreads();
  for(int r=0;r<4;r++){
    int idx=r*256+t; int g=idx>>6, d=idx&63;
    float c=(float)(cgs[g+1]-cgs[g]);
    gm[g][d]=pooled[idx]/fmaxf(c,1.f);
  }
  __syncthreads();
  for(int r=0;r<4;r++){
    int idx=r*256+t; int g=idx>>6, d=idx&63;
    float a=fc1b[d];
    for(int k2=0;k2<64;k2++) a+=gm[g][k2]*fc1W[k2*64+d];
    t1[g][d]=fmaxf(a,0.f);
  }
  __syncthreads();
  for(int r=0;r<4;r++){
    int idx=r*256+t; int g=idx>>6, d=idx&63;
    float a=fc2b[d];
    for(int k2=0;k2<64;k2++) a+=t1[g][k2]*fc2W[k2*64+d];
    out[idx]=a;
  }
}

extern "C" void kernel_launch(void* const* d_in, const int* in_sizes, int n_in,
                              void* d_out, int out_size, void* d_ws, size_t ws_size,
                              hipStream_t stream){
  const float* x       =(const float*)d_in[0];
  const int*   ei      =(const int*)  d_in[1];
  const int*   src     =ei;
  const int*   dst     =ei+EE;
  const int*   batch   =(const int*)  d_in[2];
  const float* gat1_W  =(const float*)d_in[3];
  const float* gat1_as =(const float*)d_in[4];
  const float* gat1_ad =(const float*)d_in[5];
  const float* gat1_b  =(const float*)d_in[6];
  const float* gat2_W  =(const float*)d_in[7];
  const float* gat2_as =(const float*)d_in[8];
  const float* gat2_ad =(const float*)d_in[9];
  const float* gat2_b  =(const float*)d_in[10];
  const float* gin_W1  =(const float*)d_in[11];
  const float* gin_b1  =(const float*)d_in[12];
  const float* gin_W2  =(const float*)d_in[13];
  const float* gin_b2  =(const float*)d_in[14];
  const float* sage1_Wl=(const float*)d_in[15];
  const float* sage1_bl=(const float*)d_in[16];
  const float* sage1_Wr=(const float*)d_in[17];
  const float* sage2_Wl=(const float*)d_in[18];
  const float* sage2_bl=(const float*)d_in[19];
  const float* sage2_Wr=(const float*)d_in[20];
  const float* tr_Wq   =(const float*)d_in[21];
  const float* tr_bq   =(const float*)d_in[22];
  const float* tr_Wk   =(const float*)d_in[23];
  const float* tr_bk   =(const float*)d_in[24];
  const float* tr_Wv   =(const float*)d_in[25];
  const float* tr_bv   =(const float*)d_in[26];
  const float* tr_Ws   =(const float*)d_in[27];
  const float* tr_bs   =(const float*)d_in[28];
  const float* ec_W1   =(const float*)d_in[29];
  const float* ec_b1   =(const float*)d_in[30];
  const float* ec_W2   =(const float*)d_in[31];
  const float* ec_b2   =(const float*)d_in[32];
  const float* fc1_W   =(const float*)d_in[33];
  const float* fc1_b   =(const float*)d_in[34];
  const float* fc2_W   =(const float*)d_in[35];
  const float* fc2_b   =(const float*)d_in[36];

  // ---- workspace layout ----
  float* base=(float*)d_ws;
  size_t off=0;
  auto alloc=[&](size_t n){ float* p=base+off; off+=n; return p; };
  float* A_big =alloc((size_t)NN*256);     // GAT h bf16 / SAGE xcat f32 / TR q+k bf16
  float* nb0   =alloc(N64);
  float* nb1   =alloc(N64);                // nb1..nb4 contiguous
  float* nb2   =alloc(N64);
  float* nb3   =alloc(N64);
  float* nb4   =alloc(N64);
  float* nb5   =alloc(N64);                // emax (as unsigned, zeroed)
  float* logitE=alloc((size_t)EE*4);
  float* ls    =alloc(NN*4);               // GAT ls
  float* ldb   =alloc(NN*4);               // GAT ld / EdgeConv Wd (4096)
  float* invdeg=alloc(NN);
  float* pooled=alloc(GG*64);
  int* ibase=(int*)(base+off);
  int* srcS  =ibase;
  int* dstS  =ibase+EE;
  int* cnt   =ibase+2*EE;
  int* fillp =ibase+2*EE+NN;               // cnt,fillp contiguous (zeroed together)
  int* rowptr=ibase+2*EE+2*NN;             // NN+1 ints
  int* bsum  =ibase+2*EE+3*NN+8;           // 49 ints
  int* boff  =bsum+64;                     // 49 ints

  const int BT=256;
  const int NSB=cdiv(NN,1024);             // 49 scan blocks
  // ---- zero init ----
  zero_kernel<<<cdiv(2*NN,BT),BT,0,stream>>>((unsigned*)cnt,2*NN);
  zero_kernel<<<cdiv(GG*64,BT),BT,0,stream>>>((unsigned*)pooled,GG*64);
  zero_kernel<<<cdiv(N64,BT),BT,0,stream>>>((unsigned*)nb5,N64);
  // ---- CSR ----
  hist_kernel<<<cdiv(EE,BT),BT,0,stream>>>(dst,cnt);
  scan1_kernel<<<NSB,1024,0,stream>>>(cnt,rowptr,bsum);
  scan2_kernel<<<1,64,0,stream>>>(bsum,boff,rowptr,NSB);
  scan3_kernel<<<cdiv(NN,BT),BT,0,stream>>>(rowptr,boff);
  fill_kernel<<<cdiv(EE,BT),BT,0,stream>>>(src,dst,rowptr,fillp,srcS,dstS);
  invdeg_kernel<<<cdiv(NN,BT),BT,0,stream>>>(cnt,invdeg);

  const int GB=cdiv(NN,64);        // 782 row tiles
  const int GW=cdiv(NN,4);         // wave-per-node blocks (12500)

  unsigned short* hbf=(unsigned short*)A_big;          // GAT h bf16 [N,256]
  unsigned short* x2b=(unsigned short*)nb1;            // x2 bf16 [N,64]
  unsigned short* x3b=(unsigned short*)nb1;            // x3 bf16 (x2 dead by then)
  unsigned short* xsb=(unsigned short*)nb2;            // xs bf16
  unsigned short* qb =(unsigned short*)A_big;          // TR q bf16 [N,256]
  unsigned short* kb =qb+(size_t)NN*256;               // TR k bf16 [N,256]
  unsigned short* vb =(unsigned short*)nb1;            // TR v bf16 [N,256] (spans nb1+nb2)

  // ---- GAT1 (attn dots fused in GEMM epilogue; h stored bf16) ----
  gemm_kernel<128><<<dim3(GB,4),BT,0,stream>>>(x,gat1_W,nullptr,256,0,nullptr,nullptr,nullptr,hbf,256,0,
                                               gat1_as,gat1_ad,ls,ldb);
  gat1p_kernel<<<GW,BT,0,stream>>>(hbf,rowptr,srcS,ls,ldb,gat1_b,nb0,nullptr);         // x1 f32
  // ---- GAT2 ----
  gemm_kernel<64><<<dim3(GB,4),BT,0,stream>>>(nb0,gat2_W,nullptr,256,0,nullptr,nullptr,nullptr,hbf,256,0,
                                              gat2_as,gat2_ad,ls,ldb);
  gat1p_kernel<<<GW,BT,0,stream>>>(hbf,rowptr,srcS,ls,ldb,gat2_b,nullptr,x2b);         // x2 bf16
  // ---- GIN ----
  agg_kernel<<<GW,BT,0,stream>>>(x2b,rowptr,srcS,nb2);                                 // t f32
  gemm_kernel<64><<<dim3(GB,1),BT,0,stream>>>(nb2,gin_W1,nullptr,64,0,gin_b1,nullptr,nb3,nullptr,64,1,
                                              nullptr,nullptr,nullptr,nullptr);
  gemm_kernel<64><<<dim3(GB,1),BT,0,stream>>>(nb3,gin_W2,nullptr,64,0,gin_b2,nullptr,nullptr,x3b,64,1,
                                              nullptr,nullptr,nullptr,nullptr);        // x3 bf16
  // ---- SAGE1: xcat=[mean(x3), x3] @ [Wl;Wr] + bl ----
  agg2_kernel<<<GW,BT,0,stream>>>(x3b,rowptr,srcS,invdeg,A_big);
  gemm_kernel<128><<<dim3(GB,1),BT,0,stream>>>(A_big,sage1_Wl,sage1_Wr,64,0,sage1_bl,nullptr,nullptr,xsb,64,1,
                                               nullptr,nullptr,nullptr,nullptr);       // xs bf16
  // ---- SAGE2 ----
  agg2_kernel<<<GW,BT,0,stream>>>(xsb,rowptr,srcS,invdeg,A_big);
  gemm_kernel<128><<<dim3(GB,1),BT,0,stream>>>(A_big,sage2_Wl,sage2_Wr,64,0,sage2_bl,nullptr,nb0,nullptr,64,1,
                                               nullptr,nullptr,nullptr,nullptr);       // x4 f32
  // ---- TransformerConv (q/k/v bf16) ----
  gemm_kernel<64><<<dim3(GB,4),BT,0,stream>>>(nb0,tr_Wq,nullptr,256,0,tr_bq,nullptr,nullptr,qb,256,0,
                                              nullptr,nullptr,nullptr,nullptr);
  gemm_kernel<64><<<dim3(GB,4),BT,0,stream>>>(nb0,tr_Wk,nullptr,256,0,tr_bk,nullptr,nullptr,kb,256,0,
                                              nullptr,nullptr,nullptr,nullptr);
  tr_pass1_kernel<<<cdiv(EE,16),BT,0,stream>>>(srcS,dstS,qb,kb,logitE);                // logits
  gemm_kernel<64><<<dim3(GB,4),BT,0,stream>>>(nb0,tr_Wv,nullptr,256,0,tr_bv,nullptr,nullptr,vb,256,0,
                                              nullptr,nullptr,nullptr,nullptr);        // v bf16
  gemm_kernel<64><<<dim3(GB,1),BT,0,stream>>>(nb0,tr_Ws,nullptr,64,0,tr_bs,nullptr,nb3,nullptr,64,0,
                                              nullptr,nullptr,nullptr,nullptr);        // skip f32
  tr_pass2_kernel<<<GW,BT,0,stream>>>(rowptr,srcS,logitE,vb,nb3,nb4);                  // x5 f32
  // ---- EdgeConv (factored): P=x5@(W1a-W1b)+b1, Q=x5@W1b ----
  wd_kernel<<<16,BT,0,stream>>>(ec_W1,ldb);
  gemm_kernel<64><<<dim3(GB,1),BT,0,stream>>>(nb4,ldb,nullptr,64,0,ec_b1,nullptr,nb1,nullptr,64,0,
                                              nullptr,nullptr,nullptr,nullptr);        // P (v dead)
  gemm_kernel<64><<<dim3(GB,1),BT,0,stream>>>(nb4,ec_W1+4096,nullptr,64,0,nullptr,nullptr,nb2,nullptr,64,0,
                                              nullptr,nullptr,nullptr,nullptr);        // Q
  edgeconv2_kernel<<<EE/64,BT,0,stream>>>(nb1,nb2,srcS,dstS,ec_W2,ec_b2,(unsigned*)nb5);
  // ---- pool (emax decode fused) + MLP ----
  pool_kernel<<<cdiv(NN,200),BT,0,stream>>>((unsigned*)nb5,batch,pooled);
  final_kernel<<<1,BT,0,stream>>>(pooled,batch,fc1_W,fc1_b,fc2_W,fc2_b,(float*)d_out);
}

// Round 9
// 879.366 us; speedup vs baseline: 2.6636x; 1.1093x over previous
//
#include <hip/hip_runtime.h>

#define NN 50000
#define EE 640000
#define GG 16
#define N64 (NN*64)

static inline int cdiv(int a,int b){return (a+b-1)/b;}

typedef __attribute__((ext_vector_type(8))) short bfrag;   // 8 bf16 (4 VGPR)
typedef __attribute__((ext_vector_type(4))) float ffrag;   // mfma accumulator

__device__ __forceinline__ float lrelu(float x){ return x>0.f? x : 0.2f*x; }
__device__ __forceinline__ unsigned fenc(float f){
  unsigned u=__float_as_uint(f);
  return (u&0x80000000u)? ~u : (u|0x80000000u);
}
__device__ __forceinline__ float bf2f(unsigned short u){ return __uint_as_float(((unsigned)u)<<16); }
__device__ __forceinline__ unsigned short f2bf(float f){
  unsigned u=__float_as_uint(f);
  u += 0x7FFFu + ((u>>16)&1u);
  return (unsigned short)(u>>16);
}
__device__ __forceinline__ void mac4(float* acc, const float4 av,
    const float4 w0, const float4 w1, const float4 w2, const float4 w3){
  acc[0]+=av.x*w0.x+av.y*w1.x+av.z*w2.x+av.w*w3.x;
  acc[1]+=av.x*w0.y+av.y*w1.y+av.z*w2.y+av.w*w3.y;
  acc[2]+=av.x*w0.z+av.y*w1.z+av.z*w2.z+av.w*w3.z;
  acc[3]+=av.x*w0.w+av.y*w1.w+av.z*w2.w+av.w*w3.w;
}

__global__ void zero_kernel(unsigned* p, int n){
  int i=blockIdx.x*blockDim.x+threadIdx.x;
  if(i<n) p[i]=0u;
}

__global__ void hist_kernel(const int* __restrict__ dst, int* __restrict__ cnt){
  int e=blockIdx.x*blockDim.x+threadIdx.x;
  if(e<EE) atomicAdd(&cnt[dst[e]],1);
}

__global__ __launch_bounds__(1024) void scan1_kernel(const int* __restrict__ cnt,
    int* __restrict__ rowptr, int* __restrict__ bsum){
  __shared__ int wsum[16];
  int t=threadIdx.x, b=blockIdx.x;
  int i=b*1024+t;
  int v=(i<NN)?cnt[i]:0;
  int lane=t&63, w=t>>6;
  int inc=v;
  #pragma unroll
  for(int o=1;o<64;o<<=1){ int u=__shfl_up(inc,o,64); if(lane>=o) inc+=u; }
  if(lane==63) wsum[w]=inc;
  __syncthreads();
  if(t<16){
    int s=wsum[t];
    #pragma unroll
    for(int o=1;o<16;o<<=1){ int u=__shfl_up(s,o,16); if(t>=o) s+=u; }
    wsum[t]=s;
  }
  __syncthreads();
  int woff=(w>0)?wsum[w-1]:0;
  if(i<NN) rowptr[i]=woff+inc-v;
  if(t==1023) bsum[b]=wsum[15];
}

__global__ void scan2_kernel(const int* __restrict__ bsum, int* __restrict__ boff, int* __restrict__ rowptr, int nb){
  int t=threadIdx.x;
  int v=(t<nb)?bsum[t]:0;
  int inc=v;
  #pragma unroll
  for(int o=1;o<64;o<<=1){ int u=__shfl_up(inc,o,64); if(t>=o) inc+=u; }
  if(t<nb) boff[t]=inc-v;
  if(t==63) rowptr[NN]=inc;
}

// + invdeg fused
__global__ void scan3_kernel(int* __restrict__ rowptr, const int* __restrict__ boff,
                             const int* __restrict__ cnt, float* __restrict__ invdeg){
  int i=blockIdx.x*blockDim.x+threadIdx.x;
  if(i<NN){
    rowptr[i]+=boff[i>>10];
    invdeg[i]=1.f/fmaxf((float)cnt[i],1.f);
  }
}

__global__ void fill_kernel(const int* __restrict__ src, const int* __restrict__ dst,
                            const int* __restrict__ rowptr, int* __restrict__ fillp,
                            int* __restrict__ srcS, int* __restrict__ dstS){
  int e=blockIdx.x*blockDim.x+threadIdx.x;
  if(e>=EE) return;
  int d=dst[e];
  int p=rowptr[d]+atomicAdd(&fillp[d],1);
  srcS[p]=src[e]; dstS[p]=d;
}

// convert x [N,128] f32 -> bf16
__global__ void cvtx_kernel(const float* __restrict__ x, unsigned short* __restrict__ xb){
  int i=blockIdx.x*blockDim.x+threadIdx.x;
  if(i>=NN*32) return;
  float4 v=*(const float4*)(x+(size_t)i*4);
  ushort4 o; o.x=f2bf(v.x); o.y=f2bf(v.y); o.z=f2bf(v.z); o.w=f2bf(v.w);
  *(ushort4*)(xb+(size_t)i*4)=o;
}

// weight prep: Wt[n][k]=W[k][n] bf16, all segments + bias packs
__global__ void prep_kernel(
    const float* __restrict__ g1W, const float* __restrict__ g2W,
    const float* __restrict__ giW1, const float* __restrict__ giW2,
    const float* __restrict__ s1Wl, const float* __restrict__ s1Wr,
    const float* __restrict__ s2Wl, const float* __restrict__ s2Wr,
    const float* __restrict__ Wq, const float* __restrict__ Wk,
    const float* __restrict__ Wv, const float* __restrict__ Ws,
    const float* __restrict__ ecW1,
    const float* __restrict__ bq, const float* __restrict__ bk, const float* __restrict__ eb1,
    unsigned short* __restrict__ wt, float* __restrict__ bqk, float* __restrict__ bPQ){
  int i=blockIdx.x*blockDim.x+threadIdx.x;
  if(i<32768){ int n=i>>7,k=i&127; wt[i]=f2bf(g1W[k*256+n]); return; } i-=32768;
  if(i<16384){ int n=i>>6,k=i&63; wt[32768+i]=f2bf(g2W[k*256+n]); return; } i-=16384;
  if(i<4096){ int n=i>>6,k=i&63; wt[49152+i]=f2bf(giW1[k*64+n]); return; } i-=4096;
  if(i<4096){ int n=i>>6,k=i&63; wt[53248+i]=f2bf(giW2[k*64+n]); return; } i-=4096;
  if(i<8192){ int n=i>>7,k=i&127; float v=(k<64)?s1Wl[k*64+n]:s1Wr[(k-64)*64+n];
              wt[57344+i]=f2bf(v); return; } i-=8192;
  if(i<8192){ int n=i>>7,k=i&127; float v=(k<64)?s2Wl[k*64+n]:s2Wr[(k-64)*64+n];
              wt[65536+i]=f2bf(v); return; } i-=8192;
  if(i<32768){ int n=i>>6,k=i&63; float v=(n<256)?Wq[k*256+n]:Wk[k*256+(n-256)];
               wt[73728+i]=f2bf(v); return; } i-=32768;
  if(i<16384){ int n=i>>6,k=i&63; wt[106496+i]=f2bf(Wv[k*256+n]); return; } i-=16384;
  if(i<4096){ int n=i>>6,k=i&63; wt[122880+i]=f2bf(Ws[k*64+n]); return; } i-=4096;
  if(i<8192){ int n=i>>6,k=i&63;
              float v=(n<64)?(ecW1[k*64+n]-ecW1[(64+k)*64+n]):ecW1[(64+k)*64+(n-64)];
              wt[126976+i]=f2bf(v); return; } i-=8192;
  if(i<640){
    if(i<256) bqk[i]=bq[i];
    else if(i<512) bqk[i]=bk[i-256];
    else { int j=i-512; bPQ[j]=(j<64)?eb1[j]:0.f; }
  }
}

// bf16 MFMA GEMM: C[64x64 tile] = A[M,K]bf16 @ Wt[N,K]bf16^T (+bias)(relu)
// Cb!=null -> bf16 out else f32. lsO: GAT attn-dot epilogue, head=blockIdx.y.
template<int K>
__global__ __launch_bounds__(256) void mgemm_kernel(
    const unsigned short* __restrict__ A, const unsigned short* __restrict__ Wt,
    const float* __restrict__ bias,
    float* __restrict__ Cf, unsigned short* __restrict__ Cb, int ldc, int relu_flag,
    const float* __restrict__ a_s, const float* __restrict__ a_d,
    float* __restrict__ lsO, float* __restrict__ ldO){
  __shared__ float lsP[2][4][64];
  const int m0=blockIdx.x*64;
  const int tid=threadIdx.x;
  const int w=tid>>6, l=tid&63, lo=l&15, quad=l>>4;
  const int colg=blockIdx.y*64 + w*16 + lo;
  const unsigned short* wrow=Wt+(size_t)colg*K+quad*8;
  ffrag acc[4];
  #pragma unroll
  for(int t=0;t<4;t++) acc[t]=(ffrag){0.f,0.f,0.f,0.f};
  int rows[4];
  #pragma unroll
  for(int t=0;t<4;t++){ int r=m0+t*16+lo; rows[t]=(r<NN)?r:(NN-1); }
  #pragma unroll
  for(int kc=0;kc<K;kc+=32){
    bfrag b=*(const bfrag*)(wrow+kc);
    #pragma unroll
    for(int t=0;t<4;t++){
      bfrag a=*(const bfrag*)(A+(size_t)rows[t]*K+kc+quad*8);
      acc[t]=__builtin_amdgcn_mfma_f32_16x16x32_bf16(a,b,acc[t],0,0,0);
    }
  }
  float bv=bias?bias[colg]:0.f;
  float asv=0.f,adv=0.f;
  if(lsO){ asv=a_s[colg]; adv=a_d[colg]; }
  #pragma unroll
  for(int t=0;t<4;t++){
    #pragma unroll
    for(int r=0;r<4;r++){
      float v=acc[t][r]+bv;
      if(relu_flag) v=fmaxf(v,0.f);
      int row=m0+t*16+quad*4+r;
      if(row<NN){
        if(Cb) Cb[(size_t)row*ldc+colg]=f2bf(v);
        else   Cf[(size_t)row*ldc+colg]=v;
      }
      if(lsO){
        float ps=v*asv, pd=v*adv;
        #pragma unroll
        for(int o=1;o<16;o<<=1){ ps+=__shfl_xor(ps,o,16); pd+=__shfl_xor(pd,o,16); }
        if(lo==0){ int lr=t*16+quad*4+r; lsP[0][w][lr]=ps; lsP[1][w][lr]=pd; }
      }
    }
  }
  if(lsO){
    __syncthreads();
    if(tid<64){
      int row=m0+tid;
      if(row<NN){
        lsO[(size_t)row*4+blockIdx.y]=lsP[0][0][tid]+lsP[0][1][tid]+lsP[0][2][tid]+lsP[0][3][tid];
        ldO[(size_t)row*4+blockIdx.y]=lsP[1][0][tid]+lsP[1][1][tid]+lsP[1][2][tid]+lsP[1][3][tid];
      }
    }
  }
}

// single-pass GAT (no max subtraction), bf16 h gather, unroll 4, bf16 out.
__global__ __launch_bounds__(256) void gat1p_kernel(const unsigned short* __restrict__ h,
    const int* __restrict__ rowptr, const int* __restrict__ srcS,
    const float* __restrict__ ls4, const float* __restrict__ ld4,
    const float* __restrict__ bias, unsigned short* __restrict__ outb){
  int n=blockIdx.x*4+(threadIdx.x>>6);
  int lane=threadIdx.x&63;
  if(n>=NN) return;
  int r0=rowptr[n], r1=rowptr[n+1];
  const float4 ldv=*(const float4*)(ld4+(size_t)4*n);
  const float4 lsv=*(const float4*)(ls4+(size_t)4*n);
  float z0=__expf(lrelu(lsv.x+ldv.x)), z1=__expf(lrelu(lsv.y+ldv.y));
  float z2=__expf(lrelu(lsv.z+ldv.z)), z3=__expf(lrelu(lsv.w+ldv.w));
  const unsigned short* hn=h+(size_t)n*256;
  float a0=z0*bf2f(hn[lane]), a1=z1*bf2f(hn[64+lane]), a2=z2*bf2f(hn[128+lane]), a3=z3*bf2f(hn[192+lane]);
  int j=r0;
  for(; j+3<r1; j+=4){
    int s0=srcS[j], s1=srcS[j+1], s2=srcS[j+2], s3=srcS[j+3];
    const float4 A0=*(const float4*)(ls4+(size_t)4*s0);
    const float4 A1=*(const float4*)(ls4+(size_t)4*s1);
    const float4 A2=*(const float4*)(ls4+(size_t)4*s2);
    const float4 A3=*(const float4*)(ls4+(size_t)4*s3);
    const unsigned short* h0=h+(size_t)s0*256;
    const unsigned short* h1=h+(size_t)s1*256;
    const unsigned short* h2=h+(size_t)s2*256;
    const unsigned short* h3=h+(size_t)s3*256;
    float e00=__expf(lrelu(A0.x+ldv.x)), e01=__expf(lrelu(A0.y+ldv.y));
    float e02=__expf(lrelu(A0.z+ldv.z)), e03=__expf(lrelu(A0.w+ldv.w));
    float e10=__expf(lrelu(A1.x+ldv.x)), e11=__expf(lrelu(A1.y+ldv.y));
    float e12=__expf(lrelu(A1.z+ldv.z)), e13=__expf(lrelu(A1.w+ldv.w));
    float e20=__expf(lrelu(A2.x+ldv.x)), e21=__expf(lrelu(A2.y+ldv.y));
    float e22=__expf(lrelu(A2.z+ldv.z)), e23=__expf(lrelu(A2.w+ldv.w));
    float e30=__expf(lrelu(A3.x+ldv.x)), e31=__expf(lrelu(A3.y+ldv.y));
    float e32=__expf(lrelu(A3.z+ldv.z)), e33=__expf(lrelu(A3.w+ldv.w));
    z0+=(e00+e10)+(e20+e30); z1+=(e01+e11)+(e21+e31);
    z2+=(e02+e12)+(e22+e32); z3+=(e03+e13)+(e23+e33);
    a0+=(e00*bf2f(h0[lane])+e10*bf2f(h1[lane]))+(e20*bf2f(h2[lane])+e30*bf2f(h3[lane]));
    a1+=(e01*bf2f(h0[64+lane])+e11*bf2f(h1[64+lane]))+(e21*bf2f(h2[64+lane])+e31*bf2f(h3[64+lane]));
    a2+=(e02*bf2f(h0[128+lane])+e12*bf2f(h1[128+lane]))+(e22*bf2f(h2[128+lane])+e32*bf2f(h3[128+lane]));
    a3+=(e03*bf2f(h0[192+lane])+e13*bf2f(h1[192+lane]))+(e23*bf2f(h2[192+lane])+e33*bf2f(h3[192+lane]));
  }
  for(; j<r1; j++){
    int s0=srcS[j];
    const float4 A0=*(const float4*)(ls4+(size_t)4*s0);
    const unsigned short* h0=h+(size_t)s0*256;
    float e00=__expf(lrelu(A0.x+ldv.x)), e01=__expf(lrelu(A0.y+ldv.y));
    float e02=__expf(lrelu(A0.z+ldv.z)), e03=__expf(lrelu(A0.w+ldv.w));
    z0+=e00; z1+=e01; z2+=e02; z3+=e03;
    a0+=e00*bf2f(h0[lane]); a1+=e01*bf2f(h0[64+lane]); a2+=e02*bf2f(h0[128+lane]); a3+=e03*bf2f(h0[192+lane]);
  }
  float zi0=1.f/(z0+1e-16f), zi1=1.f/(z1+1e-16f), zi2=1.f/(z2+1e-16f), zi3=1.f/(z3+1e-16f);
  float r=fmaxf(0.25f*(a0*zi0+a1*zi1+a2*zi2+a3*zi3)+bias[lane],0.f);
  outb[(size_t)n*64+lane]=f2bf(r);
}

// GIN: self + sum (bf16 in/out), unroll 4
__global__ __launch_bounds__(256) void agg_kernel(const unsigned short* __restrict__ xin,
    const int* __restrict__ rowptr, const int* __restrict__ srcS,
    unsigned short* __restrict__ out){
  int n=blockIdx.x*4+(threadIdx.x>>6);
  int lane=threadIdx.x&63;
  if(n>=NN) return;
  int r0=rowptr[n], r1=rowptr[n+1];
  float acc=bf2f(xin[(size_t)n*64+lane]);
  int j=r0;
  for(; j+3<r1; j+=4){
    int s0=srcS[j], s1=srcS[j+1], s2=srcS[j+2], s3=srcS[j+3];
    acc+=(bf2f(xin[(size_t)s0*64+lane])+bf2f(xin[(size_t)s1*64+lane]))
        +(bf2f(xin[(size_t)s2*64+lane])+bf2f(xin[(size_t)s3*64+lane]));
  }
  for(; j<r1; j++) acc+=bf2f(xin[(size_t)srcS[j]*64+lane]);
  out[(size_t)n*64+lane]=f2bf(acc);
}

// SAGE staging: out128b[n]=[mean_neigh, self] bf16, unroll 4
__global__ __launch_bounds__(256) void agg2_kernel(const unsigned short* __restrict__ xin,
    const int* __restrict__ rowptr, const int* __restrict__ srcS,
    const float* __restrict__ invdeg, unsigned short* __restrict__ out128b){
  int n=blockIdx.x*4+(threadIdx.x>>6);
  int lane=threadIdx.x&63;
  if(n>=NN) return;
  int r0=rowptr[n], r1=rowptr[n+1];
  float acc=0.f;
  int j=r0;
  for(; j+3<r1; j+=4){
    int s0=srcS[j], s1=srcS[j+1], s2=srcS[j+2], s3=srcS[j+3];
    acc+=(bf2f(xin[(size_t)s0*64+lane])+bf2f(xin[(size_t)s1*64+lane]))
        +(bf2f(xin[(size_t)s2*64+lane])+bf2f(xin[(size_t)s3*64+lane]));
  }
  for(; j<r1; j++) acc+=bf2f(xin[(size_t)srcS[j]*64+lane]);
  out128b[(size_t)n*128+lane]=f2bf(acc*invdeg[n]);
  out128b[(size_t)n*128+64+lane]=xin[(size_t)n*64+lane];
}

// TR pass1 (edge-parallel SDDMM): qk combined [N,512] bf16 (q cols 0..255, k cols 256..511)
__global__ __launch_bounds__(256) void tr_pass1_kernel(const int* __restrict__ srcS, const int* __restrict__ dstS,
    const unsigned short* __restrict__ qk, float* __restrict__ lg){
  int e=blockIdx.x*16+(threadIdx.x>>4);
  int t=threadIdx.x&15;
  if(e>=EE) return;
  int s=srcS[e], d=dstS[e];
  const unsigned short* qd=qk+(size_t)d*512+t*4;
  const unsigned short* ks=qk+(size_t)s*512+256+t*4;
  ushort4 ku0=*(const ushort4*)(ks);
  ushort4 ku1=*(const ushort4*)(ks+64);
  ushort4 ku2=*(const ushort4*)(ks+128);
  ushort4 ku3=*(const ushort4*)(ks+192);
  ushort4 qu0=*(const ushort4*)(qd);
  ushort4 qu1=*(const ushort4*)(qd+64);
  ushort4 qu2=*(const ushort4*)(qd+128);
  ushort4 qu3=*(const ushort4*)(qd+192);
  float v0=bf2f(ku0.x)*bf2f(qu0.x)+bf2f(ku0.y)*bf2f(qu0.y)+bf2f(ku0.z)*bf2f(qu0.z)+bf2f(ku0.w)*bf2f(qu0.w);
  float v1=bf2f(ku1.x)*bf2f(qu1.x)+bf2f(ku1.y)*bf2f(qu1.y)+bf2f(ku1.z)*bf2f(qu1.z)+bf2f(ku1.w)*bf2f(qu1.w);
  float v2=bf2f(ku2.x)*bf2f(qu2.x)+bf2f(ku2.y)*bf2f(qu2.y)+bf2f(ku2.z)*bf2f(qu2.z)+bf2f(ku2.w)*bf2f(qu2.w);
  float v3=bf2f(ku3.x)*bf2f(qu3.x)+bf2f(ku3.y)*bf2f(qu3.y)+bf2f(ku3.z)*bf2f(qu3.z)+bf2f(ku3.w)*bf2f(qu3.w);
  #pragma unroll
  for(int o=1;o<16;o<<=1){
    v0+=__shfl_xor(v0,o,16); v1+=__shfl_xor(v1,o,16);
    v2+=__shfl_xor(v2,o,16); v3+=__shfl_xor(v3,o,16);
  }
  if(t==0)
    *(float4*)(lg+(size_t)4*e)=make_float4(v0*0.125f,v1*0.125f,v2*0.125f,v3*0.125f);
}

// TR pass2: exp + bf16 v-gather + skip + relu -> x5 bf16 (unroll 4)
__global__ __launch_bounds__(256) void tr_pass2_kernel(const int* __restrict__ rowptr, const int* __restrict__ srcS,
    const float* __restrict__ lg,
    const unsigned short* __restrict__ v, const float* __restrict__ skip, unsigned short* __restrict__ x5b){
  int n=blockIdx.x*4+(threadIdx.x>>6);
  int lane=threadIdx.x&63;
  if(n>=NN) return;
  int r0=rowptr[n], r1=rowptr[n+1];
  float z0=0.f,z1=0.f,z2=0.f,z3=0.f;
  float a0=0.f,a1=0.f,a2=0.f,a3=0.f;
  int j=r0;
  for(; j+3<r1; j+=4){
    int s0=srcS[j], s1=srcS[j+1], s2=srcS[j+2], s3=srcS[j+3];
    const float4 f0=*(const float4*)(lg+(size_t)4*j);
    const float4 f1=*(const float4*)(lg+(size_t)4*(j+1));
    const float4 f2=*(const float4*)(lg+(size_t)4*(j+2));
    const float4 f3=*(const float4*)(lg+(size_t)4*(j+3));
    const unsigned short* v0=v+(size_t)s0*256;
    const unsigned short* v1=v+(size_t)s1*256;
    const unsigned short* v2=v+(size_t)s2*256;
    const unsigned short* v3=v+(size_t)s3*256;
    float e00=__expf(f0.x), e01=__expf(f0.y), e02=__expf(f0.z), e03=__expf(f0.w);
    float e10=__expf(f1.x), e11=__expf(f1.y), e12=__expf(f1.z), e13=__expf(f1.w);
    float e20=__expf(f2.x), e21=__expf(f2.y), e22=__expf(f2.z), e23=__expf(f2.w);
    float e30=__expf(f3.x), e31=__expf(f3.y), e32=__expf(f3.z), e33=__expf(f3.w);
    z0+=(e00+e10)+(e20+e30); z1+=(e01+e11)+(e21+e31);
    z2+=(e02+e12)+(e22+e32); z3+=(e03+e13)+(e23+e33);
    a0+=(e00*bf2f(v0[lane])+e10*bf2f(v1[lane]))+(e20*bf2f(v2[lane])+e30*bf2f(v3[lane]));
    a1+=(e01*bf2f(v0[64+lane])+e11*bf2f(v1[64+lane]))+(e21*bf2f(v2[64+lane])+e31*bf2f(v3[64+lane]));
    a2+=(e02*bf2f(v0[128+lane])+e12*bf2f(v1[128+lane]))+(e22*bf2f(v2[128+lane])+e32*bf2f(v3[128+lane]));
    a3+=(e03*bf2f(v0[192+lane])+e13*bf2f(v1[192+lane]))+(e23*bf2f(v2[192+lane])+e33*bf2f(v3[192+lane]));
  }
  for(; j<r1; j++){
    int s0=srcS[j];
    const float4 f0=*(const float4*)(lg+(size_t)4*j);
    const unsigned short* v0=v+(size_t)s0*256;
    float e00=__expf(f0.x), e01=__expf(f0.y), e02=__expf(f0.z), e03=__expf(f0.w);
    z0+=e00; z1+=e01; z2+=e02; z3+=e03;
    a0+=e00*bf2f(v0[lane]); a1+=e01*bf2f(v0[64+lane]); a2+=e02*bf2f(v0[128+lane]); a3+=e03*bf2f(v0[192+lane]);
  }
  float zi0=1.f/(z0+1e-16f), zi1=1.f/(z1+1e-16f), zi2=1.f/(z2+1e-16f), zi3=1.f/(z3+1e-16f);
  float t=0.25f*(a0*zi0+a1*zi1+a2*zi2+a3*zi3)+skip[(size_t)n*64+lane];
  x5b[(size_t)n*64+lane]=f2bf(fmaxf(t,0.f));
}

// EdgeConv: hidden=relu(P[dst]+Q[src]) (PQ [N,128]: P cols 0..63, Q 64..127)
// -> GEMM2 -> LDS segmented max; interior dst plain store, boundary atomicMax.
__global__ __launch_bounds__(256) void edgeconv2_kernel(
    const float* __restrict__ PQ,
    const int* __restrict__ srcS, const int* __restrict__ dstS,
    const float* __restrict__ W2, const float* __restrict__ b2,
    unsigned* __restrict__ emax){
  __shared__ float As[64][68];
  __shared__ float Ws[64][64];
  __shared__ int dstL[64];
  const int e0=blockIdx.x*64;
  const int tid=threadIdx.x, tx=tid&15, ty=tid>>4;
  if(tid<64) dstL[tid]=dstS[e0+tid];
  #pragma unroll
  for(int it=0;it<4;it++){
    int linear=it*1024+tid*4;
    int m=linear>>6, k=linear&63;
    int e=e0+m;
    int dn=dstS[e], sn=srcS[e];
    const float4 p=*(const float4*)(PQ+(size_t)dn*128+k);
    const float4 q=*(const float4*)(PQ+(size_t)sn*128+64+k);
    float4 v=make_float4(fmaxf(p.x+q.x,0.f),fmaxf(p.y+q.y,0.f),fmaxf(p.z+q.z,0.f),fmaxf(p.w+q.w,0.f));
    *(float4*)&As[m][k]=v;
  }
  #pragma unroll
  for(int it=0;it<4;it++){
    int linear=it*1024+tid*4;
    int k=linear>>6, n=linear&63;
    *(float4*)&Ws[k][n]=*(const float4*)(W2+(size_t)k*64+n);
  }
  __syncthreads();
  float acc2[4][4];
  #pragma unroll
  for(int i=0;i<4;i++)
    #pragma unroll
    for(int j=0;j<4;j++) acc2[i][j]=b2[tx*4+j];
  #pragma unroll 8
  for(int k=0;k<64;k+=4){
    float4 a0=*(float4*)&As[ty*4+0][k];
    float4 a1=*(float4*)&As[ty*4+1][k];
    float4 a2=*(float4*)&As[ty*4+2][k];
    float4 a3=*(float4*)&As[ty*4+3][k];
    float4 w0=*(float4*)&Ws[k+0][tx*4];
    float4 w1=*(float4*)&Ws[k+1][tx*4];
    float4 w2=*(float4*)&Ws[k+2][tx*4];
    float4 w3=*(float4*)&Ws[k+3][tx*4];
    mac4(acc2[0],a0,w0,w1,w2,w3);
    mac4(acc2[1],a1,w0,w1,w2,w3);
    mac4(acc2[2],a2,w0,w1,w2,w3);
    mac4(acc2[3],a3,w0,w1,w2,w3);
  }
  __syncthreads();
  #pragma unroll
  for(int i=0;i<4;i++)
    #pragma unroll
    for(int j=0;j<4;j++)
      As[ty*4+i][tx*4+j]=acc2[i][j];
  __syncthreads();
  if(tid<64){
    const int c=tid;
    const int dFirst=dstL[0], dLast=dstL[63];
    int dprev=dFirst;
    float mx=As[0][c];
    #pragma unroll 8
    for(int m=1;m<64;m++){
      int dn=dstL[m];
      float v=As[m][c];
      if(dn!=dprev){
        unsigned* addr=&emax[(size_t)dprev*64+c];
        unsigned enc=fenc(mx);
        if(dprev!=dFirst && dprev!=dLast) *addr=enc;
        else atomicMax(addr,enc);
        dprev=dn; mx=v;
      }else mx=fmaxf(mx,v);
    }
    unsigned* addr=&emax[(size_t)dprev*64+c];
    unsigned enc=fenc(mx);
    if(dprev!=dFirst && dprev!=dLast) *addr=enc;
    else atomicMax(addr,enc);
  }
}

__global__ __launch_bounds__(256) void pool_kernel(const unsigned* __restrict__ emax, const int* __restrict__ batch,
                                                   float* __restrict__ pooled){
  const int NB=200;
  int base=blockIdx.x*NB;
  int lane=threadIdx.x&63;
  int wsub=threadIdx.x>>6;
  float acc=0.f; int curg=-1;
  for(int idx=wsub; idx<NB; idx+=4){
    int n=base+idx;
    if(n>=NN) break;
    int g=batch[n];
    if(g!=curg){
      if(curg>=0) atomicAdd(&pooled[curg*64+lane],acc);
      acc=0.f; curg=g;
    }
    unsigned u=emax[(size_t)n*64+lane];
    acc+=(u>=0x80000000u)? __uint_as_float(u&0x7fffffffu) : 0.f;
  }
  if(curg>=0) atomicAdd(&pooled[curg*64+lane],acc);
}

__global__ __launch_bounds__(256) void final_kernel(const float* __restrict__ pooled, const int* __restrict__ batch,
    const float* __restrict__ fc1W, const float* __restrict__ fc1b,
    const float* __restrict__ fc2W, const float* __restrict__ fc2b,
    float* __restrict__ out){
  __shared__ float gm[16][64];
  __shared__ float t1[16][64];
  __shared__ int cgs[17];
  int t=threadIdx.x;
  if(t<17){
    int lo=0, hi=NN;
    while(lo<hi){ int mid=(lo+hi)>>1; if(batch[mid]<t) lo=mid+1; else hi=mid; }
    cgs[t]=lo;
  }
  __syncthreads();
  for(int r=0;r<4;r++){
    int idx=r*256+t; int g=idx>>6, d=idx&63;
    float c=(float)(cgs[g+1]-cgs[g]);
    gm[g][d]=pooled[idx]/fmaxf(c,1.f);
  }
  __syncthreads();
  for(int r=0;r<4;r++){
    int idx=r*256+t; int g=idx>>6, d=idx&63;
    float a=fc1b[d];
    for(int k2=0;k2<64;k2++) a+=gm[g][k2]*fc1W[k2*64+d];
    t1[g][d]=fmaxf(a,0.f);
  }
  __syncthreads();
  for(int r=0;r<4;r++){
    int idx=r*256+t; int g=idx>>6, d=idx&63;
    float a=fc2b[d];
    for(int k2=0;k2<64;k2++) a+=t1[g][k2]*fc2W[k2*64+d];
    out[idx]=a;
  }
}

extern "C" void kernel_launch(void* const* d_in, const int* in_sizes, int n_in,
                              void* d_out, int out_size, void* d_ws, size_t ws_size,
                              hipStream_t stream){
  const float* x       =(const float*)d_in[0];
  const int*   ei      =(const int*)  d_in[1];
  const int*   src     =ei;
  const int*   dst     =ei+EE;
  const int*   batch   =(const int*)  d_in[2];
  const float* gat1_W  =(const float*)d_in[3];
  const float* gat1_as =(const float*)d_in[4];
  const float* gat1_ad =(const float*)d_in[5];
  const float* gat1_b  =(const float*)d_in[6];
  const float* gat2_W  =(const float*)d_in[7];
  const float* gat2_as =(const float*)d_in[8];
  const float* gat2_ad =(const float*)d_in[9];
  const float* gat2_b  =(const float*)d_in[10];
  const float* gin_W1  =(const float*)d_in[11];
  const float* gin_b1  =(const float*)d_in[12];
  const float* gin_W2  =(const float*)d_in[13];
  const float* gin_b2  =(const float*)d_in[14];
  const float* sage1_Wl=(const float*)d_in[15];
  const float* sage1_bl=(const float*)d_in[16];
  const float* sage1_Wr=(const float*)d_in[17];
  const float* sage2_Wl=(const float*)d_in[18];
  const float* sage2_bl=(const float*)d_in[19];
  const float* sage2_Wr=(const float*)d_in[20];
  const float* tr_Wq   =(const float*)d_in[21];
  const float* tr_bq   =(const float*)d_in[22];
  const float* tr_Wk   =(const float*)d_in[23];
  const float* tr_bk   =(const float*)d_in[24];
  const float* tr_Wv   =(const float*)d_in[25];
  const float* tr_bv   =(const float*)d_in[26];
  const float* tr_Ws   =(const float*)d_in[27];
  const float* tr_bs   =(const float*)d_in[28];
  const float* ec_W1   =(const float*)d_in[29];
  const float* ec_b1   =(const float*)d_in[30];
  const float* ec_W2   =(const float*)d_in[31];
  const float* ec_b2   =(const float*)d_in[32];
  const float* fc1_W   =(const float*)d_in[33];
  const float* fc1_b   =(const float*)d_in[34];
  const float* fc2_W   =(const float*)d_in[35];
  const float* fc2_b   =(const float*)d_in[36];

  // ---- workspace layout ----
  float* base=(float*)d_ws;
  size_t off=0;
  auto alloc=[&](size_t n){ float* p=base+off; off+=n; return p; };
  float* A_big =alloc((size_t)NN*256);     // hbf / xb / xcatb / qkb (as ushort)
  float* nb0   =alloc(N64);
  float* nb1   =alloc(N64);
  float* nb2   =alloc(N64);
  float* nb3   =alloc(N64);
  float* nb4   =alloc(N64);
  float* nb5   =alloc(N64);                // emax
  float* logitE=alloc((size_t)EE*4);
  float* ls    =alloc(NN*4);
  float* ldb   =alloc(NN*4);
  float* invdeg=alloc(NN);
  float* pooled=alloc(GG*64);
  float* wbuf  =alloc(68000);              // Wt bf16 (135168 ushorts)
  float* bbuf  =alloc(640);                // packed biases
  int* ibase=(int*)(base+off);
  int* srcS  =ibase;
  int* dstS  =ibase+EE;
  int* cnt   =ibase+2*EE;
  int* fillp =ibase+2*EE+NN;
  int* rowptr=ibase+2*EE+2*NN;
  int* bsum  =ibase+2*EE+3*NN+8;
  int* boff  =bsum+64;

  const int BT=256;
  const int NSB=cdiv(NN,1024);
  // ---- zero init ----
  zero_kernel<<<cdiv(2*NN,BT),BT,0,stream>>>((unsigned*)cnt,2*NN);
  zero_kernel<<<cdiv(GG*64,BT),BT,0,stream>>>((unsigned*)pooled,GG*64);
  zero_kernel<<<cdiv(N64,BT),BT,0,stream>>>((unsigned*)nb5,N64);
  // ---- CSR ----
  hist_kernel<<<cdiv(EE,BT),BT,0,stream>>>(dst,cnt);
  scan1_kernel<<<NSB,1024,0,stream>>>(cnt,rowptr,bsum);
  scan2_kernel<<<1,64,0,stream>>>(bsum,boff,rowptr,NSB);
  scan3_kernel<<<cdiv(NN,BT),BT,0,stream>>>(rowptr,boff,cnt,invdeg);
  fill_kernel<<<cdiv(EE,BT),BT,0,stream>>>(src,dst,rowptr,fillp,srcS,dstS);

  const int GB=cdiv(NN,64);        // 782
  const int GW=cdiv(NN,4);         // 12500

  unsigned short* wt =(unsigned short*)wbuf;
  float* bqk=bbuf;
  float* bPQ=bbuf+512;
  unsigned short* hbf  =(unsigned short*)A_big;                 // [N,256]
  unsigned short* xb   =(unsigned short*)A_big+(size_t)NN*256;  // [N,128]
  unsigned short* xcatb=(unsigned short*)A_big;                 // [N,128]
  unsigned short* qkb  =(unsigned short*)A_big;                 // [N,512]
  unsigned short* x1b  =(unsigned short*)nb0;
  unsigned short* x2b  =(unsigned short*)nb1;
  unsigned short* tb   =(unsigned short*)nb2;
  unsigned short* hb3  =(unsigned short*)nb3;
  unsigned short* x3b  =(unsigned short*)nb1;
  unsigned short* xsb  =(unsigned short*)nb2;
  unsigned short* x4b  =(unsigned short*)nb0;
  unsigned short* vb   =(unsigned short*)nb1;                   // [N,256] spans nb1+nb2
  unsigned short* x5b  =(unsigned short*)nb4;
  float* skipf=nb3;
  float* PQf  =nb1;                                             // [N,128] spans nb1+nb2

  // ---- prep: weights->bf16 W^T, x->bf16 ----
  prep_kernel<<<cdiv(135808,BT),BT,0,stream>>>(gat1_W,gat2_W,gin_W1,gin_W2,
      sage1_Wl,sage1_Wr,sage2_Wl,sage2_Wr,tr_Wq,tr_Wk,tr_Wv,tr_Ws,ec_W1,
      tr_bq,tr_bk,ec_b1,wt,bqk,bPQ);
  cvtx_kernel<<<cdiv(NN*32,BT),BT,0,stream>>>(x,xb);

  // ---- GAT1 ----
  mgemm_kernel<128><<<dim3(GB,4),BT,0,stream>>>(xb,wt,nullptr,nullptr,hbf,256,0,
                                                gat1_as,gat1_ad,ls,ldb);
  gat1p_kernel<<<GW,BT,0,stream>>>(hbf,rowptr,srcS,ls,ldb,gat1_b,x1b);
  // ---- GAT2 ----
  mgemm_kernel<64><<<dim3(GB,4),BT,0,stream>>>(x1b,wt+32768,nullptr,nullptr,hbf,256,0,
                                               gat2_as,gat2_ad,ls,ldb);
  gat1p_kernel<<<GW,BT,0,stream>>>(hbf,rowptr,srcS,ls,ldb,gat2_b,x2b);
  // ---- GIN ----
  agg_kernel<<<GW,BT,0,stream>>>(x2b,rowptr,srcS,tb);
  mgemm_kernel<64><<<dim3(GB,1),BT,0,stream>>>(tb,wt+49152,gin_b1,nullptr,hb3,64,1,
                                               nullptr,nullptr,nullptr,nullptr);
  mgemm_kernel<64><<<dim3(GB,1),BT,0,stream>>>(hb3,wt+53248,gin_b2,nullptr,x3b,64,1,
                                               nullptr,nullptr,nullptr,nullptr);
  // ---- SAGE1 ----
  agg2_kernel<<<GW,BT,0,stream>>>(x3b,rowptr,srcS,invdeg,xcatb);
  mgemm_kernel<128><<<dim3(GB,1),BT,0,stream>>>(xcatb,wt+57344,sage1_bl,nullptr,xsb,64,1,
                                                nullptr,nullptr,nullptr,nullptr);
  // ---- SAGE2 ----
  agg2_kernel<<<GW,BT,0,stream>>>(xsb,rowptr,srcS,invdeg,xcatb);
  mgemm_kernel<128><<<dim3(GB,1),BT,0,stream>>>(xcatb,wt+65536,sage2_bl,nullptr,x4b,64,1,
                                                nullptr,nullptr,nullptr,nullptr);
  // ---- TransformerConv ----
  mgemm_kernel<64><<<dim3(GB,8),BT,0,stream>>>(x4b,wt+73728,bqk,nullptr,qkb,512,0,
                                               nullptr,nullptr,nullptr,nullptr);   // q|k
  tr_pass1_kernel<<<cdiv(EE,16),BT,0,stream>>>(srcS,dstS,qkb,logitE);
  mgemm_kernel<64><<<dim3(GB,4),BT,0,stream>>>(x4b,wt+106496,tr_bv,nullptr,vb,256,0,
                                               nullptr,nullptr,nullptr,nullptr);   // v
  mgemm_kernel<64><<<dim3(GB,1),BT,0,stream>>>(x4b,wt+122880,tr_bs,skipf,nullptr,64,0,
                                               nullptr,nullptr,nullptr,nullptr);   // skip f32
  tr_pass2_kernel<<<GW,BT,0,stream>>>(rowptr,srcS,logitE,vb,skipf,x5b);
  // ---- EdgeConv: PQ = x5 @ [Wd|W1b] + [b1|0] ----
  mgemm_kernel<64><<<dim3(GB,2),BT,0,stream>>>(x5b,wt+126976,bPQ,PQf,nullptr,128,0,
                                               nullptr,nullptr,nullptr,nullptr);
  edgeconv2_kernel<<<EE/64,BT,0,stream>>>(PQf,srcS,dstS,ec_W2,ec_b2,(unsigned*)nb5);
  // ---- pool + MLP ----
  pool_kernel<<<cdiv(NN,200),BT,0,stream>>>((unsigned*)nb5,batch,pooled);
  final_kernel<<<1,BT,0,stream>>>(pooled,batch,fc1_W,fc1_b,fc2_W,fc2_b,(float*)d_out);
}

// Round 10
// 864.964 us; speedup vs baseline: 2.7079x; 1.0166x over previous
//
#include <hip/hip_runtime.h>

#define NN 50000
#define EE 640000
#define GG 16
#define N64 (NN*64)

static inline int cdiv(int a,int b){return (a+b-1)/b;}

typedef __attribute__((ext_vector_type(8))) short bfrag;   // 8 bf16 (4 VGPR)
typedef __attribute__((ext_vector_type(4))) float ffrag;   // mfma accumulator

__device__ __forceinline__ float lrelu(float x){ return x>0.f? x : 0.2f*x; }
__device__ __forceinline__ unsigned fenc(float f){
  unsigned u=__float_as_uint(f);
  return (u&0x80000000u)? ~u : (u|0x80000000u);
}
__device__ __forceinline__ float bf2f(unsigned short u){ return __uint_as_float(((unsigned)u)<<16); }
__device__ __forceinline__ unsigned short f2bf(float f){
  unsigned u=__float_as_uint(f);
  u += 0x7FFFu + ((u>>16)&1u);
  return (unsigned short)(u>>16);
}

__global__ void zero_kernel(unsigned* p, int n){
  int i=blockIdx.x*blockDim.x+threadIdx.x;
  if(i<n) p[i]=0u;
}

__global__ void hist_kernel(const int* __restrict__ dst, int* __restrict__ cnt){
  int e=blockIdx.x*blockDim.x+threadIdx.x;
  if(e<EE) atomicAdd(&cnt[dst[e]],1);
}

__global__ __launch_bounds__(1024) void scan1_kernel(const int* __restrict__ cnt,
    int* __restrict__ rowptr, int* __restrict__ bsum){
  __shared__ int wsum[16];
  int t=threadIdx.x, b=blockIdx.x;
  int i=b*1024+t;
  int v=(i<NN)?cnt[i]:0;
  int lane=t&63, w=t>>6;
  int inc=v;
  #pragma unroll
  for(int o=1;o<64;o<<=1){ int u=__shfl_up(inc,o,64); if(lane>=o) inc+=u; }
  if(lane==63) wsum[w]=inc;
  __syncthreads();
  if(t<16){
    int s=wsum[t];
    #pragma unroll
    for(int o=1;o<16;o<<=1){ int u=__shfl_up(s,o,16); if(t>=o) s+=u; }
    wsum[t]=s;
  }
  __syncthreads();
  int woff=(w>0)?wsum[w-1]:0;
  if(i<NN) rowptr[i]=woff+inc-v;
  if(t==1023) bsum[b]=wsum[15];
}

__global__ void scan2_kernel(const int* __restrict__ bsum, int* __restrict__ boff, int* __restrict__ rowptr, int nb){
  int t=threadIdx.x;
  int v=(t<nb)?bsum[t]:0;
  int inc=v;
  #pragma unroll
  for(int o=1;o<64;o<<=1){ int u=__shfl_up(inc,o,64); if(t>=o) inc+=u; }
  if(t<nb) boff[t]=inc-v;
  if(t==63) rowptr[NN]=inc;
}

__global__ void scan3_kernel(int* __restrict__ rowptr, const int* __restrict__ boff,
                             const int* __restrict__ cnt, float* __restrict__ invdeg){
  int i=blockIdx.x*blockDim.x+threadIdx.x;
  if(i<NN){
    rowptr[i]+=boff[i>>10];
    invdeg[i]=1.f/fmaxf((float)cnt[i],1.f);
  }
}

__global__ void fill_kernel(const int* __restrict__ src, const int* __restrict__ dst,
                            const int* __restrict__ rowptr, int* __restrict__ fillp,
                            int* __restrict__ srcS, int* __restrict__ dstS){
  int e=blockIdx.x*blockDim.x+threadIdx.x;
  if(e>=EE) return;
  int d=dst[e];
  int p=rowptr[d]+atomicAdd(&fillp[d],1);
  srcS[p]=src[e]; dstS[p]=d;
}

__global__ void cvtx_kernel(const float* __restrict__ x, unsigned short* __restrict__ xb){
  int i=blockIdx.x*blockDim.x+threadIdx.x;
  if(i>=NN*32) return;
  float4 v=*(const float4*)(x+(size_t)i*4);
  ushort4 o; o.x=f2bf(v.x); o.y=f2bf(v.y); o.z=f2bf(v.z); o.w=f2bf(v.w);
  *(ushort4*)(xb+(size_t)i*4)=o;
}

// weight prep: Wt[n][k]=W[k][n] bf16, all segments + bias packs
__global__ void prep_kernel(
    const float* __restrict__ g1W, const float* __restrict__ g2W,
    const float* __restrict__ giW1, const float* __restrict__ giW2,
    const float* __restrict__ s1Wl, const float* __restrict__ s1Wr,
    const float* __restrict__ s2Wl, const float* __restrict__ s2Wr,
    const float* __restrict__ Wq, const float* __restrict__ Wk,
    const float* __restrict__ Wv, const float* __restrict__ Ws,
    const float* __restrict__ ecW1, const float* __restrict__ ecW2,
    const float* __restrict__ bq, const float* __restrict__ bk, const float* __restrict__ eb1,
    unsigned short* __restrict__ wt, float* __restrict__ bqk, float* __restrict__ bPQ){
  int i=blockIdx.x*blockDim.x+threadIdx.x;
  if(i<32768){ int n=i>>7,k=i&127; wt[i]=f2bf(g1W[k*256+n]); return; } i-=32768;
  if(i<16384){ int n=i>>6,k=i&63; wt[32768+i]=f2bf(g2W[k*256+n]); return; } i-=16384;
  if(i<4096){ int n=i>>6,k=i&63; wt[49152+i]=f2bf(giW1[k*64+n]); return; } i-=4096;
  if(i<4096){ int n=i>>6,k=i&63; wt[53248+i]=f2bf(giW2[k*64+n]); return; } i-=4096;
  if(i<8192){ int n=i>>7,k=i&127; float v=(k<64)?s1Wl[k*64+n]:s1Wr[(k-64)*64+n];
              wt[57344+i]=f2bf(v); return; } i-=8192;
  if(i<8192){ int n=i>>7,k=i&127; float v=(k<64)?s2Wl[k*64+n]:s2Wr[(k-64)*64+n];
              wt[65536+i]=f2bf(v); return; } i-=8192;
  if(i<32768){ int n=i>>6,k=i&63; float v=(n<256)?Wq[k*256+n]:Wk[k*256+(n-256)];
               wt[73728+i]=f2bf(v); return; } i-=32768;
  if(i<16384){ int n=i>>6,k=i&63; wt[106496+i]=f2bf(Wv[k*256+n]); return; } i-=16384;
  if(i<4096){ int n=i>>6,k=i&63; wt[122880+i]=f2bf(Ws[k*64+n]); return; } i-=4096;
  if(i<8192){ int n=i>>6,k=i&63;
              float v=(n<64)?(ecW1[k*64+n]-ecW1[(64+k)*64+n]):ecW1[(64+k)*64+(n-64)];
              wt[126976+i]=f2bf(v); return; } i-=8192;
  if(i<4096){ int n=i>>6,k=i&63; wt[135168+i]=f2bf(ecW2[k*64+n]); return; } i-=4096;
  if(i<640){
    if(i<256) bqk[i]=bq[i];
    else if(i<512) bqk[i]=bk[i-256];
    else { int j=i-512; bPQ[j]=(j<64)?eb1[j]:0.f; }
  }
}

// bf16 MFMA GEMM: C[64x64 tile] = A[M,K]bf16 @ Wt[N,K]bf16^T (+bias)(relu)
template<int K>
__global__ __launch_bounds__(256) void mgemm_kernel(
    const unsigned short* __restrict__ A, const unsigned short* __restrict__ Wt,
    const float* __restrict__ bias,
    float* __restrict__ Cf, unsigned short* __restrict__ Cb, int ldc, int relu_flag,
    const float* __restrict__ a_s, const float* __restrict__ a_d,
    float* __restrict__ lsO, float* __restrict__ ldO){
  __shared__ float lsP[2][4][64];
  const int m0=blockIdx.x*64;
  const int tid=threadIdx.x;
  const int w=tid>>6, l=tid&63, lo=l&15, quad=l>>4;
  const int colg=blockIdx.y*64 + w*16 + lo;
  const unsigned short* wrow=Wt+(size_t)colg*K+quad*8;
  ffrag acc[4];
  #pragma unroll
  for(int t=0;t<4;t++) acc[t]=(ffrag){0.f,0.f,0.f,0.f};
  int rows[4];
  #pragma unroll
  for(int t=0;t<4;t++){ int r=m0+t*16+lo; rows[t]=(r<NN)?r:(NN-1); }
  #pragma unroll
  for(int kc=0;kc<K;kc+=32){
    bfrag b=*(const bfrag*)(wrow+kc);
    #pragma unroll
    for(int t=0;t<4;t++){
      bfrag a=*(const bfrag*)(A+(size_t)rows[t]*K+kc+quad*8);
      acc[t]=__builtin_amdgcn_mfma_f32_16x16x32_bf16(a,b,acc[t],0,0,0);
    }
  }
  float bv=bias?bias[colg]:0.f;
  float asv=0.f,adv=0.f;
  if(lsO){ asv=a_s[colg]; adv=a_d[colg]; }
  #pragma unroll
  for(int t=0;t<4;t++){
    #pragma unroll
    for(int r=0;r<4;r++){
      float v=acc[t][r]+bv;
      if(relu_flag) v=fmaxf(v,0.f);
      int row=m0+t*16+quad*4+r;
      if(row<NN){
        if(Cb) Cb[(size_t)row*ldc+colg]=f2bf(v);
        else   Cf[(size_t)row*ldc+colg]=v;
      }
      if(lsO){
        float ps=v*asv, pd=v*adv;
        #pragma unroll
        for(int o=1;o<16;o<<=1){ ps+=__shfl_xor(ps,o,16); pd+=__shfl_xor(pd,o,16); }
        if(lo==0){ int lr=t*16+quad*4+r; lsP[0][w][lr]=ps; lsP[1][w][lr]=pd; }
      }
    }
  }
  if(lsO){
    __syncthreads();
    if(tid<64){
      int row=m0+tid;
      if(row<NN){
        lsO[(size_t)row*4+blockIdx.y]=lsP[0][0][tid]+lsP[0][1][tid]+lsP[0][2][tid]+lsP[0][3][tid];
        ldO[(size_t)row*4+blockIdx.y]=lsP[1][0][tid]+lsP[1][1][tid]+lsP[1][2][tid]+lsP[1][3][tid];
      }
    }
  }
}

// single-pass GAT, 2 waves per node (edge-split), bf16 h gather, bf16 out.
__global__ __launch_bounds__(256) void gat1p_kernel(const unsigned short* __restrict__ h,
    const int* __restrict__ rowptr, const int* __restrict__ srcS,
    const float* __restrict__ ls4, const float* __restrict__ ld4,
    const float* __restrict__ bias, unsigned short* __restrict__ outb){
  __shared__ float cz[4][4];
  __shared__ float ca[4][4][64];
  int w=threadIdx.x>>6, lane=threadIdx.x&63;
  int n=blockIdx.x*2+(w>>1);
  int half=w&1;
  float z0=0.f,z1=0.f,z2=0.f,z3=0.f;
  float a0=0.f,a1=0.f,a2=0.f,a3=0.f;
  if(n<NN){
    int r0=rowptr[n], r1=rowptr[n+1];
    int mid=(r0+r1)>>1;
    const float4 ldv=*(const float4*)(ld4+(size_t)4*n);
    if(half==0){
      const float4 lsv=*(const float4*)(ls4+(size_t)4*n);
      z0=__expf(lrelu(lsv.x+ldv.x)); z1=__expf(lrelu(lsv.y+ldv.y));
      z2=__expf(lrelu(lsv.z+ldv.z)); z3=__expf(lrelu(lsv.w+ldv.w));
      const unsigned short* hn=h+(size_t)n*256;
      a0=z0*bf2f(hn[lane]); a1=z1*bf2f(hn[64+lane]);
      a2=z2*bf2f(hn[128+lane]); a3=z3*bf2f(hn[192+lane]);
    }
    int j = half? mid : r0;
    int je= half? r1  : mid;
    for(; j+3<je; j+=4){
      int s0=srcS[j], s1=srcS[j+1], s2=srcS[j+2], s3=srcS[j+3];
      const float4 A0=*(const float4*)(ls4+(size_t)4*s0);
      const float4 A1=*(const float4*)(ls4+(size_t)4*s1);
      const float4 A2=*(const float4*)(ls4+(size_t)4*s2);
      const float4 A3=*(const float4*)(ls4+(size_t)4*s3);
      const unsigned short* h0=h+(size_t)s0*256;
      const unsigned short* h1=h+(size_t)s1*256;
      const unsigned short* h2=h+(size_t)s2*256;
      const unsigned short* h3=h+(size_t)s3*256;
      float e00=__expf(lrelu(A0.x+ldv.x)), e01=__expf(lrelu(A0.y+ldv.y));
      float e02=__expf(lrelu(A0.z+ldv.z)), e03=__expf(lrelu(A0.w+ldv.w));
      float e10=__expf(lrelu(A1.x+ldv.x)), e11=__expf(lrelu(A1.y+ldv.y));
      float e12=__expf(lrelu(A1.z+ldv.z)), e13=__expf(lrelu(A1.w+ldv.w));
      float e20=__expf(lrelu(A2.x+ldv.x)), e21=__expf(lrelu(A2.y+ldv.y));
      float e22=__expf(lrelu(A2.z+ldv.z)), e23=__expf(lrelu(A2.w+ldv.w));
      float e30=__expf(lrelu(A3.x+ldv.x)), e31=__expf(lrelu(A3.y+ldv.y));
      float e32=__expf(lrelu(A3.z+ldv.z)), e33=__expf(lrelu(A3.w+ldv.w));
      z0+=(e00+e10)+(e20+e30); z1+=(e01+e11)+(e21+e31);
      z2+=(e02+e12)+(e22+e32); z3+=(e03+e13)+(e23+e33);
      a0+=(e00*bf2f(h0[lane])+e10*bf2f(h1[lane]))+(e20*bf2f(h2[lane])+e30*bf2f(h3[lane]));
      a1+=(e01*bf2f(h0[64+lane])+e11*bf2f(h1[64+lane]))+(e21*bf2f(h2[64+lane])+e31*bf2f(h3[64+lane]));
      a2+=(e02*bf2f(h0[128+lane])+e12*bf2f(h1[128+lane]))+(e22*bf2f(h2[128+lane])+e32*bf2f(h3[128+lane]));
      a3+=(e03*bf2f(h0[192+lane])+e13*bf2f(h1[192+lane]))+(e23*bf2f(h2[192+lane])+e33*bf2f(h3[192+lane]));
    }
    for(; j<je; j++){
      int s0=srcS[j];
      const float4 A0=*(const float4*)(ls4+(size_t)4*s0);
      const unsigned short* h0=h+(size_t)s0*256;
      float e00=__expf(lrelu(A0.x+ldv.x)), e01=__expf(lrelu(A0.y+ldv.y));
      float e02=__expf(lrelu(A0.z+ldv.z)), e03=__expf(lrelu(A0.w+ldv.w));
      z0+=e00; z1+=e01; z2+=e02; z3+=e03;
      a0+=e00*bf2f(h0[lane]); a1+=e01*bf2f(h0[64+lane]);
      a2+=e02*bf2f(h0[128+lane]); a3+=e03*bf2f(h0[192+lane]);
    }
  }
  if(lane==0){ cz[w][0]=z0; cz[w][1]=z1; cz[w][2]=z2; cz[w][3]=z3; }
  ca[w][0][lane]=a0; ca[w][1][lane]=a1; ca[w][2][lane]=a2; ca[w][3][lane]=a3;
  __syncthreads();
  if(threadIdx.x<128){
    int ni=threadIdx.x>>6, l=threadIdx.x&63;
    int n2=blockIdx.x*2+ni;
    if(n2<NN){
      int w0=ni*2, w1=w0+1;
      float Z0=cz[w0][0]+cz[w1][0], Z1=cz[w0][1]+cz[w1][1];
      float Z2=cz[w0][2]+cz[w1][2], Z3=cz[w0][3]+cz[w1][3];
      float A0=ca[w0][0][l]+ca[w1][0][l], A1=ca[w0][1][l]+ca[w1][1][l];
      float A2=ca[w0][2][l]+ca[w1][2][l], A3=ca[w0][3][l]+ca[w1][3][l];
      float r=0.25f*(A0/(Z0+1e-16f)+A1/(Z1+1e-16f)+A2/(Z2+1e-16f)+A3/(Z3+1e-16f))+bias[l];
      outb[(size_t)n2*64+l]=f2bf(fmaxf(r,0.f));
    }
  }
}

// GIN: self + sum (bf16 in/out), unroll 4
__global__ __launch_bounds__(256) void agg_kernel(const unsigned short* __restrict__ xin,
    const int* __restrict__ rowptr, const int* __restrict__ srcS,
    unsigned short* __restrict__ out){
  int n=blockIdx.x*4+(threadIdx.x>>6);
  int lane=threadIdx.x&63;
  if(n>=NN) return;
  int r0=rowptr[n], r1=rowptr[n+1];
  float acc=bf2f(xin[(size_t)n*64+lane]);
  int j=r0;
  for(; j+3<r1; j+=4){
    int s0=srcS[j], s1=srcS[j+1], s2=srcS[j+2], s3=srcS[j+3];
    acc+=(bf2f(xin[(size_t)s0*64+lane])+bf2f(xin[(size_t)s1*64+lane]))
        +(bf2f(xin[(size_t)s2*64+lane])+bf2f(xin[(size_t)s3*64+lane]));
  }
  for(; j<r1; j++) acc+=bf2f(xin[(size_t)srcS[j]*64+lane]);
  out[(size_t)n*64+lane]=f2bf(acc);
}

// SAGE staging: out128b[n]=[mean_neigh, self] bf16, unroll 4
__global__ __launch_bounds__(256) void agg2_kernel(const unsigned short* __restrict__ xin,
    const int* __restrict__ rowptr, const int* __restrict__ srcS,
    const float* __restrict__ invdeg, unsigned short* __restrict__ out128b){
  int n=blockIdx.x*4+(threadIdx.x>>6);
  int lane=threadIdx.x&63;
  if(n>=NN) return;
  int r0=rowptr[n], r1=rowptr[n+1];
  float acc=0.f;
  int j=r0;
  for(; j+3<r1; j+=4){
    int s0=srcS[j], s1=srcS[j+1], s2=srcS[j+2], s3=srcS[j+3];
    acc+=(bf2f(xin[(size_t)s0*64+lane])+bf2f(xin[(size_t)s1*64+lane]))
        +(bf2f(xin[(size_t)s2*64+lane])+bf2f(xin[(size_t)s3*64+lane]));
  }
  for(; j<r1; j++) acc+=bf2f(xin[(size_t)srcS[j]*64+lane]);
  out128b[(size_t)n*128+lane]=f2bf(acc*invdeg[n]);
  out128b[(size_t)n*128+64+lane]=xin[(size_t)n*64+lane];
}

// TR pass1 (edge-parallel SDDMM): qk combined [N,512] bf16
__global__ __launch_bounds__(256) void tr_pass1_kernel(const int* __restrict__ srcS, const int* __restrict__ dstS,
    const unsigned short* __restrict__ qk, float* __restrict__ lg){
  int e=blockIdx.x*16+(threadIdx.x>>4);
  int t=threadIdx.x&15;
  if(e>=EE) return;
  int s=srcS[e], d=dstS[e];
  const unsigned short* qd=qk+(size_t)d*512+t*4;
  const unsigned short* ks=qk+(size_t)s*512+256+t*4;
  ushort4 ku0=*(const ushort4*)(ks);
  ushort4 ku1=*(const ushort4*)(ks+64);
  ushort4 ku2=*(const ushort4*)(ks+128);
  ushort4 ku3=*(const ushort4*)(ks+192);
  ushort4 qu0=*(const ushort4*)(qd);
  ushort4 qu1=*(const ushort4*)(qd+64);
  ushort4 qu2=*(const ushort4*)(qd+128);
  ushort4 qu3=*(const ushort4*)(qd+192);
  float v0=bf2f(ku0.x)*bf2f(qu0.x)+bf2f(ku0.y)*bf2f(qu0.y)+bf2f(ku0.z)*bf2f(qu0.z)+bf2f(ku0.w)*bf2f(qu0.w);
  float v1=bf2f(ku1.x)*bf2f(qu1.x)+bf2f(ku1.y)*bf2f(qu1.y)+bf2f(ku1.z)*bf2f(qu1.z)+bf2f(ku1.w)*bf2f(qu1.w);
  float v2=bf2f(ku2.x)*bf2f(qu2.x)+bf2f(ku2.y)*bf2f(qu2.y)+bf2f(ku2.z)*bf2f(qu2.z)+bf2f(ku2.w)*bf2f(qu2.w);
  float v3=bf2f(ku3.x)*bf2f(qu3.x)+bf2f(ku3.y)*bf2f(qu3.y)+bf2f(ku3.z)*bf2f(qu3.z)+bf2f(ku3.w)*bf2f(qu3.w);
  #pragma unroll
  for(int o=1;o<16;o<<=1){
    v0+=__shfl_xor(v0,o,16); v1+=__shfl_xor(v1,o,16);
    v2+=__shfl_xor(v2,o,16); v3+=__shfl_xor(v3,o,16);
  }
  if(t==0)
    *(float4*)(lg+(size_t)4*e)=make_float4(v0*0.125f,v1*0.125f,v2*0.125f,v3*0.125f);
}

// TR pass2: 2 waves per node (edge-split), exp + bf16 v-gather + skip + relu -> x5 bf16
__global__ __launch_bounds__(256) void tr_pass2_kernel(const int* __restrict__ rowptr, const int* __restrict__ srcS,
    const float* __restrict__ lg,
    const unsigned short* __restrict__ v, const float* __restrict__ skip, unsigned short* __restrict__ x5b){
  __shared__ float cz[4][4];
  __shared__ float ca[4][4][64];
  int w=threadIdx.x>>6, lane=threadIdx.x&63;
  int n=blockIdx.x*2+(w>>1);
  int half=w&1;
  float z0=0.f,z1=0.f,z2=0.f,z3=0.f;
  float a0=0.f,a1=0.f,a2=0.f,a3=0.f;
  if(n<NN){
    int r0=rowptr[n], r1=rowptr[n+1];
    int mid=(r0+r1)>>1;
    int j = half? mid : r0;
    int je= half? r1  : mid;
    for(; j+3<je; j+=4){
      int s0=srcS[j], s1=srcS[j+1], s2=srcS[j+2], s3=srcS[j+3];
      const float4 f0=*(const float4*)(lg+(size_t)4*j);
      const float4 f1=*(const float4*)(lg+(size_t)4*(j+1));
      const float4 f2=*(const float4*)(lg+(size_t)4*(j+2));
      const float4 f3=*(const float4*)(lg+(size_t)4*(j+3));
      const unsigned short* v0=v+(size_t)s0*256;
      const unsigned short* v1=v+(size_t)s1*256;
      const unsigned short* v2=v+(size_t)s2*256;
      const unsigned short* v3=v+(size_t)s3*256;
      float e00=__expf(f0.x), e01=__expf(f0.y), e02=__expf(f0.z), e03=__expf(f0.w);
      float e10=__expf(f1.x), e11=__expf(f1.y), e12=__expf(f1.z), e13=__expf(f1.w);
      float e20=__expf(f2.x), e21=__expf(f2.y), e22=__expf(f2.z), e23=__expf(f2.w);
      float e30=__expf(f3.x), e31=__expf(f3.y), e32=__expf(f3.z), e33=__expf(f3.w);
      z0+=(e00+e10)+(e20+e30); z1+=(e01+e11)+(e21+e31);
      z2+=(e02+e12)+(e22+e32); z3+=(e03+e13)+(e23+e33);
      a0+=(e00*bf2f(v0[lane])+e10*bf2f(v1[lane]))+(e20*bf2f(v2[lane])+e30*bf2f(v3[lane]));
      a1+=(e01*bf2f(v0[64+lane])+e11*bf2f(v1[64+lane]))+(e21*bf2f(v2[64+lane])+e31*bf2f(v3[64+lane]));
      a2+=(e02*bf2f(v0[128+lane])+e12*bf2f(v1[128+lane]))+(e22*bf2f(v2[128+lane])+e32*bf2f(v3[128+lane]));
      a3+=(e03*bf2f(v0[192+lane])+e13*bf2f(v1[192+lane]))+(e23*bf2f(v2[192+lane])+e33*bf2f(v3[192+lane]));
    }
    for(; j<je; j++){
      int s0=srcS[j];
      const float4 f0=*(const float4*)(lg+(size_t)4*j);
      const unsigned short* v0=v+(size_t)s0*256;
      float e00=__expf(f0.x), e01=__expf(f0.y), e02=__expf(f0.z), e03=__expf(f0.w);
      z0+=e00; z1+=e01; z2+=e02; z3+=e03;
      a0+=e00*bf2f(v0[lane]); a1+=e01*bf2f(v0[64+lane]);
      a2+=e02*bf2f(v0[128+lane]); a3+=e03*bf2f(v0[192+lane]);
    }
  }
  if(lane==0){ cz[w][0]=z0; cz[w][1]=z1; cz[w][2]=z2; cz[w][3]=z3; }
  ca[w][0][lane]=a0; ca[w][1][lane]=a1; ca[w][2][lane]=a2; ca[w][3][lane]=a3;
  __syncthreads();
  if(threadIdx.x<128){
    int ni=threadIdx.x>>6, l=threadIdx.x&63;
    int n2=blockIdx.x*2+ni;
    if(n2<NN){
      int w0=ni*2, w1=w0+1;
      float Z0=cz[w0][0]+cz[w1][0], Z1=cz[w0][1]+cz[w1][1];
      float Z2=cz[w0][2]+cz[w1][2], Z3=cz[w0][3]+cz[w1][3];
      float A0=ca[w0][0][l]+ca[w1][0][l], A1=ca[w0][1][l]+ca[w1][1][l];
      float A2=ca[w0][2][l]+ca[w1][2][l], A3=ca[w0][3][l]+ca[w1][3][l];
      float t=0.25f*(A0/(Z0+1e-16f)+A1/(Z1+1e-16f)+A2/(Z2+1e-16f)+A3/(Z3+1e-16f))+skip[(size_t)n2*64+l];
      x5b[(size_t)n2*64+l]=f2bf(fmaxf(t,0.f));
    }
  }
}

// EdgeConv v4: bf16 PQ gather -> LDS bf16 hidden -> MFMA GEMM2 -> LDS segmented max
// interior dst plain store, boundary atomicMax.
__global__ __launch_bounds__(256) void edgeconv3_kernel(
    const unsigned short* __restrict__ PQ,
    const int* __restrict__ srcS, const int* __restrict__ dstS,
    const unsigned short* __restrict__ W2t, const float* __restrict__ b2,
    unsigned* __restrict__ emax){
  __shared__ unsigned short Hs[64][72];  // hidden bf16 [edge][k], padded
  __shared__ float As[64][66];           // output f32 [edge][col], padded
  __shared__ int dstL[64];
  const int e0=blockIdx.x*64;            // EE multiple of 64
  const int tid=threadIdx.x;
  if(tid<64) dstL[tid]=dstS[e0+tid];
  #pragma unroll
  for(int it=0;it<4;it++){
    int linear=it*1024+tid*4;
    int m=linear>>6, k=linear&63;
    int e=e0+m;
    int dn=dstS[e], sn=srcS[e];
    ushort4 pu=*(const ushort4*)(PQ+(size_t)dn*128+k);
    ushort4 qu=*(const ushort4*)(PQ+(size_t)sn*128+64+k);
    ushort4 hh;
    hh.x=f2bf(fmaxf(bf2f(pu.x)+bf2f(qu.x),0.f));
    hh.y=f2bf(fmaxf(bf2f(pu.y)+bf2f(qu.y),0.f));
    hh.z=f2bf(fmaxf(bf2f(pu.z)+bf2f(qu.z),0.f));
    hh.w=f2bf(fmaxf(bf2f(pu.w)+bf2f(qu.w),0.f));
    *(ushort4*)&Hs[m][k]=hh;
  }
  __syncthreads();
  const int w=tid>>6, l=tid&63, lo=l&15, quad=l>>4;
  const int colg=w*16+lo;
  ffrag acc[4];
  #pragma unroll
  for(int t=0;t<4;t++) acc[t]=(ffrag){0.f,0.f,0.f,0.f};
  #pragma unroll
  for(int kc=0;kc<64;kc+=32){
    bfrag b=*(const bfrag*)(W2t+(size_t)colg*64+kc+quad*8);
    #pragma unroll
    for(int t=0;t<4;t++){
      bfrag a=*(const bfrag*)(&Hs[t*16+lo][kc+quad*8]);
      acc[t]=__builtin_amdgcn_mfma_f32_16x16x32_bf16(a,b,acc[t],0,0,0);
    }
  }
  float bv=b2[colg];
  #pragma unroll
  for(int t=0;t<4;t++)
    #pragma unroll
    for(int r=0;r<4;r++)
      As[t*16+quad*4+r][colg]=acc[t][r]+bv;
  __syncthreads();
  if(tid<64){
    const int c=tid;
    const int dFirst=dstL[0], dLast=dstL[63];
    int dprev=dFirst;
    float mx=As[0][c];
    #pragma unroll 8
    for(int m=1;m<64;m++){
      int dn=dstL[m];
      float v=As[m][c];
      if(dn!=dprev){
        unsigned* addr=&emax[(size_t)dprev*64+c];
        unsigned enc=fenc(mx);
        if(dprev!=dFirst && dprev!=dLast) *addr=enc;
        else atomicMax(addr,enc);
        dprev=dn; mx=v;
      }else mx=fmaxf(mx,v);
    }
    unsigned* addr=&emax[(size_t)dprev*64+c];
    unsigned enc=fenc(mx);
    if(dprev!=dFirst && dprev!=dLast) *addr=enc;
    else atomicMax(addr,enc);
  }
}

__global__ __launch_bounds__(256) void pool_kernel(const unsigned* __restrict__ emax, const int* __restrict__ batch,
                                                   float* __restrict__ pooled){
  const int NB=200;
  int base=blockIdx.x*NB;
  int lane=threadIdx.x&63;
  int wsub=threadIdx.x>>6;
  float acc=0.f; int curg=-1;
  for(int idx=wsub; idx<NB; idx+=4){
    int n=base+idx;
    if(n>=NN) break;
    int g=batch[n];
    if(g!=curg){
      if(curg>=0) atomicAdd(&pooled[curg*64+lane],acc);
      acc=0.f; curg=g;
    }
    unsigned u=emax[(size_t)n*64+lane];
    acc+=(u>=0x80000000u)? __uint_as_float(u&0x7fffffffu) : 0.f;
  }
  if(curg>=0) atomicAdd(&pooled[curg*64+lane],acc);
}

__global__ __launch_bounds__(256) void final_kernel(const float* __restrict__ pooled, const int* __restrict__ batch,
    const float* __restrict__ fc1W, const float* __restrict__ fc1b,
    const float* __restrict__ fc2W, const float* __restrict__ fc2b,
    float* __restrict__ out){
  __shared__ float gm[16][64];
  __shared__ float t1[16][64];
  __shared__ int cgs[17];
  int t=threadIdx.x;
  if(t<17){
    int lo=0, hi=NN;
    while(lo<hi){ int mid=(lo+hi)>>1; if(batch[mid]<t) lo=mid+1; else hi=mid; }
    cgs[t]=lo;
  }
  __syncthreads();
  for(int r=0;r<4;r++){
    int idx=r*256+t; int g=idx>>6, d=idx&63;
    float c=(float)(cgs[g+1]-cgs[g]);
    gm[g][d]=pooled[idx]/fmaxf(c,1.f);
  }
  __syncthreads();
  for(int r=0;r<4;r++){
    int idx=r*256+t; int g=idx>>6, d=idx&63;
    float a=fc1b[d];
    for(int k2=0;k2<64;k2++) a+=gm[g][k2]*fc1W[k2*64+d];
    t1[g][d]=fmaxf(a,0.f);
  }
  __syncthreads();
  for(int r=0;r<4;r++){
    int idx=r*256+t; int g=idx>>6, d=idx&63;
    float a=fc2b[d];
    for(int k2=0;k2<64;k2++) a+=t1[g][k2]*fc2W[k2*64+d];
    out[idx]=a;
  }
}

extern "C" void kernel_launch(void* const* d_in, const int* in_sizes, int n_in,
                              void* d_out, int out_size, void* d_ws, size_t ws_size,
                              hipStream_t stream){
  const float* x       =(const float*)d_in[0];
  const int*   ei      =(const int*)  d_in[1];
  const int*   src     =ei;
  const int*   dst     =ei+EE;
  const int*   batch   =(const int*)  d_in[2];
  const float* gat1_W  =(const float*)d_in[3];
  const float* gat1_as =(const float*)d_in[4];
  const float* gat1_ad =(const float*)d_in[5];
  const float* gat1_b  =(const float*)d_in[6];
  const float* gat2_W  =(const float*)d_in[7];
  const float* gat2_as =(const float*)d_in[8];
  const float* gat2_ad =(const float*)d_in[9];
  const float* gat2_b  =(const float*)d_in[10];
  const float* gin_W1  =(const float*)d_in[11];
  const float* gin_b1  =(const float*)d_in[12];
  const float* gin_W2  =(const float*)d_in[13];
  const float* gin_b2  =(const float*)d_in[14];
  const float* sage1_Wl=(const float*)d_in[15];
  const float* sage1_bl=(const float*)d_in[16];
  const float* sage1_Wr=(const float*)d_in[17];
  const float* sage2_Wl=(const float*)d_in[18];
  const float* sage2_bl=(const float*)d_in[19];
  const float* sage2_Wr=(const float*)d_in[20];
  const float* tr_Wq   =(const float*)d_in[21];
  const float* tr_bq   =(const float*)d_in[22];
  const float* tr_Wk   =(const float*)d_in[23];
  const float* tr_bk   =(const float*)d_in[24];
  const float* tr_Wv   =(const float*)d_in[25];
  const float* tr_bv   =(const float*)d_in[26];
  const float* tr_Ws   =(const float*)d_in[27];
  const float* tr_bs   =(const float*)d_in[28];
  const float* ec_W1   =(const float*)d_in[29];
  const float* ec_b1   =(const float*)d_in[30];
  const float* ec_W2   =(const float*)d_in[31];
  const float* ec_b2   =(const float*)d_in[32];
  const float* fc1_W   =(const float*)d_in[33];
  const float* fc1_b   =(const float*)d_in[34];
  const float* fc2_W   =(const float*)d_in[35];
  const float* fc2_b   =(const float*)d_in[36];

  // ---- workspace layout ----
  float* base=(float*)d_ws;
  size_t off=0;
  auto alloc=[&](size_t n){ float* p=base+off; off+=n; return p; };
  float* A_big =alloc((size_t)NN*256);
  float* nb0   =alloc(N64);
  float* nb1   =alloc(N64);
  float* nb2   =alloc(N64);
  float* nb3   =alloc(N64);
  float* nb4   =alloc(N64);
  float* nb5   =alloc(N64);                // emax
  float* logitE=alloc((size_t)EE*4);
  float* ls    =alloc(NN*4);
  float* ldb   =alloc(NN*4);
  float* invdeg=alloc(NN);
  float* pooled=alloc(GG*64);
  float* wbuf  =alloc(70000);              // Wt bf16 (139264 ushorts)
  float* bbuf  =alloc(640);
  int* ibase=(int*)(base+off);
  int* srcS  =ibase;
  int* dstS  =ibase+EE;
  int* cnt   =ibase+2*EE;
  int* fillp =ibase+2*EE+NN;
  int* rowptr=ibase+2*EE+2*NN;
  int* bsum  =ibase+2*EE+3*NN+8;
  int* boff  =bsum+64;

  const int BT=256;
  const int NSB=cdiv(NN,1024);
  // ---- zero init ----
  zero_kernel<<<cdiv(2*NN,BT),BT,0,stream>>>((unsigned*)cnt,2*NN);
  zero_kernel<<<cdiv(GG*64,BT),BT,0,stream>>>((unsigned*)pooled,GG*64);
  zero_kernel<<<cdiv(N64,BT),BT,0,stream>>>((unsigned*)nb5,N64);
  // ---- CSR ----
  hist_kernel<<<cdiv(EE,BT),BT,0,stream>>>(dst,cnt);
  scan1_kernel<<<NSB,1024,0,stream>>>(cnt,rowptr,bsum);
  scan2_kernel<<<1,64,0,stream>>>(bsum,boff,rowptr,NSB);
  scan3_kernel<<<cdiv(NN,BT),BT,0,stream>>>(rowptr,boff,cnt,invdeg);
  fill_kernel<<<cdiv(EE,BT),BT,0,stream>>>(src,dst,rowptr,fillp,srcS,dstS);

  const int GB=cdiv(NN,64);        // 782
  const int GW=cdiv(NN,4);         // 12500
  const int GW2=cdiv(NN,2);        // 25000 (2-wave-per-node kernels)

  unsigned short* wt =(unsigned short*)wbuf;
  float* bqk=bbuf;
  float* bPQ=bbuf+512;
  unsigned short* hbf  =(unsigned short*)A_big;                 // [N,256]
  unsigned short* xb   =(unsigned short*)A_big+(size_t)NN*256;  // [N,128]
  unsigned short* xcatb=(unsigned short*)A_big;                 // [N,128]
  unsigned short* qkb  =(unsigned short*)A_big;                 // [N,512]
  unsigned short* x1b  =(unsigned short*)nb0;
  unsigned short* x2b  =(unsigned short*)nb1;
  unsigned short* tb   =(unsigned short*)nb2;
  unsigned short* hb3  =(unsigned short*)nb3;
  unsigned short* x3b  =(unsigned short*)nb1;
  unsigned short* xsb  =(unsigned short*)nb2;
  unsigned short* x4b  =(unsigned short*)nb0;
  unsigned short* vb   =(unsigned short*)nb1;                   // [N,256] spans nb1+nb2
  unsigned short* x5b  =(unsigned short*)nb4;
  float* skipf=nb3;
  unsigned short* PQb  =(unsigned short*)nb1;                   // [N,128] bf16 fits nb1

  // ---- prep: weights->bf16 W^T, x->bf16 ----
  prep_kernel<<<cdiv(139904,BT),BT,0,stream>>>(gat1_W,gat2_W,gin_W1,gin_W2,
      sage1_Wl,sage1_Wr,sage2_Wl,sage2_Wr,tr_Wq,tr_Wk,tr_Wv,tr_Ws,ec_W1,ec_W2,
      tr_bq,tr_bk,ec_b1,wt,bqk,bPQ);
  cvtx_kernel<<<cdiv(NN*32,BT),BT,0,stream>>>(x,xb);

  // ---- GAT1 ----
  mgemm_kernel<128><<<dim3(GB,4),BT,0,stream>>>(xb,wt,nullptr,nullptr,hbf,256,0,
                                                gat1_as,gat1_ad,ls,ldb);
  gat1p_kernel<<<GW2,BT,0,stream>>>(hbf,rowptr,srcS,ls,ldb,gat1_b,x1b);
  // ---- GAT2 ----
  mgemm_kernel<64><<<dim3(GB,4),BT,0,stream>>>(x1b,wt+32768,nullptr,nullptr,hbf,256,0,
                                               gat2_as,gat2_ad,ls,ldb);
  gat1p_kernel<<<GW2,BT,0,stream>>>(hbf,rowptr,srcS,ls,ldb,gat2_b,x2b);
  // ---- GIN ----
  agg_kernel<<<GW,BT,0,stream>>>(x2b,rowptr,srcS,tb);
  mgemm_kernel<64><<<dim3(GB,1),BT,0,stream>>>(tb,wt+49152,gin_b1,nullptr,hb3,64,1,
                                               nullptr,nullptr,nullptr,nullptr);
  mgemm_kernel<64><<<dim3(GB,1),BT,0,stream>>>(hb3,wt+53248,gin_b2,nullptr,x3b,64,1,
                                               nullptr,nullptr,nullptr,nullptr);
  // ---- SAGE1 ----
  agg2_kernel<<<GW,BT,0,stream>>>(x3b,rowptr,srcS,invdeg,xcatb);
  mgemm_kernel<128><<<dim3(GB,1),BT,0,stream>>>(xcatb,wt+57344,sage1_bl,nullptr,xsb,64,1,
                                                nullptr,nullptr,nullptr,nullptr);
  // ---- SAGE2 ----
  agg2_kernel<<<GW,BT,0,stream>>>(xsb,rowptr,srcS,invdeg,xcatb);
  mgemm_kernel<128><<<dim3(GB,1),BT,0,stream>>>(xcatb,wt+65536,sage2_bl,nullptr,x4b,64,1,
                                                nullptr,nullptr,nullptr,nullptr);
  // ---- TransformerConv ----
  mgemm_kernel<64><<<dim3(GB,8),BT,0,stream>>>(x4b,wt+73728,bqk,nullptr,qkb,512,0,
                                               nullptr,nullptr,nullptr,nullptr);   // q|k
  tr_pass1_kernel<<<cdiv(EE,16),BT,0,stream>>>(srcS,dstS,qkb,logitE);
  mgemm_kernel<64><<<dim3(GB,4),BT,0,stream>>>(x4b,wt+106496,tr_bv,nullptr,vb,256,0,
                                               nullptr,nullptr,nullptr,nullptr);   // v
  mgemm_kernel<64><<<dim3(GB,1),BT,0,stream>>>(x4b,wt+122880,tr_bs,skipf,nullptr,64,0,
                                               nullptr,nullptr,nullptr,nullptr);   // skip f32
  tr_pass2_kernel<<<GW2,BT,0,stream>>>(rowptr,srcS,logitE,vb,skipf,x5b);
  // ---- EdgeConv: PQ (bf16) = x5 @ [Wd|W1b] + [b1|0]; then MFMA GEMM2 ----
  mgemm_kernel<64><<<dim3(GB,2),BT,0,stream>>>(x5b,wt+126976,bPQ,nullptr,PQb,128,0,
                                               nullptr,nullptr,nullptr,nullptr);
  edgeconv3_kernel<<<EE/64,BT,0,stream>>>(PQb,srcS,dstS,wt+135168,ec_b2,(unsigned*)nb5);
  // ---- pool + MLP ----
  pool_kernel<<<cdiv(NN,200),BT,0,stream>>>((unsigned*)nb5,batch,pooled);
  final_kernel<<<1,BT,0,stream>>>(pooled,batch,fc1_W,fc1_b,fc2_W,fc2_b,(float*)d_out);
}

// Round 11
// 856.350 us; speedup vs baseline: 2.7352x; 1.0101x over previous
//
#include <hip/hip_runtime.h>

#define NN 50000
#define EE 640000
#define GG 16
#define N64 (NN*64)

static inline int cdiv(int a,int b){return (a+b-1)/b;}

typedef __attribute__((ext_vector_type(8))) short bfrag;   // 8 bf16 (4 VGPR)
typedef __attribute__((ext_vector_type(4))) float ffrag;   // mfma accumulator

__device__ __forceinline__ float lrelu(float x){ return x>0.f? x : 0.2f*x; }
__device__ __forceinline__ unsigned fenc(float f){
  unsigned u=__float_as_uint(f);
  return (u&0x80000000u)? ~u : (u|0x80000000u);
}
__device__ __forceinline__ float bf2f(unsigned short u){ return __uint_as_float(((unsigned)u)<<16); }
__device__ __forceinline__ unsigned short f2bf(float f){
  unsigned u=__float_as_uint(f);
  u += 0x7FFFu + ((u>>16)&1u);
  return (unsigned short)(u>>16);
}

__global__ void zero_kernel(unsigned* p, int n){
  int i=blockIdx.x*blockDim.x+threadIdx.x;
  if(i<n) p[i]=0u;
}

__global__ void hist_kernel(const int* __restrict__ dst, int* __restrict__ cnt){
  int e=blockIdx.x*blockDim.x+threadIdx.x;
  if(e<EE) atomicAdd(&cnt[dst[e]],1);
}

__global__ __launch_bounds__(1024) void scan1_kernel(const int* __restrict__ cnt,
    int* __restrict__ rowptr, int* __restrict__ bsum){
  __shared__ int wsum[16];
  int t=threadIdx.x, b=blockIdx.x;
  int i=b*1024+t;
  int v=(i<NN)?cnt[i]:0;
  int lane=t&63, w=t>>6;
  int inc=v;
  #pragma unroll
  for(int o=1;o<64;o<<=1){ int u=__shfl_up(inc,o,64); if(lane>=o) inc+=u; }
  if(lane==63) wsum[w]=inc;
  __syncthreads();
  if(t<16){
    int s=wsum[t];
    #pragma unroll
    for(int o=1;o<16;o<<=1){ int u=__shfl_up(s,o,16); if(t>=o) s+=u; }
    wsum[t]=s;
  }
  __syncthreads();
  int woff=(w>0)?wsum[w-1]:0;
  if(i<NN) rowptr[i]=woff+inc-v;
  if(t==1023) bsum[b]=wsum[15];
}

__global__ void scan2_kernel(const int* __restrict__ bsum, int* __restrict__ boff, int* __restrict__ rowptr, int nb){
  int t=threadIdx.x;
  int v=(t<nb)?bsum[t]:0;
  int inc=v;
  #pragma unroll
  for(int o=1;o<64;o<<=1){ int u=__shfl_up(inc,o,64); if(t>=o) inc+=u; }
  if(t<nb) boff[t]=inc-v;
  if(t==63) rowptr[NN]=inc;
}

__global__ void scan3_kernel(int* __restrict__ rowptr, const int* __restrict__ boff,
                             const int* __restrict__ cnt, float* __restrict__ invdeg){
  int i=blockIdx.x*blockDim.x+threadIdx.x;
  if(i<NN){
    rowptr[i]+=boff[i>>10];
    invdeg[i]=1.f/fmaxf((float)cnt[i],1.f);
  }
}

__global__ void fill_kernel(const int* __restrict__ src, const int* __restrict__ dst,
                            const int* __restrict__ rowptr, int* __restrict__ fillp,
                            int* __restrict__ srcS, int* __restrict__ dstS){
  int e=blockIdx.x*blockDim.x+threadIdx.x;
  if(e>=EE) return;
  int d=dst[e];
  int p=rowptr[d]+atomicAdd(&fillp[d],1);
  srcS[p]=src[e]; dstS[p]=d;
}

__global__ void cvtx_kernel(const float* __restrict__ x, unsigned short* __restrict__ xb){
  int i=blockIdx.x*blockDim.x+threadIdx.x;
  if(i>=NN*32) return;
  float4 v=*(const float4*)(x+(size_t)i*4);
  ushort4 o; o.x=f2bf(v.x); o.y=f2bf(v.y); o.z=f2bf(v.z); o.w=f2bf(v.w);
  *(ushort4*)(xb+(size_t)i*4)=o;
}

// weight prep: Wt[n][k]=W[k][n] bf16, all segments + bias packs
__global__ void prep_kernel(
    const float* __restrict__ g1W, const float* __restrict__ g2W,
    const float* __restrict__ giW1, const float* __restrict__ giW2,
    const float* __restrict__ s1Wl, const float* __restrict__ s1Wr,
    const float* __restrict__ s2Wl, const float* __restrict__ s2Wr,
    const float* __restrict__ Wq, const float* __restrict__ Wk,
    const float* __restrict__ Wv, const float* __restrict__ Ws,
    const float* __restrict__ ecW1, const float* __restrict__ ecW2,
    const float* __restrict__ bq, const float* __restrict__ bk, const float* __restrict__ eb1,
    unsigned short* __restrict__ wt, float* __restrict__ bqk, float* __restrict__ bPQ){
  int i=blockIdx.x*blockDim.x+threadIdx.x;
  if(i<32768){ int n=i>>7,k=i&127; wt[i]=f2bf(g1W[k*256+n]); return; } i-=32768;
  if(i<16384){ int n=i>>6,k=i&63; wt[32768+i]=f2bf(g2W[k*256+n]); return; } i-=16384;
  if(i<4096){ int n=i>>6,k=i&63; wt[49152+i]=f2bf(giW1[k*64+n]); return; } i-=4096;
  if(i<4096){ int n=i>>6,k=i&63; wt[53248+i]=f2bf(giW2[k*64+n]); return; } i-=4096;
  if(i<8192){ int n=i>>7,k=i&127; float v=(k<64)?s1Wl[k*64+n]:s1Wr[(k-64)*64+n];
              wt[57344+i]=f2bf(v); return; } i-=8192;
  if(i<8192){ int n=i>>7,k=i&127; float v=(k<64)?s2Wl[k*64+n]:s2Wr[(k-64)*64+n];
              wt[65536+i]=f2bf(v); return; } i-=8192;
  if(i<32768){ int n=i>>6,k=i&63; float v=(n<256)?Wq[k*256+n]:Wk[k*256+(n-256)];
               wt[73728+i]=f2bf(v); return; } i-=32768;
  if(i<16384){ int n=i>>6,k=i&63; wt[106496+i]=f2bf(Wv[k*256+n]); return; } i-=16384;
  if(i<4096){ int n=i>>6,k=i&63; wt[122880+i]=f2bf(Ws[k*64+n]); return; } i-=4096;
  if(i<8192){ int n=i>>6,k=i&63;
              float v=(n<64)?(ecW1[k*64+n]-ecW1[(64+k)*64+n]):ecW1[(64+k)*64+(n-64)];
              wt[126976+i]=f2bf(v); return; } i-=8192;
  if(i<4096){ int n=i>>6,k=i&63; wt[135168+i]=f2bf(ecW2[k*64+n]); return; } i-=4096;
  if(i<640){
    if(i<256) bqk[i]=bq[i];
    else if(i<512) bqk[i]=bk[i-256];
    else { int j=i-512; bPQ[j]=(j<64)?eb1[j]:0.f; }
  }
}

// bf16 MFMA GEMM: C[64x64 tile] = A[M,K]bf16 @ Wt[N,K]bf16^T (+bias)(relu)
template<int K>
__global__ __launch_bounds__(256) void mgemm_kernel(
    const unsigned short* __restrict__ A, const unsigned short* __restrict__ Wt,
    const float* __restrict__ bias,
    float* __restrict__ Cf, unsigned short* __restrict__ Cb, int ldc, int relu_flag,
    const float* __restrict__ a_s, const float* __restrict__ a_d,
    float* __restrict__ lsO, float* __restrict__ ldO){
  __shared__ float lsP[2][4][64];
  const int m0=blockIdx.x*64;
  const int tid=threadIdx.x;
  const int w=tid>>6, l=tid&63, lo=l&15, quad=l>>4;
  const int colg=blockIdx.y*64 + w*16 + lo;
  const unsigned short* wrow=Wt+(size_t)colg*K+quad*8;
  ffrag acc[4];
  #pragma unroll
  for(int t=0;t<4;t++) acc[t]=(ffrag){0.f,0.f,0.f,0.f};
  int rows[4];
  #pragma unroll
  for(int t=0;t<4;t++){ int r=m0+t*16+lo; rows[t]=(r<NN)?r:(NN-1); }
  #pragma unroll
  for(int kc=0;kc<K;kc+=32){
    bfrag b=*(const bfrag*)(wrow+kc);
    #pragma unroll
    for(int t=0;t<4;t++){
      bfrag a=*(const bfrag*)(A+(size_t)rows[t]*K+kc+quad*8);
      acc[t]=__builtin_amdgcn_mfma_f32_16x16x32_bf16(a,b,acc[t],0,0,0);
    }
  }
  float bv=bias?bias[colg]:0.f;
  float asv=0.f,adv=0.f;
  if(lsO){ asv=a_s[colg]; adv=a_d[colg]; }
  #pragma unroll
  for(int t=0;t<4;t++){
    #pragma unroll
    for(int r=0;r<4;r++){
      float v=acc[t][r]+bv;
      if(relu_flag) v=fmaxf(v,0.f);
      int row=m0+t*16+quad*4+r;
      if(row<NN){
        if(Cb) Cb[(size_t)row*ldc+colg]=f2bf(v);
        else   Cf[(size_t)row*ldc+colg]=v;
      }
      if(lsO){
        float ps=v*asv, pd=v*adv;
        #pragma unroll
        for(int o=1;o<16;o<<=1){ ps+=__shfl_xor(ps,o,16); pd+=__shfl_xor(pd,o,16); }
        if(lo==0){ int lr=t*16+quad*4+r; lsP[0][w][lr]=ps; lsP[1][w][lr]=pd; }
      }
    }
  }
  if(lsO){
    __syncthreads();
    if(tid<64){
      int row=m0+tid;
      if(row<NN){
        lsO[(size_t)row*4+blockIdx.y]=lsP[0][0][tid]+lsP[0][1][tid]+lsP[0][2][tid]+lsP[0][3][tid];
        ldO[(size_t)row*4+blockIdx.y]=lsP[1][0][tid]+lsP[1][1][tid]+lsP[1][2][tid]+lsP[1][3][tid];
      }
    }
  }
}

// GAT edge exps: eE[j] = exp(lrelu(ls[src]+ld[dst])), one thread per edge.
__global__ void gat_exp_kernel(const int* __restrict__ srcS, const int* __restrict__ dstS,
    const float* __restrict__ ls4, const float* __restrict__ ld4, float* __restrict__ eE){
  int j=blockIdx.x*blockDim.x+threadIdx.x;
  if(j>=EE) return;
  int s=srcS[j], d=dstS[j];
  const float4 a=*(const float4*)(ls4+(size_t)4*s);
  const float4 b=*(const float4*)(ld4+(size_t)4*d);
  *(float4*)(eE+(size_t)4*j)=make_float4(
    __expf(lrelu(a.x+b.x)),__expf(lrelu(a.y+b.y)),
    __expf(lrelu(a.z+b.z)),__expf(lrelu(a.w+b.w)));
}

// single-pass GAT, 2 waves/node edge-split, precomputed edge exps, bf16 h gather.
__global__ __launch_bounds__(256) void gat1p_kernel(const unsigned short* __restrict__ h,
    const int* __restrict__ rowptr, const int* __restrict__ srcS,
    const float* __restrict__ eE,
    const float* __restrict__ ls4, const float* __restrict__ ld4,
    const float* __restrict__ bias, unsigned short* __restrict__ outb){
  __shared__ float cz[4][4];
  __shared__ float ca[4][4][64];
  int w=threadIdx.x>>6, lane=threadIdx.x&63;
  int n=blockIdx.x*2+(w>>1);
  int half=w&1;
  float z0=0.f,z1=0.f,z2=0.f,z3=0.f;
  float a0=0.f,a1=0.f,a2=0.f,a3=0.f;
  if(n<NN){
    int r0=rowptr[n], r1=rowptr[n+1];
    int mid=(r0+r1)>>1;
    if(half==0){
      const float4 ldv=*(const float4*)(ld4+(size_t)4*n);
      const float4 lsv=*(const float4*)(ls4+(size_t)4*n);
      z0=__expf(lrelu(lsv.x+ldv.x)); z1=__expf(lrelu(lsv.y+ldv.y));
      z2=__expf(lrelu(lsv.z+ldv.z)); z3=__expf(lrelu(lsv.w+ldv.w));
      const unsigned short* hn=h+(size_t)n*256;
      a0=z0*bf2f(hn[lane]); a1=z1*bf2f(hn[64+lane]);
      a2=z2*bf2f(hn[128+lane]); a3=z3*bf2f(hn[192+lane]);
    }
    int j = half? mid : r0;
    int je= half? r1  : mid;
    for(; j+3<je; j+=4){
      int s0=srcS[j], s1=srcS[j+1], s2=srcS[j+2], s3=srcS[j+3];
      const float4 E0=*(const float4*)(eE+(size_t)4*j);
      const float4 E1=*(const float4*)(eE+(size_t)4*(j+1));
      const float4 E2=*(const float4*)(eE+(size_t)4*(j+2));
      const float4 E3=*(const float4*)(eE+(size_t)4*(j+3));
      const unsigned short* h0=h+(size_t)s0*256;
      const unsigned short* h1=h+(size_t)s1*256;
      const unsigned short* h2=h+(size_t)s2*256;
      const unsigned short* h3=h+(size_t)s3*256;
      z0+=(E0.x+E1.x)+(E2.x+E3.x); z1+=(E0.y+E1.y)+(E2.y+E3.y);
      z2+=(E0.z+E1.z)+(E2.z+E3.z); z3+=(E0.w+E1.w)+(E2.w+E3.w);
      a0+=(E0.x*bf2f(h0[lane])+E1.x*bf2f(h1[lane]))+(E2.x*bf2f(h2[lane])+E3.x*bf2f(h3[lane]));
      a1+=(E0.y*bf2f(h0[64+lane])+E1.y*bf2f(h1[64+lane]))+(E2.y*bf2f(h2[64+lane])+E3.y*bf2f(h3[64+lane]));
      a2+=(E0.z*bf2f(h0[128+lane])+E1.z*bf2f(h1[128+lane]))+(E2.z*bf2f(h2[128+lane])+E3.z*bf2f(h3[128+lane]));
      a3+=(E0.w*bf2f(h0[192+lane])+E1.w*bf2f(h1[192+lane]))+(E2.w*bf2f(h2[192+lane])+E3.w*bf2f(h3[192+lane]));
    }
    for(; j<je; j++){
      int s0=srcS[j];
      const float4 E0=*(const float4*)(eE+(size_t)4*j);
      const unsigned short* h0=h+(size_t)s0*256;
      z0+=E0.x; z1+=E0.y; z2+=E0.z; z3+=E0.w;
      a0+=E0.x*bf2f(h0[lane]); a1+=E0.y*bf2f(h0[64+lane]);
      a2+=E0.z*bf2f(h0[128+lane]); a3+=E0.w*bf2f(h0[192+lane]);
    }
  }
  if(lane==0){ cz[w][0]=z0; cz[w][1]=z1; cz[w][2]=z2; cz[w][3]=z3; }
  ca[w][0][lane]=a0; ca[w][1][lane]=a1; ca[w][2][lane]=a2; ca[w][3][lane]=a3;
  __syncthreads();
  if(threadIdx.x<128){
    int ni=threadIdx.x>>6, l=threadIdx.x&63;
    int n2=blockIdx.x*2+ni;
    if(n2<NN){
      int w0=ni*2, w1=w0+1;
      float Z0=cz[w0][0]+cz[w1][0], Z1=cz[w0][1]+cz[w1][1];
      float Z2=cz[w0][2]+cz[w1][2], Z3=cz[w0][3]+cz[w1][3];
      float A0=ca[w0][0][l]+ca[w1][0][l], A1=ca[w0][1][l]+ca[w1][1][l];
      float A2=ca[w0][2][l]+ca[w1][2][l], A3=ca[w0][3][l]+ca[w1][3][l];
      float r=0.25f*(A0/(Z0+1e-16f)+A1/(Z1+1e-16f)+A2/(Z2+1e-16f)+A3/(Z3+1e-16f))+bias[l];
      outb[(size_t)n2*64+l]=f2bf(fmaxf(r,0.f));
    }
  }
}

// GIN: self + sum (bf16 in/out), unroll 4
__global__ __launch_bounds__(256) void agg_kernel(const unsigned short* __restrict__ xin,
    const int* __restrict__ rowptr, const int* __restrict__ srcS,
    unsigned short* __restrict__ out){
  int n=blockIdx.x*4+(threadIdx.x>>6);
  int lane=threadIdx.x&63;
  if(n>=NN) return;
  int r0=rowptr[n], r1=rowptr[n+1];
  float acc=bf2f(xin[(size_t)n*64+lane]);
  int j=r0;
  for(; j+3<r1; j+=4){
    int s0=srcS[j], s1=srcS[j+1], s2=srcS[j+2], s3=srcS[j+3];
    acc+=(bf2f(xin[(size_t)s0*64+lane])+bf2f(xin[(size_t)s1*64+lane]))
        +(bf2f(xin[(size_t)s2*64+lane])+bf2f(xin[(size_t)s3*64+lane]));
  }
  for(; j<r1; j++) acc+=bf2f(xin[(size_t)srcS[j]*64+lane]);
  out[(size_t)n*64+lane]=f2bf(acc);
}

// SAGE staging: out128b[n]=[mean_neigh, self] bf16, unroll 4
__global__ __launch_bounds__(256) void agg2_kernel(const unsigned short* __restrict__ xin,
    const int* __restrict__ rowptr, const int* __restrict__ srcS,
    const float* __restrict__ invdeg, unsigned short* __restrict__ out128b){
  int n=blockIdx.x*4+(threadIdx.x>>6);
  int lane=threadIdx.x&63;
  if(n>=NN) return;
  int r0=rowptr[n], r1=rowptr[n+1];
  float acc=0.f;
  int j=r0;
  for(; j+3<r1; j+=4){
    int s0=srcS[j], s1=srcS[j+1], s2=srcS[j+2], s3=srcS[j+3];
    acc+=(bf2f(xin[(size_t)s0*64+lane])+bf2f(xin[(size_t)s1*64+lane]))
        +(bf2f(xin[(size_t)s2*64+lane])+bf2f(xin[(size_t)s3*64+lane]));
  }
  for(; j<r1; j++) acc+=bf2f(xin[(size_t)srcS[j]*64+lane]);
  out128b[(size_t)n*128+lane]=f2bf(acc*invdeg[n]);
  out128b[(size_t)n*128+64+lane]=xin[(size_t)n*64+lane];
}

// TR pass1 (edge-parallel SDDMM): qk [N,512] bf16; stores EXP of logits.
__global__ __launch_bounds__(256) void tr_pass1_kernel(const int* __restrict__ srcS, const int* __restrict__ dstS,
    const unsigned short* __restrict__ qk, float* __restrict__ lg){
  int e=blockIdx.x*16+(threadIdx.x>>4);
  int t=threadIdx.x&15;
  if(e>=EE) return;
  int s=srcS[e], d=dstS[e];
  const unsigned short* qd=qk+(size_t)d*512+t*4;
  const unsigned short* ks=qk+(size_t)s*512+256+t*4;
  ushort4 ku0=*(const ushort4*)(ks);
  ushort4 ku1=*(const ushort4*)(ks+64);
  ushort4 ku2=*(const ushort4*)(ks+128);
  ushort4 ku3=*(const ushort4*)(ks+192);
  ushort4 qu0=*(const ushort4*)(qd);
  ushort4 qu1=*(const ushort4*)(qd+64);
  ushort4 qu2=*(const ushort4*)(qd+128);
  ushort4 qu3=*(const ushort4*)(qd+192);
  float v0=bf2f(ku0.x)*bf2f(qu0.x)+bf2f(ku0.y)*bf2f(qu0.y)+bf2f(ku0.z)*bf2f(qu0.z)+bf2f(ku0.w)*bf2f(qu0.w);
  float v1=bf2f(ku1.x)*bf2f(qu1.x)+bf2f(ku1.y)*bf2f(qu1.y)+bf2f(ku1.z)*bf2f(qu1.z)+bf2f(ku1.w)*bf2f(qu1.w);
  float v2=bf2f(ku2.x)*bf2f(qu2.x)+bf2f(ku2.y)*bf2f(qu2.y)+bf2f(ku2.z)*bf2f(qu2.z)+bf2f(ku2.w)*bf2f(qu2.w);
  float v3=bf2f(ku3.x)*bf2f(qu3.x)+bf2f(ku3.y)*bf2f(qu3.y)+bf2f(ku3.z)*bf2f(qu3.z)+bf2f(ku3.w)*bf2f(qu3.w);
  #pragma unroll
  for(int o=1;o<16;o<<=1){
    v0+=__shfl_xor(v0,o,16); v1+=__shfl_xor(v1,o,16);
    v2+=__shfl_xor(v2,o,16); v3+=__shfl_xor(v3,o,16);
  }
  if(t==0)
    *(float4*)(lg+(size_t)4*e)=make_float4(__expf(v0*0.125f),__expf(v1*0.125f),
                                           __expf(v2*0.125f),__expf(v3*0.125f));
}

// TR pass2: 2 waves/node edge-split, precomputed exps + bf16 v-gather + skip + relu
__global__ __launch_bounds__(256) void tr_pass2_kernel(const int* __restrict__ rowptr, const int* __restrict__ srcS,
    const float* __restrict__ lg,
    const unsigned short* __restrict__ v, const float* __restrict__ skip, unsigned short* __restrict__ x5b){
  __shared__ float cz[4][4];
  __shared__ float ca[4][4][64];
  int w=threadIdx.x>>6, lane=threadIdx.x&63;
  int n=blockIdx.x*2+(w>>1);
  int half=w&1;
  float z0=0.f,z1=0.f,z2=0.f,z3=0.f;
  float a0=0.f,a1=0.f,a2=0.f,a3=0.f;
  if(n<NN){
    int r0=rowptr[n], r1=rowptr[n+1];
    int mid=(r0+r1)>>1;
    int j = half? mid : r0;
    int je= half? r1  : mid;
    for(; j+3<je; j+=4){
      int s0=srcS[j], s1=srcS[j+1], s2=srcS[j+2], s3=srcS[j+3];
      const float4 E0=*(const float4*)(lg+(size_t)4*j);
      const float4 E1=*(const float4*)(lg+(size_t)4*(j+1));
      const float4 E2=*(const float4*)(lg+(size_t)4*(j+2));
      const float4 E3=*(const float4*)(lg+(size_t)4*(j+3));
      const unsigned short* v0=v+(size_t)s0*256;
      const unsigned short* v1=v+(size_t)s1*256;
      const unsigned short* v2=v+(size_t)s2*256;
      const unsigned short* v3=v+(size_t)s3*256;
      z0+=(E0.x+E1.x)+(E2.x+E3.x); z1+=(E0.y+E1.y)+(E2.y+E3.y);
      z2+=(E0.z+E1.z)+(E2.z+E3.z); z3+=(E0.w+E1.w)+(E2.w+E3.w);
      a0+=(E0.x*bf2f(v0[lane])+E1.x*bf2f(v1[lane]))+(E2.x*bf2f(v2[lane])+E3.x*bf2f(v3[lane]));
      a1+=(E0.y*bf2f(v0[64+lane])+E1.y*bf2f(v1[64+lane]))+(E2.y*bf2f(v2[64+lane])+E3.y*bf2f(v3[64+lane]));
      a2+=(E0.z*bf2f(v0[128+lane])+E1.z*bf2f(v1[128+lane]))+(E2.z*bf2f(v2[128+lane])+E3.z*bf2f(v3[128+lane]));
      a3+=(E0.w*bf2f(v0[192+lane])+E1.w*bf2f(v1[192+lane]))+(E2.w*bf2f(v2[192+lane])+E3.w*bf2f(v3[192+lane]));
    }
    for(; j<je; j++){
      int s0=srcS[j];
      const float4 E0=*(const float4*)(lg+(size_t)4*j);
      const unsigned short* v0=v+(size_t)s0*256;
      z0+=E0.x; z1+=E0.y; z2+=E0.z; z3+=E0.w;
      a0+=E0.x*bf2f(v0[lane]); a1+=E0.y*bf2f(v0[64+lane]);
      a2+=E0.z*bf2f(v0[128+lane]); a3+=E0.w*bf2f(v0[192+lane]);
    }
  }
  if(lane==0){ cz[w][0]=z0; cz[w][1]=z1; cz[w][2]=z2; cz[w][3]=z3; }
  ca[w][0][lane]=a0; ca[w][1][lane]=a1; ca[w][2][lane]=a2; ca[w][3][lane]=a3;
  __syncthreads();
  if(threadIdx.x<128){
    int ni=threadIdx.x>>6, l=threadIdx.x&63;
    int n2=blockIdx.x*2+ni;
    if(n2<NN){
      int w0=ni*2, w1=w0+1;
      float Z0=cz[w0][0]+cz[w1][0], Z1=cz[w0][1]+cz[w1][1];
      float Z2=cz[w0][2]+cz[w1][2], Z3=cz[w0][3]+cz[w1][3];
      float A0=ca[w0][0][l]+ca[w1][0][l], A1=ca[w0][1][l]+ca[w1][1][l];
      float A2=ca[w0][2][l]+ca[w1][2][l], A3=ca[w0][3][l]+ca[w1][3][l];
      float t=0.25f*(A0/(Z0+1e-16f)+A1/(Z1+1e-16f)+A2/(Z2+1e-16f)+A3/(Z3+1e-16f))+skip[(size_t)n2*64+l];
      x5b[(size_t)n2*64+l]=f2bf(fmaxf(t,0.f));
    }
  }
}

// EdgeConv: bf16 PQ gather -> LDS bf16 hidden -> MFMA GEMM2 -> LDS segmented max
__global__ __launch_bounds__(256) void edgeconv3_kernel(
    const unsigned short* __restrict__ PQ,
    const int* __restrict__ srcS, const int* __restrict__ dstS,
    const unsigned short* __restrict__ W2t, const float* __restrict__ b2,
    unsigned* __restrict__ emax){
  __shared__ unsigned short Hs[64][72];
  __shared__ float As[64][66];
  __shared__ int dstL[64];
  const int e0=blockIdx.x*64;
  const int tid=threadIdx.x;
  if(tid<64) dstL[tid]=dstS[e0+tid];
  #pragma unroll
  for(int it=0;it<4;it++){
    int linear=it*1024+tid*4;
    int m=linear>>6, k=linear&63;
    int e=e0+m;
    int dn=dstS[e], sn=srcS[e];
    ushort4 pu=*(const ushort4*)(PQ+(size_t)dn*128+k);
    ushort4 qu=*(const ushort4*)(PQ+(size_t)sn*128+64+k);
    ushort4 hh;
    hh.x=f2bf(fmaxf(bf2f(pu.x)+bf2f(qu.x),0.f));
    hh.y=f2bf(fmaxf(bf2f(pu.y)+bf2f(qu.y),0.f));
    hh.z=f2bf(fmaxf(bf2f(pu.z)+bf2f(qu.z),0.f));
    hh.w=f2bf(fmaxf(bf2f(pu.w)+bf2f(qu.w),0.f));
    *(ushort4*)&Hs[m][k]=hh;
  }
  __syncthreads();
  const int w=tid>>6, l=tid&63, lo=l&15, quad=l>>4;
  const int colg=w*16+lo;
  ffrag acc[4];
  #pragma unroll
  for(int t=0;t<4;t++) acc[t]=(ffrag){0.f,0.f,0.f,0.f};
  #pragma unroll
  for(int kc=0;kc<64;kc+=32){
    bfrag b=*(const bfrag*)(W2t+(size_t)colg*64+kc+quad*8);
    #pragma unroll
    for(int t=0;t<4;t++){
      bfrag a=*(const bfrag*)(&Hs[t*16+lo][kc+quad*8]);
      acc[t]=__builtin_amdgcn_mfma_f32_16x16x32_bf16(a,b,acc[t],0,0,0);
    }
  }
  float bv=b2[colg];
  #pragma unroll
  for(int t=0;t<4;t++)
    #pragma unroll
    for(int r=0;r<4;r++)
      As[t*16+quad*4+r][colg]=acc[t][r]+bv;
  __syncthreads();
  if(tid<64){
    const int c=tid;
    const int dFirst=dstL[0], dLast=dstL[63];
    int dprev=dFirst;
    float mx=As[0][c];
    #pragma unroll 8
    for(int m=1;m<64;m++){
      int dn=dstL[m];
      float v=As[m][c];
      if(dn!=dprev){
        unsigned* addr=&emax[(size_t)dprev*64+c];
        unsigned enc=fenc(mx);
        if(dprev!=dFirst && dprev!=dLast) *addr=enc;
        else atomicMax(addr,enc);
        dprev=dn; mx=v;
      }else mx=fmaxf(mx,v);
    }
    unsigned* addr=&emax[(size_t)dprev*64+c];
    unsigned enc=fenc(mx);
    if(dprev!=dFirst && dprev!=dLast) *addr=enc;
    else atomicMax(addr,enc);
  }
}

__global__ __launch_bounds__(256) void pool_kernel(const unsigned* __restrict__ emax, const int* __restrict__ batch,
                                                   float* __restrict__ pooled){
  const int NB=200;
  int base=blockIdx.x*NB;
  int lane=threadIdx.x&63;
  int wsub=threadIdx.x>>6;
  float acc=0.f; int curg=-1;
  for(int idx=wsub; idx<NB; idx+=4){
    int n=base+idx;
    if(n>=NN) break;
    int g=batch[n];
    if(g!=curg){
      if(curg>=0) atomicAdd(&pooled[curg*64+lane],acc);
      acc=0.f; curg=g;
    }
    unsigned u=emax[(size_t)n*64+lane];
    acc+=(u>=0x80000000u)? __uint_as_float(u&0x7fffffffu) : 0.f;
  }
  if(curg>=0) atomicAdd(&pooled[curg*64+lane],acc);
}

__global__ __launch_bounds__(256) void final_kernel(const float* __restrict__ pooled, const int* __restrict__ batch,
    const float* __restrict__ fc1W, const float* __restrict__ fc1b,
    const float* __restrict__ fc2W, const float* __restrict__ fc2b,
    float* __restrict__ out){
  __shared__ float gm[16][64];
  __shared__ float t1[16][64];
  __shared__ int cgs[17];
  int t=threadIdx.x;
  if(t<17){
    int lo=0, hi=NN;
    while(lo<hi){ int mid=(lo+hi)>>1; if(batch[mid]<t) lo=mid+1; else hi=mid; }
    cgs[t]=lo;
  }
  __syncthreads();
  for(int r=0;r<4;r++){
    int idx=r*256+t; int g=idx>>6, d=idx&63;
    float c=(float)(cgs[g+1]-cgs[g]);
    gm[g][d]=pooled[idx]/fmaxf(c,1.f);
  }
  __syncthreads();
  for(int r=0;r<4;r++){
    int idx=r*256+t; int g=idx>>6, d=idx&63;
    float a=fc1b[d];
    for(int k2=0;k2<64;k2++) a+=gm[g][k2]*fc1W[k2*64+d];
    t1[g][d]=fmaxf(a,0.f);
  }
  __syncthreads();
  for(int r=0;r<4;r++){
    int idx=r*256+t; int g=idx>>6, d=idx&63;
    float a=fc2b[d];
    for(int k2=0;k2<64;k2++) a+=t1[g][k2]*fc2W[k2*64+d];
    out[idx]=a;
  }
}

extern "C" void kernel_launch(void* const* d_in, const int* in_sizes, int n_in,
                              void* d_out, int out_size, void* d_ws, size_t ws_size,
                              hipStream_t stream){
  const float* x       =(const float*)d_in[0];
  const int*   ei      =(const int*)  d_in[1];
  const int*   src     =ei;
  const int*   dst     =ei+EE;
  const int*   batch   =(const int*)  d_in[2];
  const float* gat1_W  =(const float*)d_in[3];
  const float* gat1_as =(const float*)d_in[4];
  const float* gat1_ad =(const float*)d_in[5];
  const float* gat1_b  =(const float*)d_in[6];
  const float* gat2_W  =(const float*)d_in[7];
  const float* gat2_as =(const float*)d_in[8];
  const float* gat2_ad =(const float*)d_in[9];
  const float* gat2_b  =(const float*)d_in[10];
  const float* gin_W1  =(const float*)d_in[11];
  const float* gin_b1  =(const float*)d_in[12];
  const float* gin_W2  =(const float*)d_in[13];
  const float* gin_b2  =(const float*)d_in[14];
  const float* sage1_Wl=(const float*)d_in[15];
  const float* sage1_bl=(const float*)d_in[16];
  const float* sage1_Wr=(const float*)d_in[17];
  const float* sage2_Wl=(const float*)d_in[18];
  const float* sage2_bl=(const float*)d_in[19];
  const float* sage2_Wr=(const float*)d_in[20];
  const float* tr_Wq   =(const float*)d_in[21];
  const float* tr_bq   =(const float*)d_in[22];
  const float* tr_Wk   =(const float*)d_in[23];
  const float* tr_bk   =(const float*)d_in[24];
  const float* tr_Wv   =(const float*)d_in[25];
  const float* tr_bv   =(const float*)d_in[26];
  const float* tr_Ws   =(const float*)d_in[27];
  const float* tr_bs   =(const float*)d_in[28];
  const float* ec_W1   =(const float*)d_in[29];
  const float* ec_b1   =(const float*)d_in[30];
  const float* ec_W2   =(const float*)d_in[31];
  const float* ec_b2   =(const float*)d_in[32];
  const float* fc1_W   =(const float*)d_in[33];
  const float* fc1_b   =(const float*)d_in[34];
  const float* fc2_W   =(const float*)d_in[35];
  const float* fc2_b   =(const float*)d_in[36];

  // ---- workspace layout ----
  float* base=(float*)d_ws;
  size_t off=0;
  auto alloc=[&](size_t n){ float* p=base+off; off+=n; return p; };
  float* A_big =alloc((size_t)NN*256);
  float* nb0   =alloc(N64);
  float* nb1   =alloc(N64);
  float* nb2   =alloc(N64);
  float* nb3   =alloc(N64);
  float* nb4   =alloc(N64);
  float* nb5   =alloc(N64);                // emax
  float* logitE=alloc((size_t)EE*4);
  float* ls    =alloc(NN*4);
  float* ldb   =alloc(NN*4);
  float* invdeg=alloc(NN);
  float* pooled=alloc(GG*64);
  float* wbuf  =alloc(70000);
  float* bbuf  =alloc(640);
  int* ibase=(int*)(base+off);
  int* srcS  =ibase;
  int* dstS  =ibase+EE;
  int* cnt   =ibase+2*EE;
  int* fillp =ibase+2*EE+NN;
  int* rowptr=ibase+2*EE+2*NN;
  int* bsum  =ibase+2*EE+3*NN+8;
  int* boff  =bsum+64;

  const int BT=256;
  const int NSB=cdiv(NN,1024);
  // ---- zero init ----
  zero_kernel<<<cdiv(2*NN,BT),BT,0,stream>>>((unsigned*)cnt,2*NN);
  zero_kernel<<<cdiv(GG*64,BT),BT,0,stream>>>((unsigned*)pooled,GG*64);
  zero_kernel<<<cdiv(N64,BT),BT,0,stream>>>((unsigned*)nb5,N64);
  // ---- CSR ----
  hist_kernel<<<cdiv(EE,BT),BT,0,stream>>>(dst,cnt);
  scan1_kernel<<<NSB,1024,0,stream>>>(cnt,rowptr,bsum);
  scan2_kernel<<<1,64,0,stream>>>(bsum,boff,rowptr,NSB);
  scan3_kernel<<<cdiv(NN,BT),BT,0,stream>>>(rowptr,boff,cnt,invdeg);
  fill_kernel<<<cdiv(EE,BT),BT,0,stream>>>(src,dst,rowptr,fillp,srcS,dstS);

  const int GB=cdiv(NN,64);        // 782
  const int GW=cdiv(NN,4);         // 12500
  const int GW2=cdiv(NN,2);        // 25000

  unsigned short* wt =(unsigned short*)wbuf;
  float* bqk=bbuf;
  float* bPQ=bbuf+512;
  unsigned short* hbf  =(unsigned short*)A_big;
  unsigned short* xb   =(unsigned short*)A_big+(size_t)NN*256;
  unsigned short* xcatb=(unsigned short*)A_big;
  unsigned short* qkb  =(unsigned short*)A_big;
  unsigned short* x1b  =(unsigned short*)nb0;
  unsigned short* x2b  =(unsigned short*)nb1;
  unsigned short* tb   =(unsigned short*)nb2;
  unsigned short* hb3  =(unsigned short*)nb3;
  unsigned short* x3b  =(unsigned short*)nb1;
  unsigned short* xsb  =(unsigned short*)nb2;
  unsigned short* x4b  =(unsigned short*)nb0;
  unsigned short* vb   =(unsigned short*)nb1;
  unsigned short* x5b  =(unsigned short*)nb4;
  float* skipf=nb3;
  unsigned short* PQb  =(unsigned short*)nb1;

  // ---- prep ----
  prep_kernel<<<cdiv(139904,BT),BT,0,stream>>>(gat1_W,gat2_W,gin_W1,gin_W2,
      sage1_Wl,sage1_Wr,sage2_Wl,sage2_Wr,tr_Wq,tr_Wk,tr_Wv,tr_Ws,ec_W1,ec_W2,
      tr_bq,tr_bk,ec_b1,wt,bqk,bPQ);
  cvtx_kernel<<<cdiv(NN*32,BT),BT,0,stream>>>(x,xb);

  // ---- GAT1 ----
  mgemm_kernel<128><<<dim3(GB,4),BT,0,stream>>>(xb,wt,nullptr,nullptr,hbf,256,0,
                                                gat1_as,gat1_ad,ls,ldb);
  gat_exp_kernel<<<cdiv(EE,BT),BT,0,stream>>>(srcS,dstS,ls,ldb,logitE);
  gat1p_kernel<<<GW2,BT,0,stream>>>(hbf,rowptr,srcS,logitE,ls,ldb,gat1_b,x1b);
  // ---- GAT2 ----
  mgemm_kernel<64><<<dim3(GB,4),BT,0,stream>>>(x1b,wt+32768,nullptr,nullptr,hbf,256,0,
                                               gat2_as,gat2_ad,ls,ldb);
  gat_exp_kernel<<<cdiv(EE,BT),BT,0,stream>>>(srcS,dstS,ls,ldb,logitE);
  gat1p_kernel<<<GW2,BT,0,stream>>>(hbf,rowptr,srcS,logitE,ls,ldb,gat2_b,x2b);
  // ---- GIN ----
  agg_kernel<<<GW,BT,0,stream>>>(x2b,rowptr,srcS,tb);
  mgemm_kernel<64><<<dim3(GB,1),BT,0,stream>>>(tb,wt+49152,gin_b1,nullptr,hb3,64,1,
                                               nullptr,nullptr,nullptr,nullptr);
  mgemm_kernel<64><<<dim3(GB,1),BT,0,stream>>>(hb3,wt+53248,gin_b2,nullptr,x3b,64,1,
                                               nullptr,nullptr,nullptr,nullptr);
  // ---- SAGE1 ----
  agg2_kernel<<<GW,BT,0,stream>>>(x3b,rowptr,srcS,invdeg,xcatb);
  mgemm_kernel<128><<<dim3(GB,1),BT,0,stream>>>(xcatb,wt+57344,sage1_bl,nullptr,xsb,64,1,
                                                nullptr,nullptr,nullptr,nullptr);
  // ---- SAGE2 ----
  agg2_kernel<<<GW,BT,0,stream>>>(xsb,rowptr,srcS,invdeg,xcatb);
  mgemm_kernel<128><<<dim3(GB,1),BT,0,stream>>>(xcatb,wt+65536,sage2_bl,nullptr,x4b,64,1,
                                                nullptr,nullptr,nullptr,nullptr);
  // ---- TransformerConv ----
  mgemm_kernel<64><<<dim3(GB,8),BT,0,stream>>>(x4b,wt+73728,bqk,nullptr,qkb,512,0,
                                               nullptr,nullptr,nullptr,nullptr);   // q|k
  tr_pass1_kernel<<<cdiv(EE,16),BT,0,stream>>>(srcS,dstS,qkb,logitE);              // exp(logits)
  mgemm_kernel<64><<<dim3(GB,4),BT,0,stream>>>(x4b,wt+106496,tr_bv,nullptr,vb,256,0,
                                               nullptr,nullptr,nullptr,nullptr);   // v
  mgemm_kernel<64><<<dim3(GB,1),BT,0,stream>>>(x4b,wt+122880,tr_bs,skipf,nullptr,64,0,
                                               nullptr,nullptr,nullptr,nullptr);   // skip f32
  tr_pass2_kernel<<<GW2,BT,0,stream>>>(rowptr,srcS,logitE,vb,skipf,x5b);
  // ---- EdgeConv ----
  mgemm_kernel<64><<<dim3(GB,2),BT,0,stream>>>(x5b,wt+126976,bPQ,nullptr,PQb,128,0,
                                               nullptr,nullptr,nullptr,nullptr);
  edgeconv3_kernel<<<EE/64,BT,0,stream>>>(PQb,srcS,dstS,wt+135168,ec_b2,(unsigned*)nb5);
  // ---- pool + MLP ----
  pool_kernel<<<cdiv(NN,200),BT,0,stream>>>((unsigned*)nb5,batch,pooled);
  final_kernel<<<1,BT,0,stream>>>(pooled,batch,fc1_W,fc1_b,fc2_W,fc2_b,(float*)d_out);
}